// Round 5
// baseline (3816.882 us; speedup 1.0000x reference)
//
#include <hip/hip_runtime.h>
#include <cfloat>

// ---------------------------------------------------------------------------
// GCN3D forward. Split-plane bf16 MFMA GEMMs: every f32 GEMM operand is split
// ONCE into (hi,lo) bf16 planes (Dekker); GEMMs stream planes with pure
// vector-load staging, 128x128 tiles, 3 MFMAs per fragment pair.
// B=8, N=2048->512->128, K_NB=50. Workspace 93,814,784 B.
// ---------------------------------------------------------------------------

#define BB   8
#define NP0  2048
#define NP1  512
#define NP2  128
#define KNB_ 50
#define VS0  (NP0 * 3)

typedef __attribute__((ext_vector_type(8))) short short8_t;
typedef __attribute__((ext_vector_type(4))) short short4_t;
typedef __attribute__((ext_vector_type(4))) float f32x4_t;
typedef unsigned short u16;

// ---------------- workspace layout (byte offsets) ----------------
static constexpr size_t O_V0    = 0;
static constexpr size_t O_IDX0  = 196608;
static constexpr size_t O_IDXP0 = 3473408;
static constexpr size_t O_IDX1  = 3538944;
static constexpr size_t O_IDXP1 = 4358144;
static constexpr size_t O_IDX2  = 4374528;
static constexpr size_t O_NI1   = 4579328;
static constexpr size_t O_NI2   = 4644864;
static constexpr size_t O_FGLOB = 4710400;
static constexpr size_t O_GLOB1 = 4726784;
static constexpr size_t O_COLS  = 4743168;
static constexpr size_t O_CPART = 4808704;
static constexpr size_t O_STATS = 5332992;
static constexpr size_t O_BPART = 5337088;
static constexpr size_t O_XCUR  = 5599232;    // 8,388,608 f32 activation scratch
static constexpr size_t O_XR    = 13987840;   // 4,194,304 f32 xr ksplit parts
static constexpr size_t O_PL    = 18182144;   // 58,855,424 plane pools (below)
static constexpr size_t O_AREA  = 77037568;   // 16,777,216 S / fout / pre / x1half
// end = 93,814,784  (ws_size >= 102,330,368 proven in round 1)

// plane pool sub-offsets (bytes from O_PL)
static constexpr size_t PL_WH    = 0;         // 4,786,176
static constexpr size_t PL_WL    = 4786176;
static constexpr size_t PL_FM0H  = 9572352;   // each fm0/1 plane 4,194,304
static constexpr size_t PL_FM0L  = 13766656;
static constexpr size_t PL_FM1H  = 17960960;
static constexpr size_t PL_FM1L  = 22155264;
static constexpr size_t PL_FM2H  = 26349568;  // 2,097,152 each
static constexpr size_t PL_FM2L  = 28446720;
static constexpr size_t PL_FM3H  = 30543872;
static constexpr size_t PL_FM3L  = 32641024;
static constexpr size_t PL_FM4H  = 34738176;  // 1,048,576 each
static constexpr size_t PL_FM4L  = 35786752;
static constexpr size_t PL_FMP1H = 36835328;  // 1,048,576 each
static constexpr size_t PL_FMP1L = 37883904;
static constexpr size_t PL_FMP2H = 38932480;  // 524,288 each
static constexpr size_t PL_FMP2L = 39456768;
static constexpr size_t PL_QH    = 39981056;  // 1,048,576 each
static constexpr size_t PL_QL    = 41029632;
static constexpr size_t PL_VMH   = 42078208;  // 4,194,304 each
static constexpr size_t PL_VML   = 46272512;
static constexpr size_t PL_XSH   = 50466816;  // 4,194,304 each
static constexpr size_t PL_XSL   = 54661120;  // pool ends at 58,855,424
// head aliases (phase-disjoint): x1 planes (8,388,608 each) over VM+XS planes;
// x2b (8,388,608) over XCUR.
static constexpr size_t PL_X1H = PL_VMH;
static constexpr size_t PL_X1L = PL_XSH;

__device__ __forceinline__ float bf2f(u16 h) {
  union { unsigned u; float f; } c; c.u = ((unsigned)h) << 16; return c.f;
}
__device__ __forceinline__ u16 f2bf(float f) {
  union { float f; unsigned u; } c; c.f = f;
  return (u16)((c.u + 0x7fffu + ((c.u >> 16) & 1u)) >> 16);
}

// ===========================================================================
// Plane GEMM. C[M,N] = A*B (+bias), TM x TM tile, 4 waves, 16x16x32 mfma.
// A: AMODE 0 = planes (Ah,Al) bf16 [M,K] (+opt row-gather GIDX)
//    AMODE 1 = f32 [K,M] split on the fly (attn S^T)
//    AMODE 2 = plain bf16 [M,K] (2 MFMAs/pair)
// B: planes (Bh,Bl) bf16 [N,K] (weights pre-transposed; vm stored [C][seq]).
// OUTM: 0 f32 (+opt ACC) | 1 planes row-major | 2 planes transposed [N][M]
//       (short4-packed) | 3 relu->plain bf16.
// BIASM: 0 none, 1 bias[col] f32.
// ksplit: z = zb*ksplit+ks covers K/ksplit; C slab at z*sC.
// M multiple of TM. K multiple of 32*ksplit. N arbitrary (guarded).
// ===========================================================================
template <int TM, int AMODE, int BIASM, int OUTM, bool ACC, bool GIDX>
__global__ __launch_bounds__(256) void k_mmp(
    const void* __restrict__ A1, const void* __restrict__ A2,
    const u16* __restrict__ Bh0, const u16* __restrict__ Bl0,
    const float* __restrict__ bias, void* __restrict__ C1, void* __restrict__ C2,
    int M, int N, int K, long sA, long sB, long sC, int ksplit,
    const int* __restrict__ gidx, long sG) {
  constexpr int RT = TM / 32;
  constexpr int CT = TM / 32;
  __shared__ u16 Ah[TM][40], Bh[TM][40], Bl[TM][40];
  __shared__ u16 Al[(AMODE == 2) ? 1 : TM][40];
  const int z = blockIdx.z;
  const int zb = z / ksplit, ks = z - zb * ksplit;
  const int kchunk = K / ksplit;
  const int kl0 = ks * kchunk, kl1 = kl0 + kchunk;
  const int m0 = blockIdx.x * TM, n0 = blockIdx.y * TM;
  const int t = threadIdx.x;
  const int lane = t & 63, w = t >> 6;
  const int wr = (w >> 1) * (TM / 2), wc = (w & 1) * (TM / 2);
  const int frow = lane & 15, koff = (lane >> 4) * 8;
  f32x4_t acc[RT][CT];
#pragma unroll
  for (int i = 0; i < RT; ++i)
#pragma unroll
    for (int j = 0; j < CT; ++j) acc[i][j] = (f32x4_t){0.f, 0.f, 0.f, 0.f};

  const u16* Ahg = (const u16*)A1 + (size_t)zb * sA;
  const u16* Alg = (const u16*)A2 + (size_t)zb * sA;
  const float* Afg = (const float*)A1 + (size_t)zb * sA;
  const u16* Bhg = Bh0 + (size_t)zb * sB;
  const u16* Blg = Bl0 + (size_t)zb * sB;

  // staging coordinates (constant over K loop)
  int ar, ac, arow = 0;
  if constexpr (AMODE != 1) {
    if constexpr (TM == 128) { ar = t >> 1; ac = (t & 1) * 16; }
    else                     { ar = t >> 2; ac = (t & 3) * 8; }
    arow = m0 + ar;
    if constexpr (GIDX) arow = (gidx + (size_t)zb * sG)[arow];
  }
  int bn, bc;
  if constexpr (TM == 128) { bn = t >> 1; bc = (t & 1) * 16; }
  else                     { bn = t >> 2; bc = (t & 3) * 8; }
  const bool bok = (n0 + bn) < N;
  const short8_t z8 = {0, 0, 0, 0, 0, 0, 0, 0};

  for (int k0 = kl0; k0 < kl1; k0 += 32) {
    __syncthreads();
    // ---- stage A ----
    if constexpr (AMODE == 0 || AMODE == 2) {
      const u16* s1 = Ahg + (size_t)arow * K + k0 + ac;
      if constexpr (TM == 128) {
        *(short8_t*)&Ah[ar][ac] = *(const short8_t*)s1;
        *(short8_t*)&Ah[ar][ac + 8] = *(const short8_t*)(s1 + 8);
        if constexpr (AMODE == 0) {
          const u16* s2 = Alg + (size_t)arow * K + k0 + ac;
          *(short8_t*)&Al[ar][ac] = *(const short8_t*)s2;
          *(short8_t*)&Al[ar][ac + 8] = *(const short8_t*)(s2 + 8);
        }
      } else {
        *(short8_t*)&Ah[ar][ac] = *(const short8_t*)s1;
        if constexpr (AMODE == 0)
          *(short8_t*)&Al[ar][ac] = *(const short8_t*)(Alg + (size_t)arow * K + k0 + ac);
      }
    } else {  // AMODE 1: f32 [K,M] on-the-fly split
      if constexpr (TM == 128) {
        const int m = t & 127, kq = (t >> 7) * 16;
        const float* src = Afg + (size_t)(k0 + kq) * M + (m0 + m);
#pragma unroll
        for (int j = 0; j < 16; ++j) {
          float v = src[(size_t)j * M];
          u16 h = f2bf(v);
          Ah[m][kq + j] = h;
          Al[m][kq + j] = f2bf(v - bf2f(h));
        }
      } else {
        const int m = t & 63, kq = (t >> 6) * 8;
        const float* src = Afg + (size_t)(k0 + kq) * M + (m0 + m);
#pragma unroll
        for (int j = 0; j < 8; ++j) {
          float v = src[(size_t)j * M];
          u16 h = f2bf(v);
          Ah[m][kq + j] = h;
          Al[m][kq + j] = f2bf(v - bf2f(h));
        }
      }
    }
    // ---- stage B (planes [N,K]) ----
    {
      const u16* s1 = Bhg + (size_t)(n0 + bn) * K + k0 + bc;
      const u16* s2 = Blg + (size_t)(n0 + bn) * K + k0 + bc;
      if constexpr (TM == 128) {
        *(short8_t*)&Bh[bn][bc] = bok ? *(const short8_t*)s1 : z8;
        *(short8_t*)&Bh[bn][bc + 8] = bok ? *(const short8_t*)(s1 + 8) : z8;
        *(short8_t*)&Bl[bn][bc] = bok ? *(const short8_t*)s2 : z8;
        *(short8_t*)&Bl[bn][bc + 8] = bok ? *(const short8_t*)(s2 + 8) : z8;
      } else {
        *(short8_t*)&Bh[bn][bc] = bok ? *(const short8_t*)s1 : z8;
        *(short8_t*)&Bl[bn][bc] = bok ? *(const short8_t*)s2 : z8;
      }
    }
    __syncthreads();
    short8_t ah[RT], al[RT], bh[CT], bl[CT];
#pragma unroll
    for (int i = 0; i < RT; ++i) {
      const int r = wr + i * 16 + frow;
      ah[i] = *(const short8_t*)&Ah[r][koff];
      if constexpr (AMODE != 2) al[i] = *(const short8_t*)&Al[r][koff];
    }
#pragma unroll
    for (int i = 0; i < CT; ++i) {
      const int r = wc + i * 16 + frow;
      bh[i] = *(const short8_t*)&Bh[r][koff];
      bl[i] = *(const short8_t*)&Bl[r][koff];
    }
#pragma unroll
    for (int i = 0; i < RT; ++i)
#pragma unroll
      for (int j = 0; j < CT; ++j) {
        acc[i][j] = __builtin_amdgcn_mfma_f32_16x16x32_bf16(ah[i], bh[j], acc[i][j], 0, 0, 0);
        acc[i][j] = __builtin_amdgcn_mfma_f32_16x16x32_bf16(ah[i], bl[j], acc[i][j], 0, 0, 0);
        if constexpr (AMODE != 2)
          acc[i][j] = __builtin_amdgcn_mfma_f32_16x16x32_bf16(al[i], bh[j], acc[i][j], 0, 0, 0);
      }
  }

  const int crow = (lane >> 4) * 4;
#pragma unroll
  for (int i = 0; i < RT; ++i) {
#pragma unroll
    for (int j = 0; j < CT; ++j) {
      const int gc = n0 + wc + j * 16 + frow;
      if (gc >= N) continue;
      const float bv = (BIASM == 1) ? bias[gc] : 0.f;
      const int gr0 = m0 + wr + i * 16 + crow;
      if constexpr (OUTM == 0) {
        float* Cp = (float*)C1 + (size_t)z * sC;
#pragma unroll
        for (int q = 0; q < 4; ++q) {
          float vv = acc[i][j][q] + bv;
          if (ACC) vv += Cp[(size_t)(gr0 + q) * N + gc];
          Cp[(size_t)(gr0 + q) * N + gc] = vv;
        }
      } else if constexpr (OUTM == 1) {
        u16* Ph = (u16*)C1 + (size_t)z * sC;
        u16* Pl = (u16*)C2 + (size_t)z * sC;
#pragma unroll
        for (int q = 0; q < 4; ++q) {
          float vv = acc[i][j][q] + bv;
          u16 h = f2bf(vv);
          Ph[(size_t)(gr0 + q) * N + gc] = h;
          Pl[(size_t)(gr0 + q) * N + gc] = f2bf(vv - bf2f(h));
        }
      } else if constexpr (OUTM == 2) {  // transposed planes [N][M], packed
        u16* Ph = (u16*)C1 + (size_t)z * sC;
        u16* Pl = (u16*)C2 + (size_t)z * sC;
        short4_t h4, l4;
#pragma unroll
        for (int q = 0; q < 4; ++q) {
          float vv = acc[i][j][q] + bv;
          u16 h = f2bf(vv);
          h4[q] = (short)h;
          l4[q] = (short)f2bf(vv - bf2f(h));
        }
        *(short4_t*)(Ph + (size_t)gc * M + gr0) = h4;
        *(short4_t*)(Pl + (size_t)gc * M + gr0) = l4;
      } else {  // OUTM 3: relu -> plain bf16
        u16* Cb = (u16*)C1 + (size_t)z * sC;
#pragma unroll
        for (int q = 0; q < 4; ++q) {
          float vv = fmaxf(acc[i][j][q] + bv, 0.f);
          Cb[(size_t)(gr0 + q) * N + gc] = f2bf(vv);
        }
      }
    }
  }
}

template <int TM, int AMODE, int BIASM, int OUTM, bool ACC, bool GIDX>
static void mmp(hipStream_t st, const void* A1, const void* A2,
                const u16* Bh, const u16* Bl, const float* bias,
                void* C1, void* C2, int M, int N, int K,
                long sA, long sB, long sC, int Z, int ksplit,
                const int* gidx = nullptr, long sG = 0) {
  dim3 grid(M / TM, (N + TM - 1) / TM, Z * ksplit);
  k_mmp<TM, AMODE, BIASM, OUTM, ACC, GIDX><<<grid, 256, 0, st>>>(
      A1, A2, Bh, Bl, bias, C1, C2, M, N, K, sA, sB, sC, ksplit, gidx, sG);
}

// ===========================================================================
// one-time weight split (optionally transposing [K,N] -> [N,K])
// ===========================================================================
struct SplitJob { const float* s; u16* dh; u16* dl; int n, K, N, trans; };
struct SplitJobs { SplitJob j[26]; };
__global__ void k_splitjobs(SplitJobs jobs) {
  SplitJob jb = jobs.j[blockIdx.y];
  for (int i = blockIdx.x * 256 + threadIdx.x; i < jb.n; i += gridDim.x * 256) {
    float v;
    if (jb.trans) { int k = i % jb.K, n = i / jb.K; v = jb.s[(size_t)k * jb.N + n]; }
    else v = jb.s[i];
    u16 h = f2bf(v);
    jb.dh[i] = h;
    jb.dl[i] = f2bf(v - bf2f(h));
  }
}

template <bool RELU>
__global__ void k_split4(const float* __restrict__ x, u16* __restrict__ ph,
                         u16* __restrict__ pl, int n4) {
  int i = blockIdx.x * 256 + threadIdx.x;
  if (i >= n4) return;
  float4 v = ((const float4*)x)[i];
  short4_t h4, l4;
  float vv[4] = {v.x, v.y, v.z, v.w};
#pragma unroll
  for (int q = 0; q < 4; ++q) {
    float f = RELU ? fmaxf(vv[q], 0.f) : vv[q];
    u16 h = f2bf(f);
    h4[q] = (short)h;
    l4[q] = (short)f2bf(f - bf2f(h));
  }
  *(short4_t*)(ph + (size_t)i * 4) = h4;
  *(short4_t*)(pl + (size_t)i * 4) = l4;
}

// ===========================================================================
// KNN (register distances), geometry, conv — unchanged from round 4
// ===========================================================================
template <int NCAND, int KSEL>
__global__ __launch_bounds__(256) void k_knn2(const float* __restrict__ pts, int Nq,
                                              int* __restrict__ outIdx) {
  __shared__ float sp[NCAND * 3];
  const int b = blockIdx.y;
  const float* pb = pts + (size_t)b * VS0;
  for (int i = threadIdx.x; i < NCAND * 3; i += 256) sp[i] = pb[i];
  __syncthreads();
  const int wave = threadIdx.x >> 6, lane = threadIdx.x & 63;
  const int qi = blockIdx.x * 4 + wave;
  const float qx = sp[qi * 3], qy = sp[qi * 3 + 1], qz = sp[qi * 3 + 2];
  constexpr int CH = NCAND / 64;
  float d[CH];
#pragma unroll
  for (int j = 0; j < CH; ++j) {
    const int m = lane + j * 64;
    const float dx = sp[m * 3] - qx, dy = sp[m * 3 + 1] - qy, dz = sp[m * 3 + 2] - qz;
    const float dd = dx * dx + dy * dy + dz * dz;
    d[j] = (m == qi) ? FLT_MAX : dd;
  }
  int* orow = outIdx + ((size_t)b * Nq + qi) * KSEL;
#pragma unroll 1
  for (int s = 0; s < KSEL; ++s) {
    float bd = FLT_MAX; int bj = 0;
#pragma unroll
    for (int j = 0; j < CH; ++j) {
      const bool better = d[j] < bd;
      bd = better ? d[j] : bd;
      bj = better ? j : bj;
    }
    int bm = lane + bj * 64;
#pragma unroll
    for (int off = 32; off; off >>= 1) {
      const float od = __shfl_xor(bd, off);
      const int om = __shfl_xor(bm, off);
      if (od < bd || (od == bd && om < bm)) { bd = od; bm = om; }
    }
    if (lane == 0) orow[s] = bm;
#pragma unroll
    for (int j = 0; j < CH; ++j)
      if (bm == lane + j * 64) d[j] = FLT_MAX;
  }
}

__global__ void k_transpose(const float* __restrict__ in, float* __restrict__ out) {
  int i = blockIdx.x * 256 + threadIdx.x;
  if (i >= BB * NP0 * 3) return;
  int dd = i % 3, tt = (i / 3) % NP0, b = i / (3 * NP0);
  out[i] = in[((size_t)b * 3 + dd) * NP0 + tt];
}

__global__ void k_conv_surface(const float* __restrict__ v, const int* __restrict__ idx,
                               const float* __restrict__ dirs, float* __restrict__ out,
                               int N, int M) {
  __shared__ float su[KNB_ * 3];
  int b = blockIdx.y, n = blockIdx.x, c = threadIdx.x;
  const float* vb = v + (size_t)b * VS0;
  float cx = vb[n * 3], cy = vb[n * 3 + 1], cz = vb[n * 3 + 2];
  const int* irow = idx + ((size_t)b * N + n) * KNB_;
  if (c < KNB_) {
    int j = irow[c];
    float dx = vb[j * 3] - cx, dy = vb[j * 3 + 1] - cy, dz = vb[j * 3 + 2] - cz;
    float inv = 1.f / fmaxf(sqrtf(dx * dx + dy * dy + dz * dz), 1e-12f);
    su[c * 3] = dx * inv; su[c * 3 + 1] = dy * inv; su[c * 3 + 2] = dz * inv;
  }
  __syncthreads();
  float d0 = dirs[c], d1 = dirs[M + c], d2 = dirs[2 * M + c];
  float inv = 1.f / fmaxf(sqrtf(d0 * d0 + d1 * d1 + d2 * d2), 1e-12f);
  d0 *= inv; d1 *= inv; d2 *= inv;
  float acc = 0.f;
  for (int k = 0; k < KNB_; ++k) {
    float th = fmaxf(su[k * 3] * d0 + su[k * 3 + 1] * d1 + su[k * 3 + 2] * d2, 0.f);
    acc = fmaxf(acc, th);
  }
  out[((size_t)b * N + n) * M + c] = acc;
}

__global__ void k_conv_layer(const float* __restrict__ v, const int* __restrict__ idx,
                             const float* __restrict__ dirs, const float* __restrict__ fout,
                             float* __restrict__ out, int N, int C) {
  __shared__ float su[KNB_ * 3];
  __shared__ int sidx[KNB_];
  int b = blockIdx.y, n = blockIdx.x, c = threadIdx.x;
  const float* vb = v + (size_t)b * VS0;
  float cx = vb[n * 3], cy = vb[n * 3 + 1], cz = vb[n * 3 + 2];
  const int* irow = idx + ((size_t)b * N + n) * KNB_;
  if (c < KNB_) {
    int j = irow[c]; sidx[c] = j;
    float dx = vb[j * 3] - cx, dy = vb[j * 3 + 1] - cy, dz = vb[j * 3 + 2] - cz;
    float inv = 1.f / fmaxf(sqrtf(dx * dx + dy * dy + dz * dz), 1e-12f);
    su[c * 3] = dx * inv; su[c * 3 + 1] = dy * inv; su[c * 3 + 2] = dz * inv;
  }
  __syncthreads();
  float d0 = dirs[c], d1 = dirs[C + c], d2 = dirs[2 * C + c];
  float inv = 1.f / fmaxf(sqrtf(d0 * d0 + d1 * d1 + d2 * d2), 1e-12f);
  d0 *= inv; d1 *= inv; d2 *= inv;
  const float* fb = fout + (size_t)b * N * 2 * C;
  float acc = -FLT_MAX;
  for (int k = 0; k < KNB_; ++k) {
    float th = fmaxf(su[k * 3] * d0 + su[k * 3 + 1] * d1 + su[k * 3 + 2] * d2, 0.f);
    float fs = fb[(size_t)sidx[k] * 2 * C + C + c];
    acc = fmaxf(acc, th * fs);
  }
  out[((size_t)b * N + n) * C + c] = fb[(size_t)n * 2 * C + c] + acc;
}

// ===========================================================================
// BN (2-phase) / softmax / colsum / elementwise (plane-producing)
// ===========================================================================
__global__ void k_bn_part(const float* __restrict__ x, int rows, int C, float* __restrict__ part) {
  const int blk = blockIdx.x;
  const int chunk = rows / 64;
  const int r0 = blk * chunk;
  const int c0 = threadIdx.x, c1 = threadIdx.x + 256;
  float s0 = 0, s20 = 0, s1 = 0, s21 = 0;
  for (int r = 0; r < chunk; ++r) {
    const float* row = x + (size_t)(r0 + r) * C;
    if (c0 < C) { float v = row[c0]; s0 += v; s20 += v * v; }
    if (c1 < C) { float v = row[c1]; s1 += v; s21 += v * v; }
  }
  float* p = part + (size_t)blk * 1024;
  if (c0 < C) { p[c0] = s0; p[512 + c0] = s20; }
  if (c1 < C) { p[c1] = s1; p[512 + c1] = s21; }
}

__global__ void k_bn_fin(const float* __restrict__ part, int rows, int C, float* __restrict__ stats) {
  int c = blockIdx.x * 256 + threadIdx.x;
  if (c >= C) return;
  float s = 0, s2 = 0;
  for (int b2 = 0; b2 < 64; ++b2) { s += part[b2 * 1024 + c]; s2 += part[b2 * 1024 + 512 + c]; }
  float m = s / rows;
  float var = s2 / rows - m * m;
  stats[c] = m;
  stats[C + c] = rsqrtf(var + 1e-5f);
}

template <bool ADD>
__global__ void k_bn_apply(const float* __restrict__ x, const float* __restrict__ stats,
                           const float* __restrict__ g, const float* __restrict__ bb,
                           const float* __restrict__ base, float* __restrict__ outf,
                           u16* __restrict__ ph, u16* __restrict__ pl, int total, int C) {
  int i = blockIdx.x * 256 + threadIdx.x;
  if (i >= total) return;
  int c = i % C;
  float v = (x[i] - stats[c]) * stats[C + c] * g[c] + bb[c];
  v = fmaxf(v, 0.f);
  float r = ADD ? base[i] + v : v;
  outf[i] = r;
  u16 h = f2bf(r);
  ph[i] = h;
  pl[i] = f2bf(r - bf2f(h));
}

__global__ void k_rowsoftmax(float* __restrict__ S, int N) {
  extern __shared__ float row[];
  __shared__ float red[256];
  int n = blockIdx.x;
  float* Sb = S + ((size_t)blockIdx.y * N + n) * N;
  float lmax = -FLT_MAX;
  for (int m = threadIdx.x; m < N; m += 256) { float v = Sb[m]; row[m] = v; lmax = fmaxf(lmax, v); }
  red[threadIdx.x] = lmax; __syncthreads();
  for (int o = 128; o; o >>= 1) {
    if (threadIdx.x < o) red[threadIdx.x] = fmaxf(red[threadIdx.x], red[threadIdx.x + o]);
    __syncthreads();
  }
  float mx = red[0]; __syncthreads();
  float lsum = 0.f;
  for (int m = threadIdx.x; m < N; m += 256) { float e = __expf(row[m] - mx); row[m] = e; lsum += e; }
  red[threadIdx.x] = lsum; __syncthreads();
  for (int o = 128; o; o >>= 1) {
    if (threadIdx.x < o) red[threadIdx.x] += red[threadIdx.x + o];
    __syncthreads();
  }
  float inv = 1.f / red[0];
  for (int m = threadIdx.x; m < N; m += 256) Sb[m] = row[m] * inv;
}

__global__ void k_cs_part(const float* __restrict__ S, int N, float* __restrict__ cpart, int gbase) {
  int m = blockIdx.x * 256 + threadIdx.x;
  if (m >= N) return;
  int g = blockIdx.y, pc = blockIdx.z;
  int chunk = N / 8;
  const float* Sb = S + (size_t)g * N * N;
  float s = 0;
  for (int n = pc * chunk; n < (pc + 1) * chunk; ++n) s += Sb[(size_t)n * N + m];
  cpart[((size_t)pc * 8 + (gbase + g)) * 2048 + m] = s;
}

__global__ void k_cs_fin(const float* __restrict__ cpart, int N, float* __restrict__ colsum, int gbase) {
  int m = blockIdx.x * 256 + threadIdx.x;
  if (m >= N) return;
  int b = gbase + blockIdx.y;
  float s = 0;
#pragma unroll
  for (int pc = 0; pc < 8; ++pc) s += cpart[((size_t)pc * 8 + b) * 2048 + m];
  colsum[(size_t)b * N + m] = s;
}

__global__ void k_xsub_sk(const float* __restrict__ xrpart, const float* __restrict__ colsum,
                          const float* __restrict__ fm, u16* __restrict__ xsh,
                          u16* __restrict__ xsl, int Npts, int C, int KS, int gbase, int gg) {
  int i = blockIdx.x * 256 + threadIdx.x;
  int per = Npts * C;
  if (i >= gg * per) return;
  int zb = i / per, rem = i - zb * per;
  int n = rem / C;
  float s = 0;
  for (int k2 = 0; k2 < KS; ++k2) s += xrpart[(size_t)(zb * KS + k2) * per + rem];
  int b = gbase + zb;
  float val = fm[(size_t)b * per + rem] - s / (1e-9f + colsum[(size_t)b * Npts + n]);
  u16 h = f2bf(val);
  xsh[(size_t)b * per + rem] = h;
  xsl[(size_t)b * per + rem] = f2bf(val - bf2f(h));
}

__global__ void k_pool(const u16* __restrict__ fh, const u16* __restrict__ fl,
                       const int* __restrict__ idxp, u16* __restrict__ oh,
                       u16* __restrict__ ol, int Nin, int pn, int C) {
  int b = blockIdx.y, p = blockIdx.x, c = threadIdx.x;
  const int* ir = idxp + ((size_t)b * pn + p) * 4;
  const u16* fhb = fh + (size_t)b * Nin * C;
  const u16* flb = fl + (size_t)b * Nin * C;
  float acc = -FLT_MAX;
#pragma unroll
  for (int k = 0; k < 4; ++k) {
    size_t o = (size_t)ir[k] * C + c;
    acc = fmaxf(acc, bf2f(fhb[o]) + bf2f(flb[o]));
  }
  u16 h = f2bf(acc);
  oh[((size_t)b * pn + p) * C + c] = h;
  ol[((size_t)b * pn + p) * C + c] = f2bf(acc - bf2f(h));
}

__global__ void k_maxn(const u16* __restrict__ fh, const u16* __restrict__ fl,
                       float* __restrict__ out, int N, int C) {
  int b = blockIdx.y;
  int c = blockIdx.x * 256 + threadIdx.x;
  if (c >= C) return;
  float acc = -FLT_MAX;
  for (int n = 0; n < N; ++n) {
    size_t o = ((size_t)b * N + n) * C + c;
    acc = fmaxf(acc, bf2f(fh[o]) + bf2f(fl[o]));
  }
  out[(size_t)b * C + c] = acc;
}

__global__ void k_nearest(const float* __restrict__ v, int Ns, int* __restrict__ out) {
  extern __shared__ float sp[];
  int b = blockIdx.y;
  const float* vsb = v + (size_t)b * VS0;
  for (int i = threadIdx.x; i < Ns * 3; i += 256) sp[i] = vsb[i];
  __syncthreads();
  int t = blockIdx.x * 256 + threadIdx.x;
  float tx = vsb[t * 3], ty = vsb[t * 3 + 1], tz = vsb[t * 3 + 2];
  float bd = FLT_MAX; int bi = 0;
#pragma unroll 4
  for (int s = 0; s < Ns; ++s) {
    float dx = sp[s * 3] - tx, dy = sp[s * 3 + 1] - ty, dz = sp[s * 3 + 2] - tz;
    float dd = dx * dx + dy * dy + dz * dz;
    if (dd < bd) { bd = dd; bi = s; }
  }
  out[(size_t)b * NP0 + t] = bi;
}

__global__ void k_glob1(const float* __restrict__ fglob, const float* __restrict__ onehot,
                        const float* __restrict__ h1w, const float* __restrict__ h1b,
                        float* __restrict__ out) {
  int b = blockIdx.x, j = threadIdx.x;
  float s = h1b[j];
  for (int i = 0; i < 512; ++i) s = fmaf(fglob[b * 512 + i], h1w[(size_t)(1280 + i) * 512 + j], s);
  for (int i = 0; i < 16; ++i) s = fmaf(onehot[b * 16 + i], h1w[(size_t)(1792 + i) * 512 + j], s);
  out[b * 512 + j] = s;
}

__global__ void k_fill_rows(const float* __restrict__ rowvec, float* __restrict__ out,
                            int NB, int N, int C) {
  int i = blockIdx.x * 256 + threadIdx.x;
  if (i >= NB * N * C) return;
  int c = i % C;
  int b = i / (N * C);
  out[i] = rowvec[b * C + c];
}

__global__ void k_logsoftmax(float* __restrict__ x, int rows, int C) {
  int r = blockIdx.x * 4 + (threadIdx.x >> 6);
  int lane = threadIdx.x & 63;
  if (r >= rows) return;
  float* xr = x + (size_t)r * C;
  float v = (lane < C) ? xr[lane] : -FLT_MAX;
  float mx = v;
  for (int o = 32; o; o >>= 1) mx = fmaxf(mx, __shfl_xor(mx, o));
  float e = (lane < C) ? __expf(v - mx) : 0.f;
  float s = e;
  for (int o = 32; o; o >>= 1) s += __shfl_xor(s, o);
  float lse = mx + logf(s);
  if (lane < C) xr[lane] = v - lse;
}

// ===========================================================================
// host
// ===========================================================================
struct Ws {
  float *v0, *fglob, *glob1, *colsum, *cpart, *stats, *bpart, *xcur, *xr, *S, *pre, *fout, *x1;
  int *idx0, *idxp0, *idx1, *idxp1, *idx2, *ni1, *ni2;
  u16 *wh, *wl;
  u16 *fm0h, *fm0l, *fm1h, *fm1l, *fm2h, *fm2l, *fm3h, *fm3l, *fm4h, *fm4l;
  u16 *fmp1h, *fmp1l, *fmp2h, *fmp2l, *qh, *ql, *vmh, *vml, *xsh, *xsl;
  u16 *x1h, *x1l, *x2b;
};

static void run_sa(hipStream_t st, Ws& ws, int N, int C, int Q, int bg, int KS,
                   const u16* qkh, const u16* qkl, const u16* vwh, const u16* vwl,
                   const u16* twh, const u16* twl,
                   const float* vb, const float* tb, const float* g, const float* be,
                   u16* xh, u16* xl) {
  const long sx = (long)N * C;
  // q = x qk^T -> q planes [M,Q]
  mmp<64, 0, 0, 1, false, false>(st, xh, xl, qkh, qkl, nullptr, ws.qh, ws.ql,
                                 N, Q, C, sx, 0, (long)N * Q, BB, 1);
  // vm = x vw^T + vb -> transposed planes [C][seq]
  mmp<128, 0, 1, 2, false, false>(st, xh, xl, vwh, vwl, vb, ws.vmh, ws.vml,
                                  N, C, C, sx, 0, sx, BB, 1);
  const int per = N * C;
  for (int g0 = 0; g0 < BB; g0 += bg) {
    const u16* qgh = ws.qh + (size_t)g0 * N * Q;
    const u16* qgl = ws.ql + (size_t)g0 * N * Q;
    mmp<128, 0, 0, 0, false, false>(st, qgh, qgl, qgh, qgl, nullptr, ws.S, nullptr,
                                    N, N, Q, (long)N * Q, (long)N * Q, (long)N * N, bg, 1);
    k_rowsoftmax<<<dim3(N, bg), 256, N * 4, st>>>(ws.S, N);
    k_cs_part<<<dim3((N + 255) / 256, bg, 8), 256, 0, st>>>(ws.S, N, ws.cpart, g0);
    k_cs_fin<<<dim3((N + 255) / 256, bg), 256, 0, st>>>(ws.cpart, N, ws.colsum, g0);
    // xr = S^T vm (A = f32 [K,M], B = vmT planes)
    mmp<128, 1, 0, 0, false, false>(st, ws.S, nullptr,
                                    ws.vmh + (size_t)g0 * per, ws.vml + (size_t)g0 * per,
                                    nullptr, ws.xr, nullptr, N, C, N,
                                    (long)N * N, sx, (long)N * C, bg, KS);
    k_xsub_sk<<<(bg * per + 255) / 256, 256, 0, st>>>(ws.xr, ws.colsum, ws.xcur,
                                                      ws.xsh, ws.xsl, N, C, KS, g0, bg);
  }
  // pre = xs tw^T + tb -> f32
  mmp<128, 0, 1, 0, false, false>(st, ws.xsh, ws.xsl, twh, twl, tb, ws.pre, nullptr,
                                  N, C, C, sx, 0, sx, BB, 1);
  k_bn_part<<<64, 256, 0, st>>>(ws.pre, BB * N, C, ws.bpart);
  k_bn_fin<<<(C + 255) / 256, 256, 0, st>>>(ws.bpart, BB * N, C, ws.stats);
  k_bn_apply<true><<<(BB * per + 255) / 256, 256, 0, st>>>(ws.pre, ws.stats, g, be,
                                                           ws.xcur, ws.xcur, xh, xl, BB * per, C);
}

static void run_conv(hipStream_t st, Ws& ws, const u16* finh, const u16* finl, int Cin,
                     const u16* cwh, const u16* cwl, const float* bias, const float* dirs,
                     const int* idx, int N, int C,
                     const float* bng, const float* bnb, bool doBN, u16* fmh, u16* fml) {
  mmp<128, 0, 1, 0, false, false>(st, finh, finl, cwh, cwl, bias, ws.fout, nullptr,
                                  N, 2 * C, Cin, (long)N * Cin, 0, (long)N * 2 * C, BB, 1);
  k_conv_layer<<<dim3(N, BB), C, 0, st>>>(ws.v0, idx, dirs, ws.fout, ws.xcur, N, C);
  if (doBN) {
    k_bn_part<<<64, 256, 0, st>>>(ws.xcur, BB * N, C, ws.bpart);
    k_bn_fin<<<(C + 255) / 256, 256, 0, st>>>(ws.bpart, BB * N, C, ws.stats);
    k_bn_apply<false><<<(BB * N * C + 255) / 256, 256, 0, st>>>(
        ws.xcur, ws.stats, bng, bnb, nullptr, ws.xcur, fmh, fml, BB * N * C, C);
  } else {
    k_split4<false><<<(BB * N * C / 4 + 255) / 256, 256, 0, st>>>(ws.xcur, fmh, fml, BB * N * C / 4);
  }
}

extern "C" void kernel_launch(void* const* d_in, const int* in_sizes, int n_in,
                              void* d_out, int out_size, void* d_ws, size_t ws_size,
                              hipStream_t stream) {
  auto in = [&](int i) { return (const float*)d_in[i]; };
  char* p = (char*)d_ws;
  Ws ws;
  ws.v0 = (float*)(p + O_V0);
  ws.idx0 = (int*)(p + O_IDX0); ws.idxp0 = (int*)(p + O_IDXP0);
  ws.idx1 = (int*)(p + O_IDX1); ws.idxp1 = (int*)(p + O_IDXP1);
  ws.idx2 = (int*)(p + O_IDX2);
  ws.ni1 = (int*)(p + O_NI1); ws.ni2 = (int*)(p + O_NI2);
  ws.fglob = (float*)(p + O_FGLOB); ws.glob1 = (float*)(p + O_GLOB1);
  ws.colsum = (float*)(p + O_COLS); ws.cpart = (float*)(p + O_CPART);
  ws.stats = (float*)(p + O_STATS); ws.bpart = (float*)(p + O_BPART);
  ws.xcur = (float*)(p + O_XCUR); ws.xr = (float*)(p + O_XR);
  ws.S = (float*)(p + O_AREA); ws.pre = (float*)(p + O_AREA);
  ws.fout = (float*)(p + O_AREA); ws.x1 = (float*)(p + O_AREA);
  char* pl = p + O_PL;
  ws.wh = (u16*)(pl + PL_WH); ws.wl = (u16*)(pl + PL_WL);
  ws.fm0h = (u16*)(pl + PL_FM0H); ws.fm0l = (u16*)(pl + PL_FM0L);
  ws.fm1h = (u16*)(pl + PL_FM1H); ws.fm1l = (u16*)(pl + PL_FM1L);
  ws.fm2h = (u16*)(pl + PL_FM2H); ws.fm2l = (u16*)(pl + PL_FM2L);
  ws.fm3h = (u16*)(pl + PL_FM3H); ws.fm3l = (u16*)(pl + PL_FM3L);
  ws.fm4h = (u16*)(pl + PL_FM4H); ws.fm4l = (u16*)(pl + PL_FM4L);
  ws.fmp1h = (u16*)(pl + PL_FMP1H); ws.fmp1l = (u16*)(pl + PL_FMP1L);
  ws.fmp2h = (u16*)(pl + PL_FMP2H); ws.fmp2l = (u16*)(pl + PL_FMP2L);
  ws.qh = (u16*)(pl + PL_QH); ws.ql = (u16*)(pl + PL_QL);
  ws.vmh = (u16*)(pl + PL_VMH); ws.vml = (u16*)(pl + PL_VML);
  ws.xsh = (u16*)(pl + PL_XSH); ws.xsl = (u16*)(pl + PL_XSL);
  ws.x1h = (u16*)(pl + PL_X1H); ws.x1l = (u16*)(pl + PL_X1L);
  ws.x2b = (u16*)(p + O_XCUR);
  float* out = (float*)d_out;

  // ---- one-time weight plane split (pre-transposed to [N,K]) ----
  SplitJobs jobs;
  size_t wq[26];
  size_t off = 0;
  int ji = 0;
  auto addjob = [&](const float* s, int K, int N, int trans) {
    int n = K * N;
    jobs.j[ji] = {s, ws.wh + off, ws.wl + off, n, K, N, trans};
    wq[ji] = off; off += (size_t)n; ++ji;
  };
  addjob(in(5), 128, 32, 0);  addjob(in(6), 128, 128, 0);  addjob(in(8), 128, 128, 0);
  addjob(in(17), 128, 32, 0); addjob(in(18), 128, 128, 0); addjob(in(20), 128, 128, 0);
  addjob(in(29), 256, 64, 0); addjob(in(30), 256, 256, 0); addjob(in(32), 256, 256, 0);
  addjob(in(41), 256, 64, 0); addjob(in(42), 256, 256, 0); addjob(in(44), 256, 256, 0);
  addjob(in(51), 512, 128, 0); addjob(in(52), 512, 512, 0); addjob(in(54), 512, 512, 0);
  addjob(in(12), 128, 256, 1);   // conv1_w [K,N] -> T
  addjob(in(24), 128, 512, 1);   // conv2_w
  addjob(in(36), 256, 512, 1);   // conv3_w
  addjob(in(48), 256, 1024, 1);  // conv4_w
  addjob(in(58) + 0 * 512, 128, 512, 1);          // h1 seg fm0
  addjob(in(58) + (size_t)128 * 512, 128, 512, 1);  // h1 seg fm1
  addjob(in(58) + (size_t)256 * 512, 256, 512, 1);  // h1 seg fm2
  addjob(in(58) + (size_t)512 * 512, 256, 512, 1);  // h1 seg fm3
  addjob(in(58) + (size_t)768 * 512, 512, 512, 1);  // h1 seg fm4
  addjob(in(60), 512, 512, 1);   // h2
  addjob(in(62), 512, 50, 1);    // h3
  k_splitjobs<<<dim3(32, 26), 256, 0, stream>>>(jobs);
  auto W = [&](int i) { return ws.wh + wq[i]; };
  auto Wl = [&](int i) { return ws.wl + wq[i]; };

  // ---- geometry ----
  k_transpose<<<(BB * NP0 * 3 + 255) / 256, 256, 0, stream>>>(in(0), ws.v0);
  k_knn2<NP0, KNB_><<<dim3(NP0 / 4, BB), 256, 0, stream>>>(ws.v0, NP0, ws.idx0);

  // ---- conv0 + bn0 ----
  k_conv_surface<<<dim3(NP0, BB), 128, 0, stream>>>(ws.v0, ws.idx0, in(2), ws.xcur, NP0, 128);
  k_bn_part<<<64, 256, 0, stream>>>(ws.xcur, BB * NP0, 128, ws.bpart);
  k_bn_fin<<<1, 256, 0, stream>>>(ws.bpart, BB * NP0, 128, ws.stats);
  k_bn_apply<false><<<(BB * NP0 * 128 + 255) / 256, 256, 0, stream>>>(
      ws.xcur, ws.stats, in(3), in(4), nullptr, ws.xcur, ws.fm0h, ws.fm0l, BB * NP0 * 128, 128);

  // ---- sa0, conv1+bn1, sa1 ----
  run_sa(stream, ws, NP0, 128, 32, 1, 4, W(0), Wl(0), W(1), Wl(1), W(2), Wl(2),
         in(7), in(9), in(10), in(11), ws.fm0h, ws.fm0l);
  run_conv(stream, ws, ws.fm0h, ws.fm0l, 128, W(15), Wl(15), in(13), in(14), ws.idx0,
           NP0, 128, in(15), in(16), true, ws.fm1h, ws.fm1l);
  run_sa(stream, ws, NP0, 128, 32, 1, 4, W(3), Wl(3), W(4), Wl(4), W(5), Wl(5),
         in(19), in(21), in(22), in(23), ws.fm1h, ws.fm1l);

  // ---- pool1, knn1 ----
  k_knn2<NP0, 4><<<dim3(NP1 / 4, BB), 256, 0, stream>>>(ws.v0, NP1, ws.idxp0);
  k_pool<<<dim3(NP1, BB), 128, 0, stream>>>(ws.fm1h, ws.fm1l, ws.idxp0,
                                            ws.fmp1h, ws.fmp1l, NP0, NP1, 128);
  k_knn2<NP1, KNB_><<<dim3(NP1 / 4, BB), 256, 0, stream>>>(ws.v0, NP1, ws.idx1);

  // ---- conv2+bn2, sa2, conv3+bn3, sa3 ----
  run_conv(stream, ws, ws.fmp1h, ws.fmp1l, 128, W(16), Wl(16), in(25), in(26), ws.idx1,
           NP1, 256, in(27), in(28), true, ws.fm2h, ws.fm2l);
  run_sa(stream, ws, NP1, 256, 64, 8, 1, W(6), Wl(6), W(7), Wl(7), W(8), Wl(8),
         in(31), in(33), in(34), in(35), ws.fm2h, ws.fm2l);
  run_conv(stream, ws, ws.fm2h, ws.fm2l, 256, W(17), Wl(17), in(37), in(38), ws.idx1,
           NP1, 256, in(39), in(40), true, ws.fm3h, ws.fm3l);
  run_sa(stream, ws, NP1, 256, 64, 8, 1, W(9), Wl(9), W(10), Wl(10), W(11), Wl(11),
         in(43), in(45), in(46), in(47), ws.fm3h, ws.fm3l);

  // ---- pool2, knn2, conv4 (no bn), sa4 ----
  k_knn2<NP1, 4><<<dim3(NP2 / 4, BB), 256, 0, stream>>>(ws.v0, NP2, ws.idxp1);
  k_pool<<<dim3(NP2, BB), 256, 0, stream>>>(ws.fm3h, ws.fm3l, ws.idxp1,
                                            ws.fmp2h, ws.fmp2l, NP1, NP2, 256);
  k_knn2<NP2, KNB_><<<dim3(NP2 / 4, BB), 256, 0, stream>>>(ws.v0, NP2, ws.idx2);
  run_conv(stream, ws, ws.fmp2h, ws.fmp2l, 256, W(18), Wl(18), in(49), in(50), ws.idx2,
           NP2, 512, nullptr, nullptr, false, ws.fm4h, ws.fm4l);
  run_sa(stream, ws, NP2, 512, 128, 8, 2, W(12), Wl(12), W(13), Wl(13), W(14), Wl(14),
         in(53), in(55), in(56), in(57), ws.fm4h, ws.fm4l);

  // ---- global max, nearest, head ----
  k_maxn<<<dim3(2, BB), 256, 0, stream>>>(ws.fm4h, ws.fm4l, ws.fglob, NP2, 512);
  k_nearest<<<dim3(NP0 / 256, BB), 256, NP1 * 3 * 4, stream>>>(ws.v0, NP1, ws.ni1);
  k_nearest<<<dim3(NP0 / 256, BB), 256, NP2 * 3 * 4, stream>>>(ws.v0, NP2, ws.ni2);
  k_glob1<<<BB, 512, 0, stream>>>(ws.fglob, in(1), in(58), in(59), ws.glob1);

  // head in two 4-batch halves (x1 f32 in AREA; x1 planes alias vm/xs planes;
  // x2b aliases xcur — all dead by now)
  for (int hf = 0; hf < 2; ++hf) {
    const int b0 = hf * 4;
    k_fill_rows<<<(4 * NP0 * 512 + 255) / 256, 256, 0, stream>>>(
        ws.glob1 + b0 * 512, ws.x1, 4, NP0, 512);
    mmp<128, 0, 0, 0, true, false>(stream, ws.fm0h + (size_t)b0 * NP0 * 128,
        ws.fm0l + (size_t)b0 * NP0 * 128, W(19), Wl(19), nullptr, ws.x1, nullptr,
        NP0, 512, 128, (long)NP0 * 128, 0, (long)NP0 * 512, 4, 1);
    mmp<128, 0, 0, 0, true, false>(stream, ws.fm1h + (size_t)b0 * NP0 * 128,
        ws.fm1l + (size_t)b0 * NP0 * 128, W(20), Wl(20), nullptr, ws.x1, nullptr,
        NP0, 512, 128, (long)NP0 * 128, 0, (long)NP0 * 512, 4, 1);
    mmp<128, 0, 0, 0, true, true>(stream, ws.fm2h + (size_t)b0 * NP1 * 256,
        ws.fm2l + (size_t)b0 * NP1 * 256, W(21), Wl(21), nullptr, ws.x1, nullptr,
        NP0, 512, 256, (long)NP1 * 256, 0, (long)NP0 * 512, 4, 1,
        ws.ni1 + (size_t)b0 * NP0, NP0);
    mmp<128, 0, 0, 0, true, true>(stream, ws.fm3h + (size_t)b0 * NP1 * 256,
        ws.fm3l + (size_t)b0 * NP1 * 256, W(22), Wl(22), nullptr, ws.x1, nullptr,
        NP0, 512, 256, (long)NP1 * 256, 0, (long)NP0 * 512, 4, 1,
        ws.ni1 + (size_t)b0 * NP0, NP0);
    mmp<128, 0, 0, 0, true, true>(stream, ws.fm4h + (size_t)b0 * NP2 * 512,
        ws.fm4l + (size_t)b0 * NP2 * 512, W(23), Wl(23), nullptr, ws.x1, nullptr,
        NP0, 512, 512, (long)NP2 * 512, 0, (long)NP0 * 512, 4, 1,
        ws.ni2 + (size_t)b0 * NP0, NP0);
    // relu-split x1 -> planes
    k_split4<true><<<(4 * NP0 * 512 / 4 + 255) / 256, 256, 0, stream>>>(
        ws.x1, ws.x1h, ws.x1l, 4 * NP0 * 512 / 4);
    // x2 = relu(x1 @ h2 + h2b) -> plain bf16
    mmp<128, 0, 1, 3, false, false>(stream, ws.x1h, ws.x1l, W(24), Wl(24), in(61),
        ws.x2b, nullptr, NP0, 512, 512, (long)NP0 * 512, 0, (long)NP0 * 512, 4, 1);
    // logits = x2 @ h3 + h3b -> f32
    mmp<64, 2, 1, 0, false, false>(stream, ws.x2b, nullptr, W(25), Wl(25), in(63),
        out + (size_t)b0 * NP0 * 50, nullptr, NP0, 50, 512,
        (long)NP0 * 512, 0, (long)NP0 * 50, 4, 1);
  }

  k_logsoftmax<<<(BB * NP0) / 4, 256, 0, stream>>>(out, BB * NP0, 50);
}

// Round 6
// 2398.210 us; speedup vs baseline: 1.5916x; 1.5916x over previous
//
#include <hip/hip_runtime.h>
#include <cfloat>

// ---------------------------------------------------------------------------
// GCN3D forward. Split-plane bf16 MFMA GEMMs (Dekker, f32-grade accuracy).
// Round-6: SA uses S-symmetry — attn^T built from ROW-major S reads with
// on-the-fly exp; colsum computed as a GEMM staging side-product. The
// stride-8KB column walks (k_cs_part pathology, 0.27 GB/s) are gone.
// B=8, N=2048->512->128, K_NB=50. Workspace 93,814,784 B.
// ---------------------------------------------------------------------------

#define BB   8
#define NP0  2048
#define NP1  512
#define NP2  128
#define KNB_ 50
#define VS0  (NP0 * 3)

typedef __attribute__((ext_vector_type(8))) short short8_t;
typedef __attribute__((ext_vector_type(4))) short short4_t;
typedef __attribute__((ext_vector_type(4))) float f32x4_t;
typedef unsigned short u16;

// ---------------- workspace layout (byte offsets) ----------------
static constexpr size_t O_V0    = 0;
static constexpr size_t O_IDX0  = 196608;
static constexpr size_t O_IDXP0 = 3473408;
static constexpr size_t O_IDX1  = 3538944;
static constexpr size_t O_IDXP1 = 4358144;
static constexpr size_t O_IDX2  = 4374528;
static constexpr size_t O_NI1   = 4579328;
static constexpr size_t O_NI2   = 4644864;
static constexpr size_t O_FGLOB = 4710400;
static constexpr size_t O_GLOB1 = 4726784;
static constexpr size_t O_COLS  = 4743168;   // mx / inv vectors (64KB)
static constexpr size_t O_CPART = 4808704;   // colsum parts (512KB)
static constexpr size_t O_STATS = 5332992;
static constexpr size_t O_BPART = 5337088;
static constexpr size_t O_XCUR  = 5599232;   // 8,388,608 f32 activation scratch
static constexpr size_t O_XR    = 13987840;  // 4,194,304 xr ksplit parts
static constexpr size_t O_PL    = 18182144;  // 58,855,424 plane pools
static constexpr size_t O_AREA  = 77037568;  // 16,777,216 S / fout / pre / x1half
// end = 93,814,784

static constexpr size_t PL_WH    = 0;
static constexpr size_t PL_WL    = 4786176;
static constexpr size_t PL_FM0H  = 9572352;
static constexpr size_t PL_FM0L  = 13766656;
static constexpr size_t PL_FM1H  = 17960960;
static constexpr size_t PL_FM1L  = 22155264;
static constexpr size_t PL_FM2H  = 26349568;
static constexpr size_t PL_FM2L  = 28446720;
static constexpr size_t PL_FM3H  = 30543872;
static constexpr size_t PL_FM3L  = 32641024;
static constexpr size_t PL_FM4H  = 34738176;
static constexpr size_t PL_FM4L  = 35786752;
static constexpr size_t PL_FMP1H = 36835328;
static constexpr size_t PL_FMP1L = 37883904;
static constexpr size_t PL_FMP2H = 38932480;
static constexpr size_t PL_FMP2L = 39456768;
static constexpr size_t PL_QH    = 39981056;
static constexpr size_t PL_QL    = 41029632;
static constexpr size_t PL_VMH   = 42078208;
static constexpr size_t PL_VML   = 46272512;
static constexpr size_t PL_XSH   = 50466816;
static constexpr size_t PL_XSL   = 54661120;
static constexpr size_t PL_X1H = PL_VMH;   // head aliases (phase-disjoint)
static constexpr size_t PL_X1L = PL_XSH;

__device__ __forceinline__ float bf2f(u16 h) {
  union { unsigned u; float f; } c; c.u = ((unsigned)h) << 16; return c.f;
}
__device__ __forceinline__ u16 f2bf(float f) {
  union { float f; unsigned u; } c; c.f = f;
  return (u16)((c.u + 0x7fffu + ((c.u >> 16) & 1u)) >> 16);
}

// ===========================================================================
// Plane GEMM. C[M,N] = A*B (+bias), TM x TM tile, 4 waves, 16x16x32 mfma.
// AMODE 0: planes (Ah,Al) bf16 [M,K] (+opt GIDX row gather)
// AMODE 2: plain bf16 [M,K] (2 MFMAs/pair)
// AMODE 3: A = attn^T from symmetric f32 S: row-major read S[m][k],
//          val = exp(v - mx[k])*inv[k], Dekker split; blocks with
//          blockIdx.y==0 write per-row staged sums -> cpart (colsum parts).
// B: planes (Bh,Bl) bf16 [N,K].
// OUTM: 0 f32 (+ACC) | 1 planes | 2 transposed planes [N][M] | 3 relu->bf16.
// BIASM: 0 none | 1 bias[col] | 2 bias[zb*N+col].
// ksplit: z = zb*ksplit+ks covers K/ksplit; C slab at z*sC.
// ===========================================================================
template <int TM, int AMODE, int BIASM, int OUTM, bool ACC, bool GIDX>
__global__ __launch_bounds__(256) void k_mmp(
    const void* __restrict__ A1, const void* __restrict__ A2,
    const u16* __restrict__ Bh0, const u16* __restrict__ Bl0,
    const float* __restrict__ bias, void* __restrict__ C1, void* __restrict__ C2,
    int M, int N, int K, long sA, long sB, long sC, int ksplit,
    const int* __restrict__ gidx, long sG,
    const float* __restrict__ mxv, const float* __restrict__ invv,
    float* __restrict__ cpart) {
  constexpr int RT = TM / 32;
  constexpr int CT = TM / 32;
  __shared__ u16 Ah[TM][40], Bh[TM][40], Bl[TM][40];
  __shared__ u16 Al[(AMODE == 2) ? 1 : TM][40];
  const int z = blockIdx.z;
  const int zb = z / ksplit, ks = z - zb * ksplit;
  const int kchunk = K / ksplit;
  const int kl0 = ks * kchunk, kl1 = kl0 + kchunk;
  const int m0 = blockIdx.x * TM, n0 = blockIdx.y * TM;
  const int t = threadIdx.x;
  const int lane = t & 63, w = t >> 6;
  const int wr = (w >> 1) * (TM / 2), wc = (w & 1) * (TM / 2);
  const int frow = lane & 15, koff = (lane >> 4) * 8;
  f32x4_t acc[RT][CT];
#pragma unroll
  for (int i = 0; i < RT; ++i)
#pragma unroll
    for (int j = 0; j < CT; ++j) acc[i][j] = (f32x4_t){0.f, 0.f, 0.f, 0.f};

  const u16* Ahg = (const u16*)A1 + (size_t)zb * sA;
  const u16* Alg = (const u16*)A2 + (size_t)zb * sA;
  const float* Sfg = (const float*)A1 + (size_t)zb * sA;
  const u16* Bhg = Bh0 + (size_t)zb * sB;
  const u16* Blg = Bl0 + (size_t)zb * sB;
  const float* mxg = (AMODE == 3) ? mxv + (size_t)zb * K : nullptr;
  const float* invg = (AMODE == 3) ? invv + (size_t)zb * K : nullptr;

  // staging coordinates (constant over K loop)
  int ar, ac, arow = 0;
  if constexpr (TM == 128) { ar = t >> 1; ac = (t & 1) * 16; }
  else                     { ar = t >> 2; ac = (t & 3) * 8; }
  arow = m0 + ar;
  if constexpr (GIDX) arow = (gidx + (size_t)zb * sG)[arow];
  const int bn = ar, bc = ac;
  const bool bok = (n0 + bn) < N;
  const short8_t z8 = {0, 0, 0, 0, 0, 0, 0, 0};
  float csum = 0.f;

  for (int k0 = kl0; k0 < kl1; k0 += 32) {
    __syncthreads();
    // ---- stage A ----
    if constexpr (AMODE == 0 || AMODE == 2) {
      const u16* s1 = Ahg + (size_t)arow * K + k0 + ac;
      if constexpr (TM == 128) {
        *(short8_t*)&Ah[ar][ac] = *(const short8_t*)s1;
        *(short8_t*)&Ah[ar][ac + 8] = *(const short8_t*)(s1 + 8);
        if constexpr (AMODE == 0) {
          const u16* s2 = Alg + (size_t)arow * K + k0 + ac;
          *(short8_t*)&Al[ar][ac] = *(const short8_t*)s2;
          *(short8_t*)&Al[ar][ac + 8] = *(const short8_t*)(s2 + 8);
        }
      } else {
        *(short8_t*)&Ah[ar][ac] = *(const short8_t*)s1;
        if constexpr (AMODE == 0)
          *(short8_t*)&Al[ar][ac] = *(const short8_t*)(Alg + (size_t)arow * K + k0 + ac);
      }
    } else {  // AMODE 3: symmetric-S attn transform (row-major, coalesced)
      const float* src = Sfg + (size_t)(m0 + ar) * K + k0 + ac;
      constexpr int JW = (TM == 128) ? 16 : 8;
#pragma unroll
      for (int j = 0; j < JW; ++j) {
        float v = __expf(src[j] - mxg[k0 + ac + j]) * invg[k0 + ac + j];
        csum += v;
        u16 h = f2bf(v);
        Ah[ar][ac + j] = h;
        Al[ar][ac + j] = f2bf(v - bf2f(h));
      }
    }
    // ---- stage B (planes [N,K]) ----
    {
      const u16* s1 = Bhg + (size_t)(n0 + bn) * K + k0 + bc;
      const u16* s2 = Blg + (size_t)(n0 + bn) * K + k0 + bc;
      if constexpr (TM == 128) {
        *(short8_t*)&Bh[bn][bc] = bok ? *(const short8_t*)s1 : z8;
        *(short8_t*)&Bh[bn][bc + 8] = bok ? *(const short8_t*)(s1 + 8) : z8;
        *(short8_t*)&Bl[bn][bc] = bok ? *(const short8_t*)s2 : z8;
        *(short8_t*)&Bl[bn][bc + 8] = bok ? *(const short8_t*)(s2 + 8) : z8;
      } else {
        *(short8_t*)&Bh[bn][bc] = bok ? *(const short8_t*)s1 : z8;
        *(short8_t*)&Bl[bn][bc] = bok ? *(const short8_t*)s2 : z8;
      }
    }
    __syncthreads();
    short8_t ah[RT], al[RT], bh[CT], bl[CT];
#pragma unroll
    for (int i = 0; i < RT; ++i) {
      const int r = wr + i * 16 + frow;
      ah[i] = *(const short8_t*)&Ah[r][koff];
      if constexpr (AMODE != 2) al[i] = *(const short8_t*)&Al[r][koff];
    }
#pragma unroll
    for (int i = 0; i < CT; ++i) {
      const int r = wc + i * 16 + frow;
      bh[i] = *(const short8_t*)&Bh[r][koff];
      bl[i] = *(const short8_t*)&Bl[r][koff];
    }
#pragma unroll
    for (int i = 0; i < RT; ++i)
#pragma unroll
      for (int j = 0; j < CT; ++j) {
        acc[i][j] = __builtin_amdgcn_mfma_f32_16x16x32_bf16(ah[i], bh[j], acc[i][j], 0, 0, 0);
        acc[i][j] = __builtin_amdgcn_mfma_f32_16x16x32_bf16(ah[i], bl[j], acc[i][j], 0, 0, 0);
        if constexpr (AMODE != 2)
          acc[i][j] = __builtin_amdgcn_mfma_f32_16x16x32_bf16(al[i], bh[j], acc[i][j], 0, 0, 0);
      }
  }

  // colsum side-product: per-row sums of staged attn^T (only one n0 tile)
  if constexpr (AMODE == 3) {
    if (blockIdx.y == 0) {
      float c = csum;
      c += __shfl_xor(c, 1);
      if constexpr (TM == 64) c += __shfl_xor(c, 2);
      if ((t & ((TM == 64) ? 3 : 1)) == 0)
        cpart[(size_t)z * M + m0 + ar] = c;
    }
  }

  const int crow = (lane >> 4) * 4;
#pragma unroll
  for (int i = 0; i < RT; ++i) {
#pragma unroll
    for (int j = 0; j < CT; ++j) {
      const int gc = n0 + wc + j * 16 + frow;
      if (gc >= N) continue;
      float bv = 0.f;
      if constexpr (BIASM == 1) bv = bias[gc];
      if constexpr (BIASM == 2) bv = bias[(size_t)zb * N + gc];
      const int gr0 = m0 + wr + i * 16 + crow;
      if constexpr (OUTM == 0) {
        float* Cp = (float*)C1 + (size_t)z * sC;
#pragma unroll
        for (int q = 0; q < 4; ++q) {
          float vv = acc[i][j][q] + bv;
          if (ACC) vv += Cp[(size_t)(gr0 + q) * N + gc];
          Cp[(size_t)(gr0 + q) * N + gc] = vv;
        }
      } else if constexpr (OUTM == 1) {
        u16* Ph = (u16*)C1 + (size_t)z * sC;
        u16* Pl = (u16*)C2 + (size_t)z * sC;
#pragma unroll
        for (int q = 0; q < 4; ++q) {
          float vv = acc[i][j][q] + bv;
          u16 h = f2bf(vv);
          Ph[(size_t)(gr0 + q) * N + gc] = h;
          Pl[(size_t)(gr0 + q) * N + gc] = f2bf(vv - bf2f(h));
        }
      } else if constexpr (OUTM == 2) {
        u16* Ph = (u16*)C1 + (size_t)z * sC;
        u16* Pl = (u16*)C2 + (size_t)z * sC;
        short4_t h4, l4;
#pragma unroll
        for (int q = 0; q < 4; ++q) {
          float vv = acc[i][j][q] + bv;
          u16 h = f2bf(vv);
          h4[q] = (short)h;
          l4[q] = (short)f2bf(vv - bf2f(h));
        }
        *(short4_t*)(Ph + (size_t)gc * M + gr0) = h4;
        *(short4_t*)(Pl + (size_t)gc * M + gr0) = l4;
      } else {
        u16* Cb = (u16*)C1 + (size_t)z * sC;
#pragma unroll
        for (int q = 0; q < 4; ++q) {
          float vv = fmaxf(acc[i][j][q] + bv, 0.f);
          Cb[(size_t)(gr0 + q) * N + gc] = f2bf(vv);
        }
      }
    }
  }
}

template <int TM, int AMODE, int BIASM, int OUTM, bool ACC, bool GIDX>
static void mmp(hipStream_t st, const void* A1, const void* A2,
                const u16* Bh, const u16* Bl, const float* bias,
                void* C1, void* C2, int M, int N, int K,
                long sA, long sB, long sC, int Z, int ksplit,
                const int* gidx = nullptr, long sG = 0,
                const float* mxv = nullptr, const float* invv = nullptr,
                float* cpart = nullptr) {
  dim3 grid(M / TM, (N + TM - 1) / TM, Z * ksplit);
  k_mmp<TM, AMODE, BIASM, OUTM, ACC, GIDX><<<grid, 256, 0, st>>>(
      A1, A2, Bh, Bl, bias, C1, C2, M, N, K, sA, sB, sC, ksplit, gidx, sG,
      mxv, invv, cpart);
}

// ===========================================================================
// weight split + activation split
// ===========================================================================
struct SplitJob { const float* s; u16* dh; u16* dl; int n, K, N, trans; };
struct SplitJobs { SplitJob j[26]; };
__global__ void k_splitjobs(SplitJobs jobs) {
  SplitJob jb = jobs.j[blockIdx.y];
  for (int i = blockIdx.x * 256 + threadIdx.x; i < jb.n; i += gridDim.x * 256) {
    float v;
    if (jb.trans) { int k = i % jb.K, n = i / jb.K; v = jb.s[(size_t)k * jb.N + n]; }
    else v = jb.s[i];
    u16 h = f2bf(v);
    jb.dh[i] = h;
    jb.dl[i] = f2bf(v - bf2f(h));
  }
}

template <bool RELU>
__global__ void k_split4(const float* __restrict__ x, u16* __restrict__ ph,
                         u16* __restrict__ pl, int n4) {
  int i = blockIdx.x * 256 + threadIdx.x;
  if (i >= n4) return;
  float4 v = ((const float4*)x)[i];
  short4_t h4, l4;
  float vv[4] = {v.x, v.y, v.z, v.w};
#pragma unroll
  for (int q = 0; q < 4; ++q) {
    float f = RELU ? fmaxf(vv[q], 0.f) : vv[q];
    u16 h = f2bf(f);
    h4[q] = (short)h;
    l4[q] = (short)f2bf(f - bf2f(h));
  }
  *(short4_t*)(ph + (size_t)i * 4) = h4;
  *(short4_t*)(pl + (size_t)i * 4) = l4;
}

// ===========================================================================
// KNN / geometry / conv
// ===========================================================================
template <int NCAND, int KSEL>
__global__ __launch_bounds__(256) void k_knn2(const float* __restrict__ pts, int Nq,
                                              int* __restrict__ outIdx) {
  __shared__ float sp[NCAND * 3];
  const int b = blockIdx.y;
  const float* pb = pts + (size_t)b * VS0;
  for (int i = threadIdx.x; i < NCAND * 3; i += 256) sp[i] = pb[i];
  __syncthreads();
  const int wave = threadIdx.x >> 6, lane = threadIdx.x & 63;
  const int qi = blockIdx.x * 4 + wave;
  const float qx = sp[qi * 3], qy = sp[qi * 3 + 1], qz = sp[qi * 3 + 2];
  constexpr int CH = NCAND / 64;
  float d[CH];
#pragma unroll
  for (int j = 0; j < CH; ++j) {
    const int m = lane + j * 64;
    const float dx = sp[m * 3] - qx, dy = sp[m * 3 + 1] - qy, dz = sp[m * 3 + 2] - qz;
    const float dd = dx * dx + dy * dy + dz * dz;
    d[j] = (m == qi) ? FLT_MAX : dd;
  }
  int* orow = outIdx + ((size_t)b * Nq + qi) * KSEL;
#pragma unroll 1
  for (int s = 0; s < KSEL; ++s) {
    float bd = FLT_MAX; int bj = 0;
#pragma unroll
    for (int j = 0; j < CH; ++j) {
      const bool better = d[j] < bd;
      bd = better ? d[j] : bd;
      bj = better ? j : bj;
    }
    int bm = lane + bj * 64;
#pragma unroll
    for (int off = 32; off; off >>= 1) {
      const float od = __shfl_xor(bd, off);
      const int om = __shfl_xor(bm, off);
      if (od < bd || (od == bd && om < bm)) { bd = od; bm = om; }
    }
    if (lane == 0) orow[s] = bm;
#pragma unroll
    for (int j = 0; j < CH; ++j)
      if (bm == lane + j * 64) d[j] = FLT_MAX;
  }
}

__global__ void k_transpose(const float* __restrict__ in, float* __restrict__ out) {
  int i = blockIdx.x * 256 + threadIdx.x;
  if (i >= BB * NP0 * 3) return;
  int dd = i % 3, tt = (i / 3) % NP0, b = i / (3 * NP0);
  out[i] = in[((size_t)b * 3 + dd) * NP0 + tt];
}

__global__ void k_conv_surface(const float* __restrict__ v, const int* __restrict__ idx,
                               const float* __restrict__ dirs, float* __restrict__ out,
                               int N, int M) {
  __shared__ float su[KNB_ * 3];
  int b = blockIdx.y, n = blockIdx.x, c = threadIdx.x;
  const float* vb = v + (size_t)b * VS0;
  float cx = vb[n * 3], cy = vb[n * 3 + 1], cz = vb[n * 3 + 2];
  const int* irow = idx + ((size_t)b * N + n) * KNB_;
  if (c < KNB_) {
    int j = irow[c];
    float dx = vb[j * 3] - cx, dy = vb[j * 3 + 1] - cy, dz = vb[j * 3 + 2] - cz;
    float inv = 1.f / fmaxf(sqrtf(dx * dx + dy * dy + dz * dz), 1e-12f);
    su[c * 3] = dx * inv; su[c * 3 + 1] = dy * inv; su[c * 3 + 2] = dz * inv;
  }
  __syncthreads();
  float d0 = dirs[c], d1 = dirs[M + c], d2 = dirs[2 * M + c];
  float inv = 1.f / fmaxf(sqrtf(d0 * d0 + d1 * d1 + d2 * d2), 1e-12f);
  d0 *= inv; d1 *= inv; d2 *= inv;
  float acc = 0.f;
  for (int k = 0; k < KNB_; ++k) {
    float th = fmaxf(su[k * 3] * d0 + su[k * 3 + 1] * d1 + su[k * 3 + 2] * d2, 0.f);
    acc = fmaxf(acc, th);
  }
  out[((size_t)b * N + n) * M + c] = acc;
}

__global__ void k_conv_layer(const float* __restrict__ v, const int* __restrict__ idx,
                             const float* __restrict__ dirs, const float* __restrict__ fout,
                             float* __restrict__ out, int N, int C) {
  __shared__ float su[KNB_ * 3];
  __shared__ int sidx[KNB_];
  int b = blockIdx.y, n = blockIdx.x, c = threadIdx.x;
  const float* vb = v + (size_t)b * VS0;
  float cx = vb[n * 3], cy = vb[n * 3 + 1], cz = vb[n * 3 + 2];
  const int* irow = idx + ((size_t)b * N + n) * KNB_;
  if (c < KNB_) {
    int j = irow[c]; sidx[c] = j;
    float dx = vb[j * 3] - cx, dy = vb[j * 3 + 1] - cy, dz = vb[j * 3 + 2] - cz;
    float inv = 1.f / fmaxf(sqrtf(dx * dx + dy * dy + dz * dz), 1e-12f);
    su[c * 3] = dx * inv; su[c * 3 + 1] = dy * inv; su[c * 3 + 2] = dz * inv;
  }
  __syncthreads();
  float d0 = dirs[c], d1 = dirs[C + c], d2 = dirs[2 * C + c];
  float inv = 1.f / fmaxf(sqrtf(d0 * d0 + d1 * d1 + d2 * d2), 1e-12f);
  d0 *= inv; d1 *= inv; d2 *= inv;
  const float* fb = fout + (size_t)b * N * 2 * C;
  float acc = -FLT_MAX;
  for (int k = 0; k < KNB_; ++k) {
    float th = fmaxf(su[k * 3] * d0 + su[k * 3 + 1] * d1 + su[k * 3 + 2] * d2, 0.f);
    float fs = fb[(size_t)sidx[k] * 2 * C + C + c];
    acc = fmaxf(acc, th * fs);
  }
  out[((size_t)b * N + n) * C + c] = fb[(size_t)n * 2 * C + c] + acc;
}

// ===========================================================================
// BN / rowstat / xsub / pool / misc
// ===========================================================================
__global__ void k_bn_part(const float* __restrict__ x, int rows, int C, float* __restrict__ part) {
  const int blk = blockIdx.x;
  const int chunk = rows / 64;
  const int r0 = blk * chunk;
  const int c0 = threadIdx.x, c1 = threadIdx.x + 256;
  float s0 = 0, s20 = 0, s1 = 0, s21 = 0;
  for (int r = 0; r < chunk; ++r) {
    const float* row = x + (size_t)(r0 + r) * C;
    if (c0 < C) { float v = row[c0]; s0 += v; s20 += v * v; }
    if (c1 < C) { float v = row[c1]; s1 += v; s21 += v * v; }
  }
  float* p = part + (size_t)blk * 1024;
  if (c0 < C) { p[c0] = s0; p[512 + c0] = s20; }
  if (c1 < C) { p[c1] = s1; p[512 + c1] = s21; }
}

__global__ void k_bn_fin(const float* __restrict__ part, int rows, int C, float* __restrict__ stats) {
  int c = blockIdx.x * 256 + threadIdx.x;
  if (c >= C) return;
  float s = 0, s2 = 0;
  for (int b2 = 0; b2 < 64; ++b2) { s += part[b2 * 1024 + c]; s2 += part[b2 * 1024 + 512 + c]; }
  float m = s / rows;
  float var = s2 / rows - m * m;
  stats[c] = m;
  stats[C + c] = rsqrtf(var + 1e-5f);
}

template <bool ADD>
__global__ void k_bn_apply(const float* __restrict__ x, const float* __restrict__ stats,
                           const float* __restrict__ g, const float* __restrict__ bb,
                           const float* __restrict__ base, float* __restrict__ outf,
                           u16* __restrict__ ph, u16* __restrict__ pl, int total, int C) {
  int i = blockIdx.x * 256 + threadIdx.x;
  if (i >= total) return;
  int c = i % C;
  float v = (x[i] - stats[c]) * stats[C + c] * g[c] + bb[c];
  v = fmaxf(v, 0.f);
  float r = ADD ? base[i] + v : v;
  outf[i] = r;
  u16 h = f2bf(r);
  ph[i] = h;
  pl[i] = f2bf(r - bf2f(h));
}

// per-row max and 1/sum(exp(row - max)) of S (row-major coalesced reads)
__global__ void k_rowstat(const float* __restrict__ S, int N,
                          float* __restrict__ mx, float* __restrict__ inv) {
  extern __shared__ float row[];
  __shared__ float red[256];
  int n = blockIdx.x, g = blockIdx.y;
  const float* Sb = S + ((size_t)g * N + n) * N;
  float lmax = -FLT_MAX;
  for (int m = threadIdx.x; m < N; m += 256) { float v = Sb[m]; row[m] = v; lmax = fmaxf(lmax, v); }
  red[threadIdx.x] = lmax; __syncthreads();
  for (int o = 128; o; o >>= 1) {
    if (threadIdx.x < o) red[threadIdx.x] = fmaxf(red[threadIdx.x], red[threadIdx.x + o]);
    __syncthreads();
  }
  float m0 = red[0]; __syncthreads();
  float ls = 0.f;
  for (int m = threadIdx.x; m < N; m += 256) ls += __expf(row[m] - m0);
  red[threadIdx.x] = ls; __syncthreads();
  for (int o = 128; o; o >>= 1) {
    if (threadIdx.x < o) red[threadIdx.x] += red[threadIdx.x + o];
    __syncthreads();
  }
  if (threadIdx.x == 0) {
    mx[(size_t)g * N + n] = m0;
    inv[(size_t)g * N + n] = 1.f / red[0];
  }
}

// xs = fm - (sum_ks xr)/(1e-9 + sum_ks cpart)  -> planes
__global__ void k_xsub_sk(const float* __restrict__ xrpart, const float* __restrict__ cpart,
                          const float* __restrict__ fm, u16* __restrict__ xsh,
                          u16* __restrict__ xsl, int Npts, int C, int KS, int gbase, int gg) {
  int i = blockIdx.x * 256 + threadIdx.x;
  int per = Npts * C;
  if (i >= gg * per) return;
  int zb = i / per, rem = i - zb * per;
  int n = rem / C;
  float s = 0, cs = 0;
  for (int k2 = 0; k2 < KS; ++k2) {
    s += xrpart[(size_t)(zb * KS + k2) * per + rem];
    cs += cpart[(size_t)(zb * KS + k2) * Npts + n];
  }
  int b = gbase + zb;
  float val = fm[(size_t)b * per + rem] - s / (1e-9f + cs);
  u16 h = f2bf(val);
  xsh[(size_t)b * per + rem] = h;
  xsl[(size_t)b * per + rem] = f2bf(val - bf2f(h));
}

__global__ void k_pool(const u16* __restrict__ fh, const u16* __restrict__ fl,
                       const int* __restrict__ idxp, u16* __restrict__ oh,
                       u16* __restrict__ ol, int Nin, int pn, int C) {
  int b = blockIdx.y, p = blockIdx.x, c = threadIdx.x;
  const int* ir = idxp + ((size_t)b * pn + p) * 4;
  const u16* fhb = fh + (size_t)b * Nin * C;
  const u16* flb = fl + (size_t)b * Nin * C;
  float acc = -FLT_MAX;
#pragma unroll
  for (int k = 0; k < 4; ++k) {
    size_t o = (size_t)ir[k] * C + c;
    acc = fmaxf(acc, bf2f(fhb[o]) + bf2f(flb[o]));
  }
  u16 h = f2bf(acc);
  oh[((size_t)b * pn + p) * C + c] = h;
  ol[((size_t)b * pn + p) * C + c] = f2bf(acc - bf2f(h));
}

__global__ void k_maxn(const u16* __restrict__ fh, const u16* __restrict__ fl,
                       float* __restrict__ out, int N, int C) {
  int b = blockIdx.y;
  int c = blockIdx.x * 256 + threadIdx.x;
  if (c >= C) return;
  float acc = -FLT_MAX;
  for (int n = 0; n < N; ++n) {
    size_t o = ((size_t)b * N + n) * C + c;
    acc = fmaxf(acc, bf2f(fh[o]) + bf2f(fl[o]));
  }
  out[(size_t)b * C + c] = acc;
}

__global__ void k_nearest(const float* __restrict__ v, int Ns, int* __restrict__ out) {
  extern __shared__ float sp[];
  int b = blockIdx.y;
  const float* vsb = v + (size_t)b * VS0;
  for (int i = threadIdx.x; i < Ns * 3; i += 256) sp[i] = vsb[i];
  __syncthreads();
  int t = blockIdx.x * 256 + threadIdx.x;
  float tx = vsb[t * 3], ty = vsb[t * 3 + 1], tz = vsb[t * 3 + 2];
  float bd = FLT_MAX; int bi = 0;
#pragma unroll 4
  for (int s = 0; s < Ns; ++s) {
    float dx = sp[s * 3] - tx, dy = sp[s * 3 + 1] - ty, dz = sp[s * 3 + 2] - tz;
    float dd = dx * dx + dy * dy + dz * dz;
    if (dd < bd) { bd = dd; bi = s; }
  }
  out[(size_t)b * NP0 + t] = bi;
}

__global__ void k_glob1(const float* __restrict__ fglob, const float* __restrict__ onehot,
                        const float* __restrict__ h1w, const float* __restrict__ h1b,
                        float* __restrict__ out) {
  int b = blockIdx.x, j = threadIdx.x;
  float s = h1b[j];
  for (int i = 0; i < 512; ++i) s = fmaf(fglob[b * 512 + i], h1w[(size_t)(1280 + i) * 512 + j], s);
  for (int i = 0; i < 16; ++i) s = fmaf(onehot[b * 16 + i], h1w[(size_t)(1792 + i) * 512 + j], s);
  out[b * 512 + j] = s;
}

__global__ void k_logsoftmax(float* __restrict__ x, int rows, int C) {
  int r = blockIdx.x * 4 + (threadIdx.x >> 6);
  int lane = threadIdx.x & 63;
  if (r >= rows) return;
  float* xr = x + (size_t)r * C;
  float v = (lane < C) ? xr[lane] : -FLT_MAX;
  float mx = v;
  for (int o = 32; o; o >>= 1) mx = fmaxf(mx, __shfl_xor(mx, o));
  float e = (lane < C) ? __expf(v - mx) : 0.f;
  float s = e;
  for (int o = 32; o; o >>= 1) s += __shfl_xor(s, o);
  float lse = mx + logf(s);
  if (lane < C) xr[lane] = v - lse;
}

// ===========================================================================
// host
// ===========================================================================
struct Ws {
  float *v0, *fglob, *glob1, *cols, *cpart, *stats, *bpart, *xcur, *xr, *S, *pre, *fout, *x1;
  int *idx0, *idxp0, *idx1, *idxp1, *idx2, *ni1, *ni2;
  u16 *wh, *wl;
  u16 *fm0h, *fm0l, *fm1h, *fm1l, *fm2h, *fm2l, *fm3h, *fm3l, *fm4h, *fm4l;
  u16 *fmp1h, *fmp1l, *fmp2h, *fmp2l, *qh, *ql, *vmh, *vml, *xsh, *xsl;
  u16 *x1h, *x1l, *x2b;
};

static void run_sa(hipStream_t st, Ws& ws, int N, int C, int Q, int bg, int KS,
                   const u16* qkh, const u16* qkl, const u16* vwh, const u16* vwl,
                   const u16* twh, const u16* twl,
                   const float* vb, const float* tb, const float* g, const float* be,
                   u16* xh, u16* xl) {
  const long sx = (long)N * C;
  // q = x qk^T -> planes [M,Q]
  mmp<64, 0, 0, 1, false, false>(st, xh, xl, qkh, qkl, nullptr, ws.qh, ws.ql,
                                 N, Q, C, sx, 0, (long)N * Q, BB, 1);
  // vm = x vw^T + vb -> transposed planes [C][seq]
  mmp<64, 0, 1, 2, false, false>(st, xh, xl, vwh, vwl, vb, ws.vmh, ws.vml,
                                 N, C, C, sx, 0, sx, BB, 1);
  const int per = N * C;
  float* mxv = ws.cols;
  float* invv = ws.cols + (size_t)bg * N;
  for (int g0 = 0; g0 < BB; g0 += bg) {
    const u16* qgh = ws.qh + (size_t)g0 * N * Q;
    const u16* qgl = ws.ql + (size_t)g0 * N * Q;
    // S = q q^T (f32, symmetric)
    if (N == NP0)
      mmp<128, 0, 0, 0, false, false>(st, qgh, qgl, qgh, qgl, nullptr, ws.S, nullptr,
                                      N, N, Q, (long)N * Q, (long)N * Q, (long)N * N, bg, 1);
    else
      mmp<64, 0, 0, 0, false, false>(st, qgh, qgl, qgh, qgl, nullptr, ws.S, nullptr,
                                     N, N, Q, (long)N * Q, (long)N * Q, (long)N * N, bg, 1);
    // per-row max + inv-sum
    k_rowstat<<<dim3(N, bg), 256, N * 4, st>>>(ws.S, N, mxv, invv);
    // xr = attn^T @ vm  (AMODE=3: row-major S + exp transform; colsum -> cpart)
    mmp<64, 3, 0, 0, false, false>(st, ws.S, nullptr,
                                   ws.vmh + (size_t)g0 * per, ws.vml + (size_t)g0 * per,
                                   nullptr, ws.xr, nullptr, N, C, N,
                                   (long)N * N, sx, (long)N * C, bg, KS,
                                   nullptr, 0, mxv, invv, ws.cpart);
    k_xsub_sk<<<(bg * per + 255) / 256, 256, 0, st>>>(ws.xr, ws.cpart, ws.xcur,
                                                      ws.xsh, ws.xsl, N, C, KS, g0, bg);
  }
  // pre = xs tw^T + tb -> f32
  mmp<64, 0, 1, 0, false, false>(st, ws.xsh, ws.xsl, twh, twl, tb, ws.pre, nullptr,
                                 N, C, C, sx, 0, sx, BB, 1);
  k_bn_part<<<64, 256, 0, st>>>(ws.pre, BB * N, C, ws.bpart);
  k_bn_fin<<<(C + 255) / 256, 256, 0, st>>>(ws.bpart, BB * N, C, ws.stats);
  k_bn_apply<true><<<(BB * per + 255) / 256, 256, 0, st>>>(ws.pre, ws.stats, g, be,
                                                           ws.xcur, ws.xcur, xh, xl, BB * per, C);
}

static void run_conv(hipStream_t st, Ws& ws, const u16* finh, const u16* finl, int Cin,
                     const u16* cwh, const u16* cwl, const float* bias, const float* dirs,
                     const int* idx, int N, int C,
                     const float* bng, const float* bnb, bool doBN, u16* fmh, u16* fml) {
  if (N == NP0)
    mmp<128, 0, 1, 0, false, false>(st, finh, finl, cwh, cwl, bias, ws.fout, nullptr,
                                    N, 2 * C, Cin, (long)N * Cin, 0, (long)N * 2 * C, BB, 1);
  else
    mmp<64, 0, 1, 0, false, false>(st, finh, finl, cwh, cwl, bias, ws.fout, nullptr,
                                   N, 2 * C, Cin, (long)N * Cin, 0, (long)N * 2 * C, BB, 1);
  k_conv_layer<<<dim3(N, BB), C, 0, st>>>(ws.v0, idx, dirs, ws.fout, ws.xcur, N, C);
  if (doBN) {
    k_bn_part<<<64, 256, 0, st>>>(ws.xcur, BB * N, C, ws.bpart);
    k_bn_fin<<<(C + 255) / 256, 256, 0, st>>>(ws.bpart, BB * N, C, ws.stats);
    k_bn_apply<false><<<(BB * N * C + 255) / 256, 256, 0, st>>>(
        ws.xcur, ws.stats, bng, bnb, nullptr, ws.xcur, fmh, fml, BB * N * C, C);
  } else {
    k_split4<false><<<(BB * N * C / 4 + 255) / 256, 256, 0, st>>>(ws.xcur, fmh, fml, BB * N * C / 4);
  }
}

extern "C" void kernel_launch(void* const* d_in, const int* in_sizes, int n_in,
                              void* d_out, int out_size, void* d_ws, size_t ws_size,
                              hipStream_t stream) {
  auto in = [&](int i) { return (const float*)d_in[i]; };
  char* p = (char*)d_ws;
  Ws ws;
  ws.v0 = (float*)(p + O_V0);
  ws.idx0 = (int*)(p + O_IDX0); ws.idxp0 = (int*)(p + O_IDXP0);
  ws.idx1 = (int*)(p + O_IDX1); ws.idxp1 = (int*)(p + O_IDXP1);
  ws.idx2 = (int*)(p + O_IDX2);
  ws.ni1 = (int*)(p + O_NI1); ws.ni2 = (int*)(p + O_NI2);
  ws.fglob = (float*)(p + O_FGLOB); ws.glob1 = (float*)(p + O_GLOB1);
  ws.cols = (float*)(p + O_COLS); ws.cpart = (float*)(p + O_CPART);
  ws.stats = (float*)(p + O_STATS); ws.bpart = (float*)(p + O_BPART);
  ws.xcur = (float*)(p + O_XCUR); ws.xr = (float*)(p + O_XR);
  ws.S = (float*)(p + O_AREA); ws.pre = (float*)(p + O_AREA);
  ws.fout = (float*)(p + O_AREA); ws.x1 = (float*)(p + O_AREA);
  char* pl = p + O_PL;
  ws.wh = (u16*)(pl + PL_WH); ws.wl = (u16*)(pl + PL_WL);
  ws.fm0h = (u16*)(pl + PL_FM0H); ws.fm0l = (u16*)(pl + PL_FM0L);
  ws.fm1h = (u16*)(pl + PL_FM1H); ws.fm1l = (u16*)(pl + PL_FM1L);
  ws.fm2h = (u16*)(pl + PL_FM2H); ws.fm2l = (u16*)(pl + PL_FM2L);
  ws.fm3h = (u16*)(pl + PL_FM3H); ws.fm3l = (u16*)(pl + PL_FM3L);
  ws.fm4h = (u16*)(pl + PL_FM4H); ws.fm4l = (u16*)(pl + PL_FM4L);
  ws.fmp1h = (u16*)(pl + PL_FMP1H); ws.fmp1l = (u16*)(pl + PL_FMP1L);
  ws.fmp2h = (u16*)(pl + PL_FMP2H); ws.fmp2l = (u16*)(pl + PL_FMP2L);
  ws.qh = (u16*)(pl + PL_QH); ws.ql = (u16*)(pl + PL_QL);
  ws.vmh = (u16*)(pl + PL_VMH); ws.vml = (u16*)(pl + PL_VML);
  ws.xsh = (u16*)(pl + PL_XSH); ws.xsl = (u16*)(pl + PL_XSL);
  ws.x1h = (u16*)(pl + PL_X1H); ws.x1l = (u16*)(pl + PL_X1L);
  ws.x2b = (u16*)(p + O_XCUR);
  float* out = (float*)d_out;

  // ---- one-time weight plane split (pre-transposed to [N,K]) ----
  SplitJobs jobs;
  size_t wq[26];
  size_t off = 0;
  int ji = 0;
  auto addjob = [&](const float* s, int K, int N, int trans) {
    int n = K * N;
    jobs.j[ji] = {s, ws.wh + off, ws.wl + off, n, K, N, trans};
    wq[ji] = off; off += (size_t)n; ++ji;
  };
  addjob(in(5), 128, 32, 0);  addjob(in(6), 128, 128, 0);  addjob(in(8), 128, 128, 0);
  addjob(in(17), 128, 32, 0); addjob(in(18), 128, 128, 0); addjob(in(20), 128, 128, 0);
  addjob(in(29), 256, 64, 0); addjob(in(30), 256, 256, 0); addjob(in(32), 256, 256, 0);
  addjob(in(41), 256, 64, 0); addjob(in(42), 256, 256, 0); addjob(in(44), 256, 256, 0);
  addjob(in(51), 512, 128, 0); addjob(in(52), 512, 512, 0); addjob(in(54), 512, 512, 0);
  addjob(in(12), 128, 256, 1);
  addjob(in(24), 128, 512, 1);
  addjob(in(36), 256, 512, 1);
  addjob(in(48), 256, 1024, 1);
  addjob(in(58) + 0 * 512, 128, 512, 1);
  addjob(in(58) + (size_t)128 * 512, 128, 512, 1);
  addjob(in(58) + (size_t)256 * 512, 256, 512, 1);
  addjob(in(58) + (size_t)512 * 512, 256, 512, 1);
  addjob(in(58) + (size_t)768 * 512, 512, 512, 1);
  addjob(in(60), 512, 512, 1);
  addjob(in(62), 512, 50, 1);
  k_splitjobs<<<dim3(32, 26), 256, 0, stream>>>(jobs);
  auto W = [&](int i) { return ws.wh + wq[i]; };
  auto Wl = [&](int i) { return ws.wl + wq[i]; };

  // ---- geometry ----
  k_transpose<<<(BB * NP0 * 3 + 255) / 256, 256, 0, stream>>>(in(0), ws.v0);
  k_knn2<NP0, KNB_><<<dim3(NP0 / 4, BB), 256, 0, stream>>>(ws.v0, NP0, ws.idx0);

  // ---- conv0 + bn0 ----
  k_conv_surface<<<dim3(NP0, BB), 128, 0, stream>>>(ws.v0, ws.idx0, in(2), ws.xcur, NP0, 128);
  k_bn_part<<<64, 256, 0, stream>>>(ws.xcur, BB * NP0, 128, ws.bpart);
  k_bn_fin<<<1, 256, 0, stream>>>(ws.bpart, BB * NP0, 128, ws.stats);
  k_bn_apply<false><<<(BB * NP0 * 128 + 255) / 256, 256, 0, stream>>>(
      ws.xcur, ws.stats, in(3), in(4), nullptr, ws.xcur, ws.fm0h, ws.fm0l, BB * NP0 * 128, 128);

  // ---- sa0, conv1+bn1, sa1 ----
  run_sa(stream, ws, NP0, 128, 32, 1, 4, W(0), Wl(0), W(1), Wl(1), W(2), Wl(2),
         in(7), in(9), in(10), in(11), ws.fm0h, ws.fm0l);
  run_conv(stream, ws, ws.fm0h, ws.fm0l, 128, W(15), Wl(15), in(13), in(14), ws.idx0,
           NP0, 128, in(15), in(16), true, ws.fm1h, ws.fm1l);
  run_sa(stream, ws, NP0, 128, 32, 1, 4, W(3), Wl(3), W(4), Wl(4), W(5), Wl(5),
         in(19), in(21), in(22), in(23), ws.fm1h, ws.fm1l);

  // ---- pool1, knn1 ----
  k_knn2<NP0, 4><<<dim3(NP1 / 4, BB), 256, 0, stream>>>(ws.v0, NP1, ws.idxp0);
  k_pool<<<dim3(NP1, BB), 128, 0, stream>>>(ws.fm1h, ws.fm1l, ws.idxp0,
                                            ws.fmp1h, ws.fmp1l, NP0, NP1, 128);
  k_knn2<NP1, KNB_><<<dim3(NP1 / 4, BB), 256, 0, stream>>>(ws.v0, NP1, ws.idx1);

  // ---- conv2+bn2, sa2, conv3+bn3, sa3 ----
  run_conv(stream, ws, ws.fmp1h, ws.fmp1l, 128, W(16), Wl(16), in(25), in(26), ws.idx1,
           NP1, 256, in(27), in(28), true, ws.fm2h, ws.fm2l);
  run_sa(stream, ws, NP1, 256, 64, 8, 1, W(6), Wl(6), W(7), Wl(7), W(8), Wl(8),
         in(31), in(33), in(34), in(35), ws.fm2h, ws.fm2l);
  run_conv(stream, ws, ws.fm2h, ws.fm2l, 256, W(17), Wl(17), in(37), in(38), ws.idx1,
           NP1, 256, in(39), in(40), true, ws.fm3h, ws.fm3l);
  run_sa(stream, ws, NP1, 256, 64, 8, 1, W(9), Wl(9), W(10), Wl(10), W(11), Wl(11),
         in(43), in(45), in(46), in(47), ws.fm3h, ws.fm3l);

  // ---- pool2, knn2, conv4 (no bn), sa4 ----
  k_knn2<NP1, 4><<<dim3(NP2 / 4, BB), 256, 0, stream>>>(ws.v0, NP2, ws.idxp1);
  k_pool<<<dim3(NP2, BB), 256, 0, stream>>>(ws.fm3h, ws.fm3l, ws.idxp1,
                                            ws.fmp2h, ws.fmp2l, NP1, NP2, 256);
  k_knn2<NP2, KNB_><<<dim3(NP2 / 4, BB), 256, 0, stream>>>(ws.v0, NP2, ws.idx2);
  run_conv(stream, ws, ws.fmp2h, ws.fmp2l, 256, W(18), Wl(18), in(49), in(50), ws.idx2,
           NP2, 512, nullptr, nullptr, false, ws.fm4h, ws.fm4l);
  run_sa(stream, ws, NP2, 512, 128, 8, 2, W(12), Wl(12), W(13), Wl(13), W(14), Wl(14),
         in(53), in(55), in(56), in(57), ws.fm4h, ws.fm4l);

  // ---- global max, nearest, head ----
  k_maxn<<<dim3(2, BB), 256, 0, stream>>>(ws.fm4h, ws.fm4l, ws.fglob, NP2, 512);
  k_nearest<<<dim3(NP0 / 256, BB), 256, NP1 * 3 * 4, stream>>>(ws.v0, NP1, ws.ni1);
  k_nearest<<<dim3(NP0 / 256, BB), 256, NP2 * 3 * 4, stream>>>(ws.v0, NP2, ws.ni2);
  k_glob1<<<BB, 512, 0, stream>>>(ws.fglob, in(1), in(58), in(59), ws.glob1);

  for (int hf = 0; hf < 2; ++hf) {
    const int b0 = hf * 4;
    // x1 = glob1 row-bias (BIASM=2) + 5 accumulating segment GEMMs
    mmp<128, 0, 2, 0, false, false>(stream, ws.fm0h + (size_t)b0 * NP0 * 128,
        ws.fm0l + (size_t)b0 * NP0 * 128, W(19), Wl(19), ws.glob1 + b0 * 512, ws.x1, nullptr,
        NP0, 512, 128, (long)NP0 * 128, 0, (long)NP0 * 512, 4, 1);
    mmp<128, 0, 0, 0, true, false>(stream, ws.fm1h + (size_t)b0 * NP0 * 128,
        ws.fm1l + (size_t)b0 * NP0 * 128, W(20), Wl(20), nullptr, ws.x1, nullptr,
        NP0, 512, 128, (long)NP0 * 128, 0, (long)NP0 * 512, 4, 1);
    mmp<128, 0, 0, 0, true, true>(stream, ws.fm2h + (size_t)b0 * NP1 * 256,
        ws.fm2l + (size_t)b0 * NP1 * 256, W(21), Wl(21), nullptr, ws.x1, nullptr,
        NP0, 512, 256, (long)NP1 * 256, 0, (long)NP0 * 512, 4, 1,
        ws.ni1 + (size_t)b0 * NP0, NP0);
    mmp<128, 0, 0, 0, true, true>(stream, ws.fm3h + (size_t)b0 * NP1 * 256,
        ws.fm3l + (size_t)b0 * NP1 * 256, W(22), Wl(22), nullptr, ws.x1, nullptr,
        NP0, 512, 256, (long)NP1 * 256, 0, (long)NP0 * 512, 4, 1,
        ws.ni1 + (size_t)b0 * NP0, NP0);
    mmp<128, 0, 0, 0, true, true>(stream, ws.fm4h + (size_t)b0 * NP2 * 512,
        ws.fm4l + (size_t)b0 * NP2 * 512, W(23), Wl(23), nullptr, ws.x1, nullptr,
        NP0, 512, 512, (long)NP2 * 512, 0, (long)NP0 * 512, 4, 1,
        ws.ni2 + (size_t)b0 * NP0, NP0);
    k_split4<true><<<(4 * NP0 * 512 / 4 + 255) / 256, 256, 0, stream>>>(
        ws.x1, ws.x1h, ws.x1l, 4 * NP0 * 512 / 4);
    mmp<128, 0, 1, 3, false, false>(stream, ws.x1h, ws.x1l, W(24), Wl(24), in(61),
        ws.x2b, nullptr, NP0, 512, 512, (long)NP0 * 512, 0, (long)NP0 * 512, 4, 1);
    mmp<64, 2, 1, 0, false, false>(stream, ws.x2b, nullptr, W(25), Wl(25), in(63),
        out + (size_t)b0 * NP0 * 50, nullptr, NP0, 50, 512,
        (long)NP0 * 512, 0, (long)NP0 * 50, 4, 1);
  }

  k_logsoftmax<<<(BB * NP0) / 4, 256, 0, stream>>>(out, BB * NP0, 50);
}

// Round 7
// 2149.066 us; speedup vs baseline: 1.7761x; 1.1159x over previous
//
#include <hip/hip_runtime.h>
#include <cfloat>

// ---------------------------------------------------------------------------
// GCN3D forward. Split-plane bf16 MFMA GEMMs (Dekker, f32-grade accuracy).
// Round-7: K=50 KNN rewritten as exact bitwise radix-select (bit-plane
// transpose + 31-bit descent + ballot compaction) — cost independent of K,
// ~5x fewer VALU ops than 50x argmin. Exact same neighbor sets.
// B=8, N=2048->512->128, K_NB=50. Workspace 93,814,784 B.
// ---------------------------------------------------------------------------

#define BB   8
#define NP0  2048
#define NP1  512
#define NP2  128
#define KNB_ 50
#define VS0  (NP0 * 3)

typedef __attribute__((ext_vector_type(8))) short short8_t;
typedef __attribute__((ext_vector_type(4))) short short4_t;
typedef __attribute__((ext_vector_type(4))) float f32x4_t;
typedef unsigned short u16;

// ---------------- workspace layout (byte offsets) ----------------
static constexpr size_t O_V0    = 0;
static constexpr size_t O_IDX0  = 196608;
static constexpr size_t O_IDXP0 = 3473408;
static constexpr size_t O_IDX1  = 3538944;
static constexpr size_t O_IDXP1 = 4358144;
static constexpr size_t O_IDX2  = 4374528;
static constexpr size_t O_NI1   = 4579328;
static constexpr size_t O_NI2   = 4644864;
static constexpr size_t O_FGLOB = 4710400;
static constexpr size_t O_GLOB1 = 4726784;
static constexpr size_t O_COLS  = 4743168;   // mx / inv vectors (64KB)
static constexpr size_t O_CPART = 4808704;   // colsum parts (512KB)
static constexpr size_t O_STATS = 5332992;
static constexpr size_t O_BPART = 5337088;
static constexpr size_t O_XCUR  = 5599232;   // 8,388,608 f32 activation scratch
static constexpr size_t O_XR    = 13987840;  // 4,194,304 xr ksplit parts
static constexpr size_t O_PL    = 18182144;  // 58,855,424 plane pools
static constexpr size_t O_AREA  = 77037568;  // 16,777,216 S / fout / pre / x1half
// end = 93,814,784

static constexpr size_t PL_WH    = 0;
static constexpr size_t PL_WL    = 4786176;
static constexpr size_t PL_FM0H  = 9572352;
static constexpr size_t PL_FM0L  = 13766656;
static constexpr size_t PL_FM1H  = 17960960;
static constexpr size_t PL_FM1L  = 22155264;
static constexpr size_t PL_FM2H  = 26349568;
static constexpr size_t PL_FM2L  = 28446720;
static constexpr size_t PL_FM3H  = 30543872;
static constexpr size_t PL_FM3L  = 32641024;
static constexpr size_t PL_FM4H  = 34738176;
static constexpr size_t PL_FM4L  = 35786752;
static constexpr size_t PL_FMP1H = 36835328;
static constexpr size_t PL_FMP1L = 37883904;
static constexpr size_t PL_FMP2H = 38932480;
static constexpr size_t PL_FMP2L = 39456768;
static constexpr size_t PL_QH    = 39981056;
static constexpr size_t PL_QL    = 41029632;
static constexpr size_t PL_VMH   = 42078208;
static constexpr size_t PL_VML   = 46272512;
static constexpr size_t PL_XSH   = 50466816;
static constexpr size_t PL_XSL   = 54661120;
static constexpr size_t PL_X1H = PL_VMH;   // head aliases (phase-disjoint)
static constexpr size_t PL_X1L = PL_XSH;

__device__ __forceinline__ float bf2f(u16 h) {
  union { unsigned u; float f; } c; c.u = ((unsigned)h) << 16; return c.f;
}
__device__ __forceinline__ u16 f2bf(float f) {
  union { float f; unsigned u; } c; c.f = f;
  return (u16)((c.u + 0x7fffu + ((c.u >> 16) & 1u)) >> 16);
}

// ===========================================================================
// Plane GEMM (unchanged from round 6).
// ===========================================================================
template <int TM, int AMODE, int BIASM, int OUTM, bool ACC, bool GIDX>
__global__ __launch_bounds__(256) void k_mmp(
    const void* __restrict__ A1, const void* __restrict__ A2,
    const u16* __restrict__ Bh0, const u16* __restrict__ Bl0,
    const float* __restrict__ bias, void* __restrict__ C1, void* __restrict__ C2,
    int M, int N, int K, long sA, long sB, long sC, int ksplit,
    const int* __restrict__ gidx, long sG,
    const float* __restrict__ mxv, const float* __restrict__ invv,
    float* __restrict__ cpart) {
  constexpr int RT = TM / 32;
  constexpr int CT = TM / 32;
  __shared__ u16 Ah[TM][40], Bh[TM][40], Bl[TM][40];
  __shared__ u16 Al[(AMODE == 2) ? 1 : TM][40];
  const int z = blockIdx.z;
  const int zb = z / ksplit, ks = z - zb * ksplit;
  const int kchunk = K / ksplit;
  const int kl0 = ks * kchunk, kl1 = kl0 + kchunk;
  const int m0 = blockIdx.x * TM, n0 = blockIdx.y * TM;
  const int t = threadIdx.x;
  const int lane = t & 63, w = t >> 6;
  const int wr = (w >> 1) * (TM / 2), wc = (w & 1) * (TM / 2);
  const int frow = lane & 15, koff = (lane >> 4) * 8;
  f32x4_t acc[RT][CT];
#pragma unroll
  for (int i = 0; i < RT; ++i)
#pragma unroll
    for (int j = 0; j < CT; ++j) acc[i][j] = (f32x4_t){0.f, 0.f, 0.f, 0.f};

  const u16* Ahg = (const u16*)A1 + (size_t)zb * sA;
  const u16* Alg = (const u16*)A2 + (size_t)zb * sA;
  const float* Sfg = (const float*)A1 + (size_t)zb * sA;
  const u16* Bhg = Bh0 + (size_t)zb * sB;
  const u16* Blg = Bl0 + (size_t)zb * sB;
  const float* mxg = (AMODE == 3) ? mxv + (size_t)zb * K : nullptr;
  const float* invg = (AMODE == 3) ? invv + (size_t)zb * K : nullptr;

  int ar, ac, arow = 0;
  if constexpr (TM == 128) { ar = t >> 1; ac = (t & 1) * 16; }
  else                     { ar = t >> 2; ac = (t & 3) * 8; }
  arow = m0 + ar;
  if constexpr (GIDX) arow = (gidx + (size_t)zb * sG)[arow];
  const int bn = ar, bc = ac;
  const bool bok = (n0 + bn) < N;
  const short8_t z8 = {0, 0, 0, 0, 0, 0, 0, 0};
  float csum = 0.f;

  for (int k0 = kl0; k0 < kl1; k0 += 32) {
    __syncthreads();
    if constexpr (AMODE == 0 || AMODE == 2) {
      const u16* s1 = Ahg + (size_t)arow * K + k0 + ac;
      if constexpr (TM == 128) {
        *(short8_t*)&Ah[ar][ac] = *(const short8_t*)s1;
        *(short8_t*)&Ah[ar][ac + 8] = *(const short8_t*)(s1 + 8);
        if constexpr (AMODE == 0) {
          const u16* s2 = Alg + (size_t)arow * K + k0 + ac;
          *(short8_t*)&Al[ar][ac] = *(const short8_t*)s2;
          *(short8_t*)&Al[ar][ac + 8] = *(const short8_t*)(s2 + 8);
        }
      } else {
        *(short8_t*)&Ah[ar][ac] = *(const short8_t*)s1;
        if constexpr (AMODE == 0)
          *(short8_t*)&Al[ar][ac] = *(const short8_t*)(Alg + (size_t)arow * K + k0 + ac);
      }
    } else {  // AMODE 3: symmetric-S attn transform (row-major, coalesced)
      const float* src = Sfg + (size_t)(m0 + ar) * K + k0 + ac;
      constexpr int JW = (TM == 128) ? 16 : 8;
#pragma unroll
      for (int j = 0; j < JW; ++j) {
        float v = __expf(src[j] - mxg[k0 + ac + j]) * invg[k0 + ac + j];
        csum += v;
        u16 h = f2bf(v);
        Ah[ar][ac + j] = h;
        Al[ar][ac + j] = f2bf(v - bf2f(h));
      }
    }
    {
      const u16* s1 = Bhg + (size_t)(n0 + bn) * K + k0 + bc;
      const u16* s2 = Blg + (size_t)(n0 + bn) * K + k0 + bc;
      if constexpr (TM == 128) {
        *(short8_t*)&Bh[bn][bc] = bok ? *(const short8_t*)s1 : z8;
        *(short8_t*)&Bh[bn][bc + 8] = bok ? *(const short8_t*)(s1 + 8) : z8;
        *(short8_t*)&Bl[bn][bc] = bok ? *(const short8_t*)s2 : z8;
        *(short8_t*)&Bl[bn][bc + 8] = bok ? *(const short8_t*)(s2 + 8) : z8;
      } else {
        *(short8_t*)&Bh[bn][bc] = bok ? *(const short8_t*)s1 : z8;
        *(short8_t*)&Bl[bn][bc] = bok ? *(const short8_t*)s2 : z8;
      }
    }
    __syncthreads();
    short8_t ah[RT], al[RT], bh[CT], bl[CT];
#pragma unroll
    for (int i = 0; i < RT; ++i) {
      const int r = wr + i * 16 + frow;
      ah[i] = *(const short8_t*)&Ah[r][koff];
      if constexpr (AMODE != 2) al[i] = *(const short8_t*)&Al[r][koff];
    }
#pragma unroll
    for (int i = 0; i < CT; ++i) {
      const int r = wc + i * 16 + frow;
      bh[i] = *(const short8_t*)&Bh[r][koff];
      bl[i] = *(const short8_t*)&Bl[r][koff];
    }
#pragma unroll
    for (int i = 0; i < RT; ++i)
#pragma unroll
      for (int j = 0; j < CT; ++j) {
        acc[i][j] = __builtin_amdgcn_mfma_f32_16x16x32_bf16(ah[i], bh[j], acc[i][j], 0, 0, 0);
        acc[i][j] = __builtin_amdgcn_mfma_f32_16x16x32_bf16(ah[i], bl[j], acc[i][j], 0, 0, 0);
        if constexpr (AMODE != 2)
          acc[i][j] = __builtin_amdgcn_mfma_f32_16x16x32_bf16(al[i], bh[j], acc[i][j], 0, 0, 0);
      }
  }

  if constexpr (AMODE == 3) {
    if (blockIdx.y == 0) {
      float c = csum;
      c += __shfl_xor(c, 1);
      if constexpr (TM == 64) c += __shfl_xor(c, 2);
      if ((t & ((TM == 64) ? 3 : 1)) == 0)
        cpart[(size_t)z * M + m0 + ar] = c;
    }
  }

  const int crow = (lane >> 4) * 4;
#pragma unroll
  for (int i = 0; i < RT; ++i) {
#pragma unroll
    for (int j = 0; j < CT; ++j) {
      const int gc = n0 + wc + j * 16 + frow;
      if (gc >= N) continue;
      float bv = 0.f;
      if constexpr (BIASM == 1) bv = bias[gc];
      if constexpr (BIASM == 2) bv = bias[(size_t)zb * N + gc];
      const int gr0 = m0 + wr + i * 16 + crow;
      if constexpr (OUTM == 0) {
        float* Cp = (float*)C1 + (size_t)z * sC;
#pragma unroll
        for (int q = 0; q < 4; ++q) {
          float vv = acc[i][j][q] + bv;
          if (ACC) vv += Cp[(size_t)(gr0 + q) * N + gc];
          Cp[(size_t)(gr0 + q) * N + gc] = vv;
        }
      } else if constexpr (OUTM == 1) {
        u16* Ph = (u16*)C1 + (size_t)z * sC;
        u16* Pl = (u16*)C2 + (size_t)z * sC;
#pragma unroll
        for (int q = 0; q < 4; ++q) {
          float vv = acc[i][j][q] + bv;
          u16 h = f2bf(vv);
          Ph[(size_t)(gr0 + q) * N + gc] = h;
          Pl[(size_t)(gr0 + q) * N + gc] = f2bf(vv - bf2f(h));
        }
      } else if constexpr (OUTM == 2) {
        u16* Ph = (u16*)C1 + (size_t)z * sC;
        u16* Pl = (u16*)C2 + (size_t)z * sC;
        short4_t h4, l4;
#pragma unroll
        for (int q = 0; q < 4; ++q) {
          float vv = acc[i][j][q] + bv;
          u16 h = f2bf(vv);
          h4[q] = (short)h;
          l4[q] = (short)f2bf(vv - bf2f(h));
        }
        *(short4_t*)(Ph + (size_t)gc * M + gr0) = h4;
        *(short4_t*)(Pl + (size_t)gc * M + gr0) = l4;
      } else {
        u16* Cb = (u16*)C1 + (size_t)z * sC;
#pragma unroll
        for (int q = 0; q < 4; ++q) {
          float vv = fmaxf(acc[i][j][q] + bv, 0.f);
          Cb[(size_t)(gr0 + q) * N + gc] = f2bf(vv);
        }
      }
    }
  }
}

template <int TM, int AMODE, int BIASM, int OUTM, bool ACC, bool GIDX>
static void mmp(hipStream_t st, const void* A1, const void* A2,
                const u16* Bh, const u16* Bl, const float* bias,
                void* C1, void* C2, int M, int N, int K,
                long sA, long sB, long sC, int Z, int ksplit,
                const int* gidx = nullptr, long sG = 0,
                const float* mxv = nullptr, const float* invv = nullptr,
                float* cpart = nullptr) {
  dim3 grid(M / TM, (N + TM - 1) / TM, Z * ksplit);
  k_mmp<TM, AMODE, BIASM, OUTM, ACC, GIDX><<<grid, 256, 0, st>>>(
      A1, A2, Bh, Bl, bias, C1, C2, M, N, K, sA, sB, sC, ksplit, gidx, sG,
      mxv, invv, cpart);
}

// ===========================================================================
// weight split + activation split
// ===========================================================================
struct SplitJob { const float* s; u16* dh; u16* dl; int n, K, N, trans; };
struct SplitJobs { SplitJob j[26]; };
__global__ void k_splitjobs(SplitJobs jobs) {
  SplitJob jb = jobs.j[blockIdx.y];
  for (int i = blockIdx.x * 256 + threadIdx.x; i < jb.n; i += gridDim.x * 256) {
    float v;
    if (jb.trans) { int k = i % jb.K, n = i / jb.K; v = jb.s[(size_t)k * jb.N + n]; }
    else v = jb.s[i];
    u16 h = f2bf(v);
    jb.dh[i] = h;
    jb.dl[i] = f2bf(v - bf2f(h));
  }
}

template <bool RELU>
__global__ void k_split4(const float* __restrict__ x, u16* __restrict__ ph,
                         u16* __restrict__ pl, int n4) {
  int i = blockIdx.x * 256 + threadIdx.x;
  if (i >= n4) return;
  float4 v = ((const float4*)x)[i];
  short4_t h4, l4;
  float vv[4] = {v.x, v.y, v.z, v.w};
#pragma unroll
  for (int q = 0; q < 4; ++q) {
    float f = RELU ? fmaxf(vv[q], 0.f) : vv[q];
    u16 h = f2bf(f);
    h4[q] = (short)h;
    l4[q] = (short)f2bf(f - bf2f(h));
  }
  *(short4_t*)(ph + (size_t)i * 4) = h4;
  *(short4_t*)(pl + (size_t)i * 4) = l4;
}

// ===========================================================================
// KNN. K=50: exact bitwise radix-select, cost independent of K.
//   1 wave per query; distances as monotone u32 in CH=NCAND/64 regs.
//   Bit-plane transpose -> per-bit descent (popc over active mask + wave sum)
//   finds exact 50th-smallest value T and tie count; ballot compaction emits
//   all d<T plus smallest-index ties. Set identical to stable top-k.
// K=4 (pooling): old iterative argmin (cheaper for tiny K).
// ===========================================================================
template <int NCAND, int KSEL>
__global__ __launch_bounds__(256) void k_knn_radix(const float* __restrict__ pts, int Nq,
                                                   int* __restrict__ outIdx) {
  __shared__ float sp[NCAND * 3];
  const int b = blockIdx.y;
  const float* pb = pts + (size_t)b * VS0;
  for (int i = threadIdx.x; i < NCAND * 3; i += 256) sp[i] = pb[i];
  __syncthreads();
  const int wave = threadIdx.x >> 6, lane = threadIdx.x & 63;
  const int qi = blockIdx.x * 4 + wave;
  const float qx = sp[qi * 3], qy = sp[qi * 3 + 1], qz = sp[qi * 3 + 2];
  constexpr int CH = NCAND / 64;
  unsigned d[CH];
  unsigned x[32];
#pragma unroll
  for (int j = 0; j < 32; ++j) x[j] = 0u;
#pragma unroll
  for (int j = 0; j < CH; ++j) {
    const int m = lane + j * 64;
    const float dx = sp[m * 3] - qx, dy = sp[m * 3 + 1] - qy, dz = sp[m * 3 + 2] - qz;
    const float dd = dx * dx + dy * dy + dz * dz;
    d[j] = __float_as_uint((m == qi) ? FLT_MAX : dd);
    x[j] = d[j];
  }
  // in-register 32x32 bit transpose (LSB convention): x[b] bit j = bit b of d[j]
  // stage: t = ((x[i]>>s) ^ x[i+s]) & ml;  x[i+s]^=t;  x[i]^=t<<s;
#pragma unroll
  for (int st = 0; st < 5; ++st) {
    const int s = 16 >> st;
    const unsigned ml = (s == 16) ? 0x0000FFFFu : (s == 8) ? 0x00FF00FFu
                      : (s == 4) ? 0x0F0F0F0Fu : (s == 2) ? 0x33333333u : 0x55555555u;
#pragma unroll
    for (int i = 0; i < 32; ++i) {
      if (i & s) continue;
      unsigned t = ((x[i] >> s) ^ x[i + s]) & ml;
      x[i + s] ^= t;
      x[i] ^= (t << s);
    }
  }
  // descent: find exact KSEL-th smallest value T (bit 31 = sign, always 0)
  unsigned active = (CH == 32) ? 0xFFFFFFFFu : ((1u << CH) - 1u);
  unsigned T = 0u;
  int kk = KSEL;
#pragma unroll
  for (int bb = 30; bb >= 0; --bb) {
    const unsigned zn = active & ~x[bb];
    int c0 = __popc(zn);
#pragma unroll
    for (int off = 32; off; off >>= 1) c0 += __shfl_xor(c0, off);
    if (kk <= c0) {
      active = zn;
    } else {
      kk -= c0;
      active &= x[bb];
      T |= (1u << bb);
    }
  }
  // emit: all d < T, then smallest-index ties (d == T) until 50 filled
  int* orow = outIdx + ((size_t)b * Nq + qi) * KSEL;
  const unsigned long long ltmask = (1ull << lane) - 1ull;
  int base = 0;
#pragma unroll
  for (int j = 0; j < CH; ++j) {
    const bool sel = d[j] < T;
    const unsigned long long bal = __ballot(sel);
    const int pos = base + (int)__popcll(bal & ltmask);
    if (sel) orow[pos] = lane + j * 64;
    base += (int)__popcll(bal);
  }
#pragma unroll
  for (int j = 0; j < CH; ++j) {
    const bool sel = ((active >> j) & 1u) != 0u;
    const unsigned long long bal = __ballot(sel);
    const int pos = base + (int)__popcll(bal & ltmask);
    if (sel && pos < KSEL) orow[pos] = lane + j * 64;
    base += (int)__popcll(bal);
  }
}

template <int NCAND, int KSEL>
__global__ __launch_bounds__(256) void k_knn2(const float* __restrict__ pts, int Nq,
                                              int* __restrict__ outIdx) {
  __shared__ float sp[NCAND * 3];
  const int b = blockIdx.y;
  const float* pb = pts + (size_t)b * VS0;
  for (int i = threadIdx.x; i < NCAND * 3; i += 256) sp[i] = pb[i];
  __syncthreads();
  const int wave = threadIdx.x >> 6, lane = threadIdx.x & 63;
  const int qi = blockIdx.x * 4 + wave;
  const float qx = sp[qi * 3], qy = sp[qi * 3 + 1], qz = sp[qi * 3 + 2];
  constexpr int CH = NCAND / 64;
  float d[CH];
#pragma unroll
  for (int j = 0; j < CH; ++j) {
    const int m = lane + j * 64;
    const float dx = sp[m * 3] - qx, dy = sp[m * 3 + 1] - qy, dz = sp[m * 3 + 2] - qz;
    const float dd = dx * dx + dy * dy + dz * dz;
    d[j] = (m == qi) ? FLT_MAX : dd;
  }
  int* orow = outIdx + ((size_t)b * Nq + qi) * KSEL;
#pragma unroll 1
  for (int s = 0; s < KSEL; ++s) {
    float bd = FLT_MAX; int bj = 0;
#pragma unroll
    for (int j = 0; j < CH; ++j) {
      const bool better = d[j] < bd;
      bd = better ? d[j] : bd;
      bj = better ? j : bj;
    }
    int bm = lane + bj * 64;
#pragma unroll
    for (int off = 32; off; off >>= 1) {
      const float od = __shfl_xor(bd, off);
      const int om = __shfl_xor(bm, off);
      if (od < bd || (od == bd && om < bm)) { bd = od; bm = om; }
    }
    if (lane == 0) orow[s] = bm;
#pragma unroll
    for (int j = 0; j < CH; ++j)
      if (bm == lane + j * 64) d[j] = FLT_MAX;
  }
}

__global__ void k_transpose(const float* __restrict__ in, float* __restrict__ out) {
  int i = blockIdx.x * 256 + threadIdx.x;
  if (i >= BB * NP0 * 3) return;
  int dd = i % 3, tt = (i / 3) % NP0, b = i / (3 * NP0);
  out[i] = in[((size_t)b * 3 + dd) * NP0 + tt];
}

__global__ void k_conv_surface(const float* __restrict__ v, const int* __restrict__ idx,
                               const float* __restrict__ dirs, float* __restrict__ out,
                               int N, int M) {
  __shared__ float su[KNB_ * 3];
  int b = blockIdx.y, n = blockIdx.x, c = threadIdx.x;
  const float* vb = v + (size_t)b * VS0;
  float cx = vb[n * 3], cy = vb[n * 3 + 1], cz = vb[n * 3 + 2];
  const int* irow = idx + ((size_t)b * N + n) * KNB_;
  if (c < KNB_) {
    int j = irow[c];
    float dx = vb[j * 3] - cx, dy = vb[j * 3 + 1] - cy, dz = vb[j * 3 + 2] - cz;
    float inv = 1.f / fmaxf(sqrtf(dx * dx + dy * dy + dz * dz), 1e-12f);
    su[c * 3] = dx * inv; su[c * 3 + 1] = dy * inv; su[c * 3 + 2] = dz * inv;
  }
  __syncthreads();
  float d0 = dirs[c], d1 = dirs[M + c], d2 = dirs[2 * M + c];
  float inv = 1.f / fmaxf(sqrtf(d0 * d0 + d1 * d1 + d2 * d2), 1e-12f);
  d0 *= inv; d1 *= inv; d2 *= inv;
  float acc = 0.f;
  for (int k = 0; k < KNB_; ++k) {
    float th = fmaxf(su[k * 3] * d0 + su[k * 3 + 1] * d1 + su[k * 3 + 2] * d2, 0.f);
    acc = fmaxf(acc, th);
  }
  out[((size_t)b * N + n) * M + c] = acc;
}

__global__ void k_conv_layer(const float* __restrict__ v, const int* __restrict__ idx,
                             const float* __restrict__ dirs, const float* __restrict__ fout,
                             float* __restrict__ out, int N, int C) {
  __shared__ float su[KNB_ * 3];
  __shared__ int sidx[KNB_];
  int b = blockIdx.y, n = blockIdx.x, c = threadIdx.x;
  const float* vb = v + (size_t)b * VS0;
  float cx = vb[n * 3], cy = vb[n * 3 + 1], cz = vb[n * 3 + 2];
  const int* irow = idx + ((size_t)b * N + n) * KNB_;
  if (c < KNB_) {
    int j = irow[c]; sidx[c] = j;
    float dx = vb[j * 3] - cx, dy = vb[j * 3 + 1] - cy, dz = vb[j * 3 + 2] - cz;
    float inv = 1.f / fmaxf(sqrtf(dx * dx + dy * dy + dz * dz), 1e-12f);
    su[c * 3] = dx * inv; su[c * 3 + 1] = dy * inv; su[c * 3 + 2] = dz * inv;
  }
  __syncthreads();
  float d0 = dirs[c], d1 = dirs[C + c], d2 = dirs[2 * C + c];
  float inv = 1.f / fmaxf(sqrtf(d0 * d0 + d1 * d1 + d2 * d2), 1e-12f);
  d0 *= inv; d1 *= inv; d2 *= inv;
  const float* fb = fout + (size_t)b * N * 2 * C;
  float acc = -FLT_MAX;
  for (int k = 0; k < KNB_; ++k) {
    float th = fmaxf(su[k * 3] * d0 + su[k * 3 + 1] * d1 + su[k * 3 + 2] * d2, 0.f);
    float fs = fb[(size_t)sidx[k] * 2 * C + C + c];
    acc = fmaxf(acc, th * fs);
  }
  out[((size_t)b * N + n) * C + c] = fb[(size_t)n * 2 * C + c] + acc;
}

// ===========================================================================
// BN / rowstat / xsub / pool / misc
// ===========================================================================
__global__ void k_bn_part(const float* __restrict__ x, int rows, int C, float* __restrict__ part) {
  const int blk = blockIdx.x;
  const int chunk = rows / 64;
  const int r0 = blk * chunk;
  const int c0 = threadIdx.x, c1 = threadIdx.x + 256;
  float s0 = 0, s20 = 0, s1 = 0, s21 = 0;
  for (int r = 0; r < chunk; ++r) {
    const float* row = x + (size_t)(r0 + r) * C;
    if (c0 < C) { float v = row[c0]; s0 += v; s20 += v * v; }
    if (c1 < C) { float v = row[c1]; s1 += v; s21 += v * v; }
  }
  float* p = part + (size_t)blk * 1024;
  if (c0 < C) { p[c0] = s0; p[512 + c0] = s20; }
  if (c1 < C) { p[c1] = s1; p[512 + c1] = s21; }
}

__global__ void k_bn_fin(const float* __restrict__ part, int rows, int C, float* __restrict__ stats) {
  int c = blockIdx.x * 256 + threadIdx.x;
  if (c >= C) return;
  float s = 0, s2 = 0;
  for (int b2 = 0; b2 < 64; ++b2) { s += part[b2 * 1024 + c]; s2 += part[b2 * 1024 + 512 + c]; }
  float m = s / rows;
  float var = s2 / rows - m * m;
  stats[c] = m;
  stats[C + c] = rsqrtf(var + 1e-5f);
}

template <bool ADD>
__global__ void k_bn_apply(const float* __restrict__ x, const float* __restrict__ stats,
                           const float* __restrict__ g, const float* __restrict__ bb,
                           const float* __restrict__ base, float* __restrict__ outf,
                           u16* __restrict__ ph, u16* __restrict__ pl, int total, int C) {
  int i = blockIdx.x * 256 + threadIdx.x;
  if (i >= total) return;
  int c = i % C;
  float v = (x[i] - stats[c]) * stats[C + c] * g[c] + bb[c];
  v = fmaxf(v, 0.f);
  float r = ADD ? base[i] + v : v;
  outf[i] = r;
  u16 h = f2bf(r);
  ph[i] = h;
  pl[i] = f2bf(r - bf2f(h));
}

__global__ void k_rowstat(const float* __restrict__ S, int N,
                          float* __restrict__ mx, float* __restrict__ inv) {
  extern __shared__ float row[];
  __shared__ float red[256];
  int n = blockIdx.x, g = blockIdx.y;
  const float* Sb = S + ((size_t)g * N + n) * N;
  float lmax = -FLT_MAX;
  for (int m = threadIdx.x; m < N; m += 256) { float v = Sb[m]; row[m] = v; lmax = fmaxf(lmax, v); }
  red[threadIdx.x] = lmax; __syncthreads();
  for (int o = 128; o; o >>= 1) {
    if (threadIdx.x < o) red[threadIdx.x] = fmaxf(red[threadIdx.x], red[threadIdx.x + o]);
    __syncthreads();
  }
  float m0 = red[0]; __syncthreads();
  float ls = 0.f;
  for (int m = threadIdx.x; m < N; m += 256) ls += __expf(row[m] - m0);
  red[threadIdx.x] = ls; __syncthreads();
  for (int o = 128; o; o >>= 1) {
    if (threadIdx.x < o) red[threadIdx.x] += red[threadIdx.x + o];
    __syncthreads();
  }
  if (threadIdx.x == 0) {
    mx[(size_t)g * N + n] = m0;
    inv[(size_t)g * N + n] = 1.f / red[0];
  }
}

__global__ void k_xsub_sk(const float* __restrict__ xrpart, const float* __restrict__ cpart,
                          const float* __restrict__ fm, u16* __restrict__ xsh,
                          u16* __restrict__ xsl, int Npts, int C, int KS, int gbase, int gg) {
  int i = blockIdx.x * 256 + threadIdx.x;
  int per = Npts * C;
  if (i >= gg * per) return;
  int zb = i / per, rem = i - zb * per;
  int n = rem / C;
  float s = 0, cs = 0;
  for (int k2 = 0; k2 < KS; ++k2) {
    s += xrpart[(size_t)(zb * KS + k2) * per + rem];
    cs += cpart[(size_t)(zb * KS + k2) * Npts + n];
  }
  int b = gbase + zb;
  float val = fm[(size_t)b * per + rem] - s / (1e-9f + cs);
  u16 h = f2bf(val);
  xsh[(size_t)b * per + rem] = h;
  xsl[(size_t)b * per + rem] = f2bf(val - bf2f(h));
}

__global__ void k_pool(const u16* __restrict__ fh, const u16* __restrict__ fl,
                       const int* __restrict__ idxp, u16* __restrict__ oh,
                       u16* __restrict__ ol, int Nin, int pn, int C) {
  int b = blockIdx.y, p = blockIdx.x, c = threadIdx.x;
  const int* ir = idxp + ((size_t)b * pn + p) * 4;
  const u16* fhb = fh + (size_t)b * Nin * C;
  const u16* flb = fl + (size_t)b * Nin * C;
  float acc = -FLT_MAX;
#pragma unroll
  for (int k = 0; k < 4; ++k) {
    size_t o = (size_t)ir[k] * C + c;
    acc = fmaxf(acc, bf2f(fhb[o]) + bf2f(flb[o]));
  }
  u16 h = f2bf(acc);
  oh[((size_t)b * pn + p) * C + c] = h;
  ol[((size_t)b * pn + p) * C + c] = f2bf(acc - bf2f(h));
}

__global__ void k_maxn(const u16* __restrict__ fh, const u16* __restrict__ fl,
                       float* __restrict__ out, int N, int C) {
  int b = blockIdx.y;
  int c = blockIdx.x * 256 + threadIdx.x;
  if (c >= C) return;
  float acc = -FLT_MAX;
  for (int n = 0; n < N; ++n) {
    size_t o = ((size_t)b * N + n) * C + c;
    acc = fmaxf(acc, bf2f(fh[o]) + bf2f(fl[o]));
  }
  out[(size_t)b * C + c] = acc;
}

__global__ void k_nearest(const float* __restrict__ v, int Ns, int* __restrict__ out) {
  extern __shared__ float sp[];
  int b = blockIdx.y;
  const float* vsb = v + (size_t)b * VS0;
  for (int i = threadIdx.x; i < Ns * 3; i += 256) sp[i] = vsb[i];
  __syncthreads();
  int t = blockIdx.x * 256 + threadIdx.x;
  float tx = vsb[t * 3], ty = vsb[t * 3 + 1], tz = vsb[t * 3 + 2];
  float bd = FLT_MAX; int bi = 0;
#pragma unroll 4
  for (int s = 0; s < Ns; ++s) {
    float dx = sp[s * 3] - tx, dy = sp[s * 3 + 1] - ty, dz = sp[s * 3 + 2] - tz;
    float dd = dx * dx + dy * dy + dz * dz;
    if (dd < bd) { bd = dd; bi = s; }
  }
  out[(size_t)b * NP0 + t] = bi;
}

__global__ void k_glob1(const float* __restrict__ fglob, const float* __restrict__ onehot,
                        const float* __restrict__ h1w, const float* __restrict__ h1b,
                        float* __restrict__ out) {
  int b = blockIdx.x, j = threadIdx.x;
  float s = h1b[j];
  for (int i = 0; i < 512; ++i) s = fmaf(fglob[b * 512 + i], h1w[(size_t)(1280 + i) * 512 + j], s);
  for (int i = 0; i < 16; ++i) s = fmaf(onehot[b * 16 + i], h1w[(size_t)(1792 + i) * 512 + j], s);
  out[b * 512 + j] = s;
}

__global__ void k_logsoftmax(float* __restrict__ x, int rows, int C) {
  int r = blockIdx.x * 4 + (threadIdx.x >> 6);
  int lane = threadIdx.x & 63;
  if (r >= rows) return;
  float* xr = x + (size_t)r * C;
  float v = (lane < C) ? xr[lane] : -FLT_MAX;
  float mx = v;
  for (int o = 32; o; o >>= 1) mx = fmaxf(mx, __shfl_xor(mx, o));
  float e = (lane < C) ? __expf(v - mx) : 0.f;
  float s = e;
  for (int o = 32; o; o >>= 1) s += __shfl_xor(s, o);
  float lse = mx + logf(s);
  if (lane < C) xr[lane] = v - lse;
}

// ===========================================================================
// host
// ===========================================================================
struct Ws {
  float *v0, *fglob, *glob1, *cols, *cpart, *stats, *bpart, *xcur, *xr, *S, *pre, *fout, *x1;
  int *idx0, *idxp0, *idx1, *idxp1, *idx2, *ni1, *ni2;
  u16 *wh, *wl;
  u16 *fm0h, *fm0l, *fm1h, *fm1l, *fm2h, *fm2l, *fm3h, *fm3l, *fm4h, *fm4l;
  u16 *fmp1h, *fmp1l, *fmp2h, *fmp2l, *qh, *ql, *vmh, *vml, *xsh, *xsl;
  u16 *x1h, *x1l, *x2b;
};

static void run_sa(hipStream_t st, Ws& ws, int N, int C, int Q, int bg, int KS,
                   const u16* qkh, const u16* qkl, const u16* vwh, const u16* vwl,
                   const u16* twh, const u16* twl,
                   const float* vb, const float* tb, const float* g, const float* be,
                   u16* xh, u16* xl) {
  const long sx = (long)N * C;
  mmp<64, 0, 0, 1, false, false>(st, xh, xl, qkh, qkl, nullptr, ws.qh, ws.ql,
                                 N, Q, C, sx, 0, (long)N * Q, BB, 1);
  mmp<64, 0, 1, 2, false, false>(st, xh, xl, vwh, vwl, vb, ws.vmh, ws.vml,
                                 N, C, C, sx, 0, sx, BB, 1);
  const int per = N * C;
  float* mxv = ws.cols;
  float* invv = ws.cols + (size_t)bg * N;
  for (int g0 = 0; g0 < BB; g0 += bg) {
    const u16* qgh = ws.qh + (size_t)g0 * N * Q;
    const u16* qgl = ws.ql + (size_t)g0 * N * Q;
    if (N == NP0)
      mmp<128, 0, 0, 0, false, false>(st, qgh, qgl, qgh, qgl, nullptr, ws.S, nullptr,
                                      N, N, Q, (long)N * Q, (long)N * Q, (long)N * N, bg, 1);
    else
      mmp<64, 0, 0, 0, false, false>(st, qgh, qgl, qgh, qgl, nullptr, ws.S, nullptr,
                                     N, N, Q, (long)N * Q, (long)N * Q, (long)N * N, bg, 1);
    k_rowstat<<<dim3(N, bg), 256, N * 4, st>>>(ws.S, N, mxv, invv);
    mmp<64, 3, 0, 0, false, false>(st, ws.S, nullptr,
                                   ws.vmh + (size_t)g0 * per, ws.vml + (size_t)g0 * per,
                                   nullptr, ws.xr, nullptr, N, C, N,
                                   (long)N * N, sx, (long)N * C, bg, KS,
                                   nullptr, 0, mxv, invv, ws.cpart);
    k_xsub_sk<<<(bg * per + 255) / 256, 256, 0, st>>>(ws.xr, ws.cpart, ws.xcur,
                                                      ws.xsh, ws.xsl, N, C, KS, g0, bg);
  }
  mmp<64, 0, 1, 0, false, false>(st, ws.xsh, ws.xsl, twh, twl, tb, ws.pre, nullptr,
                                 N, C, C, sx, 0, sx, BB, 1);
  k_bn_part<<<64, 256, 0, st>>>(ws.pre, BB * N, C, ws.bpart);
  k_bn_fin<<<(C + 255) / 256, 256, 0, st>>>(ws.bpart, BB * N, C, ws.stats);
  k_bn_apply<true><<<(BB * per + 255) / 256, 256, 0, st>>>(ws.pre, ws.stats, g, be,
                                                           ws.xcur, ws.xcur, xh, xl, BB * per, C);
}

static void run_conv(hipStream_t st, Ws& ws, const u16* finh, const u16* finl, int Cin,
                     const u16* cwh, const u16* cwl, const float* bias, const float* dirs,
                     const int* idx, int N, int C,
                     const float* bng, const float* bnb, bool doBN, u16* fmh, u16* fml) {
  if (N == NP0)
    mmp<128, 0, 1, 0, false, false>(st, finh, finl, cwh, cwl, bias, ws.fout, nullptr,
                                    N, 2 * C, Cin, (long)N * Cin, 0, (long)N * 2 * C, BB, 1);
  else
    mmp<64, 0, 1, 0, false, false>(st, finh, finl, cwh, cwl, bias, ws.fout, nullptr,
                                   N, 2 * C, Cin, (long)N * Cin, 0, (long)N * 2 * C, BB, 1);
  k_conv_layer<<<dim3(N, BB), C, 0, st>>>(ws.v0, idx, dirs, ws.fout, ws.xcur, N, C);
  if (doBN) {
    k_bn_part<<<64, 256, 0, st>>>(ws.xcur, BB * N, C, ws.bpart);
    k_bn_fin<<<(C + 255) / 256, 256, 0, st>>>(ws.bpart, BB * N, C, ws.stats);
    k_bn_apply<false><<<(BB * N * C + 255) / 256, 256, 0, st>>>(
        ws.xcur, ws.stats, bng, bnb, nullptr, ws.xcur, fmh, fml, BB * N * C, C);
  } else {
    k_split4<false><<<(BB * N * C / 4 + 255) / 256, 256, 0, st>>>(ws.xcur, fmh, fml, BB * N * C / 4);
  }
}

extern "C" void kernel_launch(void* const* d_in, const int* in_sizes, int n_in,
                              void* d_out, int out_size, void* d_ws, size_t ws_size,
                              hipStream_t stream) {
  auto in = [&](int i) { return (const float*)d_in[i]; };
  char* p = (char*)d_ws;
  Ws ws;
  ws.v0 = (float*)(p + O_V0);
  ws.idx0 = (int*)(p + O_IDX0); ws.idxp0 = (int*)(p + O_IDXP0);
  ws.idx1 = (int*)(p + O_IDX1); ws.idxp1 = (int*)(p + O_IDXP1);
  ws.idx2 = (int*)(p + O_IDX2);
  ws.ni1 = (int*)(p + O_NI1); ws.ni2 = (int*)(p + O_NI2);
  ws.fglob = (float*)(p + O_FGLOB); ws.glob1 = (float*)(p + O_GLOB1);
  ws.cols = (float*)(p + O_COLS); ws.cpart = (float*)(p + O_CPART);
  ws.stats = (float*)(p + O_STATS); ws.bpart = (float*)(p + O_BPART);
  ws.xcur = (float*)(p + O_XCUR); ws.xr = (float*)(p + O_XR);
  ws.S = (float*)(p + O_AREA); ws.pre = (float*)(p + O_AREA);
  ws.fout = (float*)(p + O_AREA); ws.x1 = (float*)(p + O_AREA);
  char* pl = p + O_PL;
  ws.wh = (u16*)(pl + PL_WH); ws.wl = (u16*)(pl + PL_WL);
  ws.fm0h = (u16*)(pl + PL_FM0H); ws.fm0l = (u16*)(pl + PL_FM0L);
  ws.fm1h = (u16*)(pl + PL_FM1H); ws.fm1l = (u16*)(pl + PL_FM1L);
  ws.fm2h = (u16*)(pl + PL_FM2H); ws.fm2l = (u16*)(pl + PL_FM2L);
  ws.fm3h = (u16*)(pl + PL_FM3H); ws.fm3l = (u16*)(pl + PL_FM3L);
  ws.fm4h = (u16*)(pl + PL_FM4H); ws.fm4l = (u16*)(pl + PL_FM4L);
  ws.fmp1h = (u16*)(pl + PL_FMP1H); ws.fmp1l = (u16*)(pl + PL_FMP1L);
  ws.fmp2h = (u16*)(pl + PL_FMP2H); ws.fmp2l = (u16*)(pl + PL_FMP2L);
  ws.qh = (u16*)(pl + PL_QH); ws.ql = (u16*)(pl + PL_QL);
  ws.vmh = (u16*)(pl + PL_VMH); ws.vml = (u16*)(pl + PL_VML);
  ws.xsh = (u16*)(pl + PL_XSH); ws.xsl = (u16*)(pl + PL_XSL);
  ws.x1h = (u16*)(pl + PL_X1H); ws.x1l = (u16*)(pl + PL_X1L);
  ws.x2b = (u16*)(p + O_XCUR);
  float* out = (float*)d_out;

  // ---- one-time weight plane split (pre-transposed to [N,K]) ----
  SplitJobs jobs;
  size_t wq[26];
  size_t off = 0;
  int ji = 0;
  auto addjob = [&](const float* s, int K, int N, int trans) {
    int n = K * N;
    jobs.j[ji] = {s, ws.wh + off, ws.wl + off, n, K, N, trans};
    wq[ji] = off; off += (size_t)n; ++ji;
  };
  addjob(in(5), 128, 32, 0);  addjob(in(6), 128, 128, 0);  addjob(in(8), 128, 128, 0);
  addjob(in(17), 128, 32, 0); addjob(in(18), 128, 128, 0); addjob(in(20), 128, 128, 0);
  addjob(in(29), 256, 64, 0); addjob(in(30), 256, 256, 0); addjob(in(32), 256, 256, 0);
  addjob(in(41), 256, 64, 0); addjob(in(42), 256, 256, 0); addjob(in(44), 256, 256, 0);
  addjob(in(51), 512, 128, 0); addjob(in(52), 512, 512, 0); addjob(in(54), 512, 512, 0);
  addjob(in(12), 128, 256, 1);
  addjob(in(24), 128, 512, 1);
  addjob(in(36), 256, 512, 1);
  addjob(in(48), 256, 1024, 1);
  addjob(in(58) + 0 * 512, 128, 512, 1);
  addjob(in(58) + (size_t)128 * 512, 128, 512, 1);
  addjob(in(58) + (size_t)256 * 512, 256, 512, 1);
  addjob(in(58) + (size_t)512 * 512, 256, 512, 1);
  addjob(in(58) + (size_t)768 * 512, 512, 512, 1);
  addjob(in(60), 512, 512, 1);
  addjob(in(62), 512, 50, 1);
  k_splitjobs<<<dim3(32, 26), 256, 0, stream>>>(jobs);
  auto W = [&](int i) { return ws.wh + wq[i]; };
  auto Wl = [&](int i) { return ws.wl + wq[i]; };

  // ---- geometry ----
  k_transpose<<<(BB * NP0 * 3 + 255) / 256, 256, 0, stream>>>(in(0), ws.v0);
  k_knn_radix<NP0, KNB_><<<dim3(NP0 / 4, BB), 256, 0, stream>>>(ws.v0, NP0, ws.idx0);

  // ---- conv0 + bn0 ----
  k_conv_surface<<<dim3(NP0, BB), 128, 0, stream>>>(ws.v0, ws.idx0, in(2), ws.xcur, NP0, 128);
  k_bn_part<<<64, 256, 0, stream>>>(ws.xcur, BB * NP0, 128, ws.bpart);
  k_bn_fin<<<1, 256, 0, stream>>>(ws.bpart, BB * NP0, 128, ws.stats);
  k_bn_apply<false><<<(BB * NP0 * 128 + 255) / 256, 256, 0, stream>>>(
      ws.xcur, ws.stats, in(3), in(4), nullptr, ws.xcur, ws.fm0h, ws.fm0l, BB * NP0 * 128, 128);

  // ---- sa0, conv1+bn1, sa1 ----
  run_sa(stream, ws, NP0, 128, 32, 1, 4, W(0), Wl(0), W(1), Wl(1), W(2), Wl(2),
         in(7), in(9), in(10), in(11), ws.fm0h, ws.fm0l);
  run_conv(stream, ws, ws.fm0h, ws.fm0l, 128, W(15), Wl(15), in(13), in(14), ws.idx0,
           NP0, 128, in(15), in(16), true, ws.fm1h, ws.fm1l);
  run_sa(stream, ws, NP0, 128, 32, 1, 4, W(3), Wl(3), W(4), Wl(4), W(5), Wl(5),
         in(19), in(21), in(22), in(23), ws.fm1h, ws.fm1l);

  // ---- pool1, knn1 ----
  k_knn2<NP0, 4><<<dim3(NP1 / 4, BB), 256, 0, stream>>>(ws.v0, NP1, ws.idxp0);
  k_pool<<<dim3(NP1, BB), 128, 0, stream>>>(ws.fm1h, ws.fm1l, ws.idxp0,
                                            ws.fmp1h, ws.fmp1l, NP0, NP1, 128);
  k_knn_radix<NP1, KNB_><<<dim3(NP1 / 4, BB), 256, 0, stream>>>(ws.v0, NP1, ws.idx1);

  // ---- conv2+bn2, sa2, conv3+bn3, sa3 ----
  run_conv(stream, ws, ws.fmp1h, ws.fmp1l, 128, W(16), Wl(16), in(25), in(26), ws.idx1,
           NP1, 256, in(27), in(28), true, ws.fm2h, ws.fm2l);
  run_sa(stream, ws, NP1, 256, 64, 8, 1, W(6), Wl(6), W(7), Wl(7), W(8), Wl(8),
         in(31), in(33), in(34), in(35), ws.fm2h, ws.fm2l);
  run_conv(stream, ws, ws.fm2h, ws.fm2l, 256, W(17), Wl(17), in(37), in(38), ws.idx1,
           NP1, 256, in(39), in(40), true, ws.fm3h, ws.fm3l);
  run_sa(stream, ws, NP1, 256, 64, 8, 1, W(9), Wl(9), W(10), Wl(10), W(11), Wl(11),
         in(43), in(45), in(46), in(47), ws.fm3h, ws.fm3l);

  // ---- pool2, knn2, conv4 (no bn), sa4 ----
  k_knn2<NP1, 4><<<dim3(NP2 / 4, BB), 256, 0, stream>>>(ws.v0, NP2, ws.idxp1);
  k_pool<<<dim3(NP2, BB), 256, 0, stream>>>(ws.fm3h, ws.fm3l, ws.idxp1,
                                            ws.fmp2h, ws.fmp2l, NP1, NP2, 256);
  k_knn_radix<NP2, KNB_><<<dim3(NP2 / 4, BB), 256, 0, stream>>>(ws.v0, NP2, ws.idx2);
  run_conv(stream, ws, ws.fmp2h, ws.fmp2l, 256, W(18), Wl(18), in(49), in(50), ws.idx2,
           NP2, 512, nullptr, nullptr, false, ws.fm4h, ws.fm4l);
  run_sa(stream, ws, NP2, 512, 128, 8, 2, W(12), Wl(12), W(13), Wl(13), W(14), Wl(14),
         in(53), in(55), in(56), in(57), ws.fm4h, ws.fm4l);

  // ---- global max, nearest, head ----
  k_maxn<<<dim3(2, BB), 256, 0, stream>>>(ws.fm4h, ws.fm4l, ws.fglob, NP2, 512);
  k_nearest<<<dim3(NP0 / 256, BB), 256, NP1 * 3 * 4, stream>>>(ws.v0, NP1, ws.ni1);
  k_nearest<<<dim3(NP0 / 256, BB), 256, NP2 * 3 * 4, stream>>>(ws.v0, NP2, ws.ni2);
  k_glob1<<<BB, 512, 0, stream>>>(ws.fglob, in(1), in(58), in(59), ws.glob1);

  for (int hf = 0; hf < 2; ++hf) {
    const int b0 = hf * 4;
    mmp<128, 0, 2, 0, false, false>(stream, ws.fm0h + (size_t)b0 * NP0 * 128,
        ws.fm0l + (size_t)b0 * NP0 * 128, W(19), Wl(19), ws.glob1 + b0 * 512, ws.x1, nullptr,
        NP0, 512, 128, (long)NP0 * 128, 0, (long)NP0 * 512, 4, 1);
    mmp<128, 0, 0, 0, true, false>(stream, ws.fm1h + (size_t)b0 * NP0 * 128,
        ws.fm1l + (size_t)b0 * NP0 * 128, W(20), Wl(20), nullptr, ws.x1, nullptr,
        NP0, 512, 128, (long)NP0 * 128, 0, (long)NP0 * 512, 4, 1);
    mmp<128, 0, 0, 0, true, true>(stream, ws.fm2h + (size_t)b0 * NP1 * 256,
        ws.fm2l + (size_t)b0 * NP1 * 256, W(21), Wl(21), nullptr, ws.x1, nullptr,
        NP0, 512, 256, (long)NP1 * 256, 0, (long)NP0 * 512, 4, 1,
        ws.ni1 + (size_t)b0 * NP0, NP0);
    mmp<128, 0, 0, 0, true, true>(stream, ws.fm3h + (size_t)b0 * NP1 * 256,
        ws.fm3l + (size_t)b0 * NP1 * 256, W(22), Wl(22), nullptr, ws.x1, nullptr,
        NP0, 512, 256, (long)NP1 * 256, 0, (long)NP0 * 512, 4, 1,
        ws.ni1 + (size_t)b0 * NP0, NP0);
    mmp<128, 0, 0, 0, true, true>(stream, ws.fm4h + (size_t)b0 * NP2 * 512,
        ws.fm4l + (size_t)b0 * NP2 * 512, W(23), Wl(23), nullptr, ws.x1, nullptr,
        NP0, 512, 512, (long)NP2 * 512, 0, (long)NP0 * 512, 4, 1,
        ws.ni2 + (size_t)b0 * NP0, NP0);
    k_split4<true><<<(4 * NP0 * 512 / 4 + 255) / 256, 256, 0, stream>>>(
        ws.x1, ws.x1h, ws.x1l, 4 * NP0 * 512 / 4);
    mmp<128, 0, 1, 3, false, false>(stream, ws.x1h, ws.x1l, W(24), Wl(24), in(61),
        ws.x2b, nullptr, NP0, 512, 512, (long)NP0 * 512, 0, (long)NP0 * 512, 4, 1);
    mmp<64, 2, 1, 0, false, false>(stream, ws.x2b, nullptr, W(25), Wl(25), in(63),
        out + (size_t)b0 * NP0 * 50, nullptr, NP0, 50, 512,
        (long)NP0 * 512, 0, (long)NP0 * 50, 4, 1);
  }

  k_logsoftmax<<<(BB * NP0) / 4, 256, 0, stream>>>(out, BB * NP0, 50);
}

// Round 8
// 1952.210 us; speedup vs baseline: 1.9552x; 1.1008x over previous
//
#include <hip/hip_runtime.h>
#include <cfloat>

// ---------------------------------------------------------------------------
// GCN3D forward. Split-plane bf16 MFMA GEMMs (Dekker, f32-grade accuracy).
// Round-8: flash-style fused attention — S = q q^T recomputed in-register
// (K=32..128 MFMA, ~free) instead of materialized (67 MB/batch HBM traffic).
// k_sa_stats: online row max/expsum. k_sa_xr: P=exp(S-mx)*inv -> LDS planes
// -> P@vm MFMA, csum in-register, xsub fused into epilogue.
// B=8, N=2048->512->128, K_NB=50. Workspace 93,814,784 B.
// ---------------------------------------------------------------------------

#define BB   8
#define NP0  2048
#define NP1  512
#define NP2  128
#define KNB_ 50
#define VS0  (NP0 * 3)

typedef __attribute__((ext_vector_type(8))) short short8_t;
typedef __attribute__((ext_vector_type(4))) short short4_t;
typedef __attribute__((ext_vector_type(4))) float f32x4_t;
typedef unsigned short u16;

// ---------------- workspace layout (byte offsets) ----------------
static constexpr size_t O_V0    = 0;
static constexpr size_t O_IDX0  = 196608;
static constexpr size_t O_IDXP0 = 3473408;
static constexpr size_t O_IDX1  = 3538944;
static constexpr size_t O_IDXP1 = 4358144;
static constexpr size_t O_IDX2  = 4374528;
static constexpr size_t O_NI1   = 4579328;
static constexpr size_t O_NI2   = 4644864;
static constexpr size_t O_FGLOB = 4710400;
static constexpr size_t O_GLOB1 = 4726784;
static constexpr size_t O_COLS  = 4743168;   // mx vectors (8*2048*4 = 64KB)
static constexpr size_t O_CPART = 4808704;   // inv vectors (64KB used of 512KB)
static constexpr size_t O_STATS = 5332992;
static constexpr size_t O_BPART = 5337088;
static constexpr size_t O_XCUR  = 5599232;   // 8,388,608 f32 activation scratch
static constexpr size_t O_XR    = 13987840;  // (unused after fusion)
static constexpr size_t O_PL    = 18182144;  // 58,855,424 plane pools
static constexpr size_t O_AREA  = 77037568;  // 16,777,216 fout / pre / x1half
// end = 93,814,784

static constexpr size_t PL_WH    = 0;
static constexpr size_t PL_WL    = 4786176;
static constexpr size_t PL_FM0H  = 9572352;
static constexpr size_t PL_FM0L  = 13766656;
static constexpr size_t PL_FM1H  = 17960960;
static constexpr size_t PL_FM1L  = 22155264;
static constexpr size_t PL_FM2H  = 26349568;
static constexpr size_t PL_FM2L  = 28446720;
static constexpr size_t PL_FM3H  = 30543872;
static constexpr size_t PL_FM3L  = 32641024;
static constexpr size_t PL_FM4H  = 34738176;
static constexpr size_t PL_FM4L  = 35786752;
static constexpr size_t PL_FMP1H = 36835328;
static constexpr size_t PL_FMP1L = 37883904;
static constexpr size_t PL_FMP2H = 38932480;
static constexpr size_t PL_FMP2L = 39456768;
static constexpr size_t PL_QH    = 39981056;
static constexpr size_t PL_QL    = 41029632;
static constexpr size_t PL_VMH   = 42078208;
static constexpr size_t PL_VML   = 46272512;
static constexpr size_t PL_XSH   = 50466816;
static constexpr size_t PL_XSL   = 54661120;
static constexpr size_t PL_X1H = PL_VMH;   // head aliases (phase-disjoint)
static constexpr size_t PL_X1L = PL_XSH;

__device__ __forceinline__ float bf2f(u16 h) {
  union { unsigned u; float f; } c; c.u = ((unsigned)h) << 16; return c.f;
}
__device__ __forceinline__ u16 f2bf(float f) {
  union { float f; unsigned u; } c; c.f = f;
  return (u16)((c.u + 0x7fffu + ((c.u >> 16) & 1u)) >> 16);
}

// ===========================================================================
// Plane GEMM (unchanged from round 7; AMODE 3 no longer instantiated).
// ===========================================================================
template <int TM, int AMODE, int BIASM, int OUTM, bool ACC, bool GIDX>
__global__ __launch_bounds__(256) void k_mmp(
    const void* __restrict__ A1, const void* __restrict__ A2,
    const u16* __restrict__ Bh0, const u16* __restrict__ Bl0,
    const float* __restrict__ bias, void* __restrict__ C1, void* __restrict__ C2,
    int M, int N, int K, long sA, long sB, long sC, int ksplit,
    const int* __restrict__ gidx, long sG) {
  constexpr int RT = TM / 32;
  constexpr int CT = TM / 32;
  __shared__ u16 Ah[TM][40], Bh[TM][40], Bl[TM][40];
  __shared__ u16 Al[(AMODE == 2) ? 1 : TM][40];
  const int z = blockIdx.z;
  const int zb = z / ksplit, ks = z - zb * ksplit;
  const int kchunk = K / ksplit;
  const int kl0 = ks * kchunk, kl1 = kl0 + kchunk;
  const int m0 = blockIdx.x * TM, n0 = blockIdx.y * TM;
  const int t = threadIdx.x;
  const int lane = t & 63, w = t >> 6;
  const int wr = (w >> 1) * (TM / 2), wc = (w & 1) * (TM / 2);
  const int frow = lane & 15, koff = (lane >> 4) * 8;
  f32x4_t acc[RT][CT];
#pragma unroll
  for (int i = 0; i < RT; ++i)
#pragma unroll
    for (int j = 0; j < CT; ++j) acc[i][j] = (f32x4_t){0.f, 0.f, 0.f, 0.f};

  const u16* Ahg = (const u16*)A1 + (size_t)zb * sA;
  const u16* Alg = (const u16*)A2 + (size_t)zb * sA;
  const u16* Bhg = Bh0 + (size_t)zb * sB;
  const u16* Blg = Bl0 + (size_t)zb * sB;

  int ar, ac, arow = 0;
  if constexpr (TM == 128) { ar = t >> 1; ac = (t & 1) * 16; }
  else                     { ar = t >> 2; ac = (t & 3) * 8; }
  arow = m0 + ar;
  if constexpr (GIDX) arow = (gidx + (size_t)zb * sG)[arow];
  const int bn = ar, bc = ac;
  const bool bok = (n0 + bn) < N;
  const short8_t z8 = {0, 0, 0, 0, 0, 0, 0, 0};

  for (int k0 = kl0; k0 < kl1; k0 += 32) {
    __syncthreads();
    {
      const u16* s1 = Ahg + (size_t)arow * K + k0 + ac;
      if constexpr (TM == 128) {
        *(short8_t*)&Ah[ar][ac] = *(const short8_t*)s1;
        *(short8_t*)&Ah[ar][ac + 8] = *(const short8_t*)(s1 + 8);
        if constexpr (AMODE == 0) {
          const u16* s2 = Alg + (size_t)arow * K + k0 + ac;
          *(short8_t*)&Al[ar][ac] = *(const short8_t*)s2;
          *(short8_t*)&Al[ar][ac + 8] = *(const short8_t*)(s2 + 8);
        }
      } else {
        *(short8_t*)&Ah[ar][ac] = *(const short8_t*)s1;
        if constexpr (AMODE == 0)
          *(short8_t*)&Al[ar][ac] = *(const short8_t*)(Alg + (size_t)arow * K + k0 + ac);
      }
    }
    {
      const u16* s1 = Bhg + (size_t)(n0 + bn) * K + k0 + bc;
      const u16* s2 = Blg + (size_t)(n0 + bn) * K + k0 + bc;
      if constexpr (TM == 128) {
        *(short8_t*)&Bh[bn][bc] = bok ? *(const short8_t*)s1 : z8;
        *(short8_t*)&Bh[bn][bc + 8] = bok ? *(const short8_t*)(s1 + 8) : z8;
        *(short8_t*)&Bl[bn][bc] = bok ? *(const short8_t*)s2 : z8;
        *(short8_t*)&Bl[bn][bc + 8] = bok ? *(const short8_t*)(s2 + 8) : z8;
      } else {
        *(short8_t*)&Bh[bn][bc] = bok ? *(const short8_t*)s1 : z8;
        *(short8_t*)&Bl[bn][bc] = bok ? *(const short8_t*)s2 : z8;
      }
    }
    __syncthreads();
    short8_t ah[RT], al[RT], bh[CT], bl[CT];
#pragma unroll
    for (int i = 0; i < RT; ++i) {
      const int r = wr + i * 16 + frow;
      ah[i] = *(const short8_t*)&Ah[r][koff];
      if constexpr (AMODE != 2) al[i] = *(const short8_t*)&Al[r][koff];
    }
#pragma unroll
    for (int i = 0; i < CT; ++i) {
      const int r = wc + i * 16 + frow;
      bh[i] = *(const short8_t*)&Bh[r][koff];
      bl[i] = *(const short8_t*)&Bl[r][koff];
    }
#pragma unroll
    for (int i = 0; i < RT; ++i)
#pragma unroll
      for (int j = 0; j < CT; ++j) {
        acc[i][j] = __builtin_amdgcn_mfma_f32_16x16x32_bf16(ah[i], bh[j], acc[i][j], 0, 0, 0);
        acc[i][j] = __builtin_amdgcn_mfma_f32_16x16x32_bf16(ah[i], bl[j], acc[i][j], 0, 0, 0);
        if constexpr (AMODE != 2)
          acc[i][j] = __builtin_amdgcn_mfma_f32_16x16x32_bf16(al[i], bh[j], acc[i][j], 0, 0, 0);
      }
  }

  const int crow = (lane >> 4) * 4;
#pragma unroll
  for (int i = 0; i < RT; ++i) {
#pragma unroll
    for (int j = 0; j < CT; ++j) {
      const int gc = n0 + wc + j * 16 + frow;
      if (gc >= N) continue;
      float bv = 0.f;
      if constexpr (BIASM == 1) bv = bias[gc];
      if constexpr (BIASM == 2) bv = bias[(size_t)zb * N + gc];
      const int gr0 = m0 + wr + i * 16 + crow;
      if constexpr (OUTM == 0) {
        float* Cp = (float*)C1 + (size_t)z * sC;
#pragma unroll
        for (int q = 0; q < 4; ++q) {
          float vv = acc[i][j][q] + bv;
          if (ACC) vv += Cp[(size_t)(gr0 + q) * N + gc];
          Cp[(size_t)(gr0 + q) * N + gc] = vv;
        }
      } else if constexpr (OUTM == 1) {
        u16* Ph = (u16*)C1 + (size_t)z * sC;
        u16* Pl = (u16*)C2 + (size_t)z * sC;
#pragma unroll
        for (int q = 0; q < 4; ++q) {
          float vv = acc[i][j][q] + bv;
          u16 h = f2bf(vv);
          Ph[(size_t)(gr0 + q) * N + gc] = h;
          Pl[(size_t)(gr0 + q) * N + gc] = f2bf(vv - bf2f(h));
        }
      } else if constexpr (OUTM == 2) {
        u16* Ph = (u16*)C1 + (size_t)z * sC;
        u16* Pl = (u16*)C2 + (size_t)z * sC;
        short4_t h4, l4;
#pragma unroll
        for (int q = 0; q < 4; ++q) {
          float vv = acc[i][j][q] + bv;
          u16 h = f2bf(vv);
          h4[q] = (short)h;
          l4[q] = (short)f2bf(vv - bf2f(h));
        }
        *(short4_t*)(Ph + (size_t)gc * M + gr0) = h4;
        *(short4_t*)(Pl + (size_t)gc * M + gr0) = l4;
      } else {
        u16* Cb = (u16*)C1 + (size_t)z * sC;
#pragma unroll
        for (int q = 0; q < 4; ++q) {
          float vv = fmaxf(acc[i][j][q] + bv, 0.f);
          Cb[(size_t)(gr0 + q) * N + gc] = f2bf(vv);
        }
      }
    }
  }
}

template <int TM, int AMODE, int BIASM, int OUTM, bool ACC, bool GIDX>
static void mmp(hipStream_t st, const void* A1, const void* A2,
                const u16* Bh, const u16* Bl, const float* bias,
                void* C1, void* C2, int M, int N, int K,
                long sA, long sB, long sC, int Z, int ksplit,
                const int* gidx = nullptr, long sG = 0) {
  dim3 grid(M / TM, (N + TM - 1) / TM, Z * ksplit);
  k_mmp<TM, AMODE, BIASM, OUTM, ACC, GIDX><<<grid, 256, 0, st>>>(
      A1, A2, Bh, Bl, bias, C1, C2, M, N, K, sA, sB, sC, ksplit, gidx, sG);
}

// ===========================================================================
// Fused attention. q planes [B][N][QD]; vm planes transposed [B][C][N].
// ===========================================================================
// Pass 1: per-row max + 1/sum(exp) via in-register S recompute (online).
template <int QD>
__global__ __launch_bounds__(256) void k_sa_stats(
    const u16* __restrict__ qh, const u16* __restrict__ ql, int N,
    float* __restrict__ mx, float* __restrict__ inv) {
  __shared__ float mr[2][128], sr[2][128];
  const int b = blockIdx.y;
  const int m0 = blockIdx.x * 128;
  const int t = threadIdx.x, lane = t & 63, w = t >> 6;
  const int wr = (w >> 1) * 64, wc = (w & 1) * 64;
  const int frow = lane & 15, kq = (lane >> 4) * 8;
  const u16* qhb = qh + (size_t)b * N * QD;
  const u16* qlb = ql + (size_t)b * N * QD;
  constexpr int KS = QD / 32;
  float M[4][4], S[4][4];
#pragma unroll
  for (int i = 0; i < 4; ++i)
#pragma unroll
    for (int q = 0; q < 4; ++q) { M[i][q] = -FLT_MAX; S[i][q] = 0.f; }

  for (int n0 = 0; n0 < N; n0 += 128) {
    f32x4_t acc[4][4];
#pragma unroll
    for (int i = 0; i < 4; ++i)
#pragma unroll
      for (int j = 0; j < 4; ++j) acc[i][j] = (f32x4_t){0.f, 0.f, 0.f, 0.f};
#pragma unroll
    for (int ks = 0; ks < KS; ++ks) {
      short8_t a_h[4], a_l[4], b_h[4], b_l[4];
#pragma unroll
      for (int i = 0; i < 4; ++i) {
        const size_t r = (size_t)(m0 + wr + i * 16 + frow) * QD + ks * 32 + kq;
        a_h[i] = *(const short8_t*)(qhb + r);
        a_l[i] = *(const short8_t*)(qlb + r);
      }
#pragma unroll
      for (int j = 0; j < 4; ++j) {
        const size_t r = (size_t)(n0 + wc + j * 16 + frow) * QD + ks * 32 + kq;
        b_h[j] = *(const short8_t*)(qhb + r);
        b_l[j] = *(const short8_t*)(qlb + r);
      }
#pragma unroll
      for (int i = 0; i < 4; ++i)
#pragma unroll
        for (int j = 0; j < 4; ++j) {
          acc[i][j] = __builtin_amdgcn_mfma_f32_16x16x32_bf16(a_h[i], b_h[j], acc[i][j], 0, 0, 0);
          acc[i][j] = __builtin_amdgcn_mfma_f32_16x16x32_bf16(a_h[i], b_l[j], acc[i][j], 0, 0, 0);
          acc[i][j] = __builtin_amdgcn_mfma_f32_16x16x32_bf16(a_l[i], b_h[j], acc[i][j], 0, 0, 0);
        }
    }
    // online update (rows per (i,q); 16 frow lanes share a row)
#pragma unroll
    for (int i = 0; i < 4; ++i)
#pragma unroll
      for (int q = 0; q < 4; ++q) {
        float tm = acc[i][0][q];
#pragma unroll
        for (int j = 1; j < 4; ++j) tm = fmaxf(tm, acc[i][j][q]);
#pragma unroll
        for (int off = 1; off < 16; off <<= 1) tm = fmaxf(tm, __shfl_xor(tm, off));
        const float Mn = fmaxf(M[i][q], tm);
        float ps = 0.f;
#pragma unroll
        for (int j = 0; j < 4; ++j) ps += __expf(acc[i][j][q] - Mn);
#pragma unroll
        for (int off = 1; off < 16; off <<= 1) ps += __shfl_xor(ps, off);
        S[i][q] = S[i][q] * __expf(M[i][q] - Mn) + ps;
        M[i][q] = Mn;
      }
  }
  if (frow == 0) {
#pragma unroll
    for (int i = 0; i < 4; ++i)
#pragma unroll
      for (int q = 0; q < 4; ++q) {
        const int ml = wr + i * 16 + (lane >> 4) * 4 + q;
        mr[w & 1][ml] = M[i][q];
        sr[w & 1][ml] = S[i][q];
      }
  }
  __syncthreads();
  if (t < 128) {
    const float M0 = mr[0][t], M1 = mr[1][t];
    const float Mm = fmaxf(M0, M1);
    const float Sm = sr[0][t] * __expf(M0 - Mm) + sr[1][t] * __expf(M1 - Mm);
    mx[(size_t)b * N + m0 + t] = Mm;
    inv[(size_t)b * N + m0 + t] = 1.f / Sm;
  }
}

// Pass 2: xr tile = sum_n P[m,n] vm'[c,n] with P recomputed; xsub fused.
template <int QD>
__global__ __launch_bounds__(256) void k_sa_xr(
    const u16* __restrict__ qh, const u16* __restrict__ ql,
    const u16* __restrict__ vmh, const u16* __restrict__ vml,
    const float* __restrict__ mx, const float* __restrict__ inv,
    const float* __restrict__ xcur, u16* __restrict__ xsh, u16* __restrict__ xsl,
    int N, int C) {
  __shared__ __align__(16) u16 Ph[128][136], Pl[128][136];
  __shared__ __align__(16) u16 Vh[128][72], Vl[128][72];
  const int b = blockIdx.z;
  const int m0 = blockIdx.x * 128, c0 = blockIdx.y * 128;
  const int t = threadIdx.x, lane = t & 63, w = t >> 6;
  const int wr = (w >> 1) * 64, wc = (w & 1) * 64;
  const int frow = lane & 15, kq = (lane >> 4) * 8;
  const u16* qhb = qh + (size_t)b * N * QD;
  const u16* qlb = ql + (size_t)b * N * QD;
  const u16* vhb = vmh + (size_t)b * (size_t)N * C;  // [C][N]
  const u16* vlb = vml + (size_t)b * (size_t)N * C;
  const float* mxb = mx + (size_t)b * N;
  const float* invb = inv + (size_t)b * N;
  constexpr int KS = QD / 32;
  const int vr = t >> 1, vco = (t & 1) * 32;
  f32x4_t xacc[4][4];
  float csum[4][4];
#pragma unroll
  for (int i = 0; i < 4; ++i)
#pragma unroll
    for (int j = 0; j < 4; ++j) { xacc[i][j] = (f32x4_t){0.f, 0.f, 0.f, 0.f}; csum[i][j] = 0.f; }

  for (int n0 = 0; n0 < N; n0 += 128) {
    __syncthreads();  // previous P/V reads complete
    // stage V half 0: cols n0..n0+64
    {
      const u16* s1 = vhb + (size_t)(c0 + vr) * N + n0 + vco;
      const u16* s2 = vlb + (size_t)(c0 + vr) * N + n0 + vco;
#pragma unroll
      for (int u = 0; u < 4; ++u) {
        *(short8_t*)&Vh[vr][vco + u * 8] = *(const short8_t*)(s1 + u * 8);
        *(short8_t*)&Vl[vr][vco + u * 8] = *(const short8_t*)(s2 + u * 8);
      }
    }
    // S tile (in-register, global q frags)
    f32x4_t acc[4][4];
#pragma unroll
    for (int i = 0; i < 4; ++i)
#pragma unroll
      for (int j = 0; j < 4; ++j) acc[i][j] = (f32x4_t){0.f, 0.f, 0.f, 0.f};
#pragma unroll
    for (int ks = 0; ks < KS; ++ks) {
      short8_t a_h[4], a_l[4], b_h[4], b_l[4];
#pragma unroll
      for (int i = 0; i < 4; ++i) {
        const size_t r = (size_t)(m0 + wr + i * 16 + frow) * QD + ks * 32 + kq;
        a_h[i] = *(const short8_t*)(qhb + r);
        a_l[i] = *(const short8_t*)(qlb + r);
      }
#pragma unroll
      for (int j = 0; j < 4; ++j) {
        const size_t r = (size_t)(n0 + wc + j * 16 + frow) * QD + ks * 32 + kq;
        b_h[j] = *(const short8_t*)(qhb + r);
        b_l[j] = *(const short8_t*)(qlb + r);
      }
#pragma unroll
      for (int i = 0; i < 4; ++i)
#pragma unroll
        for (int j = 0; j < 4; ++j) {
          acc[i][j] = __builtin_amdgcn_mfma_f32_16x16x32_bf16(a_h[i], b_h[j], acc[i][j], 0, 0, 0);
          acc[i][j] = __builtin_amdgcn_mfma_f32_16x16x32_bf16(a_h[i], b_l[j], acc[i][j], 0, 0, 0);
          acc[i][j] = __builtin_amdgcn_mfma_f32_16x16x32_bf16(a_l[i], b_h[j], acc[i][j], 0, 0, 0);
        }
    }
    // transform -> P planes in LDS; csum accumulate
    float mxj[4], ivj[4];
#pragma unroll
    for (int j = 0; j < 4; ++j) {
      const int n = n0 + wc + j * 16 + frow;
      mxj[j] = mxb[n];
      ivj[j] = invb[n];
    }
    const int mbase = wr + (lane >> 4) * 4;
#pragma unroll
    for (int i = 0; i < 4; ++i)
#pragma unroll
      for (int j = 0; j < 4; ++j)
#pragma unroll
        for (int q = 0; q < 4; ++q) {
          const float pv = __expf(acc[i][j][q] - mxj[j]) * ivj[j];
          csum[i][q] += pv;
          const u16 h = f2bf(pv);
          Ph[mbase + i * 16 + q][wc + j * 16 + frow] = h;
          Pl[mbase + i * 16 + q][wc + j * 16 + frow] = f2bf(pv - bf2f(h));
        }
    __syncthreads();  // P + V half0 ready
#pragma unroll
    for (int ks2 = 0; ks2 < 2; ++ks2) {
      short8_t p_h[4], p_l[4], v_h[4], v_l[4];
#pragma unroll
      for (int i = 0; i < 4; ++i) {
        p_h[i] = *(const short8_t*)&Ph[wr + i * 16 + frow][ks2 * 32 + kq];
        p_l[i] = *(const short8_t*)&Pl[wr + i * 16 + frow][ks2 * 32 + kq];
      }
#pragma unroll
      for (int j = 0; j < 4; ++j) {
        v_h[j] = *(const short8_t*)&Vh[wc + j * 16 + frow][ks2 * 32 + kq];
        v_l[j] = *(const short8_t*)&Vl[wc + j * 16 + frow][ks2 * 32 + kq];
      }
#pragma unroll
      for (int i = 0; i < 4; ++i)
#pragma unroll
        for (int j = 0; j < 4; ++j) {
          xacc[i][j] = __builtin_amdgcn_mfma_f32_16x16x32_bf16(p_h[i], v_h[j], xacc[i][j], 0, 0, 0);
          xacc[i][j] = __builtin_amdgcn_mfma_f32_16x16x32_bf16(p_h[i], v_l[j], xacc[i][j], 0, 0, 0);
          xacc[i][j] = __builtin_amdgcn_mfma_f32_16x16x32_bf16(p_l[i], v_h[j], xacc[i][j], 0, 0, 0);
        }
    }
    __syncthreads();  // V half0 reads complete
    // stage V half 1: cols n0+64..n0+128
    {
      const u16* s1 = vhb + (size_t)(c0 + vr) * N + n0 + 64 + vco;
      const u16* s2 = vlb + (size_t)(c0 + vr) * N + n0 + 64 + vco;
#pragma unroll
      for (int u = 0; u < 4; ++u) {
        *(short8_t*)&Vh[vr][vco + u * 8] = *(const short8_t*)(s1 + u * 8);
        *(short8_t*)&Vl[vr][vco + u * 8] = *(const short8_t*)(s2 + u * 8);
      }
    }
    __syncthreads();  // V half1 ready
#pragma unroll
    for (int ks2 = 0; ks2 < 2; ++ks2) {
      short8_t p_h[4], p_l[4], v_h[4], v_l[4];
#pragma unroll
      for (int i = 0; i < 4; ++i) {
        p_h[i] = *(const short8_t*)&Ph[wr + i * 16 + frow][64 + ks2 * 32 + kq];
        p_l[i] = *(const short8_t*)&Pl[wr + i * 16 + frow][64 + ks2 * 32 + kq];
      }
#pragma unroll
      for (int j = 0; j < 4; ++j) {
        v_h[j] = *(const short8_t*)&Vh[wc + j * 16 + frow][ks2 * 32 + kq];
        v_l[j] = *(const short8_t*)&Vl[wc + j * 16 + frow][ks2 * 32 + kq];
      }
#pragma unroll
      for (int i = 0; i < 4; ++i)
#pragma unroll
        for (int j = 0; j < 4; ++j) {
          xacc[i][j] = __builtin_amdgcn_mfma_f32_16x16x32_bf16(p_h[i], v_h[j], xacc[i][j], 0, 0, 0);
          xacc[i][j] = __builtin_amdgcn_mfma_f32_16x16x32_bf16(p_h[i], v_l[j], xacc[i][j], 0, 0, 0);
          xacc[i][j] = __builtin_amdgcn_mfma_f32_16x16x32_bf16(p_l[i], v_h[j], xacc[i][j], 0, 0, 0);
        }
    }
  }
  // csum: reduce over frow lanes, then cross wave-halves via LDS
#pragma unroll
  for (int i = 0; i < 4; ++i)
#pragma unroll
    for (int q = 0; q < 4; ++q)
#pragma unroll
      for (int off = 1; off < 16; off <<= 1) csum[i][q] += __shfl_xor(csum[i][q], off);
  __syncthreads();
  float* csb = (float*)&Ph[0][0];
  if (frow == 0) {
#pragma unroll
    for (int i = 0; i < 4; ++i)
#pragma unroll
      for (int q = 0; q < 4; ++q)
        csb[(w & 1) * 128 + wr + i * 16 + (lane >> 4) * 4 + q] = csum[i][q];
  }
  __syncthreads();
  if (t < 128) csb[256 + t] = csb[t] + csb[128 + t];
  __syncthreads();
  // epilogue: xs = x - xr/(1e-9+csum) -> planes
#pragma unroll
  for (int i = 0; i < 4; ++i) {
#pragma unroll
    for (int q = 0; q < 4; ++q) {
      const int mloc = wr + i * 16 + (lane >> 4) * 4 + q;
      const float cstot = csb[256 + mloc];
      const size_t rowoff = ((size_t)b * N + m0 + mloc) * C;
#pragma unroll
      for (int j = 0; j < 4; ++j) {
        const int gc = c0 + wc + j * 16 + frow;
        const float val = xcur[rowoff + gc] - xacc[i][j][q] / (1e-9f + cstot);
        const u16 h = f2bf(val);
        xsh[rowoff + gc] = h;
        xsl[rowoff + gc] = f2bf(val - bf2f(h));
      }
    }
  }
}

// ===========================================================================
// weight split + activation split
// ===========================================================================
struct SplitJob { const float* s; u16* dh; u16* dl; int n, K, N, trans; };
struct SplitJobs { SplitJob j[26]; };
__global__ void k_splitjobs(SplitJobs jobs) {
  SplitJob jb = jobs.j[blockIdx.y];
  for (int i = blockIdx.x * 256 + threadIdx.x; i < jb.n; i += gridDim.x * 256) {
    float v;
    if (jb.trans) { int k = i % jb.K, n = i / jb.K; v = jb.s[(size_t)k * jb.N + n]; }
    else v = jb.s[i];
    u16 h = f2bf(v);
    jb.dh[i] = h;
    jb.dl[i] = f2bf(v - bf2f(h));
  }
}

template <bool RELU>
__global__ void k_split4(const float* __restrict__ x, u16* __restrict__ ph,
                         u16* __restrict__ pl, int n4) {
  int i = blockIdx.x * 256 + threadIdx.x;
  if (i >= n4) return;
  float4 v = ((const float4*)x)[i];
  short4_t h4, l4;
  float vv[4] = {v.x, v.y, v.z, v.w};
#pragma unroll
  for (int q = 0; q < 4; ++q) {
    float f = RELU ? fmaxf(vv[q], 0.f) : vv[q];
    u16 h = f2bf(f);
    h4[q] = (short)h;
    l4[q] = (short)f2bf(f - bf2f(h));
  }
  *(short4_t*)(ph + (size_t)i * 4) = h4;
  *(short4_t*)(pl + (size_t)i * 4) = l4;
}

// ===========================================================================
// KNN (radix-select for K=50; iterative argmin for K=4)
// ===========================================================================
template <int NCAND, int KSEL>
__global__ __launch_bounds__(256) void k_knn_radix(const float* __restrict__ pts, int Nq,
                                                   int* __restrict__ outIdx) {
  __shared__ float sp[NCAND * 3];
  const int b = blockIdx.y;
  const float* pb = pts + (size_t)b * VS0;
  for (int i = threadIdx.x; i < NCAND * 3; i += 256) sp[i] = pb[i];
  __syncthreads();
  const int wave = threadIdx.x >> 6, lane = threadIdx.x & 63;
  const int qi = blockIdx.x * 4 + wave;
  const float qx = sp[qi * 3], qy = sp[qi * 3 + 1], qz = sp[qi * 3 + 2];
  constexpr int CH = NCAND / 64;
  unsigned d[CH];
  unsigned x[32];
#pragma unroll
  for (int j = 0; j < 32; ++j) x[j] = 0u;
#pragma unroll
  for (int j = 0; j < CH; ++j) {
    const int m = lane + j * 64;
    const float dx = sp[m * 3] - qx, dy = sp[m * 3 + 1] - qy, dz = sp[m * 3 + 2] - qz;
    const float dd = dx * dx + dy * dy + dz * dz;
    d[j] = __float_as_uint((m == qi) ? FLT_MAX : dd);
    x[j] = d[j];
  }
#pragma unroll
  for (int st = 0; st < 5; ++st) {
    const int s = 16 >> st;
    const unsigned ml = (s == 16) ? 0x0000FFFFu : (s == 8) ? 0x00FF00FFu
                      : (s == 4) ? 0x0F0F0F0Fu : (s == 2) ? 0x33333333u : 0x55555555u;
#pragma unroll
    for (int i = 0; i < 32; ++i) {
      if (i & s) continue;
      unsigned t = ((x[i] >> s) ^ x[i + s]) & ml;
      x[i + s] ^= t;
      x[i] ^= (t << s);
    }
  }
  unsigned active = (CH == 32) ? 0xFFFFFFFFu : ((1u << CH) - 1u);
  unsigned T = 0u;
  int kk = KSEL;
#pragma unroll
  for (int bb = 30; bb >= 0; --bb) {
    const unsigned zn = active & ~x[bb];
    int c0 = __popc(zn);
#pragma unroll
    for (int off = 32; off; off >>= 1) c0 += __shfl_xor(c0, off);
    if (kk <= c0) {
      active = zn;
    } else {
      kk -= c0;
      active &= x[bb];
      T |= (1u << bb);
    }
  }
  int* orow = outIdx + ((size_t)b * Nq + qi) * KSEL;
  const unsigned long long ltmask = (1ull << lane) - 1ull;
  int base = 0;
#pragma unroll
  for (int j = 0; j < CH; ++j) {
    const bool sel = d[j] < T;
    const unsigned long long bal = __ballot(sel);
    const int pos = base + (int)__popcll(bal & ltmask);
    if (sel) orow[pos] = lane + j * 64;
    base += (int)__popcll(bal);
  }
#pragma unroll
  for (int j = 0; j < CH; ++j) {
    const bool sel = ((active >> j) & 1u) != 0u;
    const unsigned long long bal = __ballot(sel);
    const int pos = base + (int)__popcll(bal & ltmask);
    if (sel && pos < KSEL) orow[pos] = lane + j * 64;
    base += (int)__popcll(bal);
  }
}

template <int NCAND, int KSEL>
__global__ __launch_bounds__(256) void k_knn2(const float* __restrict__ pts, int Nq,
                                              int* __restrict__ outIdx) {
  __shared__ float sp[NCAND * 3];
  const int b = blockIdx.y;
  const float* pb = pts + (size_t)b * VS0;
  for (int i = threadIdx.x; i < NCAND * 3; i += 256) sp[i] = pb[i];
  __syncthreads();
  const int wave = threadIdx.x >> 6, lane = threadIdx.x & 63;
  const int qi = blockIdx.x * 4 + wave;
  const float qx = sp[qi * 3], qy = sp[qi * 3 + 1], qz = sp[qi * 3 + 2];
  constexpr int CH = NCAND / 64;
  float d[CH];
#pragma unroll
  for (int j = 0; j < CH; ++j) {
    const int m = lane + j * 64;
    const float dx = sp[m * 3] - qx, dy = sp[m * 3 + 1] - qy, dz = sp[m * 3 + 2] - qz;
    const float dd = dx * dx + dy * dy + dz * dz;
    d[j] = (m == qi) ? FLT_MAX : dd;
  }
  int* orow = outIdx + ((size_t)b * Nq + qi) * KSEL;
#pragma unroll 1
  for (int s = 0; s < KSEL; ++s) {
    float bd = FLT_MAX; int bj = 0;
#pragma unroll
    for (int j = 0; j < CH; ++j) {
      const bool better = d[j] < bd;
      bd = better ? d[j] : bd;
      bj = better ? j : bj;
    }
    int bm = lane + bj * 64;
#pragma unroll
    for (int off = 32; off; off >>= 1) {
      const float od = __shfl_xor(bd, off);
      const int om = __shfl_xor(bm, off);
      if (od < bd || (od == bd && om < bm)) { bd = od; bm = om; }
    }
    if (lane == 0) orow[s] = bm;
#pragma unroll
    for (int j = 0; j < CH; ++j)
      if (bm == lane + j * 64) d[j] = FLT_MAX;
  }
}

__global__ void k_transpose(const float* __restrict__ in, float* __restrict__ out) {
  int i = blockIdx.x * 256 + threadIdx.x;
  if (i >= BB * NP0 * 3) return;
  int dd = i % 3, tt = (i / 3) % NP0, b = i / (3 * NP0);
  out[i] = in[((size_t)b * 3 + dd) * NP0 + tt];
}

__global__ void k_conv_surface(const float* __restrict__ v, const int* __restrict__ idx,
                               const float* __restrict__ dirs, float* __restrict__ out,
                               int N, int M) {
  __shared__ float su[KNB_ * 3];
  int b = blockIdx.y, n = blockIdx.x, c = threadIdx.x;
  const float* vb = v + (size_t)b * VS0;
  float cx = vb[n * 3], cy = vb[n * 3 + 1], cz = vb[n * 3 + 2];
  const int* irow = idx + ((size_t)b * N + n) * KNB_;
  if (c < KNB_) {
    int j = irow[c];
    float dx = vb[j * 3] - cx, dy = vb[j * 3 + 1] - cy, dz = vb[j * 3 + 2] - cz;
    float inv = 1.f / fmaxf(sqrtf(dx * dx + dy * dy + dz * dz), 1e-12f);
    su[c * 3] = dx * inv; su[c * 3 + 1] = dy * inv; su[c * 3 + 2] = dz * inv;
  }
  __syncthreads();
  float d0 = dirs[c], d1 = dirs[M + c], d2 = dirs[2 * M + c];
  float inv = 1.f / fmaxf(sqrtf(d0 * d0 + d1 * d1 + d2 * d2), 1e-12f);
  d0 *= inv; d1 *= inv; d2 *= inv;
  float acc = 0.f;
  for (int k = 0; k < KNB_; ++k) {
    float th = fmaxf(su[k * 3] * d0 + su[k * 3 + 1] * d1 + su[k * 3 + 2] * d2, 0.f);
    acc = fmaxf(acc, th);
  }
  out[((size_t)b * N + n) * M + c] = acc;
}

__global__ void k_conv_layer(const float* __restrict__ v, const int* __restrict__ idx,
                             const float* __restrict__ dirs, const float* __restrict__ fout,
                             float* __restrict__ out, int N, int C) {
  __shared__ float su[KNB_ * 3];
  __shared__ int sidx[KNB_];
  int b = blockIdx.y, n = blockIdx.x, c = threadIdx.x;
  const float* vb = v + (size_t)b * VS0;
  float cx = vb[n * 3], cy = vb[n * 3 + 1], cz = vb[n * 3 + 2];
  const int* irow = idx + ((size_t)b * N + n) * KNB_;
  if (c < KNB_) {
    int j = irow[c]; sidx[c] = j;
    float dx = vb[j * 3] - cx, dy = vb[j * 3 + 1] - cy, dz = vb[j * 3 + 2] - cz;
    float inv = 1.f / fmaxf(sqrtf(dx * dx + dy * dy + dz * dz), 1e-12f);
    su[c * 3] = dx * inv; su[c * 3 + 1] = dy * inv; su[c * 3 + 2] = dz * inv;
  }
  __syncthreads();
  float d0 = dirs[c], d1 = dirs[C + c], d2 = dirs[2 * C + c];
  float inv = 1.f / fmaxf(sqrtf(d0 * d0 + d1 * d1 + d2 * d2), 1e-12f);
  d0 *= inv; d1 *= inv; d2 *= inv;
  const float* fb = fout + (size_t)b * N * 2 * C;
  float acc = -FLT_MAX;
  for (int k = 0; k < KNB_; ++k) {
    float th = fmaxf(su[k * 3] * d0 + su[k * 3 + 1] * d1 + su[k * 3 + 2] * d2, 0.f);
    float fs = fb[(size_t)sidx[k] * 2 * C + C + c];
    acc = fmaxf(acc, th * fs);
  }
  out[((size_t)b * N + n) * C + c] = fb[(size_t)n * 2 * C + c] + acc;
}

// ===========================================================================
// BN / pool / misc
// ===========================================================================
__global__ void k_bn_part(const float* __restrict__ x, int rows, int C, float* __restrict__ part) {
  const int blk = blockIdx.x;
  const int chunk = rows / 64;
  const int r0 = blk * chunk;
  const int c0 = threadIdx.x, c1 = threadIdx.x + 256;
  float s0 = 0, s20 = 0, s1 = 0, s21 = 0;
  for (int r = 0; r < chunk; ++r) {
    const float* row = x + (size_t)(r0 + r) * C;
    if (c0 < C) { float v = row[c0]; s0 += v; s20 += v * v; }
    if (c1 < C) { float v = row[c1]; s1 += v; s21 += v * v; }
  }
  float* p = part + (size_t)blk * 1024;
  if (c0 < C) { p[c0] = s0; p[512 + c0] = s20; }
  if (c1 < C) { p[c1] = s1; p[512 + c1] = s21; }
}

__global__ void k_bn_fin(const float* __restrict__ part, int rows, int C, float* __restrict__ stats) {
  int c = blockIdx.x * 256 + threadIdx.x;
  if (c >= C) return;
  float s = 0, s2 = 0;
  for (int b2 = 0; b2 < 64; ++b2) { s += part[b2 * 1024 + c]; s2 += part[b2 * 1024 + 512 + c]; }
  float m = s / rows;
  float var = s2 / rows - m * m;
  stats[c] = m;
  stats[C + c] = rsqrtf(var + 1e-5f);
}

template <bool ADD>
__global__ void k_bn_apply(const float* __restrict__ x, const float* __restrict__ stats,
                           const float* __restrict__ g, const float* __restrict__ bb,
                           const float* __restrict__ base, float* __restrict__ outf,
                           u16* __restrict__ ph, u16* __restrict__ pl, int total, int C) {
  int i = blockIdx.x * 256 + threadIdx.x;
  if (i >= total) return;
  int c = i % C;
  float v = (x[i] - stats[c]) * stats[C + c] * g[c] + bb[c];
  v = fmaxf(v, 0.f);
  float r = ADD ? base[i] + v : v;
  outf[i] = r;
  u16 h = f2bf(r);
  ph[i] = h;
  pl[i] = f2bf(r - bf2f(h));
}

__global__ void k_pool(const u16* __restrict__ fh, const u16* __restrict__ fl,
                       const int* __restrict__ idxp, u16* __restrict__ oh,
                       u16* __restrict__ ol, int Nin, int pn, int C) {
  int b = blockIdx.y, p = blockIdx.x, c = threadIdx.x;
  const int* ir = idxp + ((size_t)b * pn + p) * 4;
  const u16* fhb = fh + (size_t)b * Nin * C;
  const u16* flb = fl + (size_t)b * Nin * C;
  float acc = -FLT_MAX;
#pragma unroll
  for (int k = 0; k < 4; ++k) {
    size_t o = (size_t)ir[k] * C + c;
    acc = fmaxf(acc, bf2f(fhb[o]) + bf2f(flb[o]));
  }
  u16 h = f2bf(acc);
  oh[((size_t)b * pn + p) * C + c] = h;
  ol[((size_t)b * pn + p) * C + c] = f2bf(acc - bf2f(h));
}

__global__ void k_maxn(const u16* __restrict__ fh, const u16* __restrict__ fl,
                       float* __restrict__ out, int N, int C) {
  int b = blockIdx.y;
  int c = blockIdx.x * 256 + threadIdx.x;
  if (c >= C) return;
  float acc = -FLT_MAX;
  for (int n = 0; n < N; ++n) {
    size_t o = ((size_t)b * N + n) * C + c;
    acc = fmaxf(acc, bf2f(fh[o]) + bf2f(fl[o]));
  }
  out[(size_t)b * C + c] = acc;
}

__global__ void k_nearest(const float* __restrict__ v, int Ns, int* __restrict__ out) {
  extern __shared__ float sp[];
  int b = blockIdx.y;
  const float* vsb = v + (size_t)b * VS0;
  for (int i = threadIdx.x; i < Ns * 3; i += 256) sp[i] = vsb[i];
  __syncthreads();
  int t = blockIdx.x * 256 + threadIdx.x;
  float tx = vsb[t * 3], ty = vsb[t * 3 + 1], tz = vsb[t * 3 + 2];
  float bd = FLT_MAX; int bi = 0;
#pragma unroll 4
  for (int s = 0; s < Ns; ++s) {
    float dx = sp[s * 3] - tx, dy = sp[s * 3 + 1] - ty, dz = sp[s * 3 + 2] - tz;
    float dd = dx * dx + dy * dy + dz * dz;
    if (dd < bd) { bd = dd; bi = s; }
  }
  out[(size_t)b * NP0 + t] = bi;
}

__global__ void k_glob1(const float* __restrict__ fglob, const float* __restrict__ onehot,
                        const float* __restrict__ h1w, const float* __restrict__ h1b,
                        float* __restrict__ out) {
  int b = blockIdx.x, j = threadIdx.x;
  float s = h1b[j];
  for (int i = 0; i < 512; ++i) s = fmaf(fglob[b * 512 + i], h1w[(size_t)(1280 + i) * 512 + j], s);
  for (int i = 0; i < 16; ++i) s = fmaf(onehot[b * 16 + i], h1w[(size_t)(1792 + i) * 512 + j], s);
  out[b * 512 + j] = s;
}

__global__ void k_logsoftmax(float* __restrict__ x, int rows, int C) {
  int r = blockIdx.x * 4 + (threadIdx.x >> 6);
  int lane = threadIdx.x & 63;
  if (r >= rows) return;
  float* xr = x + (size_t)r * C;
  float v = (lane < C) ? xr[lane] : -FLT_MAX;
  float mx = v;
  for (int o = 32; o; o >>= 1) mx = fmaxf(mx, __shfl_xor(mx, o));
  float e = (lane < C) ? __expf(v - mx) : 0.f;
  float s = e;
  for (int o = 32; o; o >>= 1) s += __shfl_xor(s, o);
  float lse = mx + logf(s);
  if (lane < C) xr[lane] = v - lse;
}

// ===========================================================================
// host
// ===========================================================================
struct Ws {
  float *v0, *fglob, *glob1, *mx, *inv, *stats, *bpart, *xcur, *pre, *fout, *x1;
  int *idx0, *idxp0, *idx1, *idxp1, *idx2, *ni1, *ni2;
  u16 *wh, *wl;
  u16 *fm0h, *fm0l, *fm1h, *fm1l, *fm2h, *fm2l, *fm3h, *fm3l, *fm4h, *fm4l;
  u16 *fmp1h, *fmp1l, *fmp2h, *fmp2l, *qh, *ql, *vmh, *vml, *xsh, *xsl;
  u16 *x1h, *x1l, *x2b;
};

static void run_sa(hipStream_t st, Ws& ws, int N, int C, int Q,
                   const u16* qkh, const u16* qkl, const u16* vwh, const u16* vwl,
                   const u16* twh, const u16* twl,
                   const float* vb, const float* tb, const float* g, const float* be,
                   u16* xh, u16* xl) {
  const long sx = (long)N * C;
  // q = x qk^T -> planes [N][Q]
  mmp<64, 0, 0, 1, false, false>(st, xh, xl, qkh, qkl, nullptr, ws.qh, ws.ql,
                                 N, Q, C, sx, 0, (long)N * Q, BB, 1);
  // vm = x vw^T + vb -> transposed planes [C][N]
  mmp<64, 0, 1, 2, false, false>(st, xh, xl, vwh, vwl, vb, ws.vmh, ws.vml,
                                 N, C, C, sx, 0, sx, BB, 1);
  // fused attention
  dim3 gs(N / 128, BB), gx(N / 128, C / 128, BB);
  if (Q == 32) {
    k_sa_stats<32><<<gs, 256, 0, st>>>(ws.qh, ws.ql, N, ws.mx, ws.inv);
    k_sa_xr<32><<<gx, 256, 0, st>>>(ws.qh, ws.ql, ws.vmh, ws.vml, ws.mx, ws.inv,
                                    ws.xcur, ws.xsh, ws.xsl, N, C);
  } else if (Q == 64) {
    k_sa_stats<64><<<gs, 256, 0, st>>>(ws.qh, ws.ql, N, ws.mx, ws.inv);
    k_sa_xr<64><<<gx, 256, 0, st>>>(ws.qh, ws.ql, ws.vmh, ws.vml, ws.mx, ws.inv,
                                    ws.xcur, ws.xsh, ws.xsl, N, C);
  } else {
    k_sa_stats<128><<<gs, 256, 0, st>>>(ws.qh, ws.ql, N, ws.mx, ws.inv);
    k_sa_xr<128><<<gx, 256, 0, st>>>(ws.qh, ws.ql, ws.vmh, ws.vml, ws.mx, ws.inv,
                                     ws.xcur, ws.xsh, ws.xsl, N, C);
  }
  // pre = xs tw^T + tb -> f32
  mmp<64, 0, 1, 0, false, false>(st, ws.xsh, ws.xsl, twh, twl, tb, ws.pre, nullptr,
                                 N, C, C, sx, 0, sx, BB, 1);
  k_bn_part<<<64, 256, 0, st>>>(ws.pre, BB * N, C, ws.bpart);
  k_bn_fin<<<(C + 255) / 256, 256, 0, st>>>(ws.bpart, BB * N, C, ws.stats);
  k_bn_apply<true><<<(BB * N * C + 255) / 256, 256, 0, st>>>(ws.pre, ws.stats, g, be,
                                                             ws.xcur, ws.xcur, xh, xl, BB * N * C, C);
}

static void run_conv(hipStream_t st, Ws& ws, const u16* finh, const u16* finl, int Cin,
                     const u16* cwh, const u16* cwl, const float* bias, const float* dirs,
                     const int* idx, int N, int C,
                     const float* bng, const float* bnb, bool doBN, u16* fmh, u16* fml) {
  if (N == NP0)
    mmp<128, 0, 1, 0, false, false>(st, finh, finl, cwh, cwl, bias, ws.fout, nullptr,
                                    N, 2 * C, Cin, (long)N * Cin, 0, (long)N * 2 * C, BB, 1);
  else
    mmp<64, 0, 1, 0, false, false>(st, finh, finl, cwh, cwl, bias, ws.fout, nullptr,
                                   N, 2 * C, Cin, (long)N * Cin, 0, (long)N * 2 * C, BB, 1);
  k_conv_layer<<<dim3(N, BB), C, 0, st>>>(ws.v0, idx, dirs, ws.fout, ws.xcur, N, C);
  if (doBN) {
    k_bn_part<<<64, 256, 0, st>>>(ws.xcur, BB * N, C, ws.bpart);
    k_bn_fin<<<(C + 255) / 256, 256, 0, st>>>(ws.bpart, BB * N, C, ws.stats);
    k_bn_apply<false><<<(BB * N * C + 255) / 256, 256, 0, st>>>(
        ws.xcur, ws.stats, bng, bnb, nullptr, ws.xcur, fmh, fml, BB * N * C, C);
  } else {
    k_split4<false><<<(BB * N * C / 4 + 255) / 256, 256, 0, st>>>(ws.xcur, fmh, fml, BB * N * C / 4);
  }
}

extern "C" void kernel_launch(void* const* d_in, const int* in_sizes, int n_in,
                              void* d_out, int out_size, void* d_ws, size_t ws_size,
                              hipStream_t stream) {
  auto in = [&](int i) { return (const float*)d_in[i]; };
  char* p = (char*)d_ws;
  Ws ws;
  ws.v0 = (float*)(p + O_V0);
  ws.idx0 = (int*)(p + O_IDX0); ws.idxp0 = (int*)(p + O_IDXP0);
  ws.idx1 = (int*)(p + O_IDX1); ws.idxp1 = (int*)(p + O_IDXP1);
  ws.idx2 = (int*)(p + O_IDX2);
  ws.ni1 = (int*)(p + O_NI1); ws.ni2 = (int*)(p + O_NI2);
  ws.fglob = (float*)(p + O_FGLOB); ws.glob1 = (float*)(p + O_GLOB1);
  ws.mx = (float*)(p + O_COLS); ws.inv = (float*)(p + O_CPART);
  ws.stats = (float*)(p + O_STATS); ws.bpart = (float*)(p + O_BPART);
  ws.xcur = (float*)(p + O_XCUR);
  ws.pre = (float*)(p + O_AREA);
  ws.fout = (float*)(p + O_AREA); ws.x1 = (float*)(p + O_AREA);
  char* pl = p + O_PL;
  ws.wh = (u16*)(pl + PL_WH); ws.wl = (u16*)(pl + PL_WL);
  ws.fm0h = (u16*)(pl + PL_FM0H); ws.fm0l = (u16*)(pl + PL_FM0L);
  ws.fm1h = (u16*)(pl + PL_FM1H); ws.fm1l = (u16*)(pl + PL_FM1L);
  ws.fm2h = (u16*)(pl + PL_FM2H); ws.fm2l = (u16*)(pl + PL_FM2L);
  ws.fm3h = (u16*)(pl + PL_FM3H); ws.fm3l = (u16*)(pl + PL_FM3L);
  ws.fm4h = (u16*)(pl + PL_FM4H); ws.fm4l = (u16*)(pl + PL_FM4L);
  ws.fmp1h = (u16*)(pl + PL_FMP1H); ws.fmp1l = (u16*)(pl + PL_FMP1L);
  ws.fmp2h = (u16*)(pl + PL_FMP2H); ws.fmp2l = (u16*)(pl + PL_FMP2L);
  ws.qh = (u16*)(pl + PL_QH); ws.ql = (u16*)(pl + PL_QL);
  ws.vmh = (u16*)(pl + PL_VMH); ws.vml = (u16*)(pl + PL_VML);
  ws.xsh = (u16*)(pl + PL_XSH); ws.xsl = (u16*)(pl + PL_XSL);
  ws.x1h = (u16*)(pl + PL_X1H); ws.x1l = (u16*)(pl + PL_X1L);
  ws.x2b = (u16*)(p + O_XCUR);
  float* out = (float*)d_out;

  // ---- one-time weight plane split (pre-transposed to [N,K]) ----
  SplitJobs jobs;
  size_t wq[26];
  size_t off = 0;
  int ji = 0;
  auto addjob = [&](const float* s, int K, int N, int trans) {
    int n = K * N;
    jobs.j[ji] = {s, ws.wh + off, ws.wl + off, n, K, N, trans};
    wq[ji] = off; off += (size_t)n; ++ji;
  };
  addjob(in(5), 128, 32, 0);  addjob(in(6), 128, 128, 0);  addjob(in(8), 128, 128, 0);
  addjob(in(17), 128, 32, 0); addjob(in(18), 128, 128, 0); addjob(in(20), 128, 128, 0);
  addjob(in(29), 256, 64, 0); addjob(in(30), 256, 256, 0); addjob(in(32), 256, 256, 0);
  addjob(in(41), 256, 64, 0); addjob(in(42), 256, 256, 0); addjob(in(44), 256, 256, 0);
  addjob(in(51), 512, 128, 0); addjob(in(52), 512, 512, 0); addjob(in(54), 512, 512, 0);
  addjob(in(12), 128, 256, 1);
  addjob(in(24), 128, 512, 1);
  addjob(in(36), 256, 512, 1);
  addjob(in(48), 256, 1024, 1);
  addjob(in(58) + 0 * 512, 128, 512, 1);
  addjob(in(58) + (size_t)128 * 512, 128, 512, 1);
  addjob(in(58) + (size_t)256 * 512, 256, 512, 1);
  addjob(in(58) + (size_t)512 * 512, 256, 512, 1);
  addjob(in(58) + (size_t)768 * 512, 512, 512, 1);
  addjob(in(60), 512, 512, 1);
  addjob(in(62), 512, 50, 1);
  k_splitjobs<<<dim3(32, 26), 256, 0, stream>>>(jobs);
  auto W = [&](int i) { return ws.wh + wq[i]; };
  auto Wl = [&](int i) { return ws.wl + wq[i]; };

  // ---- geometry ----
  k_transpose<<<(BB * NP0 * 3 + 255) / 256, 256, 0, stream>>>(in(0), ws.v0);
  k_knn_radix<NP0, KNB_><<<dim3(NP0 / 4, BB), 256, 0, stream>>>(ws.v0, NP0, ws.idx0);

  // ---- conv0 + bn0 ----
  k_conv_surface<<<dim3(NP0, BB), 128, 0, stream>>>(ws.v0, ws.idx0, in(2), ws.xcur, NP0, 128);
  k_bn_part<<<64, 256, 0, stream>>>(ws.xcur, BB * NP0, 128, ws.bpart);
  k_bn_fin<<<1, 256, 0, stream>>>(ws.bpart, BB * NP0, 128, ws.stats);
  k_bn_apply<false><<<(BB * NP0 * 128 + 255) / 256, 256, 0, stream>>>(
      ws.xcur, ws.stats, in(3), in(4), nullptr, ws.xcur, ws.fm0h, ws.fm0l, BB * NP0 * 128, 128);

  // ---- sa0, conv1+bn1, sa1 ----
  run_sa(stream, ws, NP0, 128, 32, W(0), Wl(0), W(1), Wl(1), W(2), Wl(2),
         in(7), in(9), in(10), in(11), ws.fm0h, ws.fm0l);
  run_conv(stream, ws, ws.fm0h, ws.fm0l, 128, W(15), Wl(15), in(13), in(14), ws.idx0,
           NP0, 128, in(15), in(16), true, ws.fm1h, ws.fm1l);
  run_sa(stream, ws, NP0, 128, 32, W(3), Wl(3), W(4), Wl(4), W(5), Wl(5),
         in(19), in(21), in(22), in(23), ws.fm1h, ws.fm1l);

  // ---- pool1, knn1 ----
  k_knn2<NP0, 4><<<dim3(NP1 / 4, BB), 256, 0, stream>>>(ws.v0, NP1, ws.idxp0);
  k_pool<<<dim3(NP1, BB), 128, 0, stream>>>(ws.fm1h, ws.fm1l, ws.idxp0,
                                            ws.fmp1h, ws.fmp1l, NP0, NP1, 128);
  k_knn_radix<NP1, KNB_><<<dim3(NP1 / 4, BB), 256, 0, stream>>>(ws.v0, NP1, ws.idx1);

  // ---- conv2+bn2, sa2, conv3+bn3, sa3 ----
  run_conv(stream, ws, ws.fmp1h, ws.fmp1l, 128, W(16), Wl(16), in(25), in(26), ws.idx1,
           NP1, 256, in(27), in(28), true, ws.fm2h, ws.fm2l);
  run_sa(stream, ws, NP1, 256, 64, W(6), Wl(6), W(7), Wl(7), W(8), Wl(8),
         in(31), in(33), in(34), in(35), ws.fm2h, ws.fm2l);
  run_conv(stream, ws, ws.fm2h, ws.fm2l, 256, W(17), Wl(17), in(37), in(38), ws.idx1,
           NP1, 256, in(39), in(40), true, ws.fm3h, ws.fm3l);
  run_sa(stream, ws, NP1, 256, 64, W(9), Wl(9), W(10), Wl(10), W(11), Wl(11),
         in(43), in(45), in(46), in(47), ws.fm3h, ws.fm3l);

  // ---- pool2, knn2, conv4 (no bn), sa4 ----
  k_knn2<NP1, 4><<<dim3(NP2 / 4, BB), 256, 0, stream>>>(ws.v0, NP2, ws.idxp1);
  k_pool<<<dim3(NP2, BB), 256, 0, stream>>>(ws.fm3h, ws.fm3l, ws.idxp1,
                                            ws.fmp2h, ws.fmp2l, NP1, NP2, 256);
  k_knn_radix<NP2, KNB_><<<dim3(NP2 / 4, BB), 256, 0, stream>>>(ws.v0, NP2, ws.idx2);
  run_conv(stream, ws, ws.fmp2h, ws.fmp2l, 256, W(18), Wl(18), in(49), in(50), ws.idx2,
           NP2, 512, nullptr, nullptr, false, ws.fm4h, ws.fm4l);
  run_sa(stream, ws, NP2, 512, 128, W(12), Wl(12), W(13), Wl(13), W(14), Wl(14),
         in(53), in(55), in(56), in(57), ws.fm4h, ws.fm4l);

  // ---- global max, nearest, head ----
  k_maxn<<<dim3(2, BB), 256, 0, stream>>>(ws.fm4h, ws.fm4l, ws.fglob, NP2, 512);
  k_nearest<<<dim3(NP0 / 256, BB), 256, NP1 * 3 * 4, stream>>>(ws.v0, NP1, ws.ni1);
  k_nearest<<<dim3(NP0 / 256, BB), 256, NP2 * 3 * 4, stream>>>(ws.v0, NP2, ws.ni2);
  k_glob1<<<BB, 512, 0, stream>>>(ws.fglob, in(1), in(58), in(59), ws.glob1);

  for (int hf = 0; hf < 2; ++hf) {
    const int b0 = hf * 4;
    mmp<128, 0, 2, 0, false, false>(stream, ws.fm0h + (size_t)b0 * NP0 * 128,
        ws.fm0l + (size_t)b0 * NP0 * 128, W(19), Wl(19), ws.glob1 + b0 * 512, ws.x1, nullptr,
        NP0, 512, 128, (long)NP0 * 128, 0, (long)NP0 * 512, 4, 1);
    mmp<128, 0, 0, 0, true, false>(stream, ws.fm1h + (size_t)b0 * NP0 * 128,
        ws.fm1l + (size_t)b0 * NP0 * 128, W(20), Wl(20), nullptr, ws.x1, nullptr,
        NP0, 512, 128, (long)NP0 * 128, 0, (long)NP0 * 512, 4, 1);
    mmp<128, 0, 0, 0, true, true>(stream, ws.fm2h + (size_t)b0 * NP1 * 256,
        ws.fm2l + (size_t)b0 * NP1 * 256, W(21), Wl(21), nullptr, ws.x1, nullptr,
        NP0, 512, 256, (long)NP1 * 256, 0, (long)NP0 * 512, 4, 1,
        ws.ni1 + (size_t)b0 * NP0, NP0);
    mmp<128, 0, 0, 0, true, true>(stream, ws.fm3h + (size_t)b0 * NP1 * 256,
        ws.fm3l + (size_t)b0 * NP1 * 256, W(22), Wl(22), nullptr, ws.x1, nullptr,
        NP0, 512, 256, (long)NP1 * 256, 0, (long)NP0 * 512, 4, 1,
        ws.ni1 + (size_t)b0 * NP0, NP0);
    mmp<128, 0, 0, 0, true, true>(stream, ws.fm4h + (size_t)b0 * NP2 * 512,
        ws.fm4l + (size_t)b0 * NP2 * 512, W(23), Wl(23), nullptr, ws.x1, nullptr,
        NP0, 512, 512, (long)NP2 * 512, 0, (long)NP0 * 512, 4, 1,
        ws.ni2 + (size_t)b0 * NP0, NP0);
    k_split4<true><<<(4 * NP0 * 512 / 4 + 255) / 256, 256, 0, stream>>>(
        ws.x1, ws.x1h, ws.x1l, 4 * NP0 * 512 / 4);
    mmp<128, 0, 1, 3, false, false>(stream, ws.x1h, ws.x1l, W(24), Wl(24), in(61),
        ws.x2b, nullptr, NP0, 512, 512, (long)NP0 * 512, 0, (long)NP0 * 512, 4, 1);
    mmp<64, 2, 1, 0, false, false>(stream, ws.x2b, nullptr, W(25), Wl(25), in(63),
        out + (size_t)b0 * NP0 * 50, nullptr, NP0, 50, 512,
        (long)NP0 * 512, 0, (long)NP0 * 50, 4, 1);
  }

  k_logsoftmax<<<(BB * NP0) / 4, 256, 0, stream>>>(out, BB * NP0, 50);
}

// Round 9
// 1775.534 us; speedup vs baseline: 2.1497x; 1.0995x over previous
//
#include <hip/hip_runtime.h>
#include <cfloat>

// ---------------------------------------------------------------------------
// GCN3D forward. Split-plane bf16 MFMA GEMMs (Dekker, f32-grade accuracy).
// Round-9: fused-SA kernels re-tiled from 128-row to 64-row m-tiles:
// 2x blocks (full CU coverage at N=2048) and LDS 106.5->71.7 KB (2 blocks/CU)
// to fix the 5.6%-occupancy latency stall seen in k_sa_xr.
// B=8, N=2048->512->128, K_NB=50. Workspace 93,814,784 B.
// ---------------------------------------------------------------------------

#define BB   8
#define NP0  2048
#define NP1  512
#define NP2  128
#define KNB_ 50
#define VS0  (NP0 * 3)

typedef __attribute__((ext_vector_type(8))) short short8_t;
typedef __attribute__((ext_vector_type(4))) short short4_t;
typedef __attribute__((ext_vector_type(4))) float f32x4_t;
typedef unsigned short u16;

// ---------------- workspace layout (byte offsets) ----------------
static constexpr size_t O_V0    = 0;
static constexpr size_t O_IDX0  = 196608;
static constexpr size_t O_IDXP0 = 3473408;
static constexpr size_t O_IDX1  = 3538944;
static constexpr size_t O_IDXP1 = 4358144;
static constexpr size_t O_IDX2  = 4374528;
static constexpr size_t O_NI1   = 4579328;
static constexpr size_t O_NI2   = 4644864;
static constexpr size_t O_FGLOB = 4710400;
static constexpr size_t O_GLOB1 = 4726784;
static constexpr size_t O_COLS  = 4743168;   // mx vectors (64KB)
static constexpr size_t O_CPART = 4808704;   // inv vectors (64KB used)
static constexpr size_t O_STATS = 5332992;
static constexpr size_t O_BPART = 5337088;
static constexpr size_t O_XCUR  = 5599232;   // 8,388,608 f32 activation scratch
static constexpr size_t O_PL    = 18182144;  // 58,855,424 plane pools
static constexpr size_t O_AREA  = 77037568;  // 16,777,216 fout / pre / x1half
// end = 93,814,784

static constexpr size_t PL_WH    = 0;
static constexpr size_t PL_WL    = 4786176;
static constexpr size_t PL_FM0H  = 9572352;
static constexpr size_t PL_FM0L  = 13766656;
static constexpr size_t PL_FM1H  = 17960960;
static constexpr size_t PL_FM1L  = 22155264;
static constexpr size_t PL_FM2H  = 26349568;
static constexpr size_t PL_FM2L  = 28446720;
static constexpr size_t PL_FM3H  = 30543872;
static constexpr size_t PL_FM3L  = 32641024;
static constexpr size_t PL_FM4H  = 34738176;
static constexpr size_t PL_FM4L  = 35786752;
static constexpr size_t PL_FMP1H = 36835328;
static constexpr size_t PL_FMP1L = 37883904;
static constexpr size_t PL_FMP2H = 38932480;
static constexpr size_t PL_FMP2L = 39456768;
static constexpr size_t PL_QH    = 39981056;
static constexpr size_t PL_QL    = 41029632;
static constexpr size_t PL_VMH   = 42078208;
static constexpr size_t PL_VML   = 46272512;
static constexpr size_t PL_XSH   = 50466816;
static constexpr size_t PL_XSL   = 54661120;
static constexpr size_t PL_X1H = PL_VMH;   // head aliases (phase-disjoint)
static constexpr size_t PL_X1L = PL_XSH;

__device__ __forceinline__ float bf2f(u16 h) {
  union { unsigned u; float f; } c; c.u = ((unsigned)h) << 16; return c.f;
}
__device__ __forceinline__ u16 f2bf(float f) {
  union { float f; unsigned u; } c; c.f = f;
  return (u16)((c.u + 0x7fffu + ((c.u >> 16) & 1u)) >> 16);
}

// ===========================================================================
// Plane GEMM (unchanged).
// ===========================================================================
template <int TM, int AMODE, int BIASM, int OUTM, bool ACC, bool GIDX>
__global__ __launch_bounds__(256) void k_mmp(
    const void* __restrict__ A1, const void* __restrict__ A2,
    const u16* __restrict__ Bh0, const u16* __restrict__ Bl0,
    const float* __restrict__ bias, void* __restrict__ C1, void* __restrict__ C2,
    int M, int N, int K, long sA, long sB, long sC, int ksplit,
    const int* __restrict__ gidx, long sG) {
  constexpr int RT = TM / 32;
  constexpr int CT = TM / 32;
  __shared__ u16 Ah[TM][40], Bh[TM][40], Bl[TM][40];
  __shared__ u16 Al[(AMODE == 2) ? 1 : TM][40];
  const int z = blockIdx.z;
  const int zb = z / ksplit, ks = z - zb * ksplit;
  const int kchunk = K / ksplit;
  const int kl0 = ks * kchunk, kl1 = kl0 + kchunk;
  const int m0 = blockIdx.x * TM, n0 = blockIdx.y * TM;
  const int t = threadIdx.x;
  const int lane = t & 63, w = t >> 6;
  const int wr = (w >> 1) * (TM / 2), wc = (w & 1) * (TM / 2);
  const int frow = lane & 15, koff = (lane >> 4) * 8;
  f32x4_t acc[RT][CT];
#pragma unroll
  for (int i = 0; i < RT; ++i)
#pragma unroll
    for (int j = 0; j < CT; ++j) acc[i][j] = (f32x4_t){0.f, 0.f, 0.f, 0.f};

  const u16* Ahg = (const u16*)A1 + (size_t)zb * sA;
  const u16* Alg = (const u16*)A2 + (size_t)zb * sA;
  const u16* Bhg = Bh0 + (size_t)zb * sB;
  const u16* Blg = Bl0 + (size_t)zb * sB;

  int ar, ac, arow = 0;
  if constexpr (TM == 128) { ar = t >> 1; ac = (t & 1) * 16; }
  else                     { ar = t >> 2; ac = (t & 3) * 8; }
  arow = m0 + ar;
  if constexpr (GIDX) arow = (gidx + (size_t)zb * sG)[arow];
  const int bn = ar, bc = ac;
  const bool bok = (n0 + bn) < N;
  const short8_t z8 = {0, 0, 0, 0, 0, 0, 0, 0};

  for (int k0 = kl0; k0 < kl1; k0 += 32) {
    __syncthreads();
    {
      const u16* s1 = Ahg + (size_t)arow * K + k0 + ac;
      if constexpr (TM == 128) {
        *(short8_t*)&Ah[ar][ac] = *(const short8_t*)s1;
        *(short8_t*)&Ah[ar][ac + 8] = *(const short8_t*)(s1 + 8);
        if constexpr (AMODE == 0) {
          const u16* s2 = Alg + (size_t)arow * K + k0 + ac;
          *(short8_t*)&Al[ar][ac] = *(const short8_t*)s2;
          *(short8_t*)&Al[ar][ac + 8] = *(const short8_t*)(s2 + 8);
        }
      } else {
        *(short8_t*)&Ah[ar][ac] = *(const short8_t*)s1;
        if constexpr (AMODE == 0)
          *(short8_t*)&Al[ar][ac] = *(const short8_t*)(Alg + (size_t)arow * K + k0 + ac);
      }
    }
    {
      const u16* s1 = Bhg + (size_t)(n0 + bn) * K + k0 + bc;
      const u16* s2 = Blg + (size_t)(n0 + bn) * K + k0 + bc;
      if constexpr (TM == 128) {
        *(short8_t*)&Bh[bn][bc] = bok ? *(const short8_t*)s1 : z8;
        *(short8_t*)&Bh[bn][bc + 8] = bok ? *(const short8_t*)(s1 + 8) : z8;
        *(short8_t*)&Bl[bn][bc] = bok ? *(const short8_t*)s2 : z8;
        *(short8_t*)&Bl[bn][bc + 8] = bok ? *(const short8_t*)(s2 + 8) : z8;
      } else {
        *(short8_t*)&Bh[bn][bc] = bok ? *(const short8_t*)s1 : z8;
        *(short8_t*)&Bl[bn][bc] = bok ? *(const short8_t*)s2 : z8;
      }
    }
    __syncthreads();
    short8_t ah[RT], al[RT], bh[CT], bl[CT];
#pragma unroll
    for (int i = 0; i < RT; ++i) {
      const int r = wr + i * 16 + frow;
      ah[i] = *(const short8_t*)&Ah[r][koff];
      if constexpr (AMODE != 2) al[i] = *(const short8_t*)&Al[r][koff];
    }
#pragma unroll
    for (int i = 0; i < CT; ++i) {
      const int r = wc + i * 16 + frow;
      bh[i] = *(const short8_t*)&Bh[r][koff];
      bl[i] = *(const short8_t*)&Bl[r][koff];
    }
#pragma unroll
    for (int i = 0; i < RT; ++i)
#pragma unroll
      for (int j = 0; j < CT; ++j) {
        acc[i][j] = __builtin_amdgcn_mfma_f32_16x16x32_bf16(ah[i], bh[j], acc[i][j], 0, 0, 0);
        acc[i][j] = __builtin_amdgcn_mfma_f32_16x16x32_bf16(ah[i], bl[j], acc[i][j], 0, 0, 0);
        if constexpr (AMODE != 2)
          acc[i][j] = __builtin_amdgcn_mfma_f32_16x16x32_bf16(al[i], bh[j], acc[i][j], 0, 0, 0);
      }
  }

  const int crow = (lane >> 4) * 4;
#pragma unroll
  for (int i = 0; i < RT; ++i) {
#pragma unroll
    for (int j = 0; j < CT; ++j) {
      const int gc = n0 + wc + j * 16 + frow;
      if (gc >= N) continue;
      float bv = 0.f;
      if constexpr (BIASM == 1) bv = bias[gc];
      if constexpr (BIASM == 2) bv = bias[(size_t)zb * N + gc];
      const int gr0 = m0 + wr + i * 16 + crow;
      if constexpr (OUTM == 0) {
        float* Cp = (float*)C1 + (size_t)z * sC;
#pragma unroll
        for (int q = 0; q < 4; ++q) {
          float vv = acc[i][j][q] + bv;
          if (ACC) vv += Cp[(size_t)(gr0 + q) * N + gc];
          Cp[(size_t)(gr0 + q) * N + gc] = vv;
        }
      } else if constexpr (OUTM == 1) {
        u16* Ph = (u16*)C1 + (size_t)z * sC;
        u16* Pl = (u16*)C2 + (size_t)z * sC;
#pragma unroll
        for (int q = 0; q < 4; ++q) {
          float vv = acc[i][j][q] + bv;
          u16 h = f2bf(vv);
          Ph[(size_t)(gr0 + q) * N + gc] = h;
          Pl[(size_t)(gr0 + q) * N + gc] = f2bf(vv - bf2f(h));
        }
      } else if constexpr (OUTM == 2) {
        u16* Ph = (u16*)C1 + (size_t)z * sC;
        u16* Pl = (u16*)C2 + (size_t)z * sC;
        short4_t h4, l4;
#pragma unroll
        for (int q = 0; q < 4; ++q) {
          float vv = acc[i][j][q] + bv;
          u16 h = f2bf(vv);
          h4[q] = (short)h;
          l4[q] = (short)f2bf(vv - bf2f(h));
        }
        *(short4_t*)(Ph + (size_t)gc * M + gr0) = h4;
        *(short4_t*)(Pl + (size_t)gc * M + gr0) = l4;
      } else {
        u16* Cb = (u16*)C1 + (size_t)z * sC;
#pragma unroll
        for (int q = 0; q < 4; ++q) {
          float vv = fmaxf(acc[i][j][q] + bv, 0.f);
          Cb[(size_t)(gr0 + q) * N + gc] = f2bf(vv);
        }
      }
    }
  }
}

template <int TM, int AMODE, int BIASM, int OUTM, bool ACC, bool GIDX>
static void mmp(hipStream_t st, const void* A1, const void* A2,
                const u16* Bh, const u16* Bl, const float* bias,
                void* C1, void* C2, int M, int N, int K,
                long sA, long sB, long sC, int Z, int ksplit,
                const int* gidx = nullptr, long sG = 0) {
  dim3 grid(M / TM, (N + TM - 1) / TM, Z * ksplit);
  k_mmp<TM, AMODE, BIASM, OUTM, ACC, GIDX><<<grid, 256, 0, st>>>(
      A1, A2, Bh, Bl, bias, C1, C2, M, N, K, sA, sB, sC, ksplit, gidx, sG);
}

// ===========================================================================
// Fused attention, 64-row m-tiles. q planes [B][N][QD]; vm planes [B][C][N].
// Wave layout: 2(m:32) x 2(n-or-c:64); per-wave acc[2][4].
// ===========================================================================
template <int QD>
__global__ __launch_bounds__(256) void k_sa_stats(
    const u16* __restrict__ qh, const u16* __restrict__ ql, int N,
    float* __restrict__ mx, float* __restrict__ inv) {
  __shared__ float mr[2][64], sr[2][64];
  const int b = blockIdx.y;
  const int m0 = blockIdx.x * 64;
  const int t = threadIdx.x, lane = t & 63, w = t >> 6;
  const int wm = (w >> 1) * 32, wn = (w & 1) * 64;
  const int frow = lane & 15, kq = (lane >> 4) * 8;
  const u16* qhb = qh + (size_t)b * N * QD;
  const u16* qlb = ql + (size_t)b * N * QD;
  constexpr int KS = QD / 32;
  float M[2][4], S[2][4];
#pragma unroll
  for (int i = 0; i < 2; ++i)
#pragma unroll
    for (int q = 0; q < 4; ++q) { M[i][q] = -FLT_MAX; S[i][q] = 0.f; }

  for (int n0 = 0; n0 < N; n0 += 128) {
    f32x4_t acc[2][4];
#pragma unroll
    for (int i = 0; i < 2; ++i)
#pragma unroll
      for (int j = 0; j < 4; ++j) acc[i][j] = (f32x4_t){0.f, 0.f, 0.f, 0.f};
#pragma unroll
    for (int ks = 0; ks < KS; ++ks) {
      short8_t a_h[2], a_l[2], b_h[4], b_l[4];
#pragma unroll
      for (int i = 0; i < 2; ++i) {
        const size_t r = (size_t)(m0 + wm + i * 16 + frow) * QD + ks * 32 + kq;
        a_h[i] = *(const short8_t*)(qhb + r);
        a_l[i] = *(const short8_t*)(qlb + r);
      }
#pragma unroll
      for (int j = 0; j < 4; ++j) {
        const size_t r = (size_t)(n0 + wn + j * 16 + frow) * QD + ks * 32 + kq;
        b_h[j] = *(const short8_t*)(qhb + r);
        b_l[j] = *(const short8_t*)(qlb + r);
      }
#pragma unroll
      for (int i = 0; i < 2; ++i)
#pragma unroll
        for (int j = 0; j < 4; ++j) {
          acc[i][j] = __builtin_amdgcn_mfma_f32_16x16x32_bf16(a_h[i], b_h[j], acc[i][j], 0, 0, 0);
          acc[i][j] = __builtin_amdgcn_mfma_f32_16x16x32_bf16(a_h[i], b_l[j], acc[i][j], 0, 0, 0);
          acc[i][j] = __builtin_amdgcn_mfma_f32_16x16x32_bf16(a_l[i], b_h[j], acc[i][j], 0, 0, 0);
        }
    }
#pragma unroll
    for (int i = 0; i < 2; ++i)
#pragma unroll
      for (int q = 0; q < 4; ++q) {
        float tm = acc[i][0][q];
#pragma unroll
        for (int j = 1; j < 4; ++j) tm = fmaxf(tm, acc[i][j][q]);
#pragma unroll
        for (int off = 1; off < 16; off <<= 1) tm = fmaxf(tm, __shfl_xor(tm, off));
        const float Mn = fmaxf(M[i][q], tm);
        float ps = 0.f;
#pragma unroll
        for (int j = 0; j < 4; ++j) ps += __expf(acc[i][j][q] - Mn);
#pragma unroll
        for (int off = 1; off < 16; off <<= 1) ps += __shfl_xor(ps, off);
        S[i][q] = S[i][q] * __expf(M[i][q] - Mn) + ps;
        M[i][q] = Mn;
      }
  }
  if (frow == 0) {
#pragma unroll
    for (int i = 0; i < 2; ++i)
#pragma unroll
      for (int q = 0; q < 4; ++q) {
        const int ml = wm + i * 16 + (lane >> 4) * 4 + q;
        mr[w & 1][ml] = M[i][q];
        sr[w & 1][ml] = S[i][q];
      }
  }
  __syncthreads();
  if (t < 64) {
    const float M0 = mr[0][t], M1 = mr[1][t];
    const float Mm = fmaxf(M0, M1);
    const float Sm = sr[0][t] * __expf(M0 - Mm) + sr[1][t] * __expf(M1 - Mm);
    mx[(size_t)b * N + m0 + t] = Mm;
    inv[(size_t)b * N + m0 + t] = 1.f / Sm;
  }
}

template <int QD>
__global__ __launch_bounds__(256) void k_sa_xr(
    const u16* __restrict__ qh, const u16* __restrict__ ql,
    const u16* __restrict__ vmh, const u16* __restrict__ vml,
    const float* __restrict__ mx, const float* __restrict__ inv,
    const float* __restrict__ xcur, u16* __restrict__ xsh, u16* __restrict__ xsl,
    int N, int C) {
  __shared__ __align__(16) u16 Ph[64][136], Pl[64][136];
  __shared__ __align__(16) u16 Vh[128][72], Vl[128][72];
  const int b = blockIdx.z;
  const int m0 = blockIdx.x * 64, c0 = blockIdx.y * 128;
  const int t = threadIdx.x, lane = t & 63, w = t >> 6;
  const int wm = (w >> 1) * 32, wn = (w & 1) * 64;
  const int frow = lane & 15, kq = (lane >> 4) * 8;
  const u16* qhb = qh + (size_t)b * N * QD;
  const u16* qlb = ql + (size_t)b * N * QD;
  const u16* vhb = vmh + (size_t)b * (size_t)N * C;  // [C][N]
  const u16* vlb = vml + (size_t)b * (size_t)N * C;
  const float* mxb = mx + (size_t)b * N;
  const float* invb = inv + (size_t)b * N;
  constexpr int KS = QD / 32;
  const int vr = t >> 1, vco = (t & 1) * 32;
  f32x4_t xacc[2][4];
  float csum[2][4];
#pragma unroll
  for (int i = 0; i < 2; ++i)
#pragma unroll
    for (int j = 0; j < 4; ++j) { xacc[i][j] = (f32x4_t){0.f, 0.f, 0.f, 0.f}; csum[i][j] = 0.f; }

  for (int n0 = 0; n0 < N; n0 += 128) {
    __syncthreads();  // previous P/V reads complete
    // stage V half 0: cols n0..n0+64
    {
      const u16* s1 = vhb + (size_t)(c0 + vr) * N + n0 + vco;
      const u16* s2 = vlb + (size_t)(c0 + vr) * N + n0 + vco;
#pragma unroll
      for (int u = 0; u < 4; ++u) {
        *(short8_t*)&Vh[vr][vco + u * 8] = *(const short8_t*)(s1 + u * 8);
        *(short8_t*)&Vl[vr][vco + u * 8] = *(const short8_t*)(s2 + u * 8);
      }
    }
    // S tile (in-register, global q frags): m 64 x n 128
    f32x4_t acc[2][4];
#pragma unroll
    for (int i = 0; i < 2; ++i)
#pragma unroll
      for (int j = 0; j < 4; ++j) acc[i][j] = (f32x4_t){0.f, 0.f, 0.f, 0.f};
#pragma unroll
    for (int ks = 0; ks < KS; ++ks) {
      short8_t a_h[2], a_l[2], b_h[4], b_l[4];
#pragma unroll
      for (int i = 0; i < 2; ++i) {
        const size_t r = (size_t)(m0 + wm + i * 16 + frow) * QD + ks * 32 + kq;
        a_h[i] = *(const short8_t*)(qhb + r);
        a_l[i] = *(const short8_t*)(qlb + r);
      }
#pragma unroll
      for (int j = 0; j < 4; ++j) {
        const size_t r = (size_t)(n0 + wn + j * 16 + frow) * QD + ks * 32 + kq;
        b_h[j] = *(const short8_t*)(qhb + r);
        b_l[j] = *(const short8_t*)(qlb + r);
      }
#pragma unroll
      for (int i = 0; i < 2; ++i)
#pragma unroll
        for (int j = 0; j < 4; ++j) {
          acc[i][j] = __builtin_amdgcn_mfma_f32_16x16x32_bf16(a_h[i], b_h[j], acc[i][j], 0, 0, 0);
          acc[i][j] = __builtin_amdgcn_mfma_f32_16x16x32_bf16(a_h[i], b_l[j], acc[i][j], 0, 0, 0);
          acc[i][j] = __builtin_amdgcn_mfma_f32_16x16x32_bf16(a_l[i], b_h[j], acc[i][j], 0, 0, 0);
        }
    }
    // transform -> P planes in LDS; csum accumulate
    float mxj[4], ivj[4];
#pragma unroll
    for (int j = 0; j < 4; ++j) {
      const int n = n0 + wn + j * 16 + frow;
      mxj[j] = mxb[n];
      ivj[j] = invb[n];
    }
    const int mbase = wm + (lane >> 4) * 4;
#pragma unroll
    for (int i = 0; i < 2; ++i)
#pragma unroll
      for (int j = 0; j < 4; ++j)
#pragma unroll
        for (int q = 0; q < 4; ++q) {
          const float pv = __expf(acc[i][j][q] - mxj[j]) * ivj[j];
          csum[i][q] += pv;
          const u16 h = f2bf(pv);
          Ph[mbase + i * 16 + q][wn + j * 16 + frow] = h;
          Pl[mbase + i * 16 + q][wn + j * 16 + frow] = f2bf(pv - bf2f(h));
        }
    __syncthreads();  // P + V half0 ready
#pragma unroll
    for (int ks2 = 0; ks2 < 2; ++ks2) {
      short8_t p_h[2], p_l[2], v_h[4], v_l[4];
#pragma unroll
      for (int i = 0; i < 2; ++i) {
        p_h[i] = *(const short8_t*)&Ph[wm + i * 16 + frow][ks2 * 32 + kq];
        p_l[i] = *(const short8_t*)&Pl[wm + i * 16 + frow][ks2 * 32 + kq];
      }
#pragma unroll
      for (int j = 0; j < 4; ++j) {
        v_h[j] = *(const short8_t*)&Vh[wn + j * 16 + frow][ks2 * 32 + kq];
        v_l[j] = *(const short8_t*)&Vl[wn + j * 16 + frow][ks2 * 32 + kq];
      }
#pragma unroll
      for (int i = 0; i < 2; ++i)
#pragma unroll
        for (int j = 0; j < 4; ++j) {
          xacc[i][j] = __builtin_amdgcn_mfma_f32_16x16x32_bf16(p_h[i], v_h[j], xacc[i][j], 0, 0, 0);
          xacc[i][j] = __builtin_amdgcn_mfma_f32_16x16x32_bf16(p_h[i], v_l[j], xacc[i][j], 0, 0, 0);
          xacc[i][j] = __builtin_amdgcn_mfma_f32_16x16x32_bf16(p_l[i], v_h[j], xacc[i][j], 0, 0, 0);
        }
    }
    __syncthreads();  // V half0 reads complete
    // stage V half 1: cols n0+64..n0+128
    {
      const u16* s1 = vhb + (size_t)(c0 + vr) * N + n0 + 64 + vco;
      const u16* s2 = vlb + (size_t)(c0 + vr) * N + n0 + 64 + vco;
#pragma unroll
      for (int u = 0; u < 4; ++u) {
        *(short8_t*)&Vh[vr][vco + u * 8] = *(const short8_t*)(s1 + u * 8);
        *(short8_t*)&Vl[vr][vco + u * 8] = *(const short8_t*)(s2 + u * 8);
      }
    }
    __syncthreads();  // V half1 ready
#pragma unroll
    for (int ks2 = 0; ks2 < 2; ++ks2) {
      short8_t p_h[2], p_l[2], v_h[4], v_l[4];
#pragma unroll
      for (int i = 0; i < 2; ++i) {
        p_h[i] = *(const short8_t*)&Ph[wm + i * 16 + frow][64 + ks2 * 32 + kq];
        p_l[i] = *(const short8_t*)&Pl[wm + i * 16 + frow][64 + ks2 * 32 + kq];
      }
#pragma unroll
      for (int j = 0; j < 4; ++j) {
        v_h[j] = *(const short8_t*)&Vh[wn + j * 16 + frow][ks2 * 32 + kq];
        v_l[j] = *(const short8_t*)&Vl[wn + j * 16 + frow][ks2 * 32 + kq];
      }
#pragma unroll
      for (int i = 0; i < 2; ++i)
#pragma unroll
        for (int j = 0; j < 4; ++j) {
          xacc[i][j] = __builtin_amdgcn_mfma_f32_16x16x32_bf16(p_h[i], v_h[j], xacc[i][j], 0, 0, 0);
          xacc[i][j] = __builtin_amdgcn_mfma_f32_16x16x32_bf16(p_h[i], v_l[j], xacc[i][j], 0, 0, 0);
          xacc[i][j] = __builtin_amdgcn_mfma_f32_16x16x32_bf16(p_l[i], v_h[j], xacc[i][j], 0, 0, 0);
        }
    }
  }
  // csum: reduce over frow lanes, then cross wave n-halves via LDS
#pragma unroll
  for (int i = 0; i < 2; ++i)
#pragma unroll
    for (int q = 0; q < 4; ++q)
#pragma unroll
      for (int off = 1; off < 16; off <<= 1) csum[i][q] += __shfl_xor(csum[i][q], off);
  __syncthreads();
  float* csb = (float*)&Ph[0][0];
  if (frow == 0) {
#pragma unroll
    for (int i = 0; i < 2; ++i)
#pragma unroll
      for (int q = 0; q < 4; ++q)
        csb[(w & 1) * 64 + wm + i * 16 + (lane >> 4) * 4 + q] = csum[i][q];
  }
  __syncthreads();
  if (t < 64) csb[128 + t] = csb[t] + csb[64 + t];
  __syncthreads();
  // epilogue: xs = x - xr/(1e-9+csum) -> planes
#pragma unroll
  for (int i = 0; i < 2; ++i) {
#pragma unroll
    for (int q = 0; q < 4; ++q) {
      const int mloc = wm + i * 16 + (lane >> 4) * 4 + q;
      const float cstot = csb[128 + mloc];
      const size_t rowoff = ((size_t)b * N + m0 + mloc) * C;
#pragma unroll
      for (int j = 0; j < 4; ++j) {
        const int gc = c0 + wn + j * 16 + frow;
        const float val = xcur[rowoff + gc] - xacc[i][j][q] / (1e-9f + cstot);
        const u16 h = f2bf(val);
        xsh[rowoff + gc] = h;
        xsl[rowoff + gc] = f2bf(val - bf2f(h));
      }
    }
  }
}

// ===========================================================================
// weight split + activation split
// ===========================================================================
struct SplitJob { const float* s; u16* dh; u16* dl; int n, K, N, trans; };
struct SplitJobs { SplitJob j[26]; };
__global__ void k_splitjobs(SplitJobs jobs) {
  SplitJob jb = jobs.j[blockIdx.y];
  for (int i = blockIdx.x * 256 + threadIdx.x; i < jb.n; i += gridDim.x * 256) {
    float v;
    if (jb.trans) { int k = i % jb.K, n = i / jb.K; v = jb.s[(size_t)k * jb.N + n]; }
    else v = jb.s[i];
    u16 h = f2bf(v);
    jb.dh[i] = h;
    jb.dl[i] = f2bf(v - bf2f(h));
  }
}

template <bool RELU>
__global__ void k_split4(const float* __restrict__ x, u16* __restrict__ ph,
                         u16* __restrict__ pl, int n4) {
  int i = blockIdx.x * 256 + threadIdx.x;
  if (i >= n4) return;
  float4 v = ((const float4*)x)[i];
  short4_t h4, l4;
  float vv[4] = {v.x, v.y, v.z, v.w};
#pragma unroll
  for (int q = 0; q < 4; ++q) {
    float f = RELU ? fmaxf(vv[q], 0.f) : vv[q];
    u16 h = f2bf(f);
    h4[q] = (short)h;
    l4[q] = (short)f2bf(f - bf2f(h));
  }
  *(short4_t*)(ph + (size_t)i * 4) = h4;
  *(short4_t*)(pl + (size_t)i * 4) = l4;
}

// ===========================================================================
// KNN (radix-select for K=50; iterative argmin for K=4)
// ===========================================================================
template <int NCAND, int KSEL>
__global__ __launch_bounds__(256) void k_knn_radix(const float* __restrict__ pts, int Nq,
                                                   int* __restrict__ outIdx) {
  __shared__ float sp[NCAND * 3];
  const int b = blockIdx.y;
  const float* pb = pts + (size_t)b * VS0;
  for (int i = threadIdx.x; i < NCAND * 3; i += 256) sp[i] = pb[i];
  __syncthreads();
  const int wave = threadIdx.x >> 6, lane = threadIdx.x & 63;
  const int qi = blockIdx.x * 4 + wave;
  const float qx = sp[qi * 3], qy = sp[qi * 3 + 1], qz = sp[qi * 3 + 2];
  constexpr int CH = NCAND / 64;
  unsigned d[CH];
  unsigned x[32];
#pragma unroll
  for (int j = 0; j < 32; ++j) x[j] = 0u;
#pragma unroll
  for (int j = 0; j < CH; ++j) {
    const int m = lane + j * 64;
    const float dx = sp[m * 3] - qx, dy = sp[m * 3 + 1] - qy, dz = sp[m * 3 + 2] - qz;
    const float dd = dx * dx + dy * dy + dz * dz;
    d[j] = __float_as_uint((m == qi) ? FLT_MAX : dd);
    x[j] = d[j];
  }
#pragma unroll
  for (int st = 0; st < 5; ++st) {
    const int s = 16 >> st;
    const unsigned ml = (s == 16) ? 0x0000FFFFu : (s == 8) ? 0x00FF00FFu
                      : (s == 4) ? 0x0F0F0F0Fu : (s == 2) ? 0x33333333u : 0x55555555u;
#pragma unroll
    for (int i = 0; i < 32; ++i) {
      if (i & s) continue;
      unsigned t = ((x[i] >> s) ^ x[i + s]) & ml;
      x[i + s] ^= t;
      x[i] ^= (t << s);
    }
  }
  unsigned active = (CH == 32) ? 0xFFFFFFFFu : ((1u << CH) - 1u);
  unsigned T = 0u;
  int kk = KSEL;
#pragma unroll
  for (int bb = 30; bb >= 0; --bb) {
    const unsigned zn = active & ~x[bb];
    int c0 = __popc(zn);
#pragma unroll
    for (int off = 32; off; off >>= 1) c0 += __shfl_xor(c0, off);
    if (kk <= c0) {
      active = zn;
    } else {
      kk -= c0;
      active &= x[bb];
      T |= (1u << bb);
    }
  }
  int* orow = outIdx + ((size_t)b * Nq + qi) * KSEL;
  const unsigned long long ltmask = (1ull << lane) - 1ull;
  int base = 0;
#pragma unroll
  for (int j = 0; j < CH; ++j) {
    const bool sel = d[j] < T;
    const unsigned long long bal = __ballot(sel);
    const int pos = base + (int)__popcll(bal & ltmask);
    if (sel) orow[pos] = lane + j * 64;
    base += (int)__popcll(bal);
  }
#pragma unroll
  for (int j = 0; j < CH; ++j) {
    const bool sel = ((active >> j) & 1u) != 0u;
    const unsigned long long bal = __ballot(sel);
    const int pos = base + (int)__popcll(bal & ltmask);
    if (sel && pos < KSEL) orow[pos] = lane + j * 64;
    base += (int)__popcll(bal);
  }
}

template <int NCAND, int KSEL>
__global__ __launch_bounds__(256) void k_knn2(const float* __restrict__ pts, int Nq,
                                              int* __restrict__ outIdx) {
  __shared__ float sp[NCAND * 3];
  const int b = blockIdx.y;
  const float* pb = pts + (size_t)b * VS0;
  for (int i = threadIdx.x; i < NCAND * 3; i += 256) sp[i] = pb[i];
  __syncthreads();
  const int wave = threadIdx.x >> 6, lane = threadIdx.x & 63;
  const int qi = blockIdx.x * 4 + wave;
  const float qx = sp[qi * 3], qy = sp[qi * 3 + 1], qz = sp[qi * 3 + 2];
  constexpr int CH = NCAND / 64;
  float d[CH];
#pragma unroll
  for (int j = 0; j < CH; ++j) {
    const int m = lane + j * 64;
    const float dx = sp[m * 3] - qx, dy = sp[m * 3 + 1] - qy, dz = sp[m * 3 + 2] - qz;
    const float dd = dx * dx + dy * dy + dz * dz;
    d[j] = (m == qi) ? FLT_MAX : dd;
  }
  int* orow = outIdx + ((size_t)b * Nq + qi) * KSEL;
#pragma unroll 1
  for (int s = 0; s < KSEL; ++s) {
    float bd = FLT_MAX; int bj = 0;
#pragma unroll
    for (int j = 0; j < CH; ++j) {
      const bool better = d[j] < bd;
      bd = better ? d[j] : bd;
      bj = better ? j : bj;
    }
    int bm = lane + bj * 64;
#pragma unroll
    for (int off = 32; off; off >>= 1) {
      const float od = __shfl_xor(bd, off);
      const int om = __shfl_xor(bm, off);
      if (od < bd || (od == bd && om < bm)) { bd = od; bm = om; }
    }
    if (lane == 0) orow[s] = bm;
#pragma unroll
    for (int j = 0; j < CH; ++j)
      if (bm == lane + j * 64) d[j] = FLT_MAX;
  }
}

__global__ void k_transpose(const float* __restrict__ in, float* __restrict__ out) {
  int i = blockIdx.x * 256 + threadIdx.x;
  if (i >= BB * NP0 * 3) return;
  int dd = i % 3, tt = (i / 3) % NP0, b = i / (3 * NP0);
  out[i] = in[((size_t)b * 3 + dd) * NP0 + tt];
}

__global__ void k_conv_surface(const float* __restrict__ v, const int* __restrict__ idx,
                               const float* __restrict__ dirs, float* __restrict__ out,
                               int N, int M) {
  __shared__ float su[KNB_ * 3];
  int b = blockIdx.y, n = blockIdx.x, c = threadIdx.x;
  const float* vb = v + (size_t)b * VS0;
  float cx = vb[n * 3], cy = vb[n * 3 + 1], cz = vb[n * 3 + 2];
  const int* irow = idx + ((size_t)b * N + n) * KNB_;
  if (c < KNB_) {
    int j = irow[c];
    float dx = vb[j * 3] - cx, dy = vb[j * 3 + 1] - cy, dz = vb[j * 3 + 2] - cz;
    float inv = 1.f / fmaxf(sqrtf(dx * dx + dy * dy + dz * dz), 1e-12f);
    su[c * 3] = dx * inv; su[c * 3 + 1] = dy * inv; su[c * 3 + 2] = dz * inv;
  }
  __syncthreads();
  float d0 = dirs[c], d1 = dirs[M + c], d2 = dirs[2 * M + c];
  float inv = 1.f / fmaxf(sqrtf(d0 * d0 + d1 * d1 + d2 * d2), 1e-12f);
  d0 *= inv; d1 *= inv; d2 *= inv;
  float acc = 0.f;
  for (int k = 0; k < KNB_; ++k) {
    float th = fmaxf(su[k * 3] * d0 + su[k * 3 + 1] * d1 + su[k * 3 + 2] * d2, 0.f);
    acc = fmaxf(acc, th);
  }
  out[((size_t)b * N + n) * M + c] = acc;
}

__global__ void k_conv_layer(const float* __restrict__ v, const int* __restrict__ idx,
                             const float* __restrict__ dirs, const float* __restrict__ fout,
                             float* __restrict__ out, int N, int C) {
  __shared__ float su[KNB_ * 3];
  __shared__ int sidx[KNB_];
  int b = blockIdx.y, n = blockIdx.x, c = threadIdx.x;
  const float* vb = v + (size_t)b * VS0;
  float cx = vb[n * 3], cy = vb[n * 3 + 1], cz = vb[n * 3 + 2];
  const int* irow = idx + ((size_t)b * N + n) * KNB_;
  if (c < KNB_) {
    int j = irow[c]; sidx[c] = j;
    float dx = vb[j * 3] - cx, dy = vb[j * 3 + 1] - cy, dz = vb[j * 3 + 2] - cz;
    float inv = 1.f / fmaxf(sqrtf(dx * dx + dy * dy + dz * dz), 1e-12f);
    su[c * 3] = dx * inv; su[c * 3 + 1] = dy * inv; su[c * 3 + 2] = dz * inv;
  }
  __syncthreads();
  float d0 = dirs[c], d1 = dirs[C + c], d2 = dirs[2 * C + c];
  float inv = 1.f / fmaxf(sqrtf(d0 * d0 + d1 * d1 + d2 * d2), 1e-12f);
  d0 *= inv; d1 *= inv; d2 *= inv;
  const float* fb = fout + (size_t)b * N * 2 * C;
  float acc = -FLT_MAX;
  for (int k = 0; k < KNB_; ++k) {
    float th = fmaxf(su[k * 3] * d0 + su[k * 3 + 1] * d1 + su[k * 3 + 2] * d2, 0.f);
    float fs = fb[(size_t)sidx[k] * 2 * C + C + c];
    acc = fmaxf(acc, th * fs);
  }
  out[((size_t)b * N + n) * C + c] = fb[(size_t)n * 2 * C + c] + acc;
}

// ===========================================================================
// BN / pool / misc
// ===========================================================================
__global__ void k_bn_part(const float* __restrict__ x, int rows, int C, float* __restrict__ part) {
  const int blk = blockIdx.x;
  const int chunk = rows / 64;
  const int r0 = blk * chunk;
  const int c0 = threadIdx.x, c1 = threadIdx.x + 256;
  float s0 = 0, s20 = 0, s1 = 0, s21 = 0;
  for (int r = 0; r < chunk; ++r) {
    const float* row = x + (size_t)(r0 + r) * C;
    if (c0 < C) { float v = row[c0]; s0 += v; s20 += v * v; }
    if (c1 < C) { float v = row[c1]; s1 += v; s21 += v * v; }
  }
  float* p = part + (size_t)blk * 1024;
  if (c0 < C) { p[c0] = s0; p[512 + c0] = s20; }
  if (c1 < C) { p[c1] = s1; p[512 + c1] = s21; }
}

__global__ void k_bn_fin(const float* __restrict__ part, int rows, int C, float* __restrict__ stats) {
  int c = blockIdx.x * 256 + threadIdx.x;
  if (c >= C) return;
  float s = 0, s2 = 0;
  for (int b2 = 0; b2 < 64; ++b2) { s += part[b2 * 1024 + c]; s2 += part[b2 * 1024 + 512 + c]; }
  float m = s / rows;
  float var = s2 / rows - m * m;
  stats[c] = m;
  stats[C + c] = rsqrtf(var + 1e-5f);
}

template <bool ADD>
__global__ void k_bn_apply(const float* __restrict__ x, const float* __restrict__ stats,
                           const float* __restrict__ g, const float* __restrict__ bb,
                           const float* __restrict__ base, float* __restrict__ outf,
                           u16* __restrict__ ph, u16* __restrict__ pl, int total, int C) {
  int i = blockIdx.x * 256 + threadIdx.x;
  if (i >= total) return;
  int c = i % C;
  float v = (x[i] - stats[c]) * stats[C + c] * g[c] + bb[c];
  v = fmaxf(v, 0.f);
  float r = ADD ? base[i] + v : v;
  outf[i] = r;
  u16 h = f2bf(r);
  ph[i] = h;
  pl[i] = f2bf(r - bf2f(h));
}

__global__ void k_pool(const u16* __restrict__ fh, const u16* __restrict__ fl,
                       const int* __restrict__ idxp, u16* __restrict__ oh,
                       u16* __restrict__ ol, int Nin, int pn, int C) {
  int b = blockIdx.y, p = blockIdx.x, c = threadIdx.x;
  const int* ir = idxp + ((size_t)b * pn + p) * 4;
  const u16* fhb = fh + (size_t)b * Nin * C;
  const u16* flb = fl + (size_t)b * Nin * C;
  float acc = -FLT_MAX;
#pragma unroll
  for (int k = 0; k < 4; ++k) {
    size_t o = (size_t)ir[k] * C + c;
    acc = fmaxf(acc, bf2f(fhb[o]) + bf2f(flb[o]));
  }
  u16 h = f2bf(acc);
  oh[((size_t)b * pn + p) * C + c] = h;
  ol[((size_t)b * pn + p) * C + c] = f2bf(acc - bf2f(h));
}

__global__ void k_maxn(const u16* __restrict__ fh, const u16* __restrict__ fl,
                       float* __restrict__ out, int N, int C) {
  int b = blockIdx.y;
  int c = blockIdx.x * 256 + threadIdx.x;
  if (c >= C) return;
  float acc = -FLT_MAX;
  for (int n = 0; n < N; ++n) {
    size_t o = ((size_t)b * N + n) * C + c;
    acc = fmaxf(acc, bf2f(fh[o]) + bf2f(fl[o]));
  }
  out[(size_t)b * C + c] = acc;
}

__global__ void k_nearest(const float* __restrict__ v, int Ns, int* __restrict__ out) {
  extern __shared__ float sp[];
  int b = blockIdx.y;
  const float* vsb = v + (size_t)b * VS0;
  for (int i = threadIdx.x; i < Ns * 3; i += 256) sp[i] = vsb[i];
  __syncthreads();
  int t = blockIdx.x * 256 + threadIdx.x;
  float tx = vsb[t * 3], ty = vsb[t * 3 + 1], tz = vsb[t * 3 + 2];
  float bd = FLT_MAX; int bi = 0;
#pragma unroll 4
  for (int s = 0; s < Ns; ++s) {
    float dx = sp[s * 3] - tx, dy = sp[s * 3 + 1] - ty, dz = sp[s * 3 + 2] - tz;
    float dd = dx * dx + dy * dy + dz * dz;
    if (dd < bd) { bd = dd; bi = s; }
  }
  out[(size_t)b * NP0 + t] = bi;
}

__global__ void k_glob1(const float* __restrict__ fglob, const float* __restrict__ onehot,
                        const float* __restrict__ h1w, const float* __restrict__ h1b,
                        float* __restrict__ out) {
  int b = blockIdx.x, j = threadIdx.x;
  float s = h1b[j];
  for (int i = 0; i < 512; ++i) s = fmaf(fglob[b * 512 + i], h1w[(size_t)(1280 + i) * 512 + j], s);
  for (int i = 0; i < 16; ++i) s = fmaf(onehot[b * 16 + i], h1w[(size_t)(1792 + i) * 512 + j], s);
  out[b * 512 + j] = s;
}

__global__ void k_logsoftmax(float* __restrict__ x, int rows, int C) {
  int r = blockIdx.x * 4 + (threadIdx.x >> 6);
  int lane = threadIdx.x & 63;
  if (r >= rows) return;
  float* xr = x + (size_t)r * C;
  float v = (lane < C) ? xr[lane] : -FLT_MAX;
  float mx = v;
  for (int o = 32; o; o >>= 1) mx = fmaxf(mx, __shfl_xor(mx, o));
  float e = (lane < C) ? __expf(v - mx) : 0.f;
  float s = e;
  for (int o = 32; o; o >>= 1) s += __shfl_xor(s, o);
  float lse = mx + logf(s);
  if (lane < C) xr[lane] = v - lse;
}

// ===========================================================================
// host
// ===========================================================================
struct Ws {
  float *v0, *fglob, *glob1, *mx, *inv, *stats, *bpart, *xcur, *pre, *fout, *x1;
  int *idx0, *idxp0, *idx1, *idxp1, *idx2, *ni1, *ni2;
  u16 *wh, *wl;
  u16 *fm0h, *fm0l, *fm1h, *fm1l, *fm2h, *fm2l, *fm3h, *fm3l, *fm4h, *fm4l;
  u16 *fmp1h, *fmp1l, *fmp2h, *fmp2l, *qh, *ql, *vmh, *vml, *xsh, *xsl;
  u16 *x1h, *x1l, *x2b;
};

static void run_sa(hipStream_t st, Ws& ws, int N, int C, int Q,
                   const u16* qkh, const u16* qkl, const u16* vwh, const u16* vwl,
                   const u16* twh, const u16* twl,
                   const float* vb, const float* tb, const float* g, const float* be,
                   u16* xh, u16* xl) {
  const long sx = (long)N * C;
  mmp<64, 0, 0, 1, false, false>(st, xh, xl, qkh, qkl, nullptr, ws.qh, ws.ql,
                                 N, Q, C, sx, 0, (long)N * Q, BB, 1);
  mmp<64, 0, 1, 2, false, false>(st, xh, xl, vwh, vwl, vb, ws.vmh, ws.vml,
                                 N, C, C, sx, 0, sx, BB, 1);
  dim3 gs(N / 64, BB), gx(N / 64, C / 128, BB);
  if (Q == 32) {
    k_sa_stats<32><<<gs, 256, 0, st>>>(ws.qh, ws.ql, N, ws.mx, ws.inv);
    k_sa_xr<32><<<gx, 256, 0, st>>>(ws.qh, ws.ql, ws.vmh, ws.vml, ws.mx, ws.inv,
                                    ws.xcur, ws.xsh, ws.xsl, N, C);
  } else if (Q == 64) {
    k_sa_stats<64><<<gs, 256, 0, st>>>(ws.qh, ws.ql, N, ws.mx, ws.inv);
    k_sa_xr<64><<<gx, 256, 0, st>>>(ws.qh, ws.ql, ws.vmh, ws.vml, ws.mx, ws.inv,
                                    ws.xcur, ws.xsh, ws.xsl, N, C);
  } else {
    k_sa_stats<128><<<gs, 256, 0, st>>>(ws.qh, ws.ql, N, ws.mx, ws.inv);
    k_sa_xr<128><<<gx, 256, 0, st>>>(ws.qh, ws.ql, ws.vmh, ws.vml, ws.mx, ws.inv,
                                     ws.xcur, ws.xsh, ws.xsl, N, C);
  }
  mmp<64, 0, 1, 0, false, false>(st, ws.xsh, ws.xsl, twh, twl, tb, ws.pre, nullptr,
                                 N, C, C, sx, 0, sx, BB, 1);
  k_bn_part<<<64, 256, 0, st>>>(ws.pre, BB * N, C, ws.bpart);
  k_bn_fin<<<(C + 255) / 256, 256, 0, st>>>(ws.bpart, BB * N, C, ws.stats);
  k_bn_apply<true><<<(BB * N * C + 255) / 256, 256, 0, st>>>(ws.pre, ws.stats, g, be,
                                                             ws.xcur, ws.xcur, xh, xl, BB * N * C, C);
}

static void run_conv(hipStream_t st, Ws& ws, const u16* finh, const u16* finl, int Cin,
                     const u16* cwh, const u16* cwl, const float* bias, const float* dirs,
                     const int* idx, int N, int C,
                     const float* bng, const float* bnb, bool doBN, u16* fmh, u16* fml) {
  if (N == NP0)
    mmp<128, 0, 1, 0, false, false>(st, finh, finl, cwh, cwl, bias, ws.fout, nullptr,
                                    N, 2 * C, Cin, (long)N * Cin, 0, (long)N * 2 * C, BB, 1);
  else
    mmp<64, 0, 1, 0, false, false>(st, finh, finl, cwh, cwl, bias, ws.fout, nullptr,
                                   N, 2 * C, Cin, (long)N * Cin, 0, (long)N * 2 * C, BB, 1);
  k_conv_layer<<<dim3(N, BB), C, 0, st>>>(ws.v0, idx, dirs, ws.fout, ws.xcur, N, C);
  if (doBN) {
    k_bn_part<<<64, 256, 0, st>>>(ws.xcur, BB * N, C, ws.bpart);
    k_bn_fin<<<(C + 255) / 256, 256, 0, st>>>(ws.bpart, BB * N, C, ws.stats);
    k_bn_apply<false><<<(BB * N * C + 255) / 256, 256, 0, st>>>(
        ws.xcur, ws.stats, bng, bnb, nullptr, ws.xcur, fmh, fml, BB * N * C, C);
  } else {
    k_split4<false><<<(BB * N * C / 4 + 255) / 256, 256, 0, st>>>(ws.xcur, fmh, fml, BB * N * C / 4);
  }
}

extern "C" void kernel_launch(void* const* d_in, const int* in_sizes, int n_in,
                              void* d_out, int out_size, void* d_ws, size_t ws_size,
                              hipStream_t stream) {
  auto in = [&](int i) { return (const float*)d_in[i]; };
  char* p = (char*)d_ws;
  Ws ws;
  ws.v0 = (float*)(p + O_V0);
  ws.idx0 = (int*)(p + O_IDX0); ws.idxp0 = (int*)(p + O_IDXP0);
  ws.idx1 = (int*)(p + O_IDX1); ws.idxp1 = (int*)(p + O_IDXP1);
  ws.idx2 = (int*)(p + O_IDX2);
  ws.ni1 = (int*)(p + O_NI1); ws.ni2 = (int*)(p + O_NI2);
  ws.fglob = (float*)(p + O_FGLOB); ws.glob1 = (float*)(p + O_GLOB1);
  ws.mx = (float*)(p + O_COLS); ws.inv = (float*)(p + O_CPART);
  ws.stats = (float*)(p + O_STATS); ws.bpart = (float*)(p + O_BPART);
  ws.xcur = (float*)(p + O_XCUR);
  ws.pre = (float*)(p + O_AREA);
  ws.fout = (float*)(p + O_AREA); ws.x1 = (float*)(p + O_AREA);
  char* pl = p + O_PL;
  ws.wh = (u16*)(pl + PL_WH); ws.wl = (u16*)(pl + PL_WL);
  ws.fm0h = (u16*)(pl + PL_FM0H); ws.fm0l = (u16*)(pl + PL_FM0L);
  ws.fm1h = (u16*)(pl + PL_FM1H); ws.fm1l = (u16*)(pl + PL_FM1L);
  ws.fm2h = (u16*)(pl + PL_FM2H); ws.fm2l = (u16*)(pl + PL_FM2L);
  ws.fm3h = (u16*)(pl + PL_FM3H); ws.fm3l = (u16*)(pl + PL_FM3L);
  ws.fm4h = (u16*)(pl + PL_FM4H); ws.fm4l = (u16*)(pl + PL_FM4L);
  ws.fmp1h = (u16*)(pl + PL_FMP1H); ws.fmp1l = (u16*)(pl + PL_FMP1L);
  ws.fmp2h = (u16*)(pl + PL_FMP2H); ws.fmp2l = (u16*)(pl + PL_FMP2L);
  ws.qh = (u16*)(pl + PL_QH); ws.ql = (u16*)(pl + PL_QL);
  ws.vmh = (u16*)(pl + PL_VMH); ws.vml = (u16*)(pl + PL_VML);
  ws.xsh = (u16*)(pl + PL_XSH); ws.xsl = (u16*)(pl + PL_XSL);
  ws.x1h = (u16*)(pl + PL_X1H); ws.x1l = (u16*)(pl + PL_X1L);
  ws.x2b = (u16*)(p + O_XCUR);
  float* out = (float*)d_out;

  // ---- one-time weight plane split (pre-transposed to [N,K]) ----
  SplitJobs jobs;
  size_t wq[26];
  size_t off = 0;
  int ji = 0;
  auto addjob = [&](const float* s, int K, int N, int trans) {
    int n = K * N;
    jobs.j[ji] = {s, ws.wh + off, ws.wl + off, n, K, N, trans};
    wq[ji] = off; off += (size_t)n; ++ji;
  };
  addjob(in(5), 128, 32, 0);  addjob(in(6), 128, 128, 0);  addjob(in(8), 128, 128, 0);
  addjob(in(17), 128, 32, 0); addjob(in(18), 128, 128, 0); addjob(in(20), 128, 128, 0);
  addjob(in(29), 256, 64, 0); addjob(in(30), 256, 256, 0); addjob(in(32), 256, 256, 0);
  addjob(in(41), 256, 64, 0); addjob(in(42), 256, 256, 0); addjob(in(44), 256, 256, 0);
  addjob(in(51), 512, 128, 0); addjob(in(52), 512, 512, 0); addjob(in(54), 512, 512, 0);
  addjob(in(12), 128, 256, 1);
  addjob(in(24), 128, 512, 1);
  addjob(in(36), 256, 512, 1);
  addjob(in(48), 256, 1024, 1);
  addjob(in(58) + 0 * 512, 128, 512, 1);
  addjob(in(58) + (size_t)128 * 512, 128, 512, 1);
  addjob(in(58) + (size_t)256 * 512, 256, 512, 1);
  addjob(in(58) + (size_t)512 * 512, 256, 512, 1);
  addjob(in(58) + (size_t)768 * 512, 512, 512, 1);
  addjob(in(60), 512, 512, 1);
  addjob(in(62), 512, 50, 1);
  k_splitjobs<<<dim3(32, 26), 256, 0, stream>>>(jobs);
  auto W = [&](int i) { return ws.wh + wq[i]; };
  auto Wl = [&](int i) { return ws.wl + wq[i]; };

  // ---- geometry ----
  k_transpose<<<(BB * NP0 * 3 + 255) / 256, 256, 0, stream>>>(in(0), ws.v0);
  k_knn_radix<NP0, KNB_><<<dim3(NP0 / 4, BB), 256, 0, stream>>>(ws.v0, NP0, ws.idx0);

  // ---- conv0 + bn0 ----
  k_conv_surface<<<dim3(NP0, BB), 128, 0, stream>>>(ws.v0, ws.idx0, in(2), ws.xcur, NP0, 128);
  k_bn_part<<<64, 256, 0, stream>>>(ws.xcur, BB * NP0, 128, ws.bpart);
  k_bn_fin<<<1, 256, 0, stream>>>(ws.bpart, BB * NP0, 128, ws.stats);
  k_bn_apply<false><<<(BB * NP0 * 128 + 255) / 256, 256, 0, stream>>>(
      ws.xcur, ws.stats, in(3), in(4), nullptr, ws.xcur, ws.fm0h, ws.fm0l, BB * NP0 * 128, 128);

  // ---- sa0, conv1+bn1, sa1 ----
  run_sa(stream, ws, NP0, 128, 32, W(0), Wl(0), W(1), Wl(1), W(2), Wl(2),
         in(7), in(9), in(10), in(11), ws.fm0h, ws.fm0l);
  run_conv(stream, ws, ws.fm0h, ws.fm0l, 128, W(15), Wl(15), in(13), in(14), ws.idx0,
           NP0, 128, in(15), in(16), true, ws.fm1h, ws.fm1l);
  run_sa(stream, ws, NP0, 128, 32, W(3), Wl(3), W(4), Wl(4), W(5), Wl(5),
         in(19), in(21), in(22), in(23), ws.fm1h, ws.fm1l);

  // ---- pool1, knn1 ----
  k_knn2<NP0, 4><<<dim3(NP1 / 4, BB), 256, 0, stream>>>(ws.v0, NP1, ws.idxp0);
  k_pool<<<dim3(NP1, BB), 128, 0, stream>>>(ws.fm1h, ws.fm1l, ws.idxp0,
                                            ws.fmp1h, ws.fmp1l, NP0, NP1, 128);
  k_knn_radix<NP1, KNB_><<<dim3(NP1 / 4, BB), 256, 0, stream>>>(ws.v0, NP1, ws.idx1);

  // ---- conv2+bn2, sa2, conv3+bn3, sa3 ----
  run_conv(stream, ws, ws.fmp1h, ws.fmp1l, 128, W(16), Wl(16), in(25), in(26), ws.idx1,
           NP1, 256, in(27), in(28), true, ws.fm2h, ws.fm2l);
  run_sa(stream, ws, NP1, 256, 64, W(6), Wl(6), W(7), Wl(7), W(8), Wl(8),
         in(31), in(33), in(34), in(35), ws.fm2h, ws.fm2l);
  run_conv(stream, ws, ws.fm2h, ws.fm2l, 256, W(17), Wl(17), in(37), in(38), ws.idx1,
           NP1, 256, in(39), in(40), true, ws.fm3h, ws.fm3l);
  run_sa(stream, ws, NP1, 256, 64, W(9), Wl(9), W(10), Wl(10), W(11), Wl(11),
         in(43), in(45), in(46), in(47), ws.fm3h, ws.fm3l);

  // ---- pool2, knn2, conv4 (no bn), sa4 ----
  k_knn2<NP1, 4><<<dim3(NP2 / 4, BB), 256, 0, stream>>>(ws.v0, NP2, ws.idxp1);
  k_pool<<<dim3(NP2, BB), 256, 0, stream>>>(ws.fm3h, ws.fm3l, ws.idxp1,
                                            ws.fmp2h, ws.fmp2l, NP1, NP2, 256);
  k_knn_radix<NP2, KNB_><<<dim3(NP2 / 4, BB), 256, 0, stream>>>(ws.v0, NP2, ws.idx2);
  run_conv(stream, ws, ws.fmp2h, ws.fmp2l, 256, W(18), Wl(18), in(49), in(50), ws.idx2,
           NP2, 512, nullptr, nullptr, false, ws.fm4h, ws.fm4l);
  run_sa(stream, ws, NP2, 512, 128, W(12), Wl(12), W(13), Wl(13), W(14), Wl(14),
         in(53), in(55), in(56), in(57), ws.fm4h, ws.fm4l);

  // ---- global max, nearest, head ----
  k_maxn<<<dim3(2, BB), 256, 0, stream>>>(ws.fm4h, ws.fm4l, ws.fglob, NP2, 512);
  k_nearest<<<dim3(NP0 / 256, BB), 256, NP1 * 3 * 4, stream>>>(ws.v0, NP1, ws.ni1);
  k_nearest<<<dim3(NP0 / 256, BB), 256, NP2 * 3 * 4, stream>>>(ws.v0, NP2, ws.ni2);
  k_glob1<<<BB, 512, 0, stream>>>(ws.fglob, in(1), in(58), in(59), ws.glob1);

  for (int hf = 0; hf < 2; ++hf) {
    const int b0 = hf * 4;
    mmp<128, 0, 2, 0, false, false>(stream, ws.fm0h + (size_t)b0 * NP0 * 128,
        ws.fm0l + (size_t)b0 * NP0 * 128, W(19), Wl(19), ws.glob1 + b0 * 512, ws.x1, nullptr,
        NP0, 512, 128, (long)NP0 * 128, 0, (long)NP0 * 512, 4, 1);
    mmp<128, 0, 0, 0, true, false>(stream, ws.fm1h + (size_t)b0 * NP0 * 128,
        ws.fm1l + (size_t)b0 * NP0 * 128, W(20), Wl(20), nullptr, ws.x1, nullptr,
        NP0, 512, 128, (long)NP0 * 128, 0, (long)NP0 * 512, 4, 1);
    mmp<128, 0, 0, 0, true, true>(stream, ws.fm2h + (size_t)b0 * NP1 * 256,
        ws.fm2l + (size_t)b0 * NP1 * 256, W(21), Wl(21), nullptr, ws.x1, nullptr,
        NP0, 512, 256, (long)NP1 * 256, 0, (long)NP0 * 512, 4, 1,
        ws.ni1 + (size_t)b0 * NP0, NP0);
    mmp<128, 0, 0, 0, true, true>(stream, ws.fm3h + (size_t)b0 * NP1 * 256,
        ws.fm3l + (size_t)b0 * NP1 * 256, W(22), Wl(22), nullptr, ws.x1, nullptr,
        NP0, 512, 256, (long)NP1 * 256, 0, (long)NP0 * 512, 4, 1,
        ws.ni1 + (size_t)b0 * NP0, NP0);
    mmp<128, 0, 0, 0, true, true>(stream, ws.fm4h + (size_t)b0 * NP2 * 512,
        ws.fm4l + (size_t)b0 * NP2 * 512, W(23), Wl(23), nullptr, ws.x1, nullptr,
        NP0, 512, 512, (long)NP2 * 512, 0, (long)NP0 * 512, 4, 1,
        ws.ni2 + (size_t)b0 * NP0, NP0);
    k_split4<true><<<(4 * NP0 * 512 / 4 + 255) / 256, 256, 0, stream>>>(
        ws.x1, ws.x1h, ws.x1l, 4 * NP0 * 512 / 4);
    mmp<128, 0, 1, 3, false, false>(stream, ws.x1h, ws.x1l, W(24), Wl(24), in(61),
        ws.x2b, nullptr, NP0, 512, 512, (long)NP0 * 512, 0, (long)NP0 * 512, 4, 1);
    mmp<64, 2, 1, 0, false, false>(stream, ws.x2b, nullptr, W(25), Wl(25), in(63),
        out + (size_t)b0 * NP0 * 50, nullptr, NP0, 50, 512,
        (long)NP0 * 512, 0, (long)NP0 * 50, 4, 1);
  }

  k_logsoftmax<<<(BB * NP0) / 4, 256, 0, stream>>>(out, BB * NP0, 50);
}

// Round 10
// 1637.996 us; speedup vs baseline: 2.3302x; 1.0840x over previous
//
#include <hip/hip_runtime.h>
#include <cfloat>

// ---------------------------------------------------------------------------
// GCN3D forward. Split-plane bf16 MFMA GEMMs (Dekker, f32-grade accuracy).
// Round-10: (1) head GEMMs hi-plane-only (BSPLIT=false, 1 MFMA/pair, 3x less
// matrix work — terminal layers tolerate bf16); (2) k_sa_xr stores P hi-only:
// LDS 71.7->50.5 KB => 3 blocks/CU, PV 3->2 MFMAs, half the f2bf VALU.
// B=8, N=2048->512->128, K_NB=50. Workspace 93,814,784 B.
// ---------------------------------------------------------------------------

#define BB   8
#define NP0  2048
#define NP1  512
#define NP2  128
#define KNB_ 50
#define VS0  (NP0 * 3)

typedef __attribute__((ext_vector_type(8))) short short8_t;
typedef __attribute__((ext_vector_type(4))) short short4_t;
typedef __attribute__((ext_vector_type(4))) float f32x4_t;
typedef unsigned short u16;

// ---------------- workspace layout (byte offsets) ----------------
static constexpr size_t O_V0    = 0;
static constexpr size_t O_IDX0  = 196608;
static constexpr size_t O_IDXP0 = 3473408;
static constexpr size_t O_IDX1  = 3538944;
static constexpr size_t O_IDXP1 = 4358144;
static constexpr size_t O_IDX2  = 4374528;
static constexpr size_t O_NI1   = 4579328;
static constexpr size_t O_NI2   = 4644864;
static constexpr size_t O_FGLOB = 4710400;
static constexpr size_t O_GLOB1 = 4726784;
static constexpr size_t O_COLS  = 4743168;   // mx vectors (64KB)
static constexpr size_t O_CPART = 4808704;   // inv vectors (64KB used)
static constexpr size_t O_STATS = 5332992;
static constexpr size_t O_BPART = 5337088;
static constexpr size_t O_XCUR  = 5599232;   // 8,388,608 f32 activation scratch
static constexpr size_t O_PL    = 18182144;  // 58,855,424 plane pools
static constexpr size_t O_AREA  = 77037568;  // 16,777,216 fout / pre / x1half
// end = 93,814,784

static constexpr size_t PL_WH    = 0;
static constexpr size_t PL_WL    = 4786176;
static constexpr size_t PL_FM0H  = 9572352;
static constexpr size_t PL_FM0L  = 13766656;
static constexpr size_t PL_FM1H  = 17960960;
static constexpr size_t PL_FM1L  = 22155264;
static constexpr size_t PL_FM2H  = 26349568;
static constexpr size_t PL_FM2L  = 28446720;
static constexpr size_t PL_FM3H  = 30543872;
static constexpr size_t PL_FM3L  = 32641024;
static constexpr size_t PL_FM4H  = 34738176;
static constexpr size_t PL_FM4L  = 35786752;
static constexpr size_t PL_FMP1H = 36835328;
static constexpr size_t PL_FMP1L = 37883904;
static constexpr size_t PL_FMP2H = 38932480;
static constexpr size_t PL_FMP2L = 39456768;
static constexpr size_t PL_QH    = 39981056;
static constexpr size_t PL_QL    = 41029632;
static constexpr size_t PL_VMH   = 42078208;
static constexpr size_t PL_VML   = 46272512;
static constexpr size_t PL_XSH   = 50466816;
static constexpr size_t PL_XSL   = 54661120;
static constexpr size_t PL_X1H = PL_VMH;   // head aliases (phase-disjoint)
static constexpr size_t PL_X1L = PL_XSH;   // (unused in hi-only head)

__device__ __forceinline__ float bf2f(u16 h) {
  union { unsigned u; float f; } c; c.u = ((unsigned)h) << 16; return c.f;
}
__device__ __forceinline__ u16 f2bf(float f) {
  union { float f; unsigned u; } c; c.f = f;
  return (u16)((c.u + 0x7fffu + ((c.u >> 16) & 1u)) >> 16);
}

// ===========================================================================
// Plane GEMM. BSPLIT=false: B hi-plane only (drops ah*bl MFMA + Bl staging).
// ===========================================================================
template <int TM, int AMODE, int BIASM, int OUTM, bool ACC, bool GIDX, bool BSPLIT = true>
__global__ __launch_bounds__(256) void k_mmp(
    const void* __restrict__ A1, const void* __restrict__ A2,
    const u16* __restrict__ Bh0, const u16* __restrict__ Bl0,
    const float* __restrict__ bias, void* __restrict__ C1, void* __restrict__ C2,
    int M, int N, int K, long sA, long sB, long sC, int ksplit,
    const int* __restrict__ gidx, long sG) {
  constexpr int RT = TM / 32;
  constexpr int CT = TM / 32;
  __shared__ u16 Ah[TM][40], Bh[TM][40];
  __shared__ u16 Bl[BSPLIT ? TM : 1][40];
  __shared__ u16 Al[(AMODE == 2) ? 1 : TM][40];
  const int z = blockIdx.z;
  const int zb = z / ksplit, ks = z - zb * ksplit;
  const int kchunk = K / ksplit;
  const int kl0 = ks * kchunk, kl1 = kl0 + kchunk;
  const int m0 = blockIdx.x * TM, n0 = blockIdx.y * TM;
  const int t = threadIdx.x;
  const int lane = t & 63, w = t >> 6;
  const int wr = (w >> 1) * (TM / 2), wc = (w & 1) * (TM / 2);
  const int frow = lane & 15, koff = (lane >> 4) * 8;
  f32x4_t acc[RT][CT];
#pragma unroll
  for (int i = 0; i < RT; ++i)
#pragma unroll
    for (int j = 0; j < CT; ++j) acc[i][j] = (f32x4_t){0.f, 0.f, 0.f, 0.f};

  const u16* Ahg = (const u16*)A1 + (size_t)zb * sA;
  const u16* Alg = (const u16*)A2 + (size_t)zb * sA;
  const u16* Bhg = Bh0 + (size_t)zb * sB;
  const u16* Blg = Bl0 + (size_t)zb * sB;

  int ar, ac, arow = 0;
  if constexpr (TM == 128) { ar = t >> 1; ac = (t & 1) * 16; }
  else                     { ar = t >> 2; ac = (t & 3) * 8; }
  arow = m0 + ar;
  if constexpr (GIDX) arow = (gidx + (size_t)zb * sG)[arow];
  const int bn = ar, bc = ac;
  const bool bok = (n0 + bn) < N;
  const short8_t z8 = {0, 0, 0, 0, 0, 0, 0, 0};

  for (int k0 = kl0; k0 < kl1; k0 += 32) {
    __syncthreads();
    {
      const u16* s1 = Ahg + (size_t)arow * K + k0 + ac;
      if constexpr (TM == 128) {
        *(short8_t*)&Ah[ar][ac] = *(const short8_t*)s1;
        *(short8_t*)&Ah[ar][ac + 8] = *(const short8_t*)(s1 + 8);
        if constexpr (AMODE == 0) {
          const u16* s2 = Alg + (size_t)arow * K + k0 + ac;
          *(short8_t*)&Al[ar][ac] = *(const short8_t*)s2;
          *(short8_t*)&Al[ar][ac + 8] = *(const short8_t*)(s2 + 8);
        }
      } else {
        *(short8_t*)&Ah[ar][ac] = *(const short8_t*)s1;
        if constexpr (AMODE == 0)
          *(short8_t*)&Al[ar][ac] = *(const short8_t*)(Alg + (size_t)arow * K + k0 + ac);
      }
    }
    {
      const u16* s1 = Bhg + (size_t)(n0 + bn) * K + k0 + bc;
      const u16* s2 = Blg + (size_t)(n0 + bn) * K + k0 + bc;
      if constexpr (TM == 128) {
        *(short8_t*)&Bh[bn][bc] = bok ? *(const short8_t*)s1 : z8;
        *(short8_t*)&Bh[bn][bc + 8] = bok ? *(const short8_t*)(s1 + 8) : z8;
        if constexpr (BSPLIT) {
          *(short8_t*)&Bl[bn][bc] = bok ? *(const short8_t*)s2 : z8;
          *(short8_t*)&Bl[bn][bc + 8] = bok ? *(const short8_t*)(s2 + 8) : z8;
        }
      } else {
        *(short8_t*)&Bh[bn][bc] = bok ? *(const short8_t*)s1 : z8;
        if constexpr (BSPLIT)
          *(short8_t*)&Bl[bn][bc] = bok ? *(const short8_t*)s2 : z8;
      }
    }
    __syncthreads();
    short8_t ah[RT], al[RT], bh[CT], bl[CT];
#pragma unroll
    for (int i = 0; i < RT; ++i) {
      const int r = wr + i * 16 + frow;
      ah[i] = *(const short8_t*)&Ah[r][koff];
      if constexpr (AMODE != 2) al[i] = *(const short8_t*)&Al[r][koff];
    }
#pragma unroll
    for (int i = 0; i < CT; ++i) {
      const int r = wc + i * 16 + frow;
      bh[i] = *(const short8_t*)&Bh[r][koff];
      if constexpr (BSPLIT) bl[i] = *(const short8_t*)&Bl[r][koff];
    }
#pragma unroll
    for (int i = 0; i < RT; ++i)
#pragma unroll
      for (int j = 0; j < CT; ++j) {
        acc[i][j] = __builtin_amdgcn_mfma_f32_16x16x32_bf16(ah[i], bh[j], acc[i][j], 0, 0, 0);
        if constexpr (BSPLIT)
          acc[i][j] = __builtin_amdgcn_mfma_f32_16x16x32_bf16(ah[i], bl[j], acc[i][j], 0, 0, 0);
        if constexpr (AMODE != 2)
          acc[i][j] = __builtin_amdgcn_mfma_f32_16x16x32_bf16(al[i], bh[j], acc[i][j], 0, 0, 0);
      }
  }

  const int crow = (lane >> 4) * 4;
#pragma unroll
  for (int i = 0; i < RT; ++i) {
#pragma unroll
    for (int j = 0; j < CT; ++j) {
      const int gc = n0 + wc + j * 16 + frow;
      if (gc >= N) continue;
      float bv = 0.f;
      if constexpr (BIASM == 1) bv = bias[gc];
      if constexpr (BIASM == 2) bv = bias[(size_t)zb * N + gc];
      const int gr0 = m0 + wr + i * 16 + crow;
      if constexpr (OUTM == 0) {
        float* Cp = (float*)C1 + (size_t)z * sC;
#pragma unroll
        for (int q = 0; q < 4; ++q) {
          float vv = acc[i][j][q] + bv;
          if (ACC) vv += Cp[(size_t)(gr0 + q) * N + gc];
          Cp[(size_t)(gr0 + q) * N + gc] = vv;
        }
      } else if constexpr (OUTM == 1) {
        u16* Ph = (u16*)C1 + (size_t)z * sC;
        u16* Pl = (u16*)C2 + (size_t)z * sC;
#pragma unroll
        for (int q = 0; q < 4; ++q) {
          float vv = acc[i][j][q] + bv;
          u16 h = f2bf(vv);
          Ph[(size_t)(gr0 + q) * N + gc] = h;
          Pl[(size_t)(gr0 + q) * N + gc] = f2bf(vv - bf2f(h));
        }
      } else if constexpr (OUTM == 2) {
        u16* Ph = (u16*)C1 + (size_t)z * sC;
        u16* Pl = (u16*)C2 + (size_t)z * sC;
        short4_t h4, l4;
#pragma unroll
        for (int q = 0; q < 4; ++q) {
          float vv = acc[i][j][q] + bv;
          u16 h = f2bf(vv);
          h4[q] = (short)h;
          l4[q] = (short)f2bf(vv - bf2f(h));
        }
        *(short4_t*)(Ph + (size_t)gc * M + gr0) = h4;
        *(short4_t*)(Pl + (size_t)gc * M + gr0) = l4;
      } else {
        u16* Cb = (u16*)C1 + (size_t)z * sC;
#pragma unroll
        for (int q = 0; q < 4; ++q) {
          float vv = fmaxf(acc[i][j][q] + bv, 0.f);
          Cb[(size_t)(gr0 + q) * N + gc] = f2bf(vv);
        }
      }
    }
  }
}

template <int TM, int AMODE, int BIASM, int OUTM, bool ACC, bool GIDX, bool BSPLIT = true>
static void mmp(hipStream_t st, const void* A1, const void* A2,
                const u16* Bh, const u16* Bl, const float* bias,
                void* C1, void* C2, int M, int N, int K,
                long sA, long sB, long sC, int Z, int ksplit,
                const int* gidx = nullptr, long sG = 0) {
  dim3 grid(M / TM, (N + TM - 1) / TM, Z * ksplit);
  k_mmp<TM, AMODE, BIASM, OUTM, ACC, GIDX, BSPLIT><<<grid, 256, 0, st>>>(
      A1, A2, Bh, Bl, bias, C1, C2, M, N, K, sA, sB, sC, ksplit, gidx, sG);
}

// ===========================================================================
// Fused attention, 64-row m-tiles. P stored hi-only (LDS 50.5 KB, 3 blk/CU).
// ===========================================================================
template <int QD>
__global__ __launch_bounds__(256) void k_sa_stats(
    const u16* __restrict__ qh, const u16* __restrict__ ql, int N,
    float* __restrict__ mx, float* __restrict__ inv) {
  __shared__ float mr[2][64], sr[2][64];
  const int b = blockIdx.y;
  const int m0 = blockIdx.x * 64;
  const int t = threadIdx.x, lane = t & 63, w = t >> 6;
  const int wm = (w >> 1) * 32, wn = (w & 1) * 64;
  const int frow = lane & 15, kq = (lane >> 4) * 8;
  const u16* qhb = qh + (size_t)b * N * QD;
  const u16* qlb = ql + (size_t)b * N * QD;
  constexpr int KS = QD / 32;
  float M[2][4], S[2][4];
#pragma unroll
  for (int i = 0; i < 2; ++i)
#pragma unroll
    for (int q = 0; q < 4; ++q) { M[i][q] = -FLT_MAX; S[i][q] = 0.f; }

  for (int n0 = 0; n0 < N; n0 += 128) {
    f32x4_t acc[2][4];
#pragma unroll
    for (int i = 0; i < 2; ++i)
#pragma unroll
      for (int j = 0; j < 4; ++j) acc[i][j] = (f32x4_t){0.f, 0.f, 0.f, 0.f};
#pragma unroll
    for (int ks = 0; ks < KS; ++ks) {
      short8_t a_h[2], a_l[2], b_h[4], b_l[4];
#pragma unroll
      for (int i = 0; i < 2; ++i) {
        const size_t r = (size_t)(m0 + wm + i * 16 + frow) * QD + ks * 32 + kq;
        a_h[i] = *(const short8_t*)(qhb + r);
        a_l[i] = *(const short8_t*)(qlb + r);
      }
#pragma unroll
      for (int j = 0; j < 4; ++j) {
        const size_t r = (size_t)(n0 + wn + j * 16 + frow) * QD + ks * 32 + kq;
        b_h[j] = *(const short8_t*)(qhb + r);
        b_l[j] = *(const short8_t*)(qlb + r);
      }
#pragma unroll
      for (int i = 0; i < 2; ++i)
#pragma unroll
        for (int j = 0; j < 4; ++j) {
          acc[i][j] = __builtin_amdgcn_mfma_f32_16x16x32_bf16(a_h[i], b_h[j], acc[i][j], 0, 0, 0);
          acc[i][j] = __builtin_amdgcn_mfma_f32_16x16x32_bf16(a_h[i], b_l[j], acc[i][j], 0, 0, 0);
          acc[i][j] = __builtin_amdgcn_mfma_f32_16x16x32_bf16(a_l[i], b_h[j], acc[i][j], 0, 0, 0);
        }
    }
#pragma unroll
    for (int i = 0; i < 2; ++i)
#pragma unroll
      for (int q = 0; q < 4; ++q) {
        float tm = acc[i][0][q];
#pragma unroll
        for (int j = 1; j < 4; ++j) tm = fmaxf(tm, acc[i][j][q]);
#pragma unroll
        for (int off = 1; off < 16; off <<= 1) tm = fmaxf(tm, __shfl_xor(tm, off));
        const float Mn = fmaxf(M[i][q], tm);
        float ps = 0.f;
#pragma unroll
        for (int j = 0; j < 4; ++j) ps += __expf(acc[i][j][q] - Mn);
#pragma unroll
        for (int off = 1; off < 16; off <<= 1) ps += __shfl_xor(ps, off);
        S[i][q] = S[i][q] * __expf(M[i][q] - Mn) + ps;
        M[i][q] = Mn;
      }
  }
  if (frow == 0) {
#pragma unroll
    for (int i = 0; i < 2; ++i)
#pragma unroll
      for (int q = 0; q < 4; ++q) {
        const int ml = wm + i * 16 + (lane >> 4) * 4 + q;
        mr[w & 1][ml] = M[i][q];
        sr[w & 1][ml] = S[i][q];
      }
  }
  __syncthreads();
  if (t < 64) {
    const float M0 = mr[0][t], M1 = mr[1][t];
    const float Mm = fmaxf(M0, M1);
    const float Sm = sr[0][t] * __expf(M0 - Mm) + sr[1][t] * __expf(M1 - Mm);
    mx[(size_t)b * N + m0 + t] = Mm;
    inv[(size_t)b * N + m0 + t] = 1.f / Sm;
  }
}

template <int QD>
__global__ __launch_bounds__(256) void k_sa_xr(
    const u16* __restrict__ qh, const u16* __restrict__ ql,
    const u16* __restrict__ vmh, const u16* __restrict__ vml,
    const float* __restrict__ mx, const float* __restrict__ inv,
    const float* __restrict__ xcur, u16* __restrict__ xsh, u16* __restrict__ xsl,
    int N, int C) {
  __shared__ __align__(16) u16 Ph[64][132];
  __shared__ __align__(16) u16 Vh[128][68], Vl[128][68];
  const int b = blockIdx.z;
  const int m0 = blockIdx.x * 64, c0 = blockIdx.y * 128;
  const int t = threadIdx.x, lane = t & 63, w = t >> 6;
  const int wm = (w >> 1) * 32, wn = (w & 1) * 64;
  const int frow = lane & 15, kq = (lane >> 4) * 8;
  const u16* qhb = qh + (size_t)b * N * QD;
  const u16* qlb = ql + (size_t)b * N * QD;
  const u16* vhb = vmh + (size_t)b * (size_t)N * C;  // [C][N]
  const u16* vlb = vml + (size_t)b * (size_t)N * C;
  const float* mxb = mx + (size_t)b * N;
  const float* invb = inv + (size_t)b * N;
  constexpr int KS = QD / 32;
  const int vr = t >> 1, vco = (t & 1) * 32;
  f32x4_t xacc[2][4];
  float csum[2][4];
#pragma unroll
  for (int i = 0; i < 2; ++i)
#pragma unroll
    for (int j = 0; j < 4; ++j) { xacc[i][j] = (f32x4_t){0.f, 0.f, 0.f, 0.f}; csum[i][j] = 0.f; }

  for (int n0 = 0; n0 < N; n0 += 128) {
    __syncthreads();  // previous P/V reads complete
    // stage V half 0: cols n0..n0+64
    {
      const u16* s1 = vhb + (size_t)(c0 + vr) * N + n0 + vco;
      const u16* s2 = vlb + (size_t)(c0 + vr) * N + n0 + vco;
#pragma unroll
      for (int u = 0; u < 4; ++u) {
        *(short8_t*)&Vh[vr][vco + u * 8] = *(const short8_t*)(s1 + u * 8);
        *(short8_t*)&Vl[vr][vco + u * 8] = *(const short8_t*)(s2 + u * 8);
      }
    }
    // S tile (in-register, global q frags): m 64 x n 128
    f32x4_t acc[2][4];
#pragma unroll
    for (int i = 0; i < 2; ++i)
#pragma unroll
      for (int j = 0; j < 4; ++j) acc[i][j] = (f32x4_t){0.f, 0.f, 0.f, 0.f};
#pragma unroll
    for (int ks = 0; ks < KS; ++ks) {
      short8_t a_h[2], a_l[2], b_h[4], b_l[4];
#pragma unroll
      for (int i = 0; i < 2; ++i) {
        const size_t r = (size_t)(m0 + wm + i * 16 + frow) * QD + ks * 32 + kq;
        a_h[i] = *(const short8_t*)(qhb + r);
        a_l[i] = *(const short8_t*)(qlb + r);
      }
#pragma unroll
      for (int j = 0; j < 4; ++j) {
        const size_t r = (size_t)(n0 + wn + j * 16 + frow) * QD + ks * 32 + kq;
        b_h[j] = *(const short8_t*)(qhb + r);
        b_l[j] = *(const short8_t*)(qlb + r);
      }
#pragma unroll
      for (int i = 0; i < 2; ++i)
#pragma unroll
        for (int j = 0; j < 4; ++j) {
          acc[i][j] = __builtin_amdgcn_mfma_f32_16x16x32_bf16(a_h[i], b_h[j], acc[i][j], 0, 0, 0);
          acc[i][j] = __builtin_amdgcn_mfma_f32_16x16x32_bf16(a_h[i], b_l[j], acc[i][j], 0, 0, 0);
          acc[i][j] = __builtin_amdgcn_mfma_f32_16x16x32_bf16(a_l[i], b_h[j], acc[i][j], 0, 0, 0);
        }
    }
    // transform -> P (hi-only) in LDS; csum accumulate
    float mxj[4], ivj[4];
#pragma unroll
    for (int j = 0; j < 4; ++j) {
      const int n = n0 + wn + j * 16 + frow;
      mxj[j] = mxb[n];
      ivj[j] = invb[n];
    }
    const int mbase = wm + (lane >> 4) * 4;
#pragma unroll
    for (int i = 0; i < 2; ++i)
#pragma unroll
      for (int j = 0; j < 4; ++j)
#pragma unroll
        for (int q = 0; q < 4; ++q) {
          const float pv = __expf(acc[i][j][q] - mxj[j]) * ivj[j];
          csum[i][q] += pv;
          Ph[mbase + i * 16 + q][wn + j * 16 + frow] = f2bf(pv);
        }
    __syncthreads();  // P + V half0 ready
#pragma unroll
    for (int ks2 = 0; ks2 < 2; ++ks2) {
      short8_t p_h[2], v_h[4], v_l[4];
#pragma unroll
      for (int i = 0; i < 2; ++i)
        p_h[i] = *(const short8_t*)&Ph[wm + i * 16 + frow][ks2 * 32 + kq];
#pragma unroll
      for (int j = 0; j < 4; ++j) {
        v_h[j] = *(const short8_t*)&Vh[wn + j * 16 + frow][ks2 * 32 + kq];
        v_l[j] = *(const short8_t*)&Vl[wn + j * 16 + frow][ks2 * 32 + kq];
      }
#pragma unroll
      for (int i = 0; i < 2; ++i)
#pragma unroll
        for (int j = 0; j < 4; ++j) {
          xacc[i][j] = __builtin_amdgcn_mfma_f32_16x16x32_bf16(p_h[i], v_h[j], xacc[i][j], 0, 0, 0);
          xacc[i][j] = __builtin_amdgcn_mfma_f32_16x16x32_bf16(p_h[i], v_l[j], xacc[i][j], 0, 0, 0);
        }
    }
    __syncthreads();  // V half0 reads complete
    // stage V half 1: cols n0+64..n0+128
    {
      const u16* s1 = vhb + (size_t)(c0 + vr) * N + n0 + 64 + vco;
      const u16* s2 = vlb + (size_t)(c0 + vr) * N + n0 + 64 + vco;
#pragma unroll
      for (int u = 0; u < 4; ++u) {
        *(short8_t*)&Vh[vr][vco + u * 8] = *(const short8_t*)(s1 + u * 8);
        *(short8_t*)&Vl[vr][vco + u * 8] = *(const short8_t*)(s2 + u * 8);
      }
    }
    __syncthreads();  // V half1 ready
#pragma unroll
    for (int ks2 = 0; ks2 < 2; ++ks2) {
      short8_t p_h[2], v_h[4], v_l[4];
#pragma unroll
      for (int i = 0; i < 2; ++i)
        p_h[i] = *(const short8_t*)&Ph[wm + i * 16 + frow][64 + ks2 * 32 + kq];
#pragma unroll
      for (int j = 0; j < 4; ++j) {
        v_h[j] = *(const short8_t*)&Vh[wn + j * 16 + frow][ks2 * 32 + kq];
        v_l[j] = *(const short8_t*)&Vl[wn + j * 16 + frow][ks2 * 32 + kq];
      }
#pragma unroll
      for (int i = 0; i < 2; ++i)
#pragma unroll
        for (int j = 0; j < 4; ++j) {
          xacc[i][j] = __builtin_amdgcn_mfma_f32_16x16x32_bf16(p_h[i], v_h[j], xacc[i][j], 0, 0, 0);
          xacc[i][j] = __builtin_amdgcn_mfma_f32_16x16x32_bf16(p_h[i], v_l[j], xacc[i][j], 0, 0, 0);
        }
    }
  }
  // csum: reduce over frow lanes, then cross wave n-halves via LDS
#pragma unroll
  for (int i = 0; i < 2; ++i)
#pragma unroll
    for (int q = 0; q < 4; ++q)
#pragma unroll
      for (int off = 1; off < 16; off <<= 1) csum[i][q] += __shfl_xor(csum[i][q], off);
  __syncthreads();
  float* csb = (float*)&Ph[0][0];
  if (frow == 0) {
#pragma unroll
    for (int i = 0; i < 2; ++i)
#pragma unroll
      for (int q = 0; q < 4; ++q)
        csb[(w & 1) * 64 + wm + i * 16 + (lane >> 4) * 4 + q] = csum[i][q];
  }
  __syncthreads();
  if (t < 64) csb[128 + t] = csb[t] + csb[64 + t];
  __syncthreads();
  // epilogue: xs = x - xr/(1e-9+csum) -> planes
#pragma unroll
  for (int i = 0; i < 2; ++i) {
#pragma unroll
    for (int q = 0; q < 4; ++q) {
      const int mloc = wm + i * 16 + (lane >> 4) * 4 + q;
      const float cstot = csb[128 + mloc];
      const size_t rowoff = ((size_t)b * N + m0 + mloc) * C;
#pragma unroll
      for (int j = 0; j < 4; ++j) {
        const int gc = c0 + wn + j * 16 + frow;
        const float val = xcur[rowoff + gc] - xacc[i][j][q] / (1e-9f + cstot);
        const u16 h = f2bf(val);
        xsh[rowoff + gc] = h;
        xsl[rowoff + gc] = f2bf(val - bf2f(h));
      }
    }
  }
}

// ===========================================================================
// weight split + activation split
// ===========================================================================
struct SplitJob { const float* s; u16* dh; u16* dl; int n, K, N, trans; };
struct SplitJobs { SplitJob j[26]; };
__global__ void k_splitjobs(SplitJobs jobs) {
  SplitJob jb = jobs.j[blockIdx.y];
  for (int i = blockIdx.x * 256 + threadIdx.x; i < jb.n; i += gridDim.x * 256) {
    float v;
    if (jb.trans) { int k = i % jb.K, n = i / jb.K; v = jb.s[(size_t)k * jb.N + n]; }
    else v = jb.s[i];
    u16 h = f2bf(v);
    jb.dh[i] = h;
    jb.dl[i] = f2bf(v - bf2f(h));
  }
}

template <bool RELU, bool LO>
__global__ void k_split4(const float* __restrict__ x, u16* __restrict__ ph,
                         u16* __restrict__ pl, int n4) {
  int i = blockIdx.x * 256 + threadIdx.x;
  if (i >= n4) return;
  float4 v = ((const float4*)x)[i];
  short4_t h4, l4;
  float vv[4] = {v.x, v.y, v.z, v.w};
#pragma unroll
  for (int q = 0; q < 4; ++q) {
    float f = RELU ? fmaxf(vv[q], 0.f) : vv[q];
    u16 h = f2bf(f);
    h4[q] = (short)h;
    if (LO) l4[q] = (short)f2bf(f - bf2f(h));
  }
  *(short4_t*)(ph + (size_t)i * 4) = h4;
  if (LO) *(short4_t*)(pl + (size_t)i * 4) = l4;
}

// ===========================================================================
// KNN (radix-select for K=50; iterative argmin for K=4)
// ===========================================================================
template <int NCAND, int KSEL>
__global__ __launch_bounds__(256) void k_knn_radix(const float* __restrict__ pts, int Nq,
                                                   int* __restrict__ outIdx) {
  __shared__ float sp[NCAND * 3];
  const int b = blockIdx.y;
  const float* pb = pts + (size_t)b * VS0;
  for (int i = threadIdx.x; i < NCAND * 3; i += 256) sp[i] = pb[i];
  __syncthreads();
  const int wave = threadIdx.x >> 6, lane = threadIdx.x & 63;
  const int qi = blockIdx.x * 4 + wave;
  const float qx = sp[qi * 3], qy = sp[qi * 3 + 1], qz = sp[qi * 3 + 2];
  constexpr int CH = NCAND / 64;
  unsigned d[CH];
  unsigned x[32];
#pragma unroll
  for (int j = 0; j < 32; ++j) x[j] = 0u;
#pragma unroll
  for (int j = 0; j < CH; ++j) {
    const int m = lane + j * 64;
    const float dx = sp[m * 3] - qx, dy = sp[m * 3 + 1] - qy, dz = sp[m * 3 + 2] - qz;
    const float dd = dx * dx + dy * dy + dz * dz;
    d[j] = __float_as_uint((m == qi) ? FLT_MAX : dd);
    x[j] = d[j];
  }
#pragma unroll
  for (int st = 0; st < 5; ++st) {
    const int s = 16 >> st;
    const unsigned ml = (s == 16) ? 0x0000FFFFu : (s == 8) ? 0x00FF00FFu
                      : (s == 4) ? 0x0F0F0F0Fu : (s == 2) ? 0x33333333u : 0x55555555u;
#pragma unroll
    for (int i = 0; i < 32; ++i) {
      if (i & s) continue;
      unsigned t = ((x[i] >> s) ^ x[i + s]) & ml;
      x[i + s] ^= t;
      x[i] ^= (t << s);
    }
  }
  unsigned active = (CH == 32) ? 0xFFFFFFFFu : ((1u << CH) - 1u);
  unsigned T = 0u;
  int kk = KSEL;
#pragma unroll
  for (int bb = 30; bb >= 0; --bb) {
    const unsigned zn = active & ~x[bb];
    int c0 = __popc(zn);
#pragma unroll
    for (int off = 32; off; off >>= 1) c0 += __shfl_xor(c0, off);
    if (kk <= c0) {
      active = zn;
    } else {
      kk -= c0;
      active &= x[bb];
      T |= (1u << bb);
    }
  }
  int* orow = outIdx + ((size_t)b * Nq + qi) * KSEL;
  const unsigned long long ltmask = (1ull << lane) - 1ull;
  int base = 0;
#pragma unroll
  for (int j = 0; j < CH; ++j) {
    const bool sel = d[j] < T;
    const unsigned long long bal = __ballot(sel);
    const int pos = base + (int)__popcll(bal & ltmask);
    if (sel) orow[pos] = lane + j * 64;
    base += (int)__popcll(bal);
  }
#pragma unroll
  for (int j = 0; j < CH; ++j) {
    const bool sel = ((active >> j) & 1u) != 0u;
    const unsigned long long bal = __ballot(sel);
    const int pos = base + (int)__popcll(bal & ltmask);
    if (sel && pos < KSEL) orow[pos] = lane + j * 64;
    base += (int)__popcll(bal);
  }
}

template <int NCAND, int KSEL>
__global__ __launch_bounds__(256) void k_knn2(const float* __restrict__ pts, int Nq,
                                              int* __restrict__ outIdx) {
  __shared__ float sp[NCAND * 3];
  const int b = blockIdx.y;
  const float* pb = pts + (size_t)b * VS0;
  for (int i = threadIdx.x; i < NCAND * 3; i += 256) sp[i] = pb[i];
  __syncthreads();
  const int wave = threadIdx.x >> 6, lane = threadIdx.x & 63;
  const int qi = blockIdx.x * 4 + wave;
  const float qx = sp[qi * 3], qy = sp[qi * 3 + 1], qz = sp[qi * 3 + 2];
  constexpr int CH = NCAND / 64;
  float d[CH];
#pragma unroll
  for (int j = 0; j < CH; ++j) {
    const int m = lane + j * 64;
    const float dx = sp[m * 3] - qx, dy = sp[m * 3 + 1] - qy, dz = sp[m * 3 + 2] - qz;
    const float dd = dx * dx + dy * dy + dz * dz;
    d[j] = (m == qi) ? FLT_MAX : dd;
  }
  int* orow = outIdx + ((size_t)b * Nq + qi) * KSEL;
#pragma unroll 1
  for (int s = 0; s < KSEL; ++s) {
    float bd = FLT_MAX; int bj = 0;
#pragma unroll
    for (int j = 0; j < CH; ++j) {
      const bool better = d[j] < bd;
      bd = better ? d[j] : bd;
      bj = better ? j : bj;
    }
    int bm = lane + bj * 64;
#pragma unroll
    for (int off = 32; off; off >>= 1) {
      const float od = __shfl_xor(bd, off);
      const int om = __shfl_xor(bm, off);
      if (od < bd || (od == bd && om < bm)) { bd = od; bm = om; }
    }
    if (lane == 0) orow[s] = bm;
#pragma unroll
    for (int j = 0; j < CH; ++j)
      if (bm == lane + j * 64) d[j] = FLT_MAX;
  }
}

__global__ void k_transpose(const float* __restrict__ in, float* __restrict__ out) {
  int i = blockIdx.x * 256 + threadIdx.x;
  if (i >= BB * NP0 * 3) return;
  int dd = i % 3, tt = (i / 3) % NP0, b = i / (3 * NP0);
  out[i] = in[((size_t)b * 3 + dd) * NP0 + tt];
}

__global__ void k_conv_surface(const float* __restrict__ v, const int* __restrict__ idx,
                               const float* __restrict__ dirs, float* __restrict__ out,
                               int N, int M) {
  __shared__ float su[KNB_ * 3];
  int b = blockIdx.y, n = blockIdx.x, c = threadIdx.x;
  const float* vb = v + (size_t)b * VS0;
  float cx = vb[n * 3], cy = vb[n * 3 + 1], cz = vb[n * 3 + 2];
  const int* irow = idx + ((size_t)b * N + n) * KNB_;
  if (c < KNB_) {
    int j = irow[c];
    float dx = vb[j * 3] - cx, dy = vb[j * 3 + 1] - cy, dz = vb[j * 3 + 2] - cz;
    float inv = 1.f / fmaxf(sqrtf(dx * dx + dy * dy + dz * dz), 1e-12f);
    su[c * 3] = dx * inv; su[c * 3 + 1] = dy * inv; su[c * 3 + 2] = dz * inv;
  }
  __syncthreads();
  float d0 = dirs[c], d1 = dirs[M + c], d2 = dirs[2 * M + c];
  float inv = 1.f / fmaxf(sqrtf(d0 * d0 + d1 * d1 + d2 * d2), 1e-12f);
  d0 *= inv; d1 *= inv; d2 *= inv;
  float acc = 0.f;
  for (int k = 0; k < KNB_; ++k) {
    float th = fmaxf(su[k * 3] * d0 + su[k * 3 + 1] * d1 + su[k * 3 + 2] * d2, 0.f);
    acc = fmaxf(acc, th);
  }
  out[((size_t)b * N + n) * M + c] = acc;
}

__global__ void k_conv_layer(const float* __restrict__ v, const int* __restrict__ idx,
                             const float* __restrict__ dirs, const float* __restrict__ fout,
                             float* __restrict__ out, int N, int C) {
  __shared__ float su[KNB_ * 3];
  __shared__ int sidx[KNB_];
  int b = blockIdx.y, n = blockIdx.x, c = threadIdx.x;
  const float* vb = v + (size_t)b * VS0;
  float cx = vb[n * 3], cy = vb[n * 3 + 1], cz = vb[n * 3 + 2];
  const int* irow = idx + ((size_t)b * N + n) * KNB_;
  if (c < KNB_) {
    int j = irow[c]; sidx[c] = j;
    float dx = vb[j * 3] - cx, dy = vb[j * 3 + 1] - cy, dz = vb[j * 3 + 2] - cz;
    float inv = 1.f / fmaxf(sqrtf(dx * dx + dy * dy + dz * dz), 1e-12f);
    su[c * 3] = dx * inv; su[c * 3 + 1] = dy * inv; su[c * 3 + 2] = dz * inv;
  }
  __syncthreads();
  float d0 = dirs[c], d1 = dirs[C + c], d2 = dirs[2 * C + c];
  float inv = 1.f / fmaxf(sqrtf(d0 * d0 + d1 * d1 + d2 * d2), 1e-12f);
  d0 *= inv; d1 *= inv; d2 *= inv;
  const float* fb = fout + (size_t)b * N * 2 * C;
  float acc = -FLT_MAX;
  for (int k = 0; k < KNB_; ++k) {
    float th = fmaxf(su[k * 3] * d0 + su[k * 3 + 1] * d1 + su[k * 3 + 2] * d2, 0.f);
    float fs = fb[(size_t)sidx[k] * 2 * C + C + c];
    acc = fmaxf(acc, th * fs);
  }
  out[((size_t)b * N + n) * C + c] = fb[(size_t)n * 2 * C + c] + acc;
}

// ===========================================================================
// BN / pool / misc
// ===========================================================================
__global__ void k_bn_part(const float* __restrict__ x, int rows, int C, float* __restrict__ part) {
  const int blk = blockIdx.x;
  const int chunk = rows / 64;
  const int r0 = blk * chunk;
  const int c0 = threadIdx.x, c1 = threadIdx.x + 256;
  float s0 = 0, s20 = 0, s1 = 0, s21 = 0;
  for (int r = 0; r < chunk; ++r) {
    const float* row = x + (size_t)(r0 + r) * C;
    if (c0 < C) { float v = row[c0]; s0 += v; s20 += v * v; }
    if (c1 < C) { float v = row[c1]; s1 += v; s21 += v * v; }
  }
  float* p = part + (size_t)blk * 1024;
  if (c0 < C) { p[c0] = s0; p[512 + c0] = s20; }
  if (c1 < C) { p[c1] = s1; p[512 + c1] = s21; }
}

__global__ void k_bn_fin(const float* __restrict__ part, int rows, int C, float* __restrict__ stats) {
  int c = blockIdx.x * 256 + threadIdx.x;
  if (c >= C) return;
  float s = 0, s2 = 0;
  for (int b2 = 0; b2 < 64; ++b2) { s += part[b2 * 1024 + c]; s2 += part[b2 * 1024 + 512 + c]; }
  float m = s / rows;
  float var = s2 / rows - m * m;
  stats[c] = m;
  stats[C + c] = rsqrtf(var + 1e-5f);
}

template <bool ADD>
__global__ void k_bn_apply(const float* __restrict__ x, const float* __restrict__ stats,
                           const float* __restrict__ g, const float* __restrict__ bb,
                           const float* __restrict__ base, float* __restrict__ outf,
                           u16* __restrict__ ph, u16* __restrict__ pl, int total, int C) {
  int i = blockIdx.x * 256 + threadIdx.x;
  if (i >= total) return;
  int c = i % C;
  float v = (x[i] - stats[c]) * stats[C + c] * g[c] + bb[c];
  v = fmaxf(v, 0.f);
  float r = ADD ? base[i] + v : v;
  outf[i] = r;
  u16 h = f2bf(r);
  ph[i] = h;
  pl[i] = f2bf(r - bf2f(h));
}

__global__ void k_pool(const u16* __restrict__ fh, const u16* __restrict__ fl,
                       const int* __restrict__ idxp, u16* __restrict__ oh,
                       u16* __restrict__ ol, int Nin, int pn, int C) {
  int b = blockIdx.y, p = blockIdx.x, c = threadIdx.x;
  const int* ir = idxp + ((size_t)b * pn + p) * 4;
  const u16* fhb = fh + (size_t)b * Nin * C;
  const u16* flb = fl + (size_t)b * Nin * C;
  float acc = -FLT_MAX;
#pragma unroll
  for (int k = 0; k < 4; ++k) {
    size_t o = (size_t)ir[k] * C + c;
    acc = fmaxf(acc, bf2f(fhb[o]) + bf2f(flb[o]));
  }
  u16 h = f2bf(acc);
  oh[((size_t)b * pn + p) * C + c] = h;
  ol[((size_t)b * pn + p) * C + c] = f2bf(acc - bf2f(h));
}

__global__ void k_maxn(const u16* __restrict__ fh, const u16* __restrict__ fl,
                       float* __restrict__ out, int N, int C) {
  int b = blockIdx.y;
  int c = blockIdx.x * 256 + threadIdx.x;
  if (c >= C) return;
  float acc = -FLT_MAX;
  for (int n = 0; n < N; ++n) {
    size_t o = ((size_t)b * N + n) * C + c;
    acc = fmaxf(acc, bf2f(fh[o]) + bf2f(fl[o]));
  }
  out[(size_t)b * C + c] = acc;
}

__global__ void k_nearest(const float* __restrict__ v, int Ns, int* __restrict__ out) {
  extern __shared__ float sp[];
  int b = blockIdx.y;
  const float* vsb = v + (size_t)b * VS0;
  for (int i = threadIdx.x; i < Ns * 3; i += 256) sp[i] = vsb[i];
  __syncthreads();
  int t = blockIdx.x * 256 + threadIdx.x;
  float tx = vsb[t * 3], ty = vsb[t * 3 + 1], tz = vsb[t * 3 + 2];
  float bd = FLT_MAX; int bi = 0;
#pragma unroll 4
  for (int s = 0; s < Ns; ++s) {
    float dx = sp[s * 3] - tx, dy = sp[s * 3 + 1] - ty, dz = sp[s * 3 + 2] - tz;
    float dd = dx * dx + dy * dy + dz * dz;
    if (dd < bd) { bd = dd; bi = s; }
  }
  out[(size_t)b * NP0 + t] = bi;
}

__global__ void k_glob1(const float* __restrict__ fglob, const float* __restrict__ onehot,
                        const float* __restrict__ h1w, const float* __restrict__ h1b,
                        float* __restrict__ out) {
  int b = blockIdx.x, j = threadIdx.x;
  float s = h1b[j];
  for (int i = 0; i < 512; ++i) s = fmaf(fglob[b * 512 + i], h1w[(size_t)(1280 + i) * 512 + j], s);
  for (int i = 0; i < 16; ++i) s = fmaf(onehot[b * 16 + i], h1w[(size_t)(1792 + i) * 512 + j], s);
  out[b * 512 + j] = s;
}

__global__ void k_logsoftmax(float* __restrict__ x, int rows, int C) {
  int r = blockIdx.x * 4 + (threadIdx.x >> 6);
  int lane = threadIdx.x & 63;
  if (r >= rows) return;
  float* xr = x + (size_t)r * C;
  float v = (lane < C) ? xr[lane] : -FLT_MAX;
  float mx = v;
  for (int o = 32; o; o >>= 1) mx = fmaxf(mx, __shfl_xor(mx, o));
  float e = (lane < C) ? __expf(v - mx) : 0.f;
  float s = e;
  for (int o = 32; o; o >>= 1) s += __shfl_xor(s, o);
  float lse = mx + logf(s);
  if (lane < C) xr[lane] = v - lse;
}

// ===========================================================================
// host
// ===========================================================================
struct Ws {
  float *v0, *fglob, *glob1, *mx, *inv, *stats, *bpart, *xcur, *pre, *fout, *x1;
  int *idx0, *idxp0, *idx1, *idxp1, *idx2, *ni1, *ni2;
  u16 *wh, *wl;
  u16 *fm0h, *fm0l, *fm1h, *fm1l, *fm2h, *fm2l, *fm3h, *fm3l, *fm4h, *fm4l;
  u16 *fmp1h, *fmp1l, *fmp2h, *fmp2l, *qh, *ql, *vmh, *vml, *xsh, *xsl;
  u16 *x1h, *x2b;
};

static void run_sa(hipStream_t st, Ws& ws, int N, int C, int Q,
                   const u16* qkh, const u16* qkl, const u16* vwh, const u16* vwl,
                   const u16* twh, const u16* twl,
                   const float* vb, const float* tb, const float* g, const float* be,
                   u16* xh, u16* xl) {
  const long sx = (long)N * C;
  mmp<64, 0, 0, 1, false, false>(st, xh, xl, qkh, qkl, nullptr, ws.qh, ws.ql,
                                 N, Q, C, sx, 0, (long)N * Q, BB, 1);
  mmp<64, 0, 1, 2, false, false>(st, xh, xl, vwh, vwl, vb, ws.vmh, ws.vml,
                                 N, C, C, sx, 0, sx, BB, 1);
  dim3 gs(N / 64, BB), gx(N / 64, C / 128, BB);
  if (Q == 32) {
    k_sa_stats<32><<<gs, 256, 0, st>>>(ws.qh, ws.ql, N, ws.mx, ws.inv);
    k_sa_xr<32><<<gx, 256, 0, st>>>(ws.qh, ws.ql, ws.vmh, ws.vml, ws.mx, ws.inv,
                                    ws.xcur, ws.xsh, ws.xsl, N, C);
  } else if (Q == 64) {
    k_sa_stats<64><<<gs, 256, 0, st>>>(ws.qh, ws.ql, N, ws.mx, ws.inv);
    k_sa_xr<64><<<gx, 256, 0, st>>>(ws.qh, ws.ql, ws.vmh, ws.vml, ws.mx, ws.inv,
                                    ws.xcur, ws.xsh, ws.xsl, N, C);
  } else {
    k_sa_stats<128><<<gs, 256, 0, st>>>(ws.qh, ws.ql, N, ws.mx, ws.inv);
    k_sa_xr<128><<<gx, 256, 0, st>>>(ws.qh, ws.ql, ws.vmh, ws.vml, ws.mx, ws.inv,
                                     ws.xcur, ws.xsh, ws.xsl, N, C);
  }
  mmp<64, 0, 1, 0, false, false>(st, ws.xsh, ws.xsl, twh, twl, tb, ws.pre, nullptr,
                                 N, C, C, sx, 0, sx, BB, 1);
  k_bn_part<<<64, 256, 0, st>>>(ws.pre, BB * N, C, ws.bpart);
  k_bn_fin<<<(C + 255) / 256, 256, 0, st>>>(ws.bpart, BB * N, C, ws.stats);
  k_bn_apply<true><<<(BB * N * C + 255) / 256, 256, 0, st>>>(ws.pre, ws.stats, g, be,
                                                             ws.xcur, ws.xcur, xh, xl, BB * N * C, C);
}

static void run_conv(hipStream_t st, Ws& ws, const u16* finh, const u16* finl, int Cin,
                     const u16* cwh, const u16* cwl, const float* bias, const float* dirs,
                     const int* idx, int N, int C,
                     const float* bng, const float* bnb, bool doBN, u16* fmh, u16* fml) {
  if (N == NP0)
    mmp<128, 0, 1, 0, false, false>(st, finh, finl, cwh, cwl, bias, ws.fout, nullptr,
                                    N, 2 * C, Cin, (long)N * Cin, 0, (long)N * 2 * C, BB, 1);
  else
    mmp<64, 0, 1, 0, false, false>(st, finh, finl, cwh, cwl, bias, ws.fout, nullptr,
                                   N, 2 * C, Cin, (long)N * Cin, 0, (long)N * 2 * C, BB, 1);
  k_conv_layer<<<dim3(N, BB), C, 0, st>>>(ws.v0, idx, dirs, ws.fout, ws.xcur, N, C);
  if (doBN) {
    k_bn_part<<<64, 256, 0, st>>>(ws.xcur, BB * N, C, ws.bpart);
    k_bn_fin<<<(C + 255) / 256, 256, 0, st>>>(ws.bpart, BB * N, C, ws.stats);
    k_bn_apply<false><<<(BB * N * C + 255) / 256, 256, 0, st>>>(
        ws.xcur, ws.stats, bng, bnb, nullptr, ws.xcur, fmh, fml, BB * N * C, C);
  } else {
    k_split4<false, true><<<(BB * N * C / 4 + 255) / 256, 256, 0, st>>>(
        ws.xcur, fmh, fml, BB * N * C / 4);
  }
}

extern "C" void kernel_launch(void* const* d_in, const int* in_sizes, int n_in,
                              void* d_out, int out_size, void* d_ws, size_t ws_size,
                              hipStream_t stream) {
  auto in = [&](int i) { return (const float*)d_in[i]; };
  char* p = (char*)d_ws;
  Ws ws;
  ws.v0 = (float*)(p + O_V0);
  ws.idx0 = (int*)(p + O_IDX0); ws.idxp0 = (int*)(p + O_IDXP0);
  ws.idx1 = (int*)(p + O_IDX1); ws.idxp1 = (int*)(p + O_IDXP1);
  ws.idx2 = (int*)(p + O_IDX2);
  ws.ni1 = (int*)(p + O_NI1); ws.ni2 = (int*)(p + O_NI2);
  ws.fglob = (float*)(p + O_FGLOB); ws.glob1 = (float*)(p + O_GLOB1);
  ws.mx = (float*)(p + O_COLS); ws.inv = (float*)(p + O_CPART);
  ws.stats = (float*)(p + O_STATS); ws.bpart = (float*)(p + O_BPART);
  ws.xcur = (float*)(p + O_XCUR);
  ws.pre = (float*)(p + O_AREA);
  ws.fout = (float*)(p + O_AREA); ws.x1 = (float*)(p + O_AREA);
  char* pl = p + O_PL;
  ws.wh = (u16*)(pl + PL_WH); ws.wl = (u16*)(pl + PL_WL);
  ws.fm0h = (u16*)(pl + PL_FM0H); ws.fm0l = (u16*)(pl + PL_FM0L);
  ws.fm1h = (u16*)(pl + PL_FM1H); ws.fm1l = (u16*)(pl + PL_FM1L);
  ws.fm2h = (u16*)(pl + PL_FM2H); ws.fm2l = (u16*)(pl + PL_FM2L);
  ws.fm3h = (u16*)(pl + PL_FM3H); ws.fm3l = (u16*)(pl + PL_FM3L);
  ws.fm4h = (u16*)(pl + PL_FM4H); ws.fm4l = (u16*)(pl + PL_FM4L);
  ws.fmp1h = (u16*)(pl + PL_FMP1H); ws.fmp1l = (u16*)(pl + PL_FMP1L);
  ws.fmp2h = (u16*)(pl + PL_FMP2H); ws.fmp2l = (u16*)(pl + PL_FMP2L);
  ws.qh = (u16*)(pl + PL_QH); ws.ql = (u16*)(pl + PL_QL);
  ws.vmh = (u16*)(pl + PL_VMH); ws.vml = (u16*)(pl + PL_VML);
  ws.xsh = (u16*)(pl + PL_XSH); ws.xsl = (u16*)(pl + PL_XSL);
  ws.x1h = (u16*)(pl + PL_X1H);
  ws.x2b = (u16*)(p + O_XCUR);
  float* out = (float*)d_out;

  // ---- one-time weight plane split (pre-transposed to [N,K]) ----
  SplitJobs jobs;
  size_t wq[26];
  size_t off = 0;
  int ji = 0;
  auto addjob = [&](const float* s, int K, int N, int trans) {
    int n = K * N;
    jobs.j[ji] = {s, ws.wh + off, ws.wl + off, n, K, N, trans};
    wq[ji] = off; off += (size_t)n; ++ji;
  };
  addjob(in(5), 128, 32, 0);  addjob(in(6), 128, 128, 0);  addjob(in(8), 128, 128, 0);
  addjob(in(17), 128, 32, 0); addjob(in(18), 128, 128, 0); addjob(in(20), 128, 128, 0);
  addjob(in(29), 256, 64, 0); addjob(in(30), 256, 256, 0); addjob(in(32), 256, 256, 0);
  addjob(in(41), 256, 64, 0); addjob(in(42), 256, 256, 0); addjob(in(44), 256, 256, 0);
  addjob(in(51), 512, 128, 0); addjob(in(52), 512, 512, 0); addjob(in(54), 512, 512, 0);
  addjob(in(12), 128, 256, 1);
  addjob(in(24), 128, 512, 1);
  addjob(in(36), 256, 512, 1);
  addjob(in(48), 256, 1024, 1);
  addjob(in(58) + 0 * 512, 128, 512, 1);
  addjob(in(58) + (size_t)128 * 512, 128, 512, 1);
  addjob(in(58) + (size_t)256 * 512, 256, 512, 1);
  addjob(in(58) + (size_t)512 * 512, 256, 512, 1);
  addjob(in(58) + (size_t)768 * 512, 512, 512, 1);
  addjob(in(60), 512, 512, 1);
  addjob(in(62), 512, 50, 1);
  k_splitjobs<<<dim3(32, 26), 256, 0, stream>>>(jobs);
  auto W = [&](int i) { return ws.wh + wq[i]; };
  auto Wl = [&](int i) { return ws.wl + wq[i]; };

  // ---- geometry ----
  k_transpose<<<(BB * NP0 * 3 + 255) / 256, 256, 0, stream>>>(in(0), ws.v0);
  k_knn_radix<NP0, KNB_><<<dim3(NP0 / 4, BB), 256, 0, stream>>>(ws.v0, NP0, ws.idx0);

  // ---- conv0 + bn0 ----
  k_conv_surface<<<dim3(NP0, BB), 128, 0, stream>>>(ws.v0, ws.idx0, in(2), ws.xcur, NP0, 128);
  k_bn_part<<<64, 256, 0, stream>>>(ws.xcur, BB * NP0, 128, ws.bpart);
  k_bn_fin<<<1, 256, 0, stream>>>(ws.bpart, BB * NP0, 128, ws.stats);
  k_bn_apply<false><<<(BB * NP0 * 128 + 255) / 256, 256, 0, stream>>>(
      ws.xcur, ws.stats, in(3), in(4), nullptr, ws.xcur, ws.fm0h, ws.fm0l, BB * NP0 * 128, 128);

  // ---- sa0, conv1+bn1, sa1 ----
  run_sa(stream, ws, NP0, 128, 32, W(0), Wl(0), W(1), Wl(1), W(2), Wl(2),
         in(7), in(9), in(10), in(11), ws.fm0h, ws.fm0l);
  run_conv(stream, ws, ws.fm0h, ws.fm0l, 128, W(15), Wl(15), in(13), in(14), ws.idx0,
           NP0, 128, in(15), in(16), true, ws.fm1h, ws.fm1l);
  run_sa(stream, ws, NP0, 128, 32, W(3), Wl(3), W(4), Wl(4), W(5), Wl(5),
         in(19), in(21), in(22), in(23), ws.fm1h, ws.fm1l);

  // ---- pool1, knn1 ----
  k_knn2<NP0, 4><<<dim3(NP1 / 4, BB), 256, 0, stream>>>(ws.v0, NP1, ws.idxp0);
  k_pool<<<dim3(NP1, BB), 128, 0, stream>>>(ws.fm1h, ws.fm1l, ws.idxp0,
                                            ws.fmp1h, ws.fmp1l, NP0, NP1, 128);
  k_knn_radix<NP1, KNB_><<<dim3(NP1 / 4, BB), 256, 0, stream>>>(ws.v0, NP1, ws.idx1);

  // ---- conv2+bn2, sa2, conv3+bn3, sa3 ----
  run_conv(stream, ws, ws.fmp1h, ws.fmp1l, 128, W(16), Wl(16), in(25), in(26), ws.idx1,
           NP1, 256, in(27), in(28), true, ws.fm2h, ws.fm2l);
  run_sa(stream, ws, NP1, 256, 64, W(6), Wl(6), W(7), Wl(7), W(8), Wl(8),
         in(31), in(33), in(34), in(35), ws.fm2h, ws.fm2l);
  run_conv(stream, ws, ws.fm2h, ws.fm2l, 256, W(17), Wl(17), in(37), in(38), ws.idx1,
           NP1, 256, in(39), in(40), true, ws.fm3h, ws.fm3l);
  run_sa(stream, ws, NP1, 256, 64, W(9), Wl(9), W(10), Wl(10), W(11), Wl(11),
         in(43), in(45), in(46), in(47), ws.fm3h, ws.fm3l);

  // ---- pool2, knn2, conv4 (no bn), sa4 ----
  k_knn2<NP1, 4><<<dim3(NP2 / 4, BB), 256, 0, stream>>>(ws.v0, NP2, ws.idxp1);
  k_pool<<<dim3(NP2, BB), 256, 0, stream>>>(ws.fm3h, ws.fm3l, ws.idxp1,
                                            ws.fmp2h, ws.fmp2l, NP1, NP2, 256);
  k_knn_radix<NP2, KNB_><<<dim3(NP2 / 4, BB), 256, 0, stream>>>(ws.v0, NP2, ws.idx2);
  run_conv(stream, ws, ws.fmp2h, ws.fmp2l, 256, W(18), Wl(18), in(49), in(50), ws.idx2,
           NP2, 512, nullptr, nullptr, false, ws.fm4h, ws.fm4l);
  run_sa(stream, ws, NP2, 512, 128, W(12), Wl(12), W(13), Wl(13), W(14), Wl(14),
         in(53), in(55), in(56), in(57), ws.fm4h, ws.fm4l);

  // ---- global max, nearest, head (hi-plane-only GEMMs) ----
  k_maxn<<<dim3(2, BB), 256, 0, stream>>>(ws.fm4h, ws.fm4l, ws.fglob, NP2, 512);
  k_nearest<<<dim3(NP0 / 256, BB), 256, NP1 * 3 * 4, stream>>>(ws.v0, NP1, ws.ni1);
  k_nearest<<<dim3(NP0 / 256, BB), 256, NP2 * 3 * 4, stream>>>(ws.v0, NP2, ws.ni2);
  k_glob1<<<BB, 512, 0, stream>>>(ws.fglob, in(1), in(58), in(59), ws.glob1);

  for (int hf = 0; hf < 2; ++hf) {
    const int b0 = hf * 4;
    mmp<128, 2, 2, 0, false, false, false>(stream, ws.fm0h + (size_t)b0 * NP0 * 128,
        nullptr, W(19), nullptr, ws.glob1 + b0 * 512, ws.x1, nullptr,
        NP0, 512, 128, (long)NP0 * 128, 0, (long)NP0 * 512, 4, 1);
    mmp<128, 2, 0, 0, true, false, false>(stream, ws.fm1h + (size_t)b0 * NP0 * 128,
        nullptr, W(20), nullptr, nullptr, ws.x1, nullptr,
        NP0, 512, 128, (long)NP0 * 128, 0, (long)NP0 * 512, 4, 1);
    mmp<128, 2, 0, 0, true, true, false>(stream, ws.fm2h + (size_t)b0 * NP1 * 256,
        nullptr, W(21), nullptr, nullptr, ws.x1, nullptr,
        NP0, 512, 256, (long)NP1 * 256, 0, (long)NP0 * 512, 4, 1,
        ws.ni1 + (size_t)b0 * NP0, NP0);
    mmp<128, 2, 0, 0, true, true, false>(stream, ws.fm3h + (size_t)b0 * NP1 * 256,
        nullptr, W(22), nullptr, nullptr, ws.x1, nullptr,
        NP0, 512, 256, (long)NP1 * 256, 0, (long)NP0 * 512, 4, 1,
        ws.ni1 + (size_t)b0 * NP0, NP0);
    mmp<128, 2, 0, 0, true, true, false>(stream, ws.fm4h + (size_t)b0 * NP2 * 512,
        nullptr, W(23), nullptr, nullptr, ws.x1, nullptr,
        NP0, 512, 512, (long)NP2 * 512, 0, (long)NP0 * 512, 4, 1,
        ws.ni2 + (size_t)b0 * NP0, NP0);
    k_split4<true, false><<<(4 * NP0 * 512 / 4 + 255) / 256, 256, 0, stream>>>(
        ws.x1, ws.x1h, nullptr, 4 * NP0 * 512 / 4);
    mmp<128, 2, 1, 3, false, false, false>(stream, ws.x1h, nullptr, W(24), nullptr, in(61),
        ws.x2b, nullptr, NP0, 512, 512, (long)NP0 * 512, 0, (long)NP0 * 512, 4, 1);
    mmp<64, 2, 1, 0, false, false, false>(stream, ws.x2b, nullptr, W(25), nullptr, in(63),
        out + (size_t)b0 * NP0 * 50, nullptr, NP0, 50, 512,
        (long)NP0 * 512, 0, (long)NP0 * 50, 4, 1);
  }

  k_logsoftmax<<<(BB * NP0) / 4, 256, 0, stream>>>(out, BB * NP0, 50);
}

// Round 11
// 1469.802 us; speedup vs baseline: 2.5969x; 1.1144x over previous
//
#include <hip/hip_runtime.h>
#include <cfloat>

// ---------------------------------------------------------------------------
// GCN3D forward. Split-plane bf16 MFMA GEMMs (Dekker, f32-grade accuracy).
// Round-11: (1) bn_part 64->256 blocks (bpart relocated into dead AREA+12MB);
// (2) q A-fragments hoisted out of the n-tile loop in fused SA (loop-invariant);
// (3) knn_radix descent processes bit-PAIRS with dual packed count chains
// (31 -> 16 serial wave-reductions, exact same selection).
// B=8, N=2048->512->128, K_NB=50. Workspace 93,814,784 B.
// ---------------------------------------------------------------------------

#define BB   8
#define NP0  2048
#define NP1  512
#define NP2  128
#define KNB_ 50
#define VS0  (NP0 * 3)

typedef __attribute__((ext_vector_type(8))) short short8_t;
typedef __attribute__((ext_vector_type(4))) short short4_t;
typedef __attribute__((ext_vector_type(4))) float f32x4_t;
typedef unsigned short u16;

// ---------------- workspace layout (byte offsets) ----------------
static constexpr size_t O_V0    = 0;
static constexpr size_t O_IDX0  = 196608;
static constexpr size_t O_IDXP0 = 3473408;
static constexpr size_t O_IDX1  = 3538944;
static constexpr size_t O_IDXP1 = 4358144;
static constexpr size_t O_IDX2  = 4374528;
static constexpr size_t O_NI1   = 4579328;
static constexpr size_t O_NI2   = 4644864;
static constexpr size_t O_FGLOB = 4710400;
static constexpr size_t O_GLOB1 = 4726784;
static constexpr size_t O_COLS  = 4743168;   // mx vectors (64KB)
static constexpr size_t O_CPART = 4808704;   // inv vectors (64KB used)
static constexpr size_t O_STATS = 5332992;
static constexpr size_t O_XCUR  = 5599232;   // 8,388,608 f32 activation scratch
static constexpr size_t O_PL    = 18182144;  // 58,855,424 plane pools
static constexpr size_t O_AREA  = 77037568;  // 16,777,216 fout / pre / x1
// bpart (256 blocks x 1024 f32 = 1MB) lives at AREA+12MB: fout/pre are either
// <=8.4MB (disjoint) or dead (fout consumed by conv_layer before bn_part runs).
static constexpr size_t O_BPART = O_AREA + 12582912;
// end = 93,814,784

static constexpr size_t PL_WH    = 0;
static constexpr size_t PL_WL    = 4786176;
static constexpr size_t PL_FM0H  = 9572352;
static constexpr size_t PL_FM0L  = 13766656;
static constexpr size_t PL_FM1H  = 17960960;
static constexpr size_t PL_FM1L  = 22155264;
static constexpr size_t PL_FM2H  = 26349568;
static constexpr size_t PL_FM2L  = 28446720;
static constexpr size_t PL_FM3H  = 30543872;
static constexpr size_t PL_FM3L  = 32641024;
static constexpr size_t PL_FM4H  = 34738176;
static constexpr size_t PL_FM4L  = 35786752;
static constexpr size_t PL_FMP1H = 36835328;
static constexpr size_t PL_FMP1L = 37883904;
static constexpr size_t PL_FMP2H = 38932480;
static constexpr size_t PL_FMP2L = 39456768;
static constexpr size_t PL_QH    = 39981056;
static constexpr size_t PL_QL    = 41029632;
static constexpr size_t PL_VMH   = 42078208;
static constexpr size_t PL_VML   = 46272512;
static constexpr size_t PL_XSH   = 50466816;
static constexpr size_t PL_XSL   = 54661120;
static constexpr size_t PL_X1H = PL_VMH;   // head aliases (phase-disjoint)

__device__ __forceinline__ float bf2f(u16 h) {
  union { unsigned u; float f; } c; c.u = ((unsigned)h) << 16; return c.f;
}
__device__ __forceinline__ u16 f2bf(float f) {
  union { float f; unsigned u; } c; c.f = f;
  return (u16)((c.u + 0x7fffu + ((c.u >> 16) & 1u)) >> 16);
}

// ===========================================================================
// Plane GEMM. BSPLIT=false: B hi-plane only.
// ===========================================================================
template <int TM, int AMODE, int BIASM, int OUTM, bool ACC, bool GIDX, bool BSPLIT = true>
__global__ __launch_bounds__(256) void k_mmp(
    const void* __restrict__ A1, const void* __restrict__ A2,
    const u16* __restrict__ Bh0, const u16* __restrict__ Bl0,
    const float* __restrict__ bias, void* __restrict__ C1, void* __restrict__ C2,
    int M, int N, int K, long sA, long sB, long sC, int ksplit,
    const int* __restrict__ gidx, long sG) {
  constexpr int RT = TM / 32;
  constexpr int CT = TM / 32;
  __shared__ u16 Ah[TM][40], Bh[TM][40];
  __shared__ u16 Bl[BSPLIT ? TM : 1][40];
  __shared__ u16 Al[(AMODE == 2) ? 1 : TM][40];
  const int z = blockIdx.z;
  const int zb = z / ksplit, ks = z - zb * ksplit;
  const int kchunk = K / ksplit;
  const int kl0 = ks * kchunk, kl1 = kl0 + kchunk;
  const int m0 = blockIdx.x * TM, n0 = blockIdx.y * TM;
  const int t = threadIdx.x;
  const int lane = t & 63, w = t >> 6;
  const int wr = (w >> 1) * (TM / 2), wc = (w & 1) * (TM / 2);
  const int frow = lane & 15, koff = (lane >> 4) * 8;
  f32x4_t acc[RT][CT];
#pragma unroll
  for (int i = 0; i < RT; ++i)
#pragma unroll
    for (int j = 0; j < CT; ++j) acc[i][j] = (f32x4_t){0.f, 0.f, 0.f, 0.f};

  const u16* Ahg = (const u16*)A1 + (size_t)zb * sA;
  const u16* Alg = (const u16*)A2 + (size_t)zb * sA;
  const u16* Bhg = Bh0 + (size_t)zb * sB;
  const u16* Blg = Bl0 + (size_t)zb * sB;

  int ar, ac, arow = 0;
  if constexpr (TM == 128) { ar = t >> 1; ac = (t & 1) * 16; }
  else                     { ar = t >> 2; ac = (t & 3) * 8; }
  arow = m0 + ar;
  if constexpr (GIDX) arow = (gidx + (size_t)zb * sG)[arow];
  const int bn = ar, bc = ac;
  const bool bok = (n0 + bn) < N;
  const short8_t z8 = {0, 0, 0, 0, 0, 0, 0, 0};

  for (int k0 = kl0; k0 < kl1; k0 += 32) {
    __syncthreads();
    {
      const u16* s1 = Ahg + (size_t)arow * K + k0 + ac;
      if constexpr (TM == 128) {
        *(short8_t*)&Ah[ar][ac] = *(const short8_t*)s1;
        *(short8_t*)&Ah[ar][ac + 8] = *(const short8_t*)(s1 + 8);
        if constexpr (AMODE == 0) {
          const u16* s2 = Alg + (size_t)arow * K + k0 + ac;
          *(short8_t*)&Al[ar][ac] = *(const short8_t*)s2;
          *(short8_t*)&Al[ar][ac + 8] = *(const short8_t*)(s2 + 8);
        }
      } else {
        *(short8_t*)&Ah[ar][ac] = *(const short8_t*)s1;
        if constexpr (AMODE == 0)
          *(short8_t*)&Al[ar][ac] = *(const short8_t*)(Alg + (size_t)arow * K + k0 + ac);
      }
    }
    {
      const u16* s1 = Bhg + (size_t)(n0 + bn) * K + k0 + bc;
      const u16* s2 = Blg + (size_t)(n0 + bn) * K + k0 + bc;
      if constexpr (TM == 128) {
        *(short8_t*)&Bh[bn][bc] = bok ? *(const short8_t*)s1 : z8;
        *(short8_t*)&Bh[bn][bc + 8] = bok ? *(const short8_t*)(s1 + 8) : z8;
        if constexpr (BSPLIT) {
          *(short8_t*)&Bl[bn][bc] = bok ? *(const short8_t*)s2 : z8;
          *(short8_t*)&Bl[bn][bc + 8] = bok ? *(const short8_t*)(s2 + 8) : z8;
        }
      } else {
        *(short8_t*)&Bh[bn][bc] = bok ? *(const short8_t*)s1 : z8;
        if constexpr (BSPLIT)
          *(short8_t*)&Bl[bn][bc] = bok ? *(const short8_t*)s2 : z8;
      }
    }
    __syncthreads();
    short8_t ah[RT], al[RT], bh[CT], bl[CT];
#pragma unroll
    for (int i = 0; i < RT; ++i) {
      const int r = wr + i * 16 + frow;
      ah[i] = *(const short8_t*)&Ah[r][koff];
      if constexpr (AMODE != 2) al[i] = *(const short8_t*)&Al[r][koff];
    }
#pragma unroll
    for (int i = 0; i < CT; ++i) {
      const int r = wc + i * 16 + frow;
      bh[i] = *(const short8_t*)&Bh[r][koff];
      if constexpr (BSPLIT) bl[i] = *(const short8_t*)&Bl[r][koff];
    }
#pragma unroll
    for (int i = 0; i < RT; ++i)
#pragma unroll
      for (int j = 0; j < CT; ++j) {
        acc[i][j] = __builtin_amdgcn_mfma_f32_16x16x32_bf16(ah[i], bh[j], acc[i][j], 0, 0, 0);
        if constexpr (BSPLIT)
          acc[i][j] = __builtin_amdgcn_mfma_f32_16x16x32_bf16(ah[i], bl[j], acc[i][j], 0, 0, 0);
        if constexpr (AMODE != 2)
          acc[i][j] = __builtin_amdgcn_mfma_f32_16x16x32_bf16(al[i], bh[j], acc[i][j], 0, 0, 0);
      }
  }

  const int crow = (lane >> 4) * 4;
#pragma unroll
  for (int i = 0; i < RT; ++i) {
#pragma unroll
    for (int j = 0; j < CT; ++j) {
      const int gc = n0 + wc + j * 16 + frow;
      if (gc >= N) continue;
      float bv = 0.f;
      if constexpr (BIASM == 1) bv = bias[gc];
      if constexpr (BIASM == 2) bv = bias[(size_t)zb * N + gc];
      const int gr0 = m0 + wr + i * 16 + crow;
      if constexpr (OUTM == 0) {
        float* Cp = (float*)C1 + (size_t)z * sC;
#pragma unroll
        for (int q = 0; q < 4; ++q) {
          float vv = acc[i][j][q] + bv;
          if (ACC) vv += Cp[(size_t)(gr0 + q) * N + gc];
          Cp[(size_t)(gr0 + q) * N + gc] = vv;
        }
      } else if constexpr (OUTM == 1) {
        u16* Ph = (u16*)C1 + (size_t)z * sC;
        u16* Pl = (u16*)C2 + (size_t)z * sC;
#pragma unroll
        for (int q = 0; q < 4; ++q) {
          float vv = acc[i][j][q] + bv;
          u16 h = f2bf(vv);
          Ph[(size_t)(gr0 + q) * N + gc] = h;
          Pl[(size_t)(gr0 + q) * N + gc] = f2bf(vv - bf2f(h));
        }
      } else if constexpr (OUTM == 2) {
        u16* Ph = (u16*)C1 + (size_t)z * sC;
        u16* Pl = (u16*)C2 + (size_t)z * sC;
        short4_t h4, l4;
#pragma unroll
        for (int q = 0; q < 4; ++q) {
          float vv = acc[i][j][q] + bv;
          u16 h = f2bf(vv);
          h4[q] = (short)h;
          l4[q] = (short)f2bf(vv - bf2f(h));
        }
        *(short4_t*)(Ph + (size_t)gc * M + gr0) = h4;
        *(short4_t*)(Pl + (size_t)gc * M + gr0) = l4;
      } else {
        u16* Cb = (u16*)C1 + (size_t)z * sC;
#pragma unroll
        for (int q = 0; q < 4; ++q) {
          float vv = fmaxf(acc[i][j][q] + bv, 0.f);
          Cb[(size_t)(gr0 + q) * N + gc] = f2bf(vv);
        }
      }
    }
  }
}

template <int TM, int AMODE, int BIASM, int OUTM, bool ACC, bool GIDX, bool BSPLIT = true>
static void mmp(hipStream_t st, const void* A1, const void* A2,
                const u16* Bh, const u16* Bl, const float* bias,
                void* C1, void* C2, int M, int N, int K,
                long sA, long sB, long sC, int Z, int ksplit,
                const int* gidx = nullptr, long sG = 0) {
  dim3 grid(M / TM, (N + TM - 1) / TM, Z * ksplit);
  k_mmp<TM, AMODE, BIASM, OUTM, ACC, GIDX, BSPLIT><<<grid, 256, 0, st>>>(
      A1, A2, Bh, Bl, bias, C1, C2, M, N, K, sA, sB, sC, ksplit, gidx, sG);
}

// ===========================================================================
// Fused attention, 64-row m-tiles. A-fragments hoisted (loop-invariant).
// ===========================================================================
template <int QD>
__global__ __launch_bounds__(256) void k_sa_stats(
    const u16* __restrict__ qh, const u16* __restrict__ ql, int N,
    float* __restrict__ mx, float* __restrict__ inv) {
  __shared__ float mr[2][64], sr[2][64];
  const int b = blockIdx.y;
  const int m0 = blockIdx.x * 64;
  const int t = threadIdx.x, lane = t & 63, w = t >> 6;
  const int wm = (w >> 1) * 32, wn = (w & 1) * 64;
  const int frow = lane & 15, kq = (lane >> 4) * 8;
  const u16* qhb = qh + (size_t)b * N * QD;
  const u16* qlb = ql + (size_t)b * N * QD;
  constexpr int KS = QD / 32;
  // hoisted m-side fragments (invariant over n0)
  short8_t ahq[KS][2], alq[KS][2];
#pragma unroll
  for (int ks = 0; ks < KS; ++ks)
#pragma unroll
    for (int i = 0; i < 2; ++i) {
      const size_t r = (size_t)(m0 + wm + i * 16 + frow) * QD + ks * 32 + kq;
      ahq[ks][i] = *(const short8_t*)(qhb + r);
      alq[ks][i] = *(const short8_t*)(qlb + r);
    }
  float M[2][4], S[2][4];
#pragma unroll
  for (int i = 0; i < 2; ++i)
#pragma unroll
    for (int q = 0; q < 4; ++q) { M[i][q] = -FLT_MAX; S[i][q] = 0.f; }

  for (int n0 = 0; n0 < N; n0 += 128) {
    f32x4_t acc[2][4];
#pragma unroll
    for (int i = 0; i < 2; ++i)
#pragma unroll
      for (int j = 0; j < 4; ++j) acc[i][j] = (f32x4_t){0.f, 0.f, 0.f, 0.f};
#pragma unroll
    for (int ks = 0; ks < KS; ++ks) {
      short8_t b_h[4], b_l[4];
#pragma unroll
      for (int j = 0; j < 4; ++j) {
        const size_t r = (size_t)(n0 + wn + j * 16 + frow) * QD + ks * 32 + kq;
        b_h[j] = *(const short8_t*)(qhb + r);
        b_l[j] = *(const short8_t*)(qlb + r);
      }
#pragma unroll
      for (int i = 0; i < 2; ++i)
#pragma unroll
        for (int j = 0; j < 4; ++j) {
          acc[i][j] = __builtin_amdgcn_mfma_f32_16x16x32_bf16(ahq[ks][i], b_h[j], acc[i][j], 0, 0, 0);
          acc[i][j] = __builtin_amdgcn_mfma_f32_16x16x32_bf16(ahq[ks][i], b_l[j], acc[i][j], 0, 0, 0);
          acc[i][j] = __builtin_amdgcn_mfma_f32_16x16x32_bf16(alq[ks][i], b_h[j], acc[i][j], 0, 0, 0);
        }
    }
#pragma unroll
    for (int i = 0; i < 2; ++i)
#pragma unroll
      for (int q = 0; q < 4; ++q) {
        float tm = acc[i][0][q];
#pragma unroll
        for (int j = 1; j < 4; ++j) tm = fmaxf(tm, acc[i][j][q]);
#pragma unroll
        for (int off = 1; off < 16; off <<= 1) tm = fmaxf(tm, __shfl_xor(tm, off));
        const float Mn = fmaxf(M[i][q], tm);
        float ps = 0.f;
#pragma unroll
        for (int j = 0; j < 4; ++j) ps += __expf(acc[i][j][q] - Mn);
#pragma unroll
        for (int off = 1; off < 16; off <<= 1) ps += __shfl_xor(ps, off);
        S[i][q] = S[i][q] * __expf(M[i][q] - Mn) + ps;
        M[i][q] = Mn;
      }
  }
  if (frow == 0) {
#pragma unroll
    for (int i = 0; i < 2; ++i)
#pragma unroll
      for (int q = 0; q < 4; ++q) {
        const int ml = wm + i * 16 + (lane >> 4) * 4 + q;
        mr[w & 1][ml] = M[i][q];
        sr[w & 1][ml] = S[i][q];
      }
  }
  __syncthreads();
  if (t < 64) {
    const float M0 = mr[0][t], M1 = mr[1][t];
    const float Mm = fmaxf(M0, M1);
    const float Sm = sr[0][t] * __expf(M0 - Mm) + sr[1][t] * __expf(M1 - Mm);
    mx[(size_t)b * N + m0 + t] = Mm;
    inv[(size_t)b * N + m0 + t] = 1.f / Sm;
  }
}

template <int QD>
__global__ __launch_bounds__(256) void k_sa_xr(
    const u16* __restrict__ qh, const u16* __restrict__ ql,
    const u16* __restrict__ vmh, const u16* __restrict__ vml,
    const float* __restrict__ mx, const float* __restrict__ inv,
    const float* __restrict__ xcur, u16* __restrict__ xsh, u16* __restrict__ xsl,
    int N, int C) {
  __shared__ __align__(16) u16 Ph[64][132];
  __shared__ __align__(16) u16 Vh[128][68], Vl[128][68];
  const int b = blockIdx.z;
  const int m0 = blockIdx.x * 64, c0 = blockIdx.y * 128;
  const int t = threadIdx.x, lane = t & 63, w = t >> 6;
  const int wm = (w >> 1) * 32, wn = (w & 1) * 64;
  const int frow = lane & 15, kq = (lane >> 4) * 8;
  const u16* qhb = qh + (size_t)b * N * QD;
  const u16* qlb = ql + (size_t)b * N * QD;
  const u16* vhb = vmh + (size_t)b * (size_t)N * C;  // [C][N]
  const u16* vlb = vml + (size_t)b * (size_t)N * C;
  const float* mxb = mx + (size_t)b * N;
  const float* invb = inv + (size_t)b * N;
  constexpr int KS = QD / 32;
  const int vr = t >> 1, vco = (t & 1) * 32;
  // hoisted m-side fragments (invariant over n0)
  short8_t ahq[KS][2], alq[KS][2];
#pragma unroll
  for (int ks = 0; ks < KS; ++ks)
#pragma unroll
    for (int i = 0; i < 2; ++i) {
      const size_t r = (size_t)(m0 + wm + i * 16 + frow) * QD + ks * 32 + kq;
      ahq[ks][i] = *(const short8_t*)(qhb + r);
      alq[ks][i] = *(const short8_t*)(qlb + r);
    }
  f32x4_t xacc[2][4];
  float csum[2][4];
#pragma unroll
  for (int i = 0; i < 2; ++i)
#pragma unroll
    for (int j = 0; j < 4; ++j) { xacc[i][j] = (f32x4_t){0.f, 0.f, 0.f, 0.f}; csum[i][j] = 0.f; }

  for (int n0 = 0; n0 < N; n0 += 128) {
    __syncthreads();  // previous P/V reads complete
    // stage V half 0
    {
      const u16* s1 = vhb + (size_t)(c0 + vr) * N + n0 + vco;
      const u16* s2 = vlb + (size_t)(c0 + vr) * N + n0 + vco;
#pragma unroll
      for (int u = 0; u < 4; ++u) {
        *(short8_t*)&Vh[vr][vco + u * 8] = *(const short8_t*)(s1 + u * 8);
        *(short8_t*)&Vl[vr][vco + u * 8] = *(const short8_t*)(s2 + u * 8);
      }
    }
    // S tile (in-register): m 64 x n 128
    f32x4_t acc[2][4];
#pragma unroll
    for (int i = 0; i < 2; ++i)
#pragma unroll
      for (int j = 0; j < 4; ++j) acc[i][j] = (f32x4_t){0.f, 0.f, 0.f, 0.f};
#pragma unroll
    for (int ks = 0; ks < KS; ++ks) {
      short8_t b_h[4], b_l[4];
#pragma unroll
      for (int j = 0; j < 4; ++j) {
        const size_t r = (size_t)(n0 + wn + j * 16 + frow) * QD + ks * 32 + kq;
        b_h[j] = *(const short8_t*)(qhb + r);
        b_l[j] = *(const short8_t*)(qlb + r);
      }
#pragma unroll
      for (int i = 0; i < 2; ++i)
#pragma unroll
        for (int j = 0; j < 4; ++j) {
          acc[i][j] = __builtin_amdgcn_mfma_f32_16x16x32_bf16(ahq[ks][i], b_h[j], acc[i][j], 0, 0, 0);
          acc[i][j] = __builtin_amdgcn_mfma_f32_16x16x32_bf16(ahq[ks][i], b_l[j], acc[i][j], 0, 0, 0);
          acc[i][j] = __builtin_amdgcn_mfma_f32_16x16x32_bf16(alq[ks][i], b_h[j], acc[i][j], 0, 0, 0);
        }
    }
    // transform -> P (hi-only) in LDS; csum accumulate
    float mxj[4], ivj[4];
#pragma unroll
    for (int j = 0; j < 4; ++j) {
      const int n = n0 + wn + j * 16 + frow;
      mxj[j] = mxb[n];
      ivj[j] = invb[n];
    }
    const int mbase = wm + (lane >> 4) * 4;
#pragma unroll
    for (int i = 0; i < 2; ++i)
#pragma unroll
      for (int j = 0; j < 4; ++j)
#pragma unroll
        for (int q = 0; q < 4; ++q) {
          const float pv = __expf(acc[i][j][q] - mxj[j]) * ivj[j];
          csum[i][q] += pv;
          Ph[mbase + i * 16 + q][wn + j * 16 + frow] = f2bf(pv);
        }
    __syncthreads();  // P + V half0 ready
#pragma unroll
    for (int ks2 = 0; ks2 < 2; ++ks2) {
      short8_t p_h[2], v_h[4], v_l[4];
#pragma unroll
      for (int i = 0; i < 2; ++i)
        p_h[i] = *(const short8_t*)&Ph[wm + i * 16 + frow][ks2 * 32 + kq];
#pragma unroll
      for (int j = 0; j < 4; ++j) {
        v_h[j] = *(const short8_t*)&Vh[wn + j * 16 + frow][ks2 * 32 + kq];
        v_l[j] = *(const short8_t*)&Vl[wn + j * 16 + frow][ks2 * 32 + kq];
      }
#pragma unroll
      for (int i = 0; i < 2; ++i)
#pragma unroll
        for (int j = 0; j < 4; ++j) {
          xacc[i][j] = __builtin_amdgcn_mfma_f32_16x16x32_bf16(p_h[i], v_h[j], xacc[i][j], 0, 0, 0);
          xacc[i][j] = __builtin_amdgcn_mfma_f32_16x16x32_bf16(p_h[i], v_l[j], xacc[i][j], 0, 0, 0);
        }
    }
    __syncthreads();  // V half0 reads complete
    // stage V half 1
    {
      const u16* s1 = vhb + (size_t)(c0 + vr) * N + n0 + 64 + vco;
      const u16* s2 = vlb + (size_t)(c0 + vr) * N + n0 + 64 + vco;
#pragma unroll
      for (int u = 0; u < 4; ++u) {
        *(short8_t*)&Vh[vr][vco + u * 8] = *(const short8_t*)(s1 + u * 8);
        *(short8_t*)&Vl[vr][vco + u * 8] = *(const short8_t*)(s2 + u * 8);
      }
    }
    __syncthreads();  // V half1 ready
#pragma unroll
    for (int ks2 = 0; ks2 < 2; ++ks2) {
      short8_t p_h[2], v_h[4], v_l[4];
#pragma unroll
      for (int i = 0; i < 2; ++i)
        p_h[i] = *(const short8_t*)&Ph[wm + i * 16 + frow][64 + ks2 * 32 + kq];
#pragma unroll
      for (int j = 0; j < 4; ++j) {
        v_h[j] = *(const short8_t*)&Vh[wn + j * 16 + frow][ks2 * 32 + kq];
        v_l[j] = *(const short8_t*)&Vl[wn + j * 16 + frow][ks2 * 32 + kq];
      }
#pragma unroll
      for (int i = 0; i < 2; ++i)
#pragma unroll
        for (int j = 0; j < 4; ++j) {
          xacc[i][j] = __builtin_amdgcn_mfma_f32_16x16x32_bf16(p_h[i], v_h[j], xacc[i][j], 0, 0, 0);
          xacc[i][j] = __builtin_amdgcn_mfma_f32_16x16x32_bf16(p_h[i], v_l[j], xacc[i][j], 0, 0, 0);
        }
    }
  }
  // csum reduce + epilogue
#pragma unroll
  for (int i = 0; i < 2; ++i)
#pragma unroll
    for (int q = 0; q < 4; ++q)
#pragma unroll
      for (int off = 1; off < 16; off <<= 1) csum[i][q] += __shfl_xor(csum[i][q], off);
  __syncthreads();
  float* csb = (float*)&Ph[0][0];
  if (frow == 0) {
#pragma unroll
    for (int i = 0; i < 2; ++i)
#pragma unroll
      for (int q = 0; q < 4; ++q)
        csb[(w & 1) * 64 + wm + i * 16 + (lane >> 4) * 4 + q] = csum[i][q];
  }
  __syncthreads();
  if (t < 64) csb[128 + t] = csb[t] + csb[64 + t];
  __syncthreads();
#pragma unroll
  for (int i = 0; i < 2; ++i) {
#pragma unroll
    for (int q = 0; q < 4; ++q) {
      const int mloc = wm + i * 16 + (lane >> 4) * 4 + q;
      const float cstot = csb[128 + mloc];
      const size_t rowoff = ((size_t)b * N + m0 + mloc) * C;
#pragma unroll
      for (int j = 0; j < 4; ++j) {
        const int gc = c0 + wn + j * 16 + frow;
        const float val = xcur[rowoff + gc] - xacc[i][j][q] / (1e-9f + cstot);
        const u16 h = f2bf(val);
        xsh[rowoff + gc] = h;
        xsl[rowoff + gc] = f2bf(val - bf2f(h));
      }
    }
  }
}

// ===========================================================================
// weight split + activation split
// ===========================================================================
struct SplitJob { const float* s; u16* dh; u16* dl; int n, K, N, trans; };
struct SplitJobs { SplitJob j[26]; };
__global__ void k_splitjobs(SplitJobs jobs) {
  SplitJob jb = jobs.j[blockIdx.y];
  for (int i = blockIdx.x * 256 + threadIdx.x; i < jb.n; i += gridDim.x * 256) {
    float v;
    if (jb.trans) { int k = i % jb.K, n = i / jb.K; v = jb.s[(size_t)k * jb.N + n]; }
    else v = jb.s[i];
    u16 h = f2bf(v);
    jb.dh[i] = h;
    jb.dl[i] = f2bf(v - bf2f(h));
  }
}

template <bool RELU, bool LO>
__global__ void k_split4(const float* __restrict__ x, u16* __restrict__ ph,
                         u16* __restrict__ pl, int n4) {
  int i = blockIdx.x * 256 + threadIdx.x;
  if (i >= n4) return;
  float4 v = ((const float4*)x)[i];
  short4_t h4, l4;
  float vv[4] = {v.x, v.y, v.z, v.w};
#pragma unroll
  for (int q = 0; q < 4; ++q) {
    float f = RELU ? fmaxf(vv[q], 0.f) : vv[q];
    u16 h = f2bf(f);
    h4[q] = (short)h;
    if (LO) l4[q] = (short)f2bf(f - bf2f(h));
  }
  *(short4_t*)(ph + (size_t)i * 4) = h4;
  if (LO) *(short4_t*)(pl + (size_t)i * 4) = l4;
}

// ===========================================================================
// KNN. Radix-select with 2-bit-pair descent (dual packed count chains).
// ===========================================================================
template <int NCAND, int KSEL>
__global__ __launch_bounds__(256) void k_knn_radix(const float* __restrict__ pts, int Nq,
                                                   int* __restrict__ outIdx) {
  __shared__ float sp[NCAND * 3];
  const int b = blockIdx.y;
  const float* pb = pts + (size_t)b * VS0;
  for (int i = threadIdx.x; i < NCAND * 3; i += 256) sp[i] = pb[i];
  __syncthreads();
  const int wave = threadIdx.x >> 6, lane = threadIdx.x & 63;
  const int qi = blockIdx.x * 4 + wave;
  const float qx = sp[qi * 3], qy = sp[qi * 3 + 1], qz = sp[qi * 3 + 2];
  constexpr int CH = NCAND / 64;
  unsigned d[CH];
  unsigned x[32];
#pragma unroll
  for (int j = 0; j < 32; ++j) x[j] = 0u;
#pragma unroll
  for (int j = 0; j < CH; ++j) {
    const int m = lane + j * 64;
    const float dx = sp[m * 3] - qx, dy = sp[m * 3 + 1] - qy, dz = sp[m * 3 + 2] - qz;
    const float dd = dx * dx + dy * dy + dz * dz;
    d[j] = __float_as_uint((m == qi) ? FLT_MAX : dd);
    x[j] = d[j];
  }
  // in-register 32x32 bit transpose (LSB convention)
#pragma unroll
  for (int st = 0; st < 5; ++st) {
    const int s = 16 >> st;
    const unsigned ml = (s == 16) ? 0x0000FFFFu : (s == 8) ? 0x00FF00FFu
                      : (s == 4) ? 0x0F0F0F0Fu : (s == 2) ? 0x33333333u : 0x55555555u;
#pragma unroll
    for (int i = 0; i < 32; ++i) {
      if (i & s) continue;
      unsigned t = ((x[i] >> s) ^ x[i + s]) & ml;
      x[i + s] ^= t;
      x[i] ^= (t << s);
    }
  }
  // 2-bit-pair descent: bits (30,29)...(2,1), then bit 0. Counts <= 2048 fit 16b.
  unsigned active = (CH == 32) ? 0xFFFFFFFFu : ((1u << CH) - 1u);
  unsigned T = 0u;
  int kk = KSEL;
#pragma unroll
  for (int bb = 30; bb >= 2; bb -= 2) {
    const unsigned mh = x[bb], mlo = x[bb - 1];
    const unsigned a00 = active & ~mh & ~mlo;
    const unsigned a01 = active & ~mh & mlo;
    const unsigned a10 = active & mh & ~mlo;
    unsigned pA = (unsigned)__popc(a00) | ((unsigned)__popc(a01) << 16);
    unsigned pB = (unsigned)__popc(a10);
#pragma unroll
    for (int off = 32; off; off >>= 1) {
      pA += __shfl_xor(pA, off);
      pB += __shfl_xor(pB, off);
    }
    const int C00 = (int)(pA & 0xFFFFu), C01 = (int)(pA >> 16), C10 = (int)pB;
    if (kk <= C00) {
      active = a00;
    } else if (kk <= C00 + C01) {
      kk -= C00; active = a01; T |= 1u << (bb - 1);
    } else if (kk <= C00 + C01 + C10) {
      kk -= C00 + C01; active = a10; T |= 1u << bb;
    } else {
      kk -= C00 + C01 + C10; active = active & mh & mlo; T |= 3u << (bb - 1);
    }
  }
  {
    const unsigned zn = active & ~x[0];
    int c0 = __popc(zn);
#pragma unroll
    for (int off = 32; off; off >>= 1) c0 += __shfl_xor(c0, off);
    if (kk <= c0) active = zn;
    else { active &= x[0]; T |= 1u; }
  }
  // emit: all d < T, then smallest-index ties until KSEL filled
  int* orow = outIdx + ((size_t)b * Nq + qi) * KSEL;
  const unsigned long long ltmask = (1ull << lane) - 1ull;
  int base = 0;
#pragma unroll
  for (int j = 0; j < CH; ++j) {
    const bool sel = d[j] < T;
    const unsigned long long bal = __ballot(sel);
    const int pos = base + (int)__popcll(bal & ltmask);
    if (sel) orow[pos] = lane + j * 64;
    base += (int)__popcll(bal);
  }
#pragma unroll
  for (int j = 0; j < CH; ++j) {
    const bool sel = ((active >> j) & 1u) != 0u;
    const unsigned long long bal = __ballot(sel);
    const int pos = base + (int)__popcll(bal & ltmask);
    if (sel && pos < KSEL) orow[pos] = lane + j * 64;
    base += (int)__popcll(bal);
  }
}

template <int NCAND, int KSEL>
__global__ __launch_bounds__(256) void k_knn2(const float* __restrict__ pts, int Nq,
                                              int* __restrict__ outIdx) {
  __shared__ float sp[NCAND * 3];
  const int b = blockIdx.y;
  const float* pb = pts + (size_t)b * VS0;
  for (int i = threadIdx.x; i < NCAND * 3; i += 256) sp[i] = pb[i];
  __syncthreads();
  const int wave = threadIdx.x >> 6, lane = threadIdx.x & 63;
  const int qi = blockIdx.x * 4 + wave;
  const float qx = sp[qi * 3], qy = sp[qi * 3 + 1], qz = sp[qi * 3 + 2];
  constexpr int CH = NCAND / 64;
  float d[CH];
#pragma unroll
  for (int j = 0; j < CH; ++j) {
    const int m = lane + j * 64;
    const float dx = sp[m * 3] - qx, dy = sp[m * 3 + 1] - qy, dz = sp[m * 3 + 2] - qz;
    const float dd = dx * dx + dy * dy + dz * dz;
    d[j] = (m == qi) ? FLT_MAX : dd;
  }
  int* orow = outIdx + ((size_t)b * Nq + qi) * KSEL;
#pragma unroll 1
  for (int s = 0; s < KSEL; ++s) {
    float bd = FLT_MAX; int bj = 0;
#pragma unroll
    for (int j = 0; j < CH; ++j) {
      const bool better = d[j] < bd;
      bd = better ? d[j] : bd;
      bj = better ? j : bj;
    }
    int bm = lane + bj * 64;
#pragma unroll
    for (int off = 32; off; off >>= 1) {
      const float od = __shfl_xor(bd, off);
      const int om = __shfl_xor(bm, off);
      if (od < bd || (od == bd && om < bm)) { bd = od; bm = om; }
    }
    if (lane == 0) orow[s] = bm;
#pragma unroll
    for (int j = 0; j < CH; ++j)
      if (bm == lane + j * 64) d[j] = FLT_MAX;
  }
}

__global__ void k_transpose(const float* __restrict__ in, float* __restrict__ out) {
  int i = blockIdx.x * 256 + threadIdx.x;
  if (i >= BB * NP0 * 3) return;
  int dd = i % 3, tt = (i / 3) % NP0, b = i / (3 * NP0);
  out[i] = in[((size_t)b * 3 + dd) * NP0 + tt];
}

__global__ void k_conv_surface(const float* __restrict__ v, const int* __restrict__ idx,
                               const float* __restrict__ dirs, float* __restrict__ out,
                               int N, int M) {
  __shared__ float su[KNB_ * 3];
  int b = blockIdx.y, n = blockIdx.x, c = threadIdx.x;
  const float* vb = v + (size_t)b * VS0;
  float cx = vb[n * 3], cy = vb[n * 3 + 1], cz = vb[n * 3 + 2];
  const int* irow = idx + ((size_t)b * N + n) * KNB_;
  if (c < KNB_) {
    int j = irow[c];
    float dx = vb[j * 3] - cx, dy = vb[j * 3 + 1] - cy, dz = vb[j * 3 + 2] - cz;
    float inv = 1.f / fmaxf(sqrtf(dx * dx + dy * dy + dz * dz), 1e-12f);
    su[c * 3] = dx * inv; su[c * 3 + 1] = dy * inv; su[c * 3 + 2] = dz * inv;
  }
  __syncthreads();
  float d0 = dirs[c], d1 = dirs[M + c], d2 = dirs[2 * M + c];
  float inv = 1.f / fmaxf(sqrtf(d0 * d0 + d1 * d1 + d2 * d2), 1e-12f);
  d0 *= inv; d1 *= inv; d2 *= inv;
  float acc = 0.f;
  for (int k = 0; k < KNB_; ++k) {
    float th = fmaxf(su[k * 3] * d0 + su[k * 3 + 1] * d1 + su[k * 3 + 2] * d2, 0.f);
    acc = fmaxf(acc, th);
  }
  out[((size_t)b * N + n) * M + c] = acc;
}

__global__ void k_conv_layer(const float* __restrict__ v, const int* __restrict__ idx,
                             const float* __restrict__ dirs, const float* __restrict__ fout,
                             float* __restrict__ out, int N, int C) {
  __shared__ float su[KNB_ * 3];
  __shared__ int sidx[KNB_];
  int b = blockIdx.y, n = blockIdx.x, c = threadIdx.x;
  const float* vb = v + (size_t)b * VS0;
  float cx = vb[n * 3], cy = vb[n * 3 + 1], cz = vb[n * 3 + 2];
  const int* irow = idx + ((size_t)b * N + n) * KNB_;
  if (c < KNB_) {
    int j = irow[c]; sidx[c] = j;
    float dx = vb[j * 3] - cx, dy = vb[j * 3 + 1] - cy, dz = vb[j * 3 + 2] - cz;
    float inv = 1.f / fmaxf(sqrtf(dx * dx + dy * dy + dz * dz), 1e-12f);
    su[c * 3] = dx * inv; su[c * 3 + 1] = dy * inv; su[c * 3 + 2] = dz * inv;
  }
  __syncthreads();
  float d0 = dirs[c], d1 = dirs[C + c], d2 = dirs[2 * C + c];
  float inv = 1.f / fmaxf(sqrtf(d0 * d0 + d1 * d1 + d2 * d2), 1e-12f);
  d0 *= inv; d1 *= inv; d2 *= inv;
  const float* fb = fout + (size_t)b * N * 2 * C;
  float acc = -FLT_MAX;
  for (int k = 0; k < KNB_; ++k) {
    float th = fmaxf(su[k * 3] * d0 + su[k * 3 + 1] * d1 + su[k * 3 + 2] * d2, 0.f);
    float fs = fb[(size_t)sidx[k] * 2 * C + C + c];
    acc = fmaxf(acc, th * fs);
  }
  out[((size_t)b * N + n) * C + c] = fb[(size_t)n * 2 * C + c] + acc;
}

// ===========================================================================
// BN (256-block partials) / pool / misc
// ===========================================================================
__global__ void k_bn_part(const float* __restrict__ x, int rows, int C, float* __restrict__ part) {
  const int blk = blockIdx.x;               // 256 blocks
  const int chunk = rows / 256;
  const int r0 = blk * chunk;
  const int c0 = threadIdx.x, c1 = threadIdx.x + 256;
  float s0 = 0, s20 = 0, s1 = 0, s21 = 0;
  for (int r = 0; r < chunk; ++r) {
    const float* row = x + (size_t)(r0 + r) * C;
    if (c0 < C) { float v = row[c0]; s0 += v; s20 += v * v; }
    if (c1 < C) { float v = row[c1]; s1 += v; s21 += v * v; }
  }
  float* p = part + (size_t)blk * 1024;
  if (c0 < C) { p[c0] = s0; p[512 + c0] = s20; }
  if (c1 < C) { p[c1] = s1; p[512 + c1] = s21; }
}

__global__ void k_bn_fin(const float* __restrict__ part, int rows, int C, float* __restrict__ stats) {
  int c = blockIdx.x * 256 + threadIdx.x;
  if (c >= C) return;
  float s = 0, s2 = 0;
  for (int b2 = 0; b2 < 256; ++b2) { s += part[b2 * 1024 + c]; s2 += part[b2 * 1024 + 512 + c]; }
  float m = s / rows;
  float var = s2 / rows - m * m;
  stats[c] = m;
  stats[C + c] = rsqrtf(var + 1e-5f);
}

template <bool ADD>
__global__ void k_bn_apply(const float* __restrict__ x, const float* __restrict__ stats,
                           const float* __restrict__ g, const float* __restrict__ bb,
                           const float* __restrict__ base, float* __restrict__ outf,
                           u16* __restrict__ ph, u16* __restrict__ pl, int total, int C) {
  int i = blockIdx.x * 256 + threadIdx.x;
  if (i >= total) return;
  int c = i % C;
  float v = (x[i] - stats[c]) * stats[C + c] * g[c] + bb[c];
  v = fmaxf(v, 0.f);
  float r = ADD ? base[i] + v : v;
  outf[i] = r;
  u16 h = f2bf(r);
  ph[i] = h;
  pl[i] = f2bf(r - bf2f(h));
}

__global__ void k_pool(const u16* __restrict__ fh, const u16* __restrict__ fl,
                       const int* __restrict__ idxp, u16* __restrict__ oh,
                       u16* __restrict__ ol, int Nin, int pn, int C) {
  int b = blockIdx.y, p = blockIdx.x, c = threadIdx.x;
  const int* ir = idxp + ((size_t)b * pn + p) * 4;
  const u16* fhb = fh + (size_t)b * Nin * C;
  const u16* flb = fl + (size_t)b * Nin * C;
  float acc = -FLT_MAX;
#pragma unroll
  for (int k = 0; k < 4; ++k) {
    size_t o = (size_t)ir[k] * C + c;
    acc = fmaxf(acc, bf2f(fhb[o]) + bf2f(flb[o]));
  }
  u16 h = f2bf(acc);
  oh[((size_t)b * pn + p) * C + c] = h;
  ol[((size_t)b * pn + p) * C + c] = f2bf(acc - bf2f(h));
}

__global__ void k_maxn(const u16* __restrict__ fh, const u16* __restrict__ fl,
                       float* __restrict__ out, int N, int C) {
  int b = blockIdx.y;
  int c = blockIdx.x * 256 + threadIdx.x;
  if (c >= C) return;
  float acc = -FLT_MAX;
  for (int n = 0; n < N; ++n) {
    size_t o = ((size_t)b * N + n) * C + c;
    acc = fmaxf(acc, bf2f(fh[o]) + bf2f(fl[o]));
  }
  out[(size_t)b * C + c] = acc;
}

__global__ void k_nearest(const float* __restrict__ v, int Ns, int* __restrict__ out) {
  extern __shared__ float sp[];
  int b = blockIdx.y;
  const float* vsb = v + (size_t)b * VS0;
  for (int i = threadIdx.x; i < Ns * 3; i += 256) sp[i] = vsb[i];
  __syncthreads();
  int t = blockIdx.x * 256 + threadIdx.x;
  float tx = vsb[t * 3], ty = vsb[t * 3 + 1], tz = vsb[t * 3 + 2];
  float bd = FLT_MAX; int bi = 0;
#pragma unroll 4
  for (int s = 0; s < Ns; ++s) {
    float dx = sp[s * 3] - tx, dy = sp[s * 3 + 1] - ty, dz = sp[s * 3 + 2] - tz;
    float dd = dx * dx + dy * dy + dz * dz;
    if (dd < bd) { bd = dd; bi = s; }
  }
  out[(size_t)b * NP0 + t] = bi;
}

__global__ void k_glob1(const float* __restrict__ fglob, const float* __restrict__ onehot,
                        const float* __restrict__ h1w, const float* __restrict__ h1b,
                        float* __restrict__ out) {
  int b = blockIdx.x, j = threadIdx.x;
  float s = h1b[j];
  for (int i = 0; i < 512; ++i) s = fmaf(fglob[b * 512 + i], h1w[(size_t)(1280 + i) * 512 + j], s);
  for (int i = 0; i < 16; ++i) s = fmaf(onehot[b * 16 + i], h1w[(size_t)(1792 + i) * 512 + j], s);
  out[b * 512 + j] = s;
}

__global__ void k_logsoftmax(float* __restrict__ x, int rows, int C) {
  int r = blockIdx.x * 4 + (threadIdx.x >> 6);
  int lane = threadIdx.x & 63;
  if (r >= rows) return;
  float* xr = x + (size_t)r * C;
  float v = (lane < C) ? xr[lane] : -FLT_MAX;
  float mx = v;
  for (int o = 32; o; o >>= 1) mx = fmaxf(mx, __shfl_xor(mx, o));
  float e = (lane < C) ? __expf(v - mx) : 0.f;
  float s = e;
  for (int o = 32; o; o >>= 1) s += __shfl_xor(s, o);
  float lse = mx + logf(s);
  if (lane < C) xr[lane] = v - lse;
}

// ===========================================================================
// host
// ===========================================================================
struct Ws {
  float *v0, *fglob, *glob1, *mx, *inv, *stats, *bpart, *xcur, *pre, *fout, *x1;
  int *idx0, *idxp0, *idx1, *idxp1, *idx2, *ni1, *ni2;
  u16 *wh, *wl;
  u16 *fm0h, *fm0l, *fm1h, *fm1l, *fm2h, *fm2l, *fm3h, *fm3l, *fm4h, *fm4l;
  u16 *fmp1h, *fmp1l, *fmp2h, *fmp2l, *qh, *ql, *vmh, *vml, *xsh, *xsl;
  u16 *x1h, *x2b;
};

static void run_sa(hipStream_t st, Ws& ws, int N, int C, int Q,
                   const u16* qkh, const u16* qkl, const u16* vwh, const u16* vwl,
                   const u16* twh, const u16* twl,
                   const float* vb, const float* tb, const float* g, const float* be,
                   u16* xh, u16* xl) {
  const long sx = (long)N * C;
  mmp<64, 0, 0, 1, false, false>(st, xh, xl, qkh, qkl, nullptr, ws.qh, ws.ql,
                                 N, Q, C, sx, 0, (long)N * Q, BB, 1);
  mmp<64, 0, 1, 2, false, false>(st, xh, xl, vwh, vwl, vb, ws.vmh, ws.vml,
                                 N, C, C, sx, 0, sx, BB, 1);
  dim3 gs(N / 64, BB), gx(N / 64, C / 128, BB);
  if (Q == 32) {
    k_sa_stats<32><<<gs, 256, 0, st>>>(ws.qh, ws.ql, N, ws.mx, ws.inv);
    k_sa_xr<32><<<gx, 256, 0, st>>>(ws.qh, ws.ql, ws.vmh, ws.vml, ws.mx, ws.inv,
                                    ws.xcur, ws.xsh, ws.xsl, N, C);
  } else if (Q == 64) {
    k_sa_stats<64><<<gs, 256, 0, st>>>(ws.qh, ws.ql, N, ws.mx, ws.inv);
    k_sa_xr<64><<<gx, 256, 0, st>>>(ws.qh, ws.ql, ws.vmh, ws.vml, ws.mx, ws.inv,
                                    ws.xcur, ws.xsh, ws.xsl, N, C);
  } else {
    k_sa_stats<128><<<gs, 256, 0, st>>>(ws.qh, ws.ql, N, ws.mx, ws.inv);
    k_sa_xr<128><<<gx, 256, 0, st>>>(ws.qh, ws.ql, ws.vmh, ws.vml, ws.mx, ws.inv,
                                     ws.xcur, ws.xsh, ws.xsl, N, C);
  }
  mmp<64, 0, 1, 0, false, false>(st, ws.xsh, ws.xsl, twh, twl, tb, ws.pre, nullptr,
                                 N, C, C, sx, 0, sx, BB, 1);
  k_bn_part<<<256, 256, 0, st>>>(ws.pre, BB * N, C, ws.bpart);
  k_bn_fin<<<(C + 255) / 256, 256, 0, st>>>(ws.bpart, BB * N, C, ws.stats);
  k_bn_apply<true><<<(BB * N * C + 255) / 256, 256, 0, st>>>(ws.pre, ws.stats, g, be,
                                                             ws.xcur, ws.xcur, xh, xl, BB * N * C, C);
}

static void run_conv(hipStream_t st, Ws& ws, const u16* finh, const u16* finl, int Cin,
                     const u16* cwh, const u16* cwl, const float* bias, const float* dirs,
                     const int* idx, int N, int C,
                     const float* bng, const float* bnb, bool doBN, u16* fmh, u16* fml) {
  if (N == NP0)
    mmp<128, 0, 1, 0, false, false>(st, finh, finl, cwh, cwl, bias, ws.fout, nullptr,
                                    N, 2 * C, Cin, (long)N * Cin, 0, (long)N * 2 * C, BB, 1);
  else
    mmp<64, 0, 1, 0, false, false>(st, finh, finl, cwh, cwl, bias, ws.fout, nullptr,
                                   N, 2 * C, Cin, (long)N * Cin, 0, (long)N * 2 * C, BB, 1);
  k_conv_layer<<<dim3(N, BB), C, 0, st>>>(ws.v0, idx, dirs, ws.fout, ws.xcur, N, C);
  if (doBN) {
    k_bn_part<<<256, 256, 0, st>>>(ws.xcur, BB * N, C, ws.bpart);
    k_bn_fin<<<(C + 255) / 256, 256, 0, st>>>(ws.bpart, BB * N, C, ws.stats);
    k_bn_apply<false><<<(BB * N * C + 255) / 256, 256, 0, st>>>(
        ws.xcur, ws.stats, bng, bnb, nullptr, ws.xcur, fmh, fml, BB * N * C, C);
  } else {
    k_split4<false, true><<<(BB * N * C / 4 + 255) / 256, 256, 0, st>>>(
        ws.xcur, fmh, fml, BB * N * C / 4);
  }
}

extern "C" void kernel_launch(void* const* d_in, const int* in_sizes, int n_in,
                              void* d_out, int out_size, void* d_ws, size_t ws_size,
                              hipStream_t stream) {
  auto in = [&](int i) { return (const float*)d_in[i]; };
  char* p = (char*)d_ws;
  Ws ws;
  ws.v0 = (float*)(p + O_V0);
  ws.idx0 = (int*)(p + O_IDX0); ws.idxp0 = (int*)(p + O_IDXP0);
  ws.idx1 = (int*)(p + O_IDX1); ws.idxp1 = (int*)(p + O_IDXP1);
  ws.idx2 = (int*)(p + O_IDX2);
  ws.ni1 = (int*)(p + O_NI1); ws.ni2 = (int*)(p + O_NI2);
  ws.fglob = (float*)(p + O_FGLOB); ws.glob1 = (float*)(p + O_GLOB1);
  ws.mx = (float*)(p + O_COLS); ws.inv = (float*)(p + O_CPART);
  ws.stats = (float*)(p + O_STATS); ws.bpart = (float*)(p + O_BPART);
  ws.xcur = (float*)(p + O_XCUR);
  ws.pre = (float*)(p + O_AREA);
  ws.fout = (float*)(p + O_AREA); ws.x1 = (float*)(p + O_AREA);
  char* pl = p + O_PL;
  ws.wh = (u16*)(pl + PL_WH); ws.wl = (u16*)(pl + PL_WL);
  ws.fm0h = (u16*)(pl + PL_FM0H); ws.fm0l = (u16*)(pl + PL_FM0L);
  ws.fm1h = (u16*)(pl + PL_FM1H); ws.fm1l = (u16*)(pl + PL_FM1L);
  ws.fm2h = (u16*)(pl + PL_FM2H); ws.fm2l = (u16*)(pl + PL_FM2L);
  ws.fm3h = (u16*)(pl + PL_FM3H); ws.fm3l = (u16*)(pl + PL_FM3L);
  ws.fm4h = (u16*)(pl + PL_FM4H); ws.fm4l = (u16*)(pl + PL_FM4L);
  ws.fmp1h = (u16*)(pl + PL_FMP1H); ws.fmp1l = (u16*)(pl + PL_FMP1L);
  ws.fmp2h = (u16*)(pl + PL_FMP2H); ws.fmp2l = (u16*)(pl + PL_FMP2L);
  ws.qh = (u16*)(pl + PL_QH); ws.ql = (u16*)(pl + PL_QL);
  ws.vmh = (u16*)(pl + PL_VMH); ws.vml = (u16*)(pl + PL_VML);
  ws.xsh = (u16*)(pl + PL_XSH); ws.xsl = (u16*)(pl + PL_XSL);
  ws.x1h = (u16*)(pl + PL_X1H);
  ws.x2b = (u16*)(p + O_XCUR);
  float* out = (float*)d_out;

  // ---- one-time weight plane split (pre-transposed to [N,K]) ----
  SplitJobs jobs;
  size_t wq[26];
  size_t off = 0;
  int ji = 0;
  auto addjob = [&](const float* s, int K, int N, int trans) {
    int n = K * N;
    jobs.j[ji] = {s, ws.wh + off, ws.wl + off, n, K, N, trans};
    wq[ji] = off; off += (size_t)n; ++ji;
  };
  addjob(in(5), 128, 32, 0);  addjob(in(6), 128, 128, 0);  addjob(in(8), 128, 128, 0);
  addjob(in(17), 128, 32, 0); addjob(in(18), 128, 128, 0); addjob(in(20), 128, 128, 0);
  addjob(in(29), 256, 64, 0); addjob(in(30), 256, 256, 0); addjob(in(32), 256, 256, 0);
  addjob(in(41), 256, 64, 0); addjob(in(42), 256, 256, 0); addjob(in(44), 256, 256, 0);
  addjob(in(51), 512, 128, 0); addjob(in(52), 512, 512, 0); addjob(in(54), 512, 512, 0);
  addjob(in(12), 128, 256, 1);
  addjob(in(24), 128, 512, 1);
  addjob(in(36), 256, 512, 1);
  addjob(in(48), 256, 1024, 1);
  addjob(in(58) + 0 * 512, 128, 512, 1);
  addjob(in(58) + (size_t)128 * 512, 128, 512, 1);
  addjob(in(58) + (size_t)256 * 512, 256, 512, 1);
  addjob(in(58) + (size_t)512 * 512, 256, 512, 1);
  addjob(in(58) + (size_t)768 * 512, 512, 512, 1);
  addjob(in(60), 512, 512, 1);
  addjob(in(62), 512, 50, 1);
  k_splitjobs<<<dim3(32, 26), 256, 0, stream>>>(jobs);
  auto W = [&](int i) { return ws.wh + wq[i]; };
  auto Wl = [&](int i) { return ws.wl + wq[i]; };

  // ---- geometry ----
  k_transpose<<<(BB * NP0 * 3 + 255) / 256, 256, 0, stream>>>(in(0), ws.v0);
  k_knn_radix<NP0, KNB_><<<dim3(NP0 / 4, BB), 256, 0, stream>>>(ws.v0, NP0, ws.idx0);

  // ---- conv0 + bn0 ----
  k_conv_surface<<<dim3(NP0, BB), 128, 0, stream>>>(ws.v0, ws.idx0, in(2), ws.xcur, NP0, 128);
  k_bn_part<<<256, 256, 0, stream>>>(ws.xcur, BB * NP0, 128, ws.bpart);
  k_bn_fin<<<1, 256, 0, stream>>>(ws.bpart, BB * NP0, 128, ws.stats);
  k_bn_apply<false><<<(BB * NP0 * 128 + 255) / 256, 256, 0, stream>>>(
      ws.xcur, ws.stats, in(3), in(4), nullptr, ws.xcur, ws.fm0h, ws.fm0l, BB * NP0 * 128, 128);

  // ---- sa0, conv1+bn1, sa1 ----
  run_sa(stream, ws, NP0, 128, 32, W(0), Wl(0), W(1), Wl(1), W(2), Wl(2),
         in(7), in(9), in(10), in(11), ws.fm0h, ws.fm0l);
  run_conv(stream, ws, ws.fm0h, ws.fm0l, 128, W(15), Wl(15), in(13), in(14), ws.idx0,
           NP0, 128, in(15), in(16), true, ws.fm1h, ws.fm1l);
  run_sa(stream, ws, NP0, 128, 32, W(3), Wl(3), W(4), Wl(4), W(5), Wl(5),
         in(19), in(21), in(22), in(23), ws.fm1h, ws.fm1l);

  // ---- pool1, knn1 ----
  k_knn2<NP0, 4><<<dim3(NP1 / 4, BB), 256, 0, stream>>>(ws.v0, NP1, ws.idxp0);
  k_pool<<<dim3(NP1, BB), 128, 0, stream>>>(ws.fm1h, ws.fm1l, ws.idxp0,
                                            ws.fmp1h, ws.fmp1l, NP0, NP1, 128);
  k_knn_radix<NP1, KNB_><<<dim3(NP1 / 4, BB), 256, 0, stream>>>(ws.v0, NP1, ws.idx1);

  // ---- conv2+bn2, sa2, conv3+bn3, sa3 ----
  run_conv(stream, ws, ws.fmp1h, ws.fmp1l, 128, W(16), Wl(16), in(25), in(26), ws.idx1,
           NP1, 256, in(27), in(28), true, ws.fm2h, ws.fm2l);
  run_sa(stream, ws, NP1, 256, 64, W(6), Wl(6), W(7), Wl(7), W(8), Wl(8),
         in(31), in(33), in(34), in(35), ws.fm2h, ws.fm2l);
  run_conv(stream, ws, ws.fm2h, ws.fm2l, 256, W(17), Wl(17), in(37), in(38), ws.idx1,
           NP1, 256, in(39), in(40), true, ws.fm3h, ws.fm3l);
  run_sa(stream, ws, NP1, 256, 64, W(9), Wl(9), W(10), Wl(10), W(11), Wl(11),
         in(43), in(45), in(46), in(47), ws.fm3h, ws.fm3l);

  // ---- pool2, knn2, conv4 (no bn), sa4 ----
  k_knn2<NP1, 4><<<dim3(NP2 / 4, BB), 256, 0, stream>>>(ws.v0, NP2, ws.idxp1);
  k_pool<<<dim3(NP2, BB), 256, 0, stream>>>(ws.fm3h, ws.fm3l, ws.idxp1,
                                            ws.fmp2h, ws.fmp2l, NP1, NP2, 256);
  k_knn_radix<NP2, KNB_><<<dim3(NP2 / 4, BB), 256, 0, stream>>>(ws.v0, NP2, ws.idx2);
  run_conv(stream, ws, ws.fmp2h, ws.fmp2l, 256, W(18), Wl(18), in(49), in(50), ws.idx2,
           NP2, 512, nullptr, nullptr, false, ws.fm4h, ws.fm4l);
  run_sa(stream, ws, NP2, 512, 128, W(12), Wl(12), W(13), Wl(13), W(14), Wl(14),
         in(53), in(55), in(56), in(57), ws.fm4h, ws.fm4l);

  // ---- global max, nearest, head (hi-plane-only GEMMs) ----
  k_maxn<<<dim3(2, BB), 256, 0, stream>>>(ws.fm4h, ws.fm4l, ws.fglob, NP2, 512);
  k_nearest<<<dim3(NP0 / 256, BB), 256, NP1 * 3 * 4, stream>>>(ws.v0, NP1, ws.ni1);
  k_nearest<<<dim3(NP0 / 256, BB), 256, NP2 * 3 * 4, stream>>>(ws.v0, NP2, ws.ni2);
  k_glob1<<<BB, 512, 0, stream>>>(ws.fglob, in(1), in(58), in(59), ws.glob1);

  for (int hf = 0; hf < 2; ++hf) {
    const int b0 = hf * 4;
    mmp<128, 2, 2, 0, false, false, false>(stream, ws.fm0h + (size_t)b0 * NP0 * 128,
        nullptr, W(19), nullptr, ws.glob1 + b0 * 512, ws.x1, nullptr,
        NP0, 512, 128, (long)NP0 * 128, 0, (long)NP0 * 512, 4, 1);
    mmp<128, 2, 0, 0, true, false, false>(stream, ws.fm1h + (size_t)b0 * NP0 * 128,
        nullptr, W(20), nullptr, nullptr, ws.x1, nullptr,
        NP0, 512, 128, (long)NP0 * 128, 0, (long)NP0 * 512, 4, 1);
    mmp<128, 2, 0, 0, true, true, false>(stream, ws.fm2h + (size_t)b0 * NP1 * 256,
        nullptr, W(21), nullptr, nullptr, ws.x1, nullptr,
        NP0, 512, 256, (long)NP1 * 256, 0, (long)NP0 * 512, 4, 1,
        ws.ni1 + (size_t)b0 * NP0, NP0);
    mmp<128, 2, 0, 0, true, true, false>(stream, ws.fm3h + (size_t)b0 * NP1 * 256,
        nullptr, W(22), nullptr, nullptr, ws.x1, nullptr,
        NP0, 512, 256, (long)NP1 * 256, 0, (long)NP0 * 512, 4, 1,
        ws.ni1 + (size_t)b0 * NP0, NP0);
    mmp<128, 2, 0, 0, true, true, false>(stream, ws.fm4h + (size_t)b0 * NP2 * 512,
        nullptr, W(23), nullptr, nullptr, ws.x1, nullptr,
        NP0, 512, 512, (long)NP2 * 512, 0, (long)NP0 * 512, 4, 1,
        ws.ni2 + (size_t)b0 * NP0, NP0);
    k_split4<true, false><<<(4 * NP0 * 512 / 4 + 255) / 256, 256, 0, stream>>>(
        ws.x1, ws.x1h, nullptr, 4 * NP0 * 512 / 4);
    mmp<128, 2, 1, 3, false, false, false>(stream, ws.x1h, nullptr, W(24), nullptr, in(61),
        ws.x2b, nullptr, NP0, 512, 512, (long)NP0 * 512, 0, (long)NP0 * 512, 4, 1);
    mmp<64, 2, 1, 0, false, false, false>(stream, ws.x2b, nullptr, W(25), nullptr, in(63),
        out + (size_t)b0 * NP0 * 50, nullptr, NP0, 50, 512,
        (long)NP0 * 512, 0, (long)NP0 * 50, 4, 1);
  }

  k_logsoftmax<<<(BB * NP0) / 4, 256, 0, stream>>>(out, BB * NP0, 50);
}

// Round 12
// 1398.845 us; speedup vs baseline: 2.7286x; 1.0507x over previous
//
#include <hip/hip_runtime.h>
#include <cfloat>

// ---------------------------------------------------------------------------
// GCN3D forward. Split-plane bf16 MFMA GEMMs (Dekker, f32-grade accuracy).
// Round-12: (1) k_sa_xr NSPLIT — n-range split across blocks (raw partials +
// k_xsub2 combine): grid 256->512 blocks at N=2048/512, breaking the
// 1-block/CU occupancy cap; (2) k_bn_fin parallelized (C/32 blocks, was 1);
// (3) knn tie-emit early break.
// B=8, N=2048->512->128, K_NB=50. Workspace 93,814,784 B.
// ---------------------------------------------------------------------------

#define BB   8
#define NP0  2048
#define NP1  512
#define NP2  128
#define KNB_ 50
#define VS0  (NP0 * 3)

typedef __attribute__((ext_vector_type(8))) short short8_t;
typedef __attribute__((ext_vector_type(4))) short short4_t;
typedef __attribute__((ext_vector_type(4))) float f32x4_t;
typedef unsigned short u16;

// ---------------- workspace layout (byte offsets) ----------------
static constexpr size_t O_V0    = 0;
static constexpr size_t O_IDX0  = 196608;
static constexpr size_t O_IDXP0 = 3473408;
static constexpr size_t O_IDX1  = 3538944;
static constexpr size_t O_IDXP1 = 4358144;
static constexpr size_t O_IDX2  = 4374528;
static constexpr size_t O_NI1   = 4579328;
static constexpr size_t O_NI2   = 4644864;
static constexpr size_t O_FGLOB = 4710400;
static constexpr size_t O_GLOB1 = 4726784;
static constexpr size_t O_COLS  = 4743168;   // mx vectors (64KB)
static constexpr size_t O_CPART = 4808704;   // inv (64KB) + csum partials (128KB)
static constexpr size_t O_STATS = 5332992;
static constexpr size_t O_XCUR  = 5599232;   // 8,388,608 f32 activation scratch
static constexpr size_t O_PL    = 18182144;  // 58,855,424 plane pools
static constexpr size_t O_AREA  = 77037568;  // 16,777,216 xr-partials / fout / pre / x1
static constexpr size_t O_BPART = O_AREA + 12582912;  // 1MB bn partials (dead window)
// end = 93,814,784
// AREA phases: xrp (16.8MB, between sa_xr and xsub2) -> pre/fout/x1 later. Disjoint.

static constexpr size_t PL_WH    = 0;
static constexpr size_t PL_WL    = 4786176;
static constexpr size_t PL_FM0H  = 9572352;
static constexpr size_t PL_FM0L  = 13766656;
static constexpr size_t PL_FM1H  = 17960960;
static constexpr size_t PL_FM1L  = 22155264;
static constexpr size_t PL_FM2H  = 26349568;
static constexpr size_t PL_FM2L  = 28446720;
static constexpr size_t PL_FM3H  = 30543872;
static constexpr size_t PL_FM3L  = 32641024;
static constexpr size_t PL_FM4H  = 34738176;
static constexpr size_t PL_FM4L  = 35786752;
static constexpr size_t PL_FMP1H = 36835328;
static constexpr size_t PL_FMP1L = 37883904;
static constexpr size_t PL_FMP2H = 38932480;
static constexpr size_t PL_FMP2L = 39456768;
static constexpr size_t PL_QH    = 39981056;
static constexpr size_t PL_QL    = 41029632;
static constexpr size_t PL_VMH   = 42078208;
static constexpr size_t PL_VML   = 46272512;
static constexpr size_t PL_XSH   = 50466816;
static constexpr size_t PL_XSL   = 54661120;
static constexpr size_t PL_X1H = PL_VMH;   // head aliases (phase-disjoint)

__device__ __forceinline__ float bf2f(u16 h) {
  union { unsigned u; float f; } c; c.u = ((unsigned)h) << 16; return c.f;
}
__device__ __forceinline__ u16 f2bf(float f) {
  union { float f; unsigned u; } c; c.f = f;
  return (u16)((c.u + 0x7fffu + ((c.u >> 16) & 1u)) >> 16);
}

// ===========================================================================
// Plane GEMM. BSPLIT=false: B hi-plane only.
// ===========================================================================
template <int TM, int AMODE, int BIASM, int OUTM, bool ACC, bool GIDX, bool BSPLIT = true>
__global__ __launch_bounds__(256) void k_mmp(
    const void* __restrict__ A1, const void* __restrict__ A2,
    const u16* __restrict__ Bh0, const u16* __restrict__ Bl0,
    const float* __restrict__ bias, void* __restrict__ C1, void* __restrict__ C2,
    int M, int N, int K, long sA, long sB, long sC, int ksplit,
    const int* __restrict__ gidx, long sG) {
  constexpr int RT = TM / 32;
  constexpr int CT = TM / 32;
  __shared__ u16 Ah[TM][40], Bh[TM][40];
  __shared__ u16 Bl[BSPLIT ? TM : 1][40];
  __shared__ u16 Al[(AMODE == 2) ? 1 : TM][40];
  const int z = blockIdx.z;
  const int zb = z / ksplit, ks = z - zb * ksplit;
  const int kchunk = K / ksplit;
  const int kl0 = ks * kchunk, kl1 = kl0 + kchunk;
  const int m0 = blockIdx.x * TM, n0 = blockIdx.y * TM;
  const int t = threadIdx.x;
  const int lane = t & 63, w = t >> 6;
  const int wr = (w >> 1) * (TM / 2), wc = (w & 1) * (TM / 2);
  const int frow = lane & 15, koff = (lane >> 4) * 8;
  f32x4_t acc[RT][CT];
#pragma unroll
  for (int i = 0; i < RT; ++i)
#pragma unroll
    for (int j = 0; j < CT; ++j) acc[i][j] = (f32x4_t){0.f, 0.f, 0.f, 0.f};

  const u16* Ahg = (const u16*)A1 + (size_t)zb * sA;
  const u16* Alg = (const u16*)A2 + (size_t)zb * sA;
  const u16* Bhg = Bh0 + (size_t)zb * sB;
  const u16* Blg = Bl0 + (size_t)zb * sB;

  int ar, ac, arow = 0;
  if constexpr (TM == 128) { ar = t >> 1; ac = (t & 1) * 16; }
  else                     { ar = t >> 2; ac = (t & 3) * 8; }
  arow = m0 + ar;
  if constexpr (GIDX) arow = (gidx + (size_t)zb * sG)[arow];
  const int bn = ar, bc = ac;
  const bool bok = (n0 + bn) < N;
  const short8_t z8 = {0, 0, 0, 0, 0, 0, 0, 0};

  for (int k0 = kl0; k0 < kl1; k0 += 32) {
    __syncthreads();
    {
      const u16* s1 = Ahg + (size_t)arow * K + k0 + ac;
      if constexpr (TM == 128) {
        *(short8_t*)&Ah[ar][ac] = *(const short8_t*)s1;
        *(short8_t*)&Ah[ar][ac + 8] = *(const short8_t*)(s1 + 8);
        if constexpr (AMODE == 0) {
          const u16* s2 = Alg + (size_t)arow * K + k0 + ac;
          *(short8_t*)&Al[ar][ac] = *(const short8_t*)s2;
          *(short8_t*)&Al[ar][ac + 8] = *(const short8_t*)(s2 + 8);
        }
      } else {
        *(short8_t*)&Ah[ar][ac] = *(const short8_t*)s1;
        if constexpr (AMODE == 0)
          *(short8_t*)&Al[ar][ac] = *(const short8_t*)(Alg + (size_t)arow * K + k0 + ac);
      }
    }
    {
      const u16* s1 = Bhg + (size_t)(n0 + bn) * K + k0 + bc;
      const u16* s2 = Blg + (size_t)(n0 + bn) * K + k0 + bc;
      if constexpr (TM == 128) {
        *(short8_t*)&Bh[bn][bc] = bok ? *(const short8_t*)s1 : z8;
        *(short8_t*)&Bh[bn][bc + 8] = bok ? *(const short8_t*)(s1 + 8) : z8;
        if constexpr (BSPLIT) {
          *(short8_t*)&Bl[bn][bc] = bok ? *(const short8_t*)s2 : z8;
          *(short8_t*)&Bl[bn][bc + 8] = bok ? *(const short8_t*)(s2 + 8) : z8;
        }
      } else {
        *(short8_t*)&Bh[bn][bc] = bok ? *(const short8_t*)s1 : z8;
        if constexpr (BSPLIT)
          *(short8_t*)&Bl[bn][bc] = bok ? *(const short8_t*)s2 : z8;
      }
    }
    __syncthreads();
    short8_t ah[RT], al[RT], bh[CT], bl[CT];
#pragma unroll
    for (int i = 0; i < RT; ++i) {
      const int r = wr + i * 16 + frow;
      ah[i] = *(const short8_t*)&Ah[r][koff];
      if constexpr (AMODE != 2) al[i] = *(const short8_t*)&Al[r][koff];
    }
#pragma unroll
    for (int i = 0; i < CT; ++i) {
      const int r = wc + i * 16 + frow;
      bh[i] = *(const short8_t*)&Bh[r][koff];
      if constexpr (BSPLIT) bl[i] = *(const short8_t*)&Bl[r][koff];
    }
#pragma unroll
    for (int i = 0; i < RT; ++i)
#pragma unroll
      for (int j = 0; j < CT; ++j) {
        acc[i][j] = __builtin_amdgcn_mfma_f32_16x16x32_bf16(ah[i], bh[j], acc[i][j], 0, 0, 0);
        if constexpr (BSPLIT)
          acc[i][j] = __builtin_amdgcn_mfma_f32_16x16x32_bf16(ah[i], bl[j], acc[i][j], 0, 0, 0);
        if constexpr (AMODE != 2)
          acc[i][j] = __builtin_amdgcn_mfma_f32_16x16x32_bf16(al[i], bh[j], acc[i][j], 0, 0, 0);
      }
  }

  const int crow = (lane >> 4) * 4;
#pragma unroll
  for (int i = 0; i < RT; ++i) {
#pragma unroll
    for (int j = 0; j < CT; ++j) {
      const int gc = n0 + wc + j * 16 + frow;
      if (gc >= N) continue;
      float bv = 0.f;
      if constexpr (BIASM == 1) bv = bias[gc];
      if constexpr (BIASM == 2) bv = bias[(size_t)zb * N + gc];
      const int gr0 = m0 + wr + i * 16 + crow;
      if constexpr (OUTM == 0) {
        float* Cp = (float*)C1 + (size_t)z * sC;
#pragma unroll
        for (int q = 0; q < 4; ++q) {
          float vv = acc[i][j][q] + bv;
          if (ACC) vv += Cp[(size_t)(gr0 + q) * N + gc];
          Cp[(size_t)(gr0 + q) * N + gc] = vv;
        }
      } else if constexpr (OUTM == 1) {
        u16* Ph = (u16*)C1 + (size_t)z * sC;
        u16* Pl = (u16*)C2 + (size_t)z * sC;
#pragma unroll
        for (int q = 0; q < 4; ++q) {
          float vv = acc[i][j][q] + bv;
          u16 h = f2bf(vv);
          Ph[(size_t)(gr0 + q) * N + gc] = h;
          Pl[(size_t)(gr0 + q) * N + gc] = f2bf(vv - bf2f(h));
        }
      } else if constexpr (OUTM == 2) {
        u16* Ph = (u16*)C1 + (size_t)z * sC;
        u16* Pl = (u16*)C2 + (size_t)z * sC;
        short4_t h4, l4;
#pragma unroll
        for (int q = 0; q < 4; ++q) {
          float vv = acc[i][j][q] + bv;
          u16 h = f2bf(vv);
          h4[q] = (short)h;
          l4[q] = (short)f2bf(vv - bf2f(h));
        }
        *(short4_t*)(Ph + (size_t)gc * M + gr0) = h4;
        *(short4_t*)(Pl + (size_t)gc * M + gr0) = l4;
      } else {
        u16* Cb = (u16*)C1 + (size_t)z * sC;
#pragma unroll
        for (int q = 0; q < 4; ++q) {
          float vv = fmaxf(acc[i][j][q] + bv, 0.f);
          Cb[(size_t)(gr0 + q) * N + gc] = f2bf(vv);
        }
      }
    }
  }
}

template <int TM, int AMODE, int BIASM, int OUTM, bool ACC, bool GIDX, bool BSPLIT = true>
static void mmp(hipStream_t st, const void* A1, const void* A2,
                const u16* Bh, const u16* Bl, const float* bias,
                void* C1, void* C2, int M, int N, int K,
                long sA, long sB, long sC, int Z, int ksplit,
                const int* gidx = nullptr, long sG = 0) {
  dim3 grid(M / TM, (N + TM - 1) / TM, Z * ksplit);
  k_mmp<TM, AMODE, BIASM, OUTM, ACC, GIDX, BSPLIT><<<grid, 256, 0, st>>>(
      A1, A2, Bh, Bl, bias, C1, C2, M, N, K, sA, sB, sC, ksplit, gidx, sG);
}

// ===========================================================================
// Fused attention, 64-row m-tiles, NSPLIT n-range partitioning.
// ===========================================================================
template <int QD>
__global__ __launch_bounds__(256) void k_sa_stats(
    const u16* __restrict__ qh, const u16* __restrict__ ql, int N,
    float* __restrict__ mx, float* __restrict__ inv) {
  __shared__ float mr[2][64], sr[2][64];
  const int b = blockIdx.y;
  const int m0 = blockIdx.x * 64;
  const int t = threadIdx.x, lane = t & 63, w = t >> 6;
  const int wm = (w >> 1) * 32, wn = (w & 1) * 64;
  const int frow = lane & 15, kq = (lane >> 4) * 8;
  const u16* qhb = qh + (size_t)b * N * QD;
  const u16* qlb = ql + (size_t)b * N * QD;
  constexpr int KS = QD / 32;
  short8_t ahq[KS][2], alq[KS][2];
#pragma unroll
  for (int ks = 0; ks < KS; ++ks)
#pragma unroll
    for (int i = 0; i < 2; ++i) {
      const size_t r = (size_t)(m0 + wm + i * 16 + frow) * QD + ks * 32 + kq;
      ahq[ks][i] = *(const short8_t*)(qhb + r);
      alq[ks][i] = *(const short8_t*)(qlb + r);
    }
  float M[2][4], S[2][4];
#pragma unroll
  for (int i = 0; i < 2; ++i)
#pragma unroll
    for (int q = 0; q < 4; ++q) { M[i][q] = -FLT_MAX; S[i][q] = 0.f; }

  for (int n0 = 0; n0 < N; n0 += 128) {
    f32x4_t acc[2][4];
#pragma unroll
    for (int i = 0; i < 2; ++i)
#pragma unroll
      for (int j = 0; j < 4; ++j) acc[i][j] = (f32x4_t){0.f, 0.f, 0.f, 0.f};
#pragma unroll
    for (int ks = 0; ks < KS; ++ks) {
      short8_t b_h[4], b_l[4];
#pragma unroll
      for (int j = 0; j < 4; ++j) {
        const size_t r = (size_t)(n0 + wn + j * 16 + frow) * QD + ks * 32 + kq;
        b_h[j] = *(const short8_t*)(qhb + r);
        b_l[j] = *(const short8_t*)(qlb + r);
      }
#pragma unroll
      for (int i = 0; i < 2; ++i)
#pragma unroll
        for (int j = 0; j < 4; ++j) {
          acc[i][j] = __builtin_amdgcn_mfma_f32_16x16x32_bf16(ahq[ks][i], b_h[j], acc[i][j], 0, 0, 0);
          acc[i][j] = __builtin_amdgcn_mfma_f32_16x16x32_bf16(ahq[ks][i], b_l[j], acc[i][j], 0, 0, 0);
          acc[i][j] = __builtin_amdgcn_mfma_f32_16x16x32_bf16(alq[ks][i], b_h[j], acc[i][j], 0, 0, 0);
        }
    }
#pragma unroll
    for (int i = 0; i < 2; ++i)
#pragma unroll
      for (int q = 0; q < 4; ++q) {
        float tm = acc[i][0][q];
#pragma unroll
        for (int j = 1; j < 4; ++j) tm = fmaxf(tm, acc[i][j][q]);
#pragma unroll
        for (int off = 1; off < 16; off <<= 1) tm = fmaxf(tm, __shfl_xor(tm, off));
        const float Mn = fmaxf(M[i][q], tm);
        float ps = 0.f;
#pragma unroll
        for (int j = 0; j < 4; ++j) ps += __expf(acc[i][j][q] - Mn);
#pragma unroll
        for (int off = 1; off < 16; off <<= 1) ps += __shfl_xor(ps, off);
        S[i][q] = S[i][q] * __expf(M[i][q] - Mn) + ps;
        M[i][q] = Mn;
      }
  }
  if (frow == 0) {
#pragma unroll
    for (int i = 0; i < 2; ++i)
#pragma unroll
      for (int q = 0; q < 4; ++q) {
        const int ml = wm + i * 16 + (lane >> 4) * 4 + q;
        mr[w & 1][ml] = M[i][q];
        sr[w & 1][ml] = S[i][q];
      }
  }
  __syncthreads();
  if (t < 64) {
    const float M0 = mr[0][t], M1 = mr[1][t];
    const float Mm = fmaxf(M0, M1);
    const float Sm = sr[0][t] * __expf(M0 - Mm) + sr[1][t] * __expf(M1 - Mm);
    mx[(size_t)b * N + m0 + t] = Mm;
    inv[(size_t)b * N + m0 + t] = 1.f / Sm;
  }
}

// NSPLIT==1: fused xsub epilogue. NSPLIT>1: write raw xacc+csum partials.
template <int QD, int NSPLIT>
__global__ __launch_bounds__(256) void k_sa_xr(
    const u16* __restrict__ qh, const u16* __restrict__ ql,
    const u16* __restrict__ vmh, const u16* __restrict__ vml,
    const float* __restrict__ mx, const float* __restrict__ inv,
    const float* __restrict__ xcur, u16* __restrict__ xsh, u16* __restrict__ xsl,
    float* __restrict__ xrp, float* __restrict__ csump,
    int N, int C) {
  __shared__ __align__(16) u16 Ph[64][132];
  __shared__ __align__(16) u16 Vh[128][68], Vl[128][68];
  const int b = blockIdx.z / NSPLIT, sidx = blockIdx.z % NSPLIT;
  const int m0 = blockIdx.x * 64, c0 = blockIdx.y * 128;
  const int t = threadIdx.x, lane = t & 63, w = t >> 6;
  const int wm = (w >> 1) * 32, wn = (w & 1) * 64;
  const int frow = lane & 15, kq = (lane >> 4) * 8;
  const u16* qhb = qh + (size_t)b * N * QD;
  const u16* qlb = ql + (size_t)b * N * QD;
  const u16* vhb = vmh + (size_t)b * (size_t)N * C;  // [C][N]
  const u16* vlb = vml + (size_t)b * (size_t)N * C;
  const float* mxb = mx + (size_t)b * N;
  const float* invb = inv + (size_t)b * N;
  constexpr int KS = QD / 32;
  const int vr = t >> 1, vco = (t & 1) * 32;
  short8_t ahq[KS][2], alq[KS][2];
#pragma unroll
  for (int ks = 0; ks < KS; ++ks)
#pragma unroll
    for (int i = 0; i < 2; ++i) {
      const size_t r = (size_t)(m0 + wm + i * 16 + frow) * QD + ks * 32 + kq;
      ahq[ks][i] = *(const short8_t*)(qhb + r);
      alq[ks][i] = *(const short8_t*)(qlb + r);
    }
  f32x4_t xacc[2][4];
  float csum[2][4];
#pragma unroll
  for (int i = 0; i < 2; ++i)
#pragma unroll
    for (int j = 0; j < 4; ++j) { xacc[i][j] = (f32x4_t){0.f, 0.f, 0.f, 0.f}; csum[i][j] = 0.f; }

  const int nlo = sidx * (N / NSPLIT), nhi = nlo + N / NSPLIT;
  for (int n0 = nlo; n0 < nhi; n0 += 128) {
    __syncthreads();
    // stage V half 0
    {
      const u16* s1 = vhb + (size_t)(c0 + vr) * N + n0 + vco;
      const u16* s2 = vlb + (size_t)(c0 + vr) * N + n0 + vco;
#pragma unroll
      for (int u = 0; u < 4; ++u) {
        *(short8_t*)&Vh[vr][vco + u * 8] = *(const short8_t*)(s1 + u * 8);
        *(short8_t*)&Vl[vr][vco + u * 8] = *(const short8_t*)(s2 + u * 8);
      }
    }
    // S tile (in-register)
    f32x4_t acc[2][4];
#pragma unroll
    for (int i = 0; i < 2; ++i)
#pragma unroll
      for (int j = 0; j < 4; ++j) acc[i][j] = (f32x4_t){0.f, 0.f, 0.f, 0.f};
#pragma unroll
    for (int ks = 0; ks < KS; ++ks) {
      short8_t b_h[4], b_l[4];
#pragma unroll
      for (int j = 0; j < 4; ++j) {
        const size_t r = (size_t)(n0 + wn + j * 16 + frow) * QD + ks * 32 + kq;
        b_h[j] = *(const short8_t*)(qhb + r);
        b_l[j] = *(const short8_t*)(qlb + r);
      }
#pragma unroll
      for (int i = 0; i < 2; ++i)
#pragma unroll
        for (int j = 0; j < 4; ++j) {
          acc[i][j] = __builtin_amdgcn_mfma_f32_16x16x32_bf16(ahq[ks][i], b_h[j], acc[i][j], 0, 0, 0);
          acc[i][j] = __builtin_amdgcn_mfma_f32_16x16x32_bf16(ahq[ks][i], b_l[j], acc[i][j], 0, 0, 0);
          acc[i][j] = __builtin_amdgcn_mfma_f32_16x16x32_bf16(alq[ks][i], b_h[j], acc[i][j], 0, 0, 0);
        }
    }
    // transform -> P (hi-only); csum accumulate
    float mxj[4], ivj[4];
#pragma unroll
    for (int j = 0; j < 4; ++j) {
      const int n = n0 + wn + j * 16 + frow;
      mxj[j] = mxb[n];
      ivj[j] = invb[n];
    }
    const int mbase = wm + (lane >> 4) * 4;
#pragma unroll
    for (int i = 0; i < 2; ++i)
#pragma unroll
      for (int j = 0; j < 4; ++j)
#pragma unroll
        for (int q = 0; q < 4; ++q) {
          const float pv = __expf(acc[i][j][q] - mxj[j]) * ivj[j];
          csum[i][q] += pv;
          Ph[mbase + i * 16 + q][wn + j * 16 + frow] = f2bf(pv);
        }
    __syncthreads();
#pragma unroll
    for (int ks2 = 0; ks2 < 2; ++ks2) {
      short8_t p_h[2], v_h[4], v_l[4];
#pragma unroll
      for (int i = 0; i < 2; ++i)
        p_h[i] = *(const short8_t*)&Ph[wm + i * 16 + frow][ks2 * 32 + kq];
#pragma unroll
      for (int j = 0; j < 4; ++j) {
        v_h[j] = *(const short8_t*)&Vh[wn + j * 16 + frow][ks2 * 32 + kq];
        v_l[j] = *(const short8_t*)&Vl[wn + j * 16 + frow][ks2 * 32 + kq];
      }
#pragma unroll
      for (int i = 0; i < 2; ++i)
#pragma unroll
        for (int j = 0; j < 4; ++j) {
          xacc[i][j] = __builtin_amdgcn_mfma_f32_16x16x32_bf16(p_h[i], v_h[j], xacc[i][j], 0, 0, 0);
          xacc[i][j] = __builtin_amdgcn_mfma_f32_16x16x32_bf16(p_h[i], v_l[j], xacc[i][j], 0, 0, 0);
        }
    }
    __syncthreads();
    // stage V half 1
    {
      const u16* s1 = vhb + (size_t)(c0 + vr) * N + n0 + 64 + vco;
      const u16* s2 = vlb + (size_t)(c0 + vr) * N + n0 + 64 + vco;
#pragma unroll
      for (int u = 0; u < 4; ++u) {
        *(short8_t*)&Vh[vr][vco + u * 8] = *(const short8_t*)(s1 + u * 8);
        *(short8_t*)&Vl[vr][vco + u * 8] = *(const short8_t*)(s2 + u * 8);
      }
    }
    __syncthreads();
#pragma unroll
    for (int ks2 = 0; ks2 < 2; ++ks2) {
      short8_t p_h[2], v_h[4], v_l[4];
#pragma unroll
      for (int i = 0; i < 2; ++i)
        p_h[i] = *(const short8_t*)&Ph[wm + i * 16 + frow][64 + ks2 * 32 + kq];
#pragma unroll
      for (int j = 0; j < 4; ++j) {
        v_h[j] = *(const short8_t*)&Vh[wn + j * 16 + frow][ks2 * 32 + kq];
        v_l[j] = *(const short8_t*)&Vl[wn + j * 16 + frow][ks2 * 32 + kq];
      }
#pragma unroll
      for (int i = 0; i < 2; ++i)
#pragma unroll
        for (int j = 0; j < 4; ++j) {
          xacc[i][j] = __builtin_amdgcn_mfma_f32_16x16x32_bf16(p_h[i], v_h[j], xacc[i][j], 0, 0, 0);
          xacc[i][j] = __builtin_amdgcn_mfma_f32_16x16x32_bf16(p_h[i], v_l[j], xacc[i][j], 0, 0, 0);
        }
    }
  }
  // csum reduce across frow + wave halves
#pragma unroll
  for (int i = 0; i < 2; ++i)
#pragma unroll
    for (int q = 0; q < 4; ++q)
#pragma unroll
      for (int off = 1; off < 16; off <<= 1) csum[i][q] += __shfl_xor(csum[i][q], off);
  __syncthreads();
  float* csb = (float*)&Ph[0][0];
  if (frow == 0) {
#pragma unroll
    for (int i = 0; i < 2; ++i)
#pragma unroll
      for (int q = 0; q < 4; ++q)
        csb[(w & 1) * 64 + wm + i * 16 + (lane >> 4) * 4 + q] = csum[i][q];
  }
  __syncthreads();
  if (t < 64) csb[128 + t] = csb[t] + csb[64 + t];
  __syncthreads();
  if constexpr (NSPLIT > 1) {
    if (t < 64 && blockIdx.y == 0)
      csump[((size_t)sidx * BB + b) * N + m0 + t] = csb[128 + t];
    float* xp = xrp + (size_t)sidx * BB * N * C;
#pragma unroll
    for (int i = 0; i < 2; ++i)
#pragma unroll
      for (int q = 0; q < 4; ++q) {
        const int mloc = wm + i * 16 + (lane >> 4) * 4 + q;
        const size_t rowoff = ((size_t)b * N + m0 + mloc) * C;
#pragma unroll
        for (int j = 0; j < 4; ++j)
          xp[rowoff + c0 + wn + j * 16 + frow] = xacc[i][j][q];
      }
  } else {
#pragma unroll
    for (int i = 0; i < 2; ++i) {
#pragma unroll
      for (int q = 0; q < 4; ++q) {
        const int mloc = wm + i * 16 + (lane >> 4) * 4 + q;
        const float cstot = csb[128 + mloc];
        const size_t rowoff = ((size_t)b * N + m0 + mloc) * C;
#pragma unroll
        for (int j = 0; j < 4; ++j) {
          const int gc = c0 + wn + j * 16 + frow;
          const float val = xcur[rowoff + gc] - xacc[i][j][q] / (1e-9f + cstot);
          const u16 h = f2bf(val);
          xsh[rowoff + gc] = h;
          xsl[rowoff + gc] = f2bf(val - bf2f(h));
        }
      }
    }
  }
}

// combine NSPLIT partials: xs = xcur - (sum xr)/(1e-9 + sum csum) -> planes
template <int NS>
__global__ void k_xsub2(const float* __restrict__ xrp, const float* __restrict__ csump,
                        const float* __restrict__ xcur, u16* __restrict__ xsh,
                        u16* __restrict__ xsl, int N, int C) {
  const size_t total = (size_t)BB * N * C;
  size_t i = (size_t)blockIdx.x * 256 + threadIdx.x;
  if (i >= total) return;
  const size_t row = i / C;
  float s = 0.f, cs = 0.f;
#pragma unroll
  for (int k = 0; k < NS; ++k) {
    s += xrp[(size_t)k * total + i];
    cs += csump[(size_t)k * BB * N + row];
  }
  const float val = xcur[i] - s / (1e-9f + cs);
  const u16 h = f2bf(val);
  xsh[i] = h;
  xsl[i] = f2bf(val - bf2f(h));
}

// ===========================================================================
// weight split + activation split
// ===========================================================================
struct SplitJob { const float* s; u16* dh; u16* dl; int n, K, N, trans; };
struct SplitJobs { SplitJob j[26]; };
__global__ void k_splitjobs(SplitJobs jobs) {
  SplitJob jb = jobs.j[blockIdx.y];
  for (int i = blockIdx.x * 256 + threadIdx.x; i < jb.n; i += gridDim.x * 256) {
    float v;
    if (jb.trans) { int k = i % jb.K, n = i / jb.K; v = jb.s[(size_t)k * jb.N + n]; }
    else v = jb.s[i];
    u16 h = f2bf(v);
    jb.dh[i] = h;
    jb.dl[i] = f2bf(v - bf2f(h));
  }
}

template <bool RELU, bool LO>
__global__ void k_split4(const float* __restrict__ x, u16* __restrict__ ph,
                         u16* __restrict__ pl, int n4) {
  int i = blockIdx.x * 256 + threadIdx.x;
  if (i >= n4) return;
  float4 v = ((const float4*)x)[i];
  short4_t h4, l4;
  float vv[4] = {v.x, v.y, v.z, v.w};
#pragma unroll
  for (int q = 0; q < 4; ++q) {
    float f = RELU ? fmaxf(vv[q], 0.f) : vv[q];
    u16 h = f2bf(f);
    h4[q] = (short)h;
    if (LO) l4[q] = (short)f2bf(f - bf2f(h));
  }
  *(short4_t*)(ph + (size_t)i * 4) = h4;
  if (LO) *(short4_t*)(pl + (size_t)i * 4) = l4;
}

// ===========================================================================
// KNN. Radix-select (2-bit-pair descent) + early tie break.
// ===========================================================================
template <int NCAND, int KSEL>
__global__ __launch_bounds__(256) void k_knn_radix(const float* __restrict__ pts, int Nq,
                                                   int* __restrict__ outIdx) {
  __shared__ float sp[NCAND * 3];
  const int b = blockIdx.y;
  const float* pb = pts + (size_t)b * VS0;
  for (int i = threadIdx.x; i < NCAND * 3; i += 256) sp[i] = pb[i];
  __syncthreads();
  const int wave = threadIdx.x >> 6, lane = threadIdx.x & 63;
  const int qi = blockIdx.x * 4 + wave;
  const float qx = sp[qi * 3], qy = sp[qi * 3 + 1], qz = sp[qi * 3 + 2];
  constexpr int CH = NCAND / 64;
  unsigned d[CH];
  unsigned x[32];
#pragma unroll
  for (int j = 0; j < 32; ++j) x[j] = 0u;
#pragma unroll
  for (int j = 0; j < CH; ++j) {
    const int m = lane + j * 64;
    const float dx = sp[m * 3] - qx, dy = sp[m * 3 + 1] - qy, dz = sp[m * 3 + 2] - qz;
    const float dd = dx * dx + dy * dy + dz * dz;
    d[j] = __float_as_uint((m == qi) ? FLT_MAX : dd);
    x[j] = d[j];
  }
#pragma unroll
  for (int st = 0; st < 5; ++st) {
    const int s = 16 >> st;
    const unsigned ml = (s == 16) ? 0x0000FFFFu : (s == 8) ? 0x00FF00FFu
                      : (s == 4) ? 0x0F0F0F0Fu : (s == 2) ? 0x33333333u : 0x55555555u;
#pragma unroll
    for (int i = 0; i < 32; ++i) {
      if (i & s) continue;
      unsigned t = ((x[i] >> s) ^ x[i + s]) & ml;
      x[i + s] ^= t;
      x[i] ^= (t << s);
    }
  }
  unsigned active = (CH == 32) ? 0xFFFFFFFFu : ((1u << CH) - 1u);
  unsigned T = 0u;
  int kk = KSEL;
#pragma unroll
  for (int bb = 30; bb >= 2; bb -= 2) {
    const unsigned mh = x[bb], mlo = x[bb - 1];
    const unsigned a00 = active & ~mh & ~mlo;
    const unsigned a01 = active & ~mh & mlo;
    const unsigned a10 = active & mh & ~mlo;
    unsigned pA = (unsigned)__popc(a00) | ((unsigned)__popc(a01) << 16);
    unsigned pB = (unsigned)__popc(a10);
#pragma unroll
    for (int off = 32; off; off >>= 1) {
      pA += __shfl_xor(pA, off);
      pB += __shfl_xor(pB, off);
    }
    const int C00 = (int)(pA & 0xFFFFu), C01 = (int)(pA >> 16), C10 = (int)pB;
    if (kk <= C00) {
      active = a00;
    } else if (kk <= C00 + C01) {
      kk -= C00; active = a01; T |= 1u << (bb - 1);
    } else if (kk <= C00 + C01 + C10) {
      kk -= C00 + C01; active = a10; T |= 1u << bb;
    } else {
      kk -= C00 + C01 + C10; active = active & mh & mlo; T |= 3u << (bb - 1);
    }
  }
  {
    const unsigned zn = active & ~x[0];
    int c0 = __popc(zn);
#pragma unroll
    for (int off = 32; off; off >>= 1) c0 += __shfl_xor(c0, off);
    if (kk <= c0) active = zn;
    else { active &= x[0]; T |= 1u; }
  }
  int* orow = outIdx + ((size_t)b * Nq + qi) * KSEL;
  const unsigned long long ltmask = (1ull << lane) - 1ull;
  int base = 0;
#pragma unroll
  for (int j = 0; j < CH; ++j) {
    const bool sel = d[j] < T;
    const unsigned long long bal = __ballot(sel);
    const int pos = base + (int)__popcll(bal & ltmask);
    if (sel) orow[pos] = lane + j * 64;
    base += (int)__popcll(bal);
  }
  for (int j = 0; j < CH; ++j) {
    if (base >= KSEL) break;   // uniform (base is wave-uniform)
    const bool sel = ((active >> j) & 1u) != 0u;
    const unsigned long long bal = __ballot(sel);
    const int pos = base + (int)__popcll(bal & ltmask);
    if (sel && pos < KSEL) orow[pos] = lane + j * 64;
    base += (int)__popcll(bal);
  }
}

template <int NCAND, int KSEL>
__global__ __launch_bounds__(256) void k_knn2(const float* __restrict__ pts, int Nq,
                                              int* __restrict__ outIdx) {
  __shared__ float sp[NCAND * 3];
  const int b = blockIdx.y;
  const float* pb = pts + (size_t)b * VS0;
  for (int i = threadIdx.x; i < NCAND * 3; i += 256) sp[i] = pb[i];
  __syncthreads();
  const int wave = threadIdx.x >> 6, lane = threadIdx.x & 63;
  const int qi = blockIdx.x * 4 + wave;
  const float qx = sp[qi * 3], qy = sp[qi * 3 + 1], qz = sp[qi * 3 + 2];
  constexpr int CH = NCAND / 64;
  float d[CH];
#pragma unroll
  for (int j = 0; j < CH; ++j) {
    const int m = lane + j * 64;
    const float dx = sp[m * 3] - qx, dy = sp[m * 3 + 1] - qy, dz = sp[m * 3 + 2] - qz;
    const float dd = dx * dx + dy * dy + dz * dz;
    d[j] = (m == qi) ? FLT_MAX : dd;
  }
  int* orow = outIdx + ((size_t)b * Nq + qi) * KSEL;
#pragma unroll 1
  for (int s = 0; s < KSEL; ++s) {
    float bd = FLT_MAX; int bj = 0;
#pragma unroll
    for (int j = 0; j < CH; ++j) {
      const bool better = d[j] < bd;
      bd = better ? d[j] : bd;
      bj = better ? j : bj;
    }
    int bm = lane + bj * 64;
#pragma unroll
    for (int off = 32; off; off >>= 1) {
      const float od = __shfl_xor(bd, off);
      const int om = __shfl_xor(bm, off);
      if (od < bd || (od == bd && om < bm)) { bd = od; bm = om; }
    }
    if (lane == 0) orow[s] = bm;
#pragma unroll
    for (int j = 0; j < CH; ++j)
      if (bm == lane + j * 64) d[j] = FLT_MAX;
  }
}

__global__ void k_transpose(const float* __restrict__ in, float* __restrict__ out) {
  int i = blockIdx.x * 256 + threadIdx.x;
  if (i >= BB * NP0 * 3) return;
  int dd = i % 3, tt = (i / 3) % NP0, b = i / (3 * NP0);
  out[i] = in[((size_t)b * 3 + dd) * NP0 + tt];
}

__global__ void k_conv_surface(const float* __restrict__ v, const int* __restrict__ idx,
                               const float* __restrict__ dirs, float* __restrict__ out,
                               int N, int M) {
  __shared__ float su[KNB_ * 3];
  int b = blockIdx.y, n = blockIdx.x, c = threadIdx.x;
  const float* vb = v + (size_t)b * VS0;
  float cx = vb[n * 3], cy = vb[n * 3 + 1], cz = vb[n * 3 + 2];
  const int* irow = idx + ((size_t)b * N + n) * KNB_;
  if (c < KNB_) {
    int j = irow[c];
    float dx = vb[j * 3] - cx, dy = vb[j * 3 + 1] - cy, dz = vb[j * 3 + 2] - cz;
    float inv = 1.f / fmaxf(sqrtf(dx * dx + dy * dy + dz * dz), 1e-12f);
    su[c * 3] = dx * inv; su[c * 3 + 1] = dy * inv; su[c * 3 + 2] = dz * inv;
  }
  __syncthreads();
  float d0 = dirs[c], d1 = dirs[M + c], d2 = dirs[2 * M + c];
  float inv = 1.f / fmaxf(sqrtf(d0 * d0 + d1 * d1 + d2 * d2), 1e-12f);
  d0 *= inv; d1 *= inv; d2 *= inv;
  float acc = 0.f;
  for (int k = 0; k < KNB_; ++k) {
    float th = fmaxf(su[k * 3] * d0 + su[k * 3 + 1] * d1 + su[k * 3 + 2] * d2, 0.f);
    acc = fmaxf(acc, th);
  }
  out[((size_t)b * N + n) * M + c] = acc;
}

__global__ void k_conv_layer(const float* __restrict__ v, const int* __restrict__ idx,
                             const float* __restrict__ dirs, const float* __restrict__ fout,
                             float* __restrict__ out, int N, int C) {
  __shared__ float su[KNB_ * 3];
  __shared__ int sidx[KNB_];
  int b = blockIdx.y, n = blockIdx.x, c = threadIdx.x;
  const float* vb = v + (size_t)b * VS0;
  float cx = vb[n * 3], cy = vb[n * 3 + 1], cz = vb[n * 3 + 2];
  const int* irow = idx + ((size_t)b * N + n) * KNB_;
  if (c < KNB_) {
    int j = irow[c]; sidx[c] = j;
    float dx = vb[j * 3] - cx, dy = vb[j * 3 + 1] - cy, dz = vb[j * 3 + 2] - cz;
    float inv = 1.f / fmaxf(sqrtf(dx * dx + dy * dy + dz * dz), 1e-12f);
    su[c * 3] = dx * inv; su[c * 3 + 1] = dy * inv; su[c * 3 + 2] = dz * inv;
  }
  __syncthreads();
  float d0 = dirs[c], d1 = dirs[C + c], d2 = dirs[2 * C + c];
  float inv = 1.f / fmaxf(sqrtf(d0 * d0 + d1 * d1 + d2 * d2), 1e-12f);
  d0 *= inv; d1 *= inv; d2 *= inv;
  const float* fb = fout + (size_t)b * N * 2 * C;
  float acc = -FLT_MAX;
  for (int k = 0; k < KNB_; ++k) {
    float th = fmaxf(su[k * 3] * d0 + su[k * 3 + 1] * d1 + su[k * 3 + 2] * d2, 0.f);
    float fs = fb[(size_t)sidx[k] * 2 * C + C + c];
    acc = fmaxf(acc, th * fs);
  }
  out[((size_t)b * N + n) * C + c] = fb[(size_t)n * 2 * C + c] + acc;
}

// ===========================================================================
// BN (256-block partials; parallel fin) / pool / misc
// ===========================================================================
__global__ void k_bn_part(const float* __restrict__ x, int rows, int C, float* __restrict__ part) {
  const int blk = blockIdx.x;               // 256 blocks
  const int chunk = rows / 256;
  const int r0 = blk * chunk;
  const int c0 = threadIdx.x, c1 = threadIdx.x + 256;
  float s0 = 0, s20 = 0, s1 = 0, s21 = 0;
  for (int r = 0; r < chunk; ++r) {
    const float* row = x + (size_t)(r0 + r) * C;
    if (c0 < C) { float v = row[c0]; s0 += v; s20 += v * v; }
    if (c1 < C) { float v = row[c1]; s1 += v; s21 += v * v; }
  }
  float* p = part + (size_t)blk * 1024;
  if (c0 < C) { p[c0] = s0; p[512 + c0] = s20; }
  if (c1 < C) { p[c1] = s1; p[512 + c1] = s21; }
}

__global__ void k_bn_fin(const float* __restrict__ part, int rows, int C, float* __restrict__ stats) {
  __shared__ float sm0[8][32], sm1[8][32];
  const int cl = threadIdx.x & 31, ch = threadIdx.x >> 5;   // 8 chunks of 32 partial-blocks
  const int c = blockIdx.x * 32 + cl;
  float s = 0, s2 = 0;
  if (c < C) {
    for (int b2 = ch * 32; b2 < ch * 32 + 32; ++b2) {
      s += part[b2 * 1024 + c];
      s2 += part[b2 * 1024 + 512 + c];
    }
  }
  sm0[ch][cl] = s; sm1[ch][cl] = s2;
  __syncthreads();
  if (ch == 0 && c < C) {
    float S = 0, S2 = 0;
#pragma unroll
    for (int k = 0; k < 8; ++k) { S += sm0[k][cl]; S2 += sm1[k][cl]; }
    float m = S / rows;
    float var = S2 / rows - m * m;
    stats[c] = m;
    stats[C + c] = rsqrtf(var + 1e-5f);
  }
}

template <bool ADD>
__global__ void k_bn_apply(const float* __restrict__ x, const float* __restrict__ stats,
                           const float* __restrict__ g, const float* __restrict__ bb,
                           const float* __restrict__ base, float* __restrict__ outf,
                           u16* __restrict__ ph, u16* __restrict__ pl, int total, int C) {
  int i = blockIdx.x * 256 + threadIdx.x;
  if (i >= total) return;
  int c = i % C;
  float v = (x[i] - stats[c]) * stats[C + c] * g[c] + bb[c];
  v = fmaxf(v, 0.f);
  float r = ADD ? base[i] + v : v;
  outf[i] = r;
  u16 h = f2bf(r);
  ph[i] = h;
  pl[i] = f2bf(r - bf2f(h));
}

__global__ void k_pool(const u16* __restrict__ fh, const u16* __restrict__ fl,
                       const int* __restrict__ idxp, u16* __restrict__ oh,
                       u16* __restrict__ ol, int Nin, int pn, int C) {
  int b = blockIdx.y, p = blockIdx.x, c = threadIdx.x;
  const int* ir = idxp + ((size_t)b * pn + p) * 4;
  const u16* fhb = fh + (size_t)b * Nin * C;
  const u16* flb = fl + (size_t)b * Nin * C;
  float acc = -FLT_MAX;
#pragma unroll
  for (int k = 0; k < 4; ++k) {
    size_t o = (size_t)ir[k] * C + c;
    acc = fmaxf(acc, bf2f(fhb[o]) + bf2f(flb[o]));
  }
  u16 h = f2bf(acc);
  oh[((size_t)b * pn + p) * C + c] = h;
  ol[((size_t)b * pn + p) * C + c] = f2bf(acc - bf2f(h));
}

__global__ void k_maxn(const u16* __restrict__ fh, const u16* __restrict__ fl,
                       float* __restrict__ out, int N, int C) {
  int b = blockIdx.y;
  int c = blockIdx.x * 256 + threadIdx.x;
  if (c >= C) return;
  float acc = -FLT_MAX;
  for (int n = 0; n < N; ++n) {
    size_t o = ((size_t)b * N + n) * C + c;
    acc = fmaxf(acc, bf2f(fh[o]) + bf2f(fl[o]));
  }
  out[(size_t)b * C + c] = acc;
}

__global__ void k_nearest(const float* __restrict__ v, int Ns, int* __restrict__ out) {
  extern __shared__ float sp[];
  int b = blockIdx.y;
  const float* vsb = v + (size_t)b * VS0;
  for (int i = threadIdx.x; i < Ns * 3; i += 256) sp[i] = vsb[i];
  __syncthreads();
  int t = blockIdx.x * 256 + threadIdx.x;
  float tx = vsb[t * 3], ty = vsb[t * 3 + 1], tz = vsb[t * 3 + 2];
  float bd = FLT_MAX; int bi = 0;
#pragma unroll 4
  for (int s = 0; s < Ns; ++s) {
    float dx = sp[s * 3] - tx, dy = sp[s * 3 + 1] - ty, dz = sp[s * 3 + 2] - tz;
    float dd = dx * dx + dy * dy + dz * dz;
    if (dd < bd) { bd = dd; bi = s; }
  }
  out[(size_t)b * NP0 + t] = bi;
}

__global__ void k_glob1(const float* __restrict__ fglob, const float* __restrict__ onehot,
                        const float* __restrict__ h1w, const float* __restrict__ h1b,
                        float* __restrict__ out) {
  int b = blockIdx.x, j = threadIdx.x;
  float s = h1b[j];
  for (int i = 0; i < 512; ++i) s = fmaf(fglob[b * 512 + i], h1w[(size_t)(1280 + i) * 512 + j], s);
  for (int i = 0; i < 16; ++i) s = fmaf(onehot[b * 16 + i], h1w[(size_t)(1792 + i) * 512 + j], s);
  out[b * 512 + j] = s;
}

__global__ void k_logsoftmax(float* __restrict__ x, int rows, int C) {
  int r = blockIdx.x * 4 + (threadIdx.x >> 6);
  int lane = threadIdx.x & 63;
  if (r >= rows) return;
  float* xr = x + (size_t)r * C;
  float v = (lane < C) ? xr[lane] : -FLT_MAX;
  float mx = v;
  for (int o = 32; o; o >>= 1) mx = fmaxf(mx, __shfl_xor(mx, o));
  float e = (lane < C) ? __expf(v - mx) : 0.f;
  float s = e;
  for (int o = 32; o; o >>= 1) s += __shfl_xor(s, o);
  float lse = mx + logf(s);
  if (lane < C) xr[lane] = v - lse;
}

// ===========================================================================
// host
// ===========================================================================
struct Ws {
  float *v0, *fglob, *glob1, *mx, *inv, *csump, *stats, *bpart, *xcur, *pre, *fout, *x1, *xrp;
  int *idx0, *idxp0, *idx1, *idxp1, *idx2, *ni1, *ni2;
  u16 *wh, *wl;
  u16 *fm0h, *fm0l, *fm1h, *fm1l, *fm2h, *fm2l, *fm3h, *fm3l, *fm4h, *fm4l;
  u16 *fmp1h, *fmp1l, *fmp2h, *fmp2l, *qh, *ql, *vmh, *vml, *xsh, *xsl;
  u16 *x1h, *x2b;
};

static void run_sa(hipStream_t st, Ws& ws, int N, int C, int Q,
                   const u16* qkh, const u16* qkl, const u16* vwh, const u16* vwl,
                   const u16* twh, const u16* twl,
                   const float* vb, const float* tb, const float* g, const float* be,
                   u16* xh, u16* xl) {
  const long sx = (long)N * C;
  mmp<64, 0, 0, 1, false, false>(st, xh, xl, qkh, qkl, nullptr, ws.qh, ws.ql,
                                 N, Q, C, sx, 0, (long)N * Q, BB, 1);
  mmp<64, 0, 1, 2, false, false>(st, xh, xl, vwh, vwl, vb, ws.vmh, ws.vml,
                                 N, C, C, sx, 0, sx, BB, 1);
  dim3 gs(N / 64, BB);
  if (Q == 32) {        // N=2048, C=128: NSPLIT=2
    k_sa_stats<32><<<gs, 256, 0, st>>>(ws.qh, ws.ql, N, ws.mx, ws.inv);
    dim3 gx(N / 64, C / 128, BB * 2);
    k_sa_xr<32, 2><<<gx, 256, 0, st>>>(ws.qh, ws.ql, ws.vmh, ws.vml, ws.mx, ws.inv,
                                       nullptr, nullptr, nullptr, ws.xrp, ws.csump, N, C);
    k_xsub2<2><<<((size_t)BB * N * C + 255) / 256, 256, 0, st>>>(
        ws.xrp, ws.csump, ws.xcur, ws.xsh, ws.xsl, N, C);
  } else if (Q == 64) { // N=512, C=256: NSPLIT=2
    k_sa_stats<64><<<gs, 256, 0, st>>>(ws.qh, ws.ql, N, ws.mx, ws.inv);
    dim3 gx(N / 64, C / 128, BB * 2);
    k_sa_xr<64, 2><<<gx, 256, 0, st>>>(ws.qh, ws.ql, ws.vmh, ws.vml, ws.mx, ws.inv,
                                       nullptr, nullptr, nullptr, ws.xrp, ws.csump, N, C);
    k_xsub2<2><<<((size_t)BB * N * C + 255) / 256, 256, 0, st>>>(
        ws.xrp, ws.csump, ws.xcur, ws.xsh, ws.xsl, N, C);
  } else {              // N=128, C=512: in-kernel epilogue
    k_sa_stats<128><<<gs, 256, 0, st>>>(ws.qh, ws.ql, N, ws.mx, ws.inv);
    dim3 gx(N / 64, C / 128, BB);
    k_sa_xr<128, 1><<<gx, 256, 0, st>>>(ws.qh, ws.ql, ws.vmh, ws.vml, ws.mx, ws.inv,
                                        ws.xcur, ws.xsh, ws.xsl, nullptr, nullptr, N, C);
  }
  mmp<64, 0, 1, 0, false, false>(st, ws.xsh, ws.xsl, twh, twl, tb, ws.pre, nullptr,
                                 N, C, C, sx, 0, sx, BB, 1);
  k_bn_part<<<256, 256, 0, st>>>(ws.pre, BB * N, C, ws.bpart);
  k_bn_fin<<<(C + 31) / 32, 256, 0, st>>>(ws.bpart, BB * N, C, ws.stats);
  k_bn_apply<true><<<(BB * N * C + 255) / 256, 256, 0, st>>>(ws.pre, ws.stats, g, be,
                                                             ws.xcur, ws.xcur, xh, xl, BB * N * C, C);
}

static void run_conv(hipStream_t st, Ws& ws, const u16* finh, const u16* finl, int Cin,
                     const u16* cwh, const u16* cwl, const float* bias, const float* dirs,
                     const int* idx, int N, int C,
                     const float* bng, const float* bnb, bool doBN, u16* fmh, u16* fml) {
  if (N == NP0)
    mmp<128, 0, 1, 0, false, false>(st, finh, finl, cwh, cwl, bias, ws.fout, nullptr,
                                    N, 2 * C, Cin, (long)N * Cin, 0, (long)N * 2 * C, BB, 1);
  else
    mmp<64, 0, 1, 0, false, false>(st, finh, finl, cwh, cwl, bias, ws.fout, nullptr,
                                   N, 2 * C, Cin, (long)N * Cin, 0, (long)N * 2 * C, BB, 1);
  k_conv_layer<<<dim3(N, BB), C, 0, st>>>(ws.v0, idx, dirs, ws.fout, ws.xcur, N, C);
  if (doBN) {
    k_bn_part<<<256, 256, 0, st>>>(ws.xcur, BB * N, C, ws.bpart);
    k_bn_fin<<<(C + 31) / 32, 256, 0, st>>>(ws.bpart, BB * N, C, ws.stats);
    k_bn_apply<false><<<(BB * N * C + 255) / 256, 256, 0, st>>>(
        ws.xcur, ws.stats, bng, bnb, nullptr, ws.xcur, fmh, fml, BB * N * C, C);
  } else {
    k_split4<false, true><<<(BB * N * C / 4 + 255) / 256, 256, 0, st>>>(
        ws.xcur, fmh, fml, BB * N * C / 4);
  }
}

extern "C" void kernel_launch(void* const* d_in, const int* in_sizes, int n_in,
                              void* d_out, int out_size, void* d_ws, size_t ws_size,
                              hipStream_t stream) {
  auto in = [&](int i) { return (const float*)d_in[i]; };
  char* p = (char*)d_ws;
  Ws ws;
  ws.v0 = (float*)(p + O_V0);
  ws.idx0 = (int*)(p + O_IDX0); ws.idxp0 = (int*)(p + O_IDXP0);
  ws.idx1 = (int*)(p + O_IDX1); ws.idxp1 = (int*)(p + O_IDXP1);
  ws.idx2 = (int*)(p + O_IDX2);
  ws.ni1 = (int*)(p + O_NI1); ws.ni2 = (int*)(p + O_NI2);
  ws.fglob = (float*)(p + O_FGLOB); ws.glob1 = (float*)(p + O_GLOB1);
  ws.mx = (float*)(p + O_COLS); ws.inv = (float*)(p + O_CPART);
  ws.csump = (float*)(p + O_CPART + 65536);
  ws.stats = (float*)(p + O_STATS); ws.bpart = (float*)(p + O_BPART);
  ws.xcur = (float*)(p + O_XCUR);
  ws.pre = (float*)(p + O_AREA);
  ws.fout = (float*)(p + O_AREA); ws.x1 = (float*)(p + O_AREA);
  ws.xrp = (float*)(p + O_AREA);
  char* pl = p + O_PL;
  ws.wh = (u16*)(pl + PL_WH); ws.wl = (u16*)(pl + PL_WL);
  ws.fm0h = (u16*)(pl + PL_FM0H); ws.fm0l = (u16*)(pl + PL_FM0L);
  ws.fm1h = (u16*)(pl + PL_FM1H); ws.fm1l = (u16*)(pl + PL_FM1L);
  ws.fm2h = (u16*)(pl + PL_FM2H); ws.fm2l = (u16*)(pl + PL_FM2L);
  ws.fm3h = (u16*)(pl + PL_FM3H); ws.fm3l = (u16*)(pl + PL_FM3L);
  ws.fm4h = (u16*)(pl + PL_FM4H); ws.fm4l = (u16*)(pl + PL_FM4L);
  ws.fmp1h = (u16*)(pl + PL_FMP1H); ws.fmp1l = (u16*)(pl + PL_FMP1L);
  ws.fmp2h = (u16*)(pl + PL_FMP2H); ws.fmp2l = (u16*)(pl + PL_FMP2L);
  ws.qh = (u16*)(pl + PL_QH); ws.ql = (u16*)(pl + PL_QL);
  ws.vmh = (u16*)(pl + PL_VMH); ws.vml = (u16*)(pl + PL_VML);
  ws.xsh = (u16*)(pl + PL_XSH); ws.xsl = (u16*)(pl + PL_XSL);
  ws.x1h = (u16*)(pl + PL_X1H);
  ws.x2b = (u16*)(p + O_XCUR);
  float* out = (float*)d_out;

  // ---- one-time weight plane split (pre-transposed to [N,K]) ----
  SplitJobs jobs;
  size_t wq[26];
  size_t off = 0;
  int ji = 0;
  auto addjob = [&](const float* s, int K, int N, int trans) {
    int n = K * N;
    jobs.j[ji] = {s, ws.wh + off, ws.wl + off, n, K, N, trans};
    wq[ji] = off; off += (size_t)n; ++ji;
  };
  addjob(in(5), 128, 32, 0);  addjob(in(6), 128, 128, 0);  addjob(in(8), 128, 128, 0);
  addjob(in(17), 128, 32, 0); addjob(in(18), 128, 128, 0); addjob(in(20), 128, 128, 0);
  addjob(in(29), 256, 64, 0); addjob(in(30), 256, 256, 0); addjob(in(32), 256, 256, 0);
  addjob(in(41), 256, 64, 0); addjob(in(42), 256, 256, 0); addjob(in(44), 256, 256, 0);
  addjob(in(51), 512, 128, 0); addjob(in(52), 512, 512, 0); addjob(in(54), 512, 512, 0);
  addjob(in(12), 128, 256, 1);
  addjob(in(24), 128, 512, 1);
  addjob(in(36), 256, 512, 1);
  addjob(in(48), 256, 1024, 1);
  addjob(in(58) + 0 * 512, 128, 512, 1);
  addjob(in(58) + (size_t)128 * 512, 128, 512, 1);
  addjob(in(58) + (size_t)256 * 512, 256, 512, 1);
  addjob(in(58) + (size_t)512 * 512, 256, 512, 1);
  addjob(in(58) + (size_t)768 * 512, 512, 512, 1);
  addjob(in(60), 512, 512, 1);
  addjob(in(62), 512, 50, 1);
  k_splitjobs<<<dim3(32, 26), 256, 0, stream>>>(jobs);
  auto W = [&](int i) { return ws.wh + wq[i]; };
  auto Wl = [&](int i) { return ws.wl + wq[i]; };

  // ---- geometry ----
  k_transpose<<<(BB * NP0 * 3 + 255) / 256, 256, 0, stream>>>(in(0), ws.v0);
  k_knn_radix<NP0, KNB_><<<dim3(NP0 / 4, BB), 256, 0, stream>>>(ws.v0, NP0, ws.idx0);

  // ---- conv0 + bn0 ----
  k_conv_surface<<<dim3(NP0, BB), 128, 0, stream>>>(ws.v0, ws.idx0, in(2), ws.xcur, NP0, 128);
  k_bn_part<<<256, 256, 0, stream>>>(ws.xcur, BB * NP0, 128, ws.bpart);
  k_bn_fin<<<4, 256, 0, stream>>>(ws.bpart, BB * NP0, 128, ws.stats);
  k_bn_apply<false><<<(BB * NP0 * 128 + 255) / 256, 256, 0, stream>>>(
      ws.xcur, ws.stats, in(3), in(4), nullptr, ws.xcur, ws.fm0h, ws.fm0l, BB * NP0 * 128, 128);

  // ---- sa0, conv1+bn1, sa1 ----
  run_sa(stream, ws, NP0, 128, 32, W(0), Wl(0), W(1), Wl(1), W(2), Wl(2),
         in(7), in(9), in(10), in(11), ws.fm0h, ws.fm0l);
  run_conv(stream, ws, ws.fm0h, ws.fm0l, 128, W(15), Wl(15), in(13), in(14), ws.idx0,
           NP0, 128, in(15), in(16), true, ws.fm1h, ws.fm1l);
  run_sa(stream, ws, NP0, 128, 32, W(3), Wl(3), W(4), Wl(4), W(5), Wl(5),
         in(19), in(21), in(22), in(23), ws.fm1h, ws.fm1l);

  // ---- pool1, knn1 ----
  k_knn2<NP0, 4><<<dim3(NP1 / 4, BB), 256, 0, stream>>>(ws.v0, NP1, ws.idxp0);
  k_pool<<<dim3(NP1, BB), 128, 0, stream>>>(ws.fm1h, ws.fm1l, ws.idxp0,
                                            ws.fmp1h, ws.fmp1l, NP0, NP1, 128);
  k_knn_radix<NP1, KNB_><<<dim3(NP1 / 4, BB), 256, 0, stream>>>(ws.v0, NP1, ws.idx1);

  // ---- conv2+bn2, sa2, conv3+bn3, sa3 ----
  run_conv(stream, ws, ws.fmp1h, ws.fmp1l, 128, W(16), Wl(16), in(25), in(26), ws.idx1,
           NP1, 256, in(27), in(28), true, ws.fm2h, ws.fm2l);
  run_sa(stream, ws, NP1, 256, 64, W(6), Wl(6), W(7), Wl(7), W(8), Wl(8),
         in(31), in(33), in(34), in(35), ws.fm2h, ws.fm2l);
  run_conv(stream, ws, ws.fm2h, ws.fm2l, 256, W(17), Wl(17), in(37), in(38), ws.idx1,
           NP1, 256, in(39), in(40), true, ws.fm3h, ws.fm3l);
  run_sa(stream, ws, NP1, 256, 64, W(9), Wl(9), W(10), Wl(10), W(11), Wl(11),
         in(43), in(45), in(46), in(47), ws.fm3h, ws.fm3l);

  // ---- pool2, knn2, conv4 (no bn), sa4 ----
  k_knn2<NP1, 4><<<dim3(NP2 / 4, BB), 256, 0, stream>>>(ws.v0, NP2, ws.idxp1);
  k_pool<<<dim3(NP2, BB), 256, 0, stream>>>(ws.fm3h, ws.fm3l, ws.idxp1,
                                            ws.fmp2h, ws.fmp2l, NP1, NP2, 256);
  k_knn_radix<NP2, KNB_><<<dim3(NP2 / 4, BB), 256, 0, stream>>>(ws.v0, NP2, ws.idx2);
  run_conv(stream, ws, ws.fmp2h, ws.fmp2l, 256, W(18), Wl(18), in(49), in(50), ws.idx2,
           NP2, 512, nullptr, nullptr, false, ws.fm4h, ws.fm4l);
  run_sa(stream, ws, NP2, 512, 128, W(12), Wl(12), W(13), Wl(13), W(14), Wl(14),
         in(53), in(55), in(56), in(57), ws.fm4h, ws.fm4l);

  // ---- global max, nearest, head (hi-plane-only GEMMs) ----
  k_maxn<<<dim3(2, BB), 256, 0, stream>>>(ws.fm4h, ws.fm4l, ws.fglob, NP2, 512);
  k_nearest<<<dim3(NP0 / 256, BB), 256, NP1 * 3 * 4, stream>>>(ws.v0, NP1, ws.ni1);
  k_nearest<<<dim3(NP0 / 256, BB), 256, NP2 * 3 * 4, stream>>>(ws.v0, NP2, ws.ni2);
  k_glob1<<<BB, 512, 0, stream>>>(ws.fglob, in(1), in(58), in(59), ws.glob1);

  for (int hf = 0; hf < 2; ++hf) {
    const int b0 = hf * 4;
    mmp<128, 2, 2, 0, false, false, false>(stream, ws.fm0h + (size_t)b0 * NP0 * 128,
        nullptr, W(19), nullptr, ws.glob1 + b0 * 512, ws.x1, nullptr,
        NP0, 512, 128, (long)NP0 * 128, 0, (long)NP0 * 512, 4, 1);
    mmp<128, 2, 0, 0, true, false, false>(stream, ws.fm1h + (size_t)b0 * NP0 * 128,
        nullptr, W(20), nullptr, nullptr, ws.x1, nullptr,
        NP0, 512, 128, (long)NP0 * 128, 0, (long)NP0 * 512, 4, 1);
    mmp<128, 2, 0, 0, true, true, false>(stream, ws.fm2h + (size_t)b0 * NP1 * 256,
        nullptr, W(21), nullptr, nullptr, ws.x1, nullptr,
        NP0, 512, 256, (long)NP1 * 256, 0, (long)NP0 * 512, 4, 1,
        ws.ni1 + (size_t)b0 * NP0, NP0);
    mmp<128, 2, 0, 0, true, true, false>(stream, ws.fm3h + (size_t)b0 * NP1 * 256,
        nullptr, W(22), nullptr, nullptr, ws.x1, nullptr,
        NP0, 512, 256, (long)NP1 * 256, 0, (long)NP0 * 512, 4, 1,
        ws.ni1 + (size_t)b0 * NP0, NP0);
    mmp<128, 2, 0, 0, true, true, false>(stream, ws.fm4h + (size_t)b0 * NP2 * 512,
        nullptr, W(23), nullptr, nullptr, ws.x1, nullptr,
        NP0, 512, 512, (long)NP2 * 512, 0, (long)NP0 * 512, 4, 1,
        ws.ni2 + (size_t)b0 * NP0, NP0);
    k_split4<true, false><<<(4 * NP0 * 512 / 4 + 255) / 256, 256, 0, stream>>>(
        ws.x1, ws.x1h, nullptr, 4 * NP0 * 512 / 4);
    mmp<128, 2, 1, 3, false, false, false>(stream, ws.x1h, nullptr, W(24), nullptr, in(61),
        ws.x2b, nullptr, NP0, 512, 512, (long)NP0 * 512, 0, (long)NP0 * 512, 4, 1);
    mmp<64, 2, 1, 0, false, false, false>(stream, ws.x2b, nullptr, W(25), nullptr, in(63),
        out + (size_t)b0 * NP0 * 50, nullptr, NP0, 50, 512,
        (long)NP0 * 512, 0, (long)NP0 * 50, 4, 1);
  }

  k_logsoftmax<<<(BB * NP0) / 4, 256, 0, stream>>>(out, BB * NP0, 50);
}

// Round 13
// 1311.754 us; speedup vs baseline: 2.9098x; 1.0664x over previous
//
#include <hip/hip_runtime.h>
#include <cfloat>

// ---------------------------------------------------------------------------
// GCN3D forward. Split-plane bf16 MFMA GEMMs (Dekker, f32-grade accuracy).
// Round-13: (1) head fused: k_xcat gather (1280-wide bf16 concat) + ONE
// K=1280 GEMM per half (register accumulation; was 5 ACC GEMMs + split pass
// round-tripping ~200MB); (2) SA@512 NSPLIT 2->4 (512 blocks).
// B=8, N=2048->512->128, K_NB=50. Workspace ~98.0 MB (<=102.3MB proven).
// ---------------------------------------------------------------------------

#define BB   8
#define NP0  2048
#define NP1  512
#define NP2  128
#define KNB_ 50
#define VS0  (NP0 * 3)

typedef __attribute__((ext_vector_type(8))) short short8_t;
typedef __attribute__((ext_vector_type(4))) short short4_t;
typedef __attribute__((ext_vector_type(4))) float f32x4_t;
typedef unsigned short u16;

// ---------------- workspace layout (byte offsets) ----------------
static constexpr size_t O_V0    = 0;
static constexpr size_t O_IDX0  = 196608;
static constexpr size_t O_IDXP0 = 3473408;
static constexpr size_t O_IDX1  = 3538944;
static constexpr size_t O_IDXP1 = 4358144;
static constexpr size_t O_IDX2  = 4374528;
static constexpr size_t O_NI1   = 4579328;
static constexpr size_t O_NI2   = 4644864;
static constexpr size_t O_FGLOB = 4710400;
static constexpr size_t O_GLOB1 = 4726784;
static constexpr size_t O_COLS  = 4743168;   // mx vectors (64KB)
static constexpr size_t O_CPART = 4808704;   // inv (64KB) + csum partials (<=448KB)
static constexpr size_t O_STATS = 5332992;
static constexpr size_t O_XCUR  = 5599232;   // 8,388,608 f32 activation scratch
static constexpr size_t O_PL    = 18182144;  // 58,855,424 plane pools
static constexpr size_t O_AREA  = 77037568;  // xrp / fout / pre / xcat(head, 21MB)
static constexpr size_t O_BPART = O_AREA + 12582912;  // 1MB bn partials
// head xcat extends AREA to 77.0+21.0 = 98.0MB <= 102.3MB proven (round 0).
// Temporal aliasing: xrp(16.8MB)<->bpart safe (xrp dead before bn_part runs);
// xcat only live during head (bn/xr dead).

static constexpr size_t PL_WH    = 0;
static constexpr size_t PL_WL    = 4786176;
static constexpr size_t PL_FM0H  = 9572352;
static constexpr size_t PL_FM0L  = 13766656;
static constexpr size_t PL_FM1H  = 17960960;
static constexpr size_t PL_FM1L  = 22155264;
static constexpr size_t PL_FM2H  = 26349568;
static constexpr size_t PL_FM2L  = 28446720;
static constexpr size_t PL_FM3H  = 30543872;
static constexpr size_t PL_FM3L  = 32641024;
static constexpr size_t PL_FM4H  = 34738176;
static constexpr size_t PL_FM4L  = 35786752;
static constexpr size_t PL_FMP1H = 36835328;
static constexpr size_t PL_FMP1L = 37883904;
static constexpr size_t PL_FMP2H = 38932480;
static constexpr size_t PL_FMP2L = 39456768;
static constexpr size_t PL_QH    = 39981056;
static constexpr size_t PL_QL    = 41029632;
static constexpr size_t PL_VMH   = 42078208;
static constexpr size_t PL_VML   = 46272512;
static constexpr size_t PL_XSH   = 50466816;
static constexpr size_t PL_XSL   = 54661120;
static constexpr size_t PL_X1H = PL_VMH;   // head alias (vm planes dead at head)

__device__ __forceinline__ float bf2f(u16 h) {
  union { unsigned u; float f; } c; c.u = ((unsigned)h) << 16; return c.f;
}
__device__ __forceinline__ u16 f2bf(float f) {
  union { float f; unsigned u; } c; c.f = f;
  return (u16)((c.u + 0x7fffu + ((c.u >> 16) & 1u)) >> 16);
}

// ===========================================================================
// Plane GEMM. BSPLIT=false: B hi-plane only. AMODE 2: plain bf16 A.
// ===========================================================================
template <int TM, int AMODE, int BIASM, int OUTM, bool ACC, bool GIDX, bool BSPLIT = true>
__global__ __launch_bounds__(256) void k_mmp(
    const void* __restrict__ A1, const void* __restrict__ A2,
    const u16* __restrict__ Bh0, const u16* __restrict__ Bl0,
    const float* __restrict__ bias, void* __restrict__ C1, void* __restrict__ C2,
    int M, int N, int K, long sA, long sB, long sC, int ksplit,
    const int* __restrict__ gidx, long sG) {
  constexpr int RT = TM / 32;
  constexpr int CT = TM / 32;
  __shared__ u16 Ah[TM][40], Bh[TM][40];
  __shared__ u16 Bl[BSPLIT ? TM : 1][40];
  __shared__ u16 Al[(AMODE == 2) ? 1 : TM][40];
  const int z = blockIdx.z;
  const int zb = z / ksplit, ks = z - zb * ksplit;
  const int kchunk = K / ksplit;
  const int kl0 = ks * kchunk, kl1 = kl0 + kchunk;
  const int m0 = blockIdx.x * TM, n0 = blockIdx.y * TM;
  const int t = threadIdx.x;
  const int lane = t & 63, w = t >> 6;
  const int wr = (w >> 1) * (TM / 2), wc = (w & 1) * (TM / 2);
  const int frow = lane & 15, koff = (lane >> 4) * 8;
  f32x4_t acc[RT][CT];
#pragma unroll
  for (int i = 0; i < RT; ++i)
#pragma unroll
    for (int j = 0; j < CT; ++j) acc[i][j] = (f32x4_t){0.f, 0.f, 0.f, 0.f};

  const u16* Ahg = (const u16*)A1 + (size_t)zb * sA;
  const u16* Alg = (const u16*)A2 + (size_t)zb * sA;
  const u16* Bhg = Bh0 + (size_t)zb * sB;
  const u16* Blg = Bl0 + (size_t)zb * sB;

  int ar, ac, arow = 0;
  if constexpr (TM == 128) { ar = t >> 1; ac = (t & 1) * 16; }
  else                     { ar = t >> 2; ac = (t & 3) * 8; }
  arow = m0 + ar;
  if constexpr (GIDX) arow = (gidx + (size_t)zb * sG)[arow];
  const int bn = ar, bc = ac;
  const bool bok = (n0 + bn) < N;
  const short8_t z8 = {0, 0, 0, 0, 0, 0, 0, 0};

  for (int k0 = kl0; k0 < kl1; k0 += 32) {
    __syncthreads();
    {
      const u16* s1 = Ahg + (size_t)arow * K + k0 + ac;
      if constexpr (TM == 128) {
        *(short8_t*)&Ah[ar][ac] = *(const short8_t*)s1;
        *(short8_t*)&Ah[ar][ac + 8] = *(const short8_t*)(s1 + 8);
        if constexpr (AMODE == 0) {
          const u16* s2 = Alg + (size_t)arow * K + k0 + ac;
          *(short8_t*)&Al[ar][ac] = *(const short8_t*)s2;
          *(short8_t*)&Al[ar][ac + 8] = *(const short8_t*)(s2 + 8);
        }
      } else {
        *(short8_t*)&Ah[ar][ac] = *(const short8_t*)s1;
        if constexpr (AMODE == 0)
          *(short8_t*)&Al[ar][ac] = *(const short8_t*)(Alg + (size_t)arow * K + k0 + ac);
      }
    }
    {
      const u16* s1 = Bhg + (size_t)(n0 + bn) * K + k0 + bc;
      const u16* s2 = Blg + (size_t)(n0 + bn) * K + k0 + bc;
      if constexpr (TM == 128) {
        *(short8_t*)&Bh[bn][bc] = bok ? *(const short8_t*)s1 : z8;
        *(short8_t*)&Bh[bn][bc + 8] = bok ? *(const short8_t*)(s1 + 8) : z8;
        if constexpr (BSPLIT) {
          *(short8_t*)&Bl[bn][bc] = bok ? *(const short8_t*)s2 : z8;
          *(short8_t*)&Bl[bn][bc + 8] = bok ? *(const short8_t*)(s2 + 8) : z8;
        }
      } else {
        *(short8_t*)&Bh[bn][bc] = bok ? *(const short8_t*)s1 : z8;
        if constexpr (BSPLIT)
          *(short8_t*)&Bl[bn][bc] = bok ? *(const short8_t*)s2 : z8;
      }
    }
    __syncthreads();
    short8_t ah[RT], al[RT], bh[CT], bl[CT];
#pragma unroll
    for (int i = 0; i < RT; ++i) {
      const int r = wr + i * 16 + frow;
      ah[i] = *(const short8_t*)&Ah[r][koff];
      if constexpr (AMODE != 2) al[i] = *(const short8_t*)&Al[r][koff];
    }
#pragma unroll
    for (int i = 0; i < CT; ++i) {
      const int r = wc + i * 16 + frow;
      bh[i] = *(const short8_t*)&Bh[r][koff];
      if constexpr (BSPLIT) bl[i] = *(const short8_t*)&Bl[r][koff];
    }
#pragma unroll
    for (int i = 0; i < RT; ++i)
#pragma unroll
      for (int j = 0; j < CT; ++j) {
        acc[i][j] = __builtin_amdgcn_mfma_f32_16x16x32_bf16(ah[i], bh[j], acc[i][j], 0, 0, 0);
        if constexpr (BSPLIT)
          acc[i][j] = __builtin_amdgcn_mfma_f32_16x16x32_bf16(ah[i], bl[j], acc[i][j], 0, 0, 0);
        if constexpr (AMODE != 2)
          acc[i][j] = __builtin_amdgcn_mfma_f32_16x16x32_bf16(al[i], bh[j], acc[i][j], 0, 0, 0);
      }
  }

  const int crow = (lane >> 4) * 4;
#pragma unroll
  for (int i = 0; i < RT; ++i) {
#pragma unroll
    for (int j = 0; j < CT; ++j) {
      const int gc = n0 + wc + j * 16 + frow;
      if (gc >= N) continue;
      float bv = 0.f;
      if constexpr (BIASM == 1) bv = bias[gc];
      if constexpr (BIASM == 2) bv = bias[(size_t)zb * N + gc];
      const int gr0 = m0 + wr + i * 16 + crow;
      if constexpr (OUTM == 0) {
        float* Cp = (float*)C1 + (size_t)z * sC;
#pragma unroll
        for (int q = 0; q < 4; ++q) {
          float vv = acc[i][j][q] + bv;
          if (ACC) vv += Cp[(size_t)(gr0 + q) * N + gc];
          Cp[(size_t)(gr0 + q) * N + gc] = vv;
        }
      } else if constexpr (OUTM == 1) {
        u16* Ph = (u16*)C1 + (size_t)z * sC;
        u16* Pl = (u16*)C2 + (size_t)z * sC;
#pragma unroll
        for (int q = 0; q < 4; ++q) {
          float vv = acc[i][j][q] + bv;
          u16 h = f2bf(vv);
          Ph[(size_t)(gr0 + q) * N + gc] = h;
          Pl[(size_t)(gr0 + q) * N + gc] = f2bf(vv - bf2f(h));
        }
      } else if constexpr (OUTM == 2) {
        u16* Ph = (u16*)C1 + (size_t)z * sC;
        u16* Pl = (u16*)C2 + (size_t)z * sC;
        short4_t h4, l4;
#pragma unroll
        for (int q = 0; q < 4; ++q) {
          float vv = acc[i][j][q] + bv;
          u16 h = f2bf(vv);
          h4[q] = (short)h;
          l4[q] = (short)f2bf(vv - bf2f(h));
        }
        *(short4_t*)(Ph + (size_t)gc * M + gr0) = h4;
        *(short4_t*)(Pl + (size_t)gc * M + gr0) = l4;
      } else {
        u16* Cb = (u16*)C1 + (size_t)z * sC;
#pragma unroll
        for (int q = 0; q < 4; ++q) {
          float vv = fmaxf(acc[i][j][q] + bv, 0.f);
          Cb[(size_t)(gr0 + q) * N + gc] = f2bf(vv);
        }
      }
    }
  }
}

template <int TM, int AMODE, int BIASM, int OUTM, bool ACC, bool GIDX, bool BSPLIT = true>
static void mmp(hipStream_t st, const void* A1, const void* A2,
                const u16* Bh, const u16* Bl, const float* bias,
                void* C1, void* C2, int M, int N, int K,
                long sA, long sB, long sC, int Z, int ksplit,
                const int* gidx = nullptr, long sG = 0) {
  dim3 grid(M / TM, (N + TM - 1) / TM, Z * ksplit);
  k_mmp<TM, AMODE, BIASM, OUTM, ACC, GIDX, BSPLIT><<<grid, 256, 0, st>>>(
      A1, A2, Bh, Bl, bias, C1, C2, M, N, K, sA, sB, sC, ksplit, gidx, sG);
}

// ===========================================================================
// Fused attention, 64-row m-tiles, NSPLIT n-range partitioning.
// ===========================================================================
template <int QD>
__global__ __launch_bounds__(256) void k_sa_stats(
    const u16* __restrict__ qh, const u16* __restrict__ ql, int N,
    float* __restrict__ mx, float* __restrict__ inv) {
  __shared__ float mr[2][64], sr[2][64];
  const int b = blockIdx.y;
  const int m0 = blockIdx.x * 64;
  const int t = threadIdx.x, lane = t & 63, w = t >> 6;
  const int wm = (w >> 1) * 32, wn = (w & 1) * 64;
  const int frow = lane & 15, kq = (lane >> 4) * 8;
  const u16* qhb = qh + (size_t)b * N * QD;
  const u16* qlb = ql + (size_t)b * N * QD;
  constexpr int KS = QD / 32;
  short8_t ahq[KS][2], alq[KS][2];
#pragma unroll
  for (int ks = 0; ks < KS; ++ks)
#pragma unroll
    for (int i = 0; i < 2; ++i) {
      const size_t r = (size_t)(m0 + wm + i * 16 + frow) * QD + ks * 32 + kq;
      ahq[ks][i] = *(const short8_t*)(qhb + r);
      alq[ks][i] = *(const short8_t*)(qlb + r);
    }
  float M[2][4], S[2][4];
#pragma unroll
  for (int i = 0; i < 2; ++i)
#pragma unroll
    for (int q = 0; q < 4; ++q) { M[i][q] = -FLT_MAX; S[i][q] = 0.f; }

  for (int n0 = 0; n0 < N; n0 += 128) {
    f32x4_t acc[2][4];
#pragma unroll
    for (int i = 0; i < 2; ++i)
#pragma unroll
      for (int j = 0; j < 4; ++j) acc[i][j] = (f32x4_t){0.f, 0.f, 0.f, 0.f};
#pragma unroll
    for (int ks = 0; ks < KS; ++ks) {
      short8_t b_h[4], b_l[4];
#pragma unroll
      for (int j = 0; j < 4; ++j) {
        const size_t r = (size_t)(n0 + wn + j * 16 + frow) * QD + ks * 32 + kq;
        b_h[j] = *(const short8_t*)(qhb + r);
        b_l[j] = *(const short8_t*)(qlb + r);
      }
#pragma unroll
      for (int i = 0; i < 2; ++i)
#pragma unroll
        for (int j = 0; j < 4; ++j) {
          acc[i][j] = __builtin_amdgcn_mfma_f32_16x16x32_bf16(ahq[ks][i], b_h[j], acc[i][j], 0, 0, 0);
          acc[i][j] = __builtin_amdgcn_mfma_f32_16x16x32_bf16(ahq[ks][i], b_l[j], acc[i][j], 0, 0, 0);
          acc[i][j] = __builtin_amdgcn_mfma_f32_16x16x32_bf16(alq[ks][i], b_h[j], acc[i][j], 0, 0, 0);
        }
    }
#pragma unroll
    for (int i = 0; i < 2; ++i)
#pragma unroll
      for (int q = 0; q < 4; ++q) {
        float tm = acc[i][0][q];
#pragma unroll
        for (int j = 1; j < 4; ++j) tm = fmaxf(tm, acc[i][j][q]);
#pragma unroll
        for (int off = 1; off < 16; off <<= 1) tm = fmaxf(tm, __shfl_xor(tm, off));
        const float Mn = fmaxf(M[i][q], tm);
        float ps = 0.f;
#pragma unroll
        for (int j = 0; j < 4; ++j) ps += __expf(acc[i][j][q] - Mn);
#pragma unroll
        for (int off = 1; off < 16; off <<= 1) ps += __shfl_xor(ps, off);
        S[i][q] = S[i][q] * __expf(M[i][q] - Mn) + ps;
        M[i][q] = Mn;
      }
  }
  if (frow == 0) {
#pragma unroll
    for (int i = 0; i < 2; ++i)
#pragma unroll
      for (int q = 0; q < 4; ++q) {
        const int ml = wm + i * 16 + (lane >> 4) * 4 + q;
        mr[w & 1][ml] = M[i][q];
        sr[w & 1][ml] = S[i][q];
      }
  }
  __syncthreads();
  if (t < 64) {
    const float M0 = mr[0][t], M1 = mr[1][t];
    const float Mm = fmaxf(M0, M1);
    const float Sm = sr[0][t] * __expf(M0 - Mm) + sr[1][t] * __expf(M1 - Mm);
    mx[(size_t)b * N + m0 + t] = Mm;
    inv[(size_t)b * N + m0 + t] = 1.f / Sm;
  }
}

template <int QD, int NSPLIT>
__global__ __launch_bounds__(256) void k_sa_xr(
    const u16* __restrict__ qh, const u16* __restrict__ ql,
    const u16* __restrict__ vmh, const u16* __restrict__ vml,
    const float* __restrict__ mx, const float* __restrict__ inv,
    const float* __restrict__ xcur, u16* __restrict__ xsh, u16* __restrict__ xsl,
    float* __restrict__ xrp, float* __restrict__ csump,
    int N, int C) {
  __shared__ __align__(16) u16 Ph[64][132];
  __shared__ __align__(16) u16 Vh[128][68], Vl[128][68];
  const int b = blockIdx.z / NSPLIT, sidx = blockIdx.z % NSPLIT;
  const int m0 = blockIdx.x * 64, c0 = blockIdx.y * 128;
  const int t = threadIdx.x, lane = t & 63, w = t >> 6;
  const int wm = (w >> 1) * 32, wn = (w & 1) * 64;
  const int frow = lane & 15, kq = (lane >> 4) * 8;
  const u16* qhb = qh + (size_t)b * N * QD;
  const u16* qlb = ql + (size_t)b * N * QD;
  const u16* vhb = vmh + (size_t)b * (size_t)N * C;  // [C][N]
  const u16* vlb = vml + (size_t)b * (size_t)N * C;
  const float* mxb = mx + (size_t)b * N;
  const float* invb = inv + (size_t)b * N;
  constexpr int KS = QD / 32;
  const int vr = t >> 1, vco = (t & 1) * 32;
  short8_t ahq[KS][2], alq[KS][2];
#pragma unroll
  for (int ks = 0; ks < KS; ++ks)
#pragma unroll
    for (int i = 0; i < 2; ++i) {
      const size_t r = (size_t)(m0 + wm + i * 16 + frow) * QD + ks * 32 + kq;
      ahq[ks][i] = *(const short8_t*)(qhb + r);
      alq[ks][i] = *(const short8_t*)(qlb + r);
    }
  f32x4_t xacc[2][4];
  float csum[2][4];
#pragma unroll
  for (int i = 0; i < 2; ++i)
#pragma unroll
    for (int j = 0; j < 4; ++j) { xacc[i][j] = (f32x4_t){0.f, 0.f, 0.f, 0.f}; csum[i][j] = 0.f; }

  const int nlo = sidx * (N / NSPLIT), nhi = nlo + N / NSPLIT;
  for (int n0 = nlo; n0 < nhi; n0 += 128) {
    __syncthreads();
    {
      const u16* s1 = vhb + (size_t)(c0 + vr) * N + n0 + vco;
      const u16* s2 = vlb + (size_t)(c0 + vr) * N + n0 + vco;
#pragma unroll
      for (int u = 0; u < 4; ++u) {
        *(short8_t*)&Vh[vr][vco + u * 8] = *(const short8_t*)(s1 + u * 8);
        *(short8_t*)&Vl[vr][vco + u * 8] = *(const short8_t*)(s2 + u * 8);
      }
    }
    f32x4_t acc[2][4];
#pragma unroll
    for (int i = 0; i < 2; ++i)
#pragma unroll
      for (int j = 0; j < 4; ++j) acc[i][j] = (f32x4_t){0.f, 0.f, 0.f, 0.f};
#pragma unroll
    for (int ks = 0; ks < KS; ++ks) {
      short8_t b_h[4], b_l[4];
#pragma unroll
      for (int j = 0; j < 4; ++j) {
        const size_t r = (size_t)(n0 + wn + j * 16 + frow) * QD + ks * 32 + kq;
        b_h[j] = *(const short8_t*)(qhb + r);
        b_l[j] = *(const short8_t*)(qlb + r);
      }
#pragma unroll
      for (int i = 0; i < 2; ++i)
#pragma unroll
        for (int j = 0; j < 4; ++j) {
          acc[i][j] = __builtin_amdgcn_mfma_f32_16x16x32_bf16(ahq[ks][i], b_h[j], acc[i][j], 0, 0, 0);
          acc[i][j] = __builtin_amdgcn_mfma_f32_16x16x32_bf16(ahq[ks][i], b_l[j], acc[i][j], 0, 0, 0);
          acc[i][j] = __builtin_amdgcn_mfma_f32_16x16x32_bf16(alq[ks][i], b_h[j], acc[i][j], 0, 0, 0);
        }
    }
    float mxj[4], ivj[4];
#pragma unroll
    for (int j = 0; j < 4; ++j) {
      const int n = n0 + wn + j * 16 + frow;
      mxj[j] = mxb[n];
      ivj[j] = invb[n];
    }
    const int mbase = wm + (lane >> 4) * 4;
#pragma unroll
    for (int i = 0; i < 2; ++i)
#pragma unroll
      for (int j = 0; j < 4; ++j)
#pragma unroll
        for (int q = 0; q < 4; ++q) {
          const float pv = __expf(acc[i][j][q] - mxj[j]) * ivj[j];
          csum[i][q] += pv;
          Ph[mbase + i * 16 + q][wn + j * 16 + frow] = f2bf(pv);
        }
    __syncthreads();
#pragma unroll
    for (int ks2 = 0; ks2 < 2; ++ks2) {
      short8_t p_h[2], v_h[4], v_l[4];
#pragma unroll
      for (int i = 0; i < 2; ++i)
        p_h[i] = *(const short8_t*)&Ph[wm + i * 16 + frow][ks2 * 32 + kq];
#pragma unroll
      for (int j = 0; j < 4; ++j) {
        v_h[j] = *(const short8_t*)&Vh[wn + j * 16 + frow][ks2 * 32 + kq];
        v_l[j] = *(const short8_t*)&Vl[wn + j * 16 + frow][ks2 * 32 + kq];
      }
#pragma unroll
      for (int i = 0; i < 2; ++i)
#pragma unroll
        for (int j = 0; j < 4; ++j) {
          xacc[i][j] = __builtin_amdgcn_mfma_f32_16x16x32_bf16(p_h[i], v_h[j], xacc[i][j], 0, 0, 0);
          xacc[i][j] = __builtin_amdgcn_mfma_f32_16x16x32_bf16(p_h[i], v_l[j], xacc[i][j], 0, 0, 0);
        }
    }
    __syncthreads();
    {
      const u16* s1 = vhb + (size_t)(c0 + vr) * N + n0 + 64 + vco;
      const u16* s2 = vlb + (size_t)(c0 + vr) * N + n0 + 64 + vco;
#pragma unroll
      for (int u = 0; u < 4; ++u) {
        *(short8_t*)&Vh[vr][vco + u * 8] = *(const short8_t*)(s1 + u * 8);
        *(short8_t*)&Vl[vr][vco + u * 8] = *(const short8_t*)(s2 + u * 8);
      }
    }
    __syncthreads();
#pragma unroll
    for (int ks2 = 0; ks2 < 2; ++ks2) {
      short8_t p_h[2], v_h[4], v_l[4];
#pragma unroll
      for (int i = 0; i < 2; ++i)
        p_h[i] = *(const short8_t*)&Ph[wm + i * 16 + frow][64 + ks2 * 32 + kq];
#pragma unroll
      for (int j = 0; j < 4; ++j) {
        v_h[j] = *(const short8_t*)&Vh[wn + j * 16 + frow][ks2 * 32 + kq];
        v_l[j] = *(const short8_t*)&Vl[wn + j * 16 + frow][ks2 * 32 + kq];
      }
#pragma unroll
      for (int i = 0; i < 2; ++i)
#pragma unroll
        for (int j = 0; j < 4; ++j) {
          xacc[i][j] = __builtin_amdgcn_mfma_f32_16x16x32_bf16(p_h[i], v_h[j], xacc[i][j], 0, 0, 0);
          xacc[i][j] = __builtin_amdgcn_mfma_f32_16x16x32_bf16(p_h[i], v_l[j], xacc[i][j], 0, 0, 0);
        }
    }
  }
#pragma unroll
  for (int i = 0; i < 2; ++i)
#pragma unroll
    for (int q = 0; q < 4; ++q)
#pragma unroll
      for (int off = 1; off < 16; off <<= 1) csum[i][q] += __shfl_xor(csum[i][q], off);
  __syncthreads();
  float* csb = (float*)&Ph[0][0];
  if (frow == 0) {
#pragma unroll
    for (int i = 0; i < 2; ++i)
#pragma unroll
      for (int q = 0; q < 4; ++q)
        csb[(w & 1) * 64 + wm + i * 16 + (lane >> 4) * 4 + q] = csum[i][q];
  }
  __syncthreads();
  if (t < 64) csb[128 + t] = csb[t] + csb[64 + t];
  __syncthreads();
  if constexpr (NSPLIT > 1) {
    if (t < 64 && blockIdx.y == 0)
      csump[((size_t)sidx * BB + b) * N + m0 + t] = csb[128 + t];
    float* xp = xrp + (size_t)sidx * BB * N * C;
#pragma unroll
    for (int i = 0; i < 2; ++i)
#pragma unroll
      for (int q = 0; q < 4; ++q) {
        const int mloc = wm + i * 16 + (lane >> 4) * 4 + q;
        const size_t rowoff = ((size_t)b * N + m0 + mloc) * C;
#pragma unroll
        for (int j = 0; j < 4; ++j)
          xp[rowoff + c0 + wn + j * 16 + frow] = xacc[i][j][q];
      }
  } else {
#pragma unroll
    for (int i = 0; i < 2; ++i) {
#pragma unroll
      for (int q = 0; q < 4; ++q) {
        const int mloc = wm + i * 16 + (lane >> 4) * 4 + q;
        const float cstot = csb[128 + mloc];
        const size_t rowoff = ((size_t)b * N + m0 + mloc) * C;
#pragma unroll
        for (int j = 0; j < 4; ++j) {
          const int gc = c0 + wn + j * 16 + frow;
          const float val = xcur[rowoff + gc] - xacc[i][j][q] / (1e-9f + cstot);
          const u16 h = f2bf(val);
          xsh[rowoff + gc] = h;
          xsl[rowoff + gc] = f2bf(val - bf2f(h));
        }
      }
    }
  }
}

template <int NS>
__global__ void k_xsub2(const float* __restrict__ xrp, const float* __restrict__ csump,
                        const float* __restrict__ xcur, u16* __restrict__ xsh,
                        u16* __restrict__ xsl, int N, int C) {
  const size_t total = (size_t)BB * N * C;
  size_t i = (size_t)blockIdx.x * 256 + threadIdx.x;
  if (i >= total) return;
  const size_t row = i / C;
  float s = 0.f, cs = 0.f;
#pragma unroll
  for (int k = 0; k < NS; ++k) {
    s += xrp[(size_t)k * total + i];
    cs += csump[(size_t)k * BB * N + row];
  }
  const float val = xcur[i] - s / (1e-9f + cs);
  const u16 h = f2bf(val);
  xsh[i] = h;
  xsl[i] = f2bf(val - bf2f(h));
}

// ===========================================================================
// weight split + activation split + head gather
// ===========================================================================
struct SplitJob { const float* s; u16* dh; u16* dl; int n, K, N, trans; };
struct SplitJobs { SplitJob j[22]; };
__global__ void k_splitjobs(SplitJobs jobs) {
  SplitJob jb = jobs.j[blockIdx.y];
  for (int i = blockIdx.x * 256 + threadIdx.x; i < jb.n; i += gridDim.x * 256) {
    float v;
    if (jb.trans) { int k = i % jb.K, n = i / jb.K; v = jb.s[(size_t)k * jb.N + n]; }
    else v = jb.s[i];
    u16 h = f2bf(v);
    jb.dh[i] = h;
    jb.dl[i] = f2bf(v - bf2f(h));
  }
}

template <bool RELU, bool LO>
__global__ void k_split4(const float* __restrict__ x, u16* __restrict__ ph,
                         u16* __restrict__ pl, int n4) {
  int i = blockIdx.x * 256 + threadIdx.x;
  if (i >= n4) return;
  float4 v = ((const float4*)x)[i];
  short4_t h4, l4;
  float vv[4] = {v.x, v.y, v.z, v.w};
#pragma unroll
  for (int q = 0; q < 4; ++q) {
    float f = RELU ? fmaxf(vv[q], 0.f) : vv[q];
    u16 h = f2bf(f);
    h4[q] = (short)h;
    if (LO) l4[q] = (short)f2bf(f - bf2f(h));
  }
  *(short4_t*)(ph + (size_t)i * 4) = h4;
  if (LO) *(short4_t*)(pl + (size_t)i * 4) = l4;
}

// gather 1280-wide bf16 concat rows (4 batches starting at b0)
__global__ void k_xcat(const u16* __restrict__ f0, const u16* __restrict__ f1,
                       const u16* __restrict__ f2, const u16* __restrict__ f3,
                       const u16* __restrict__ f4, const int* __restrict__ ni1,
                       const int* __restrict__ ni2, u16* __restrict__ xcat, int b0) {
  const int G = 1280 / 8;
  int i = blockIdx.x * 256 + threadIdx.x;
  if (i >= 4 * NP0 * G) return;
  const int g = i % G, n = (i / G) % NP0, bl = i / (G * NP0);
  const int b = b0 + bl;
  const int k = g * 8;
  short8_t v;
  if (k < 128)      v = *(const short8_t*)(f0 + ((size_t)b * NP0 + n) * 128 + k);
  else if (k < 256) v = *(const short8_t*)(f1 + ((size_t)b * NP0 + n) * 128 + (k - 128));
  else if (k < 512) v = *(const short8_t*)(f2 + ((size_t)b * NP1 + ni1[b * NP0 + n]) * 256 + (k - 256));
  else if (k < 768) v = *(const short8_t*)(f3 + ((size_t)b * NP1 + ni1[b * NP0 + n]) * 256 + (k - 512));
  else              v = *(const short8_t*)(f4 + ((size_t)b * NP2 + ni2[b * NP0 + n]) * 512 + (k - 768));
  *(short8_t*)(xcat + ((size_t)bl * NP0 + n) * 1280 + k) = v;
}

// ===========================================================================
// KNN (radix-select, 2-bit-pair descent) / k_knn2 (K=4)
// ===========================================================================
template <int NCAND, int KSEL>
__global__ __launch_bounds__(256) void k_knn_radix(const float* __restrict__ pts, int Nq,
                                                   int* __restrict__ outIdx) {
  __shared__ float sp[NCAND * 3];
  const int b = blockIdx.y;
  const float* pb = pts + (size_t)b * VS0;
  for (int i = threadIdx.x; i < NCAND * 3; i += 256) sp[i] = pb[i];
  __syncthreads();
  const int wave = threadIdx.x >> 6, lane = threadIdx.x & 63;
  const int qi = blockIdx.x * 4 + wave;
  const float qx = sp[qi * 3], qy = sp[qi * 3 + 1], qz = sp[qi * 3 + 2];
  constexpr int CH = NCAND / 64;
  unsigned d[CH];
  unsigned x[32];
#pragma unroll
  for (int j = 0; j < 32; ++j) x[j] = 0u;
#pragma unroll
  for (int j = 0; j < CH; ++j) {
    const int m = lane + j * 64;
    const float dx = sp[m * 3] - qx, dy = sp[m * 3 + 1] - qy, dz = sp[m * 3 + 2] - qz;
    const float dd = dx * dx + dy * dy + dz * dz;
    d[j] = __float_as_uint((m == qi) ? FLT_MAX : dd);
    x[j] = d[j];
  }
#pragma unroll
  for (int st = 0; st < 5; ++st) {
    const int s = 16 >> st;
    const unsigned ml = (s == 16) ? 0x0000FFFFu : (s == 8) ? 0x00FF00FFu
                      : (s == 4) ? 0x0F0F0F0Fu : (s == 2) ? 0x33333333u : 0x55555555u;
#pragma unroll
    for (int i = 0; i < 32; ++i) {
      if (i & s) continue;
      unsigned t = ((x[i] >> s) ^ x[i + s]) & ml;
      x[i + s] ^= t;
      x[i] ^= (t << s);
    }
  }
  unsigned active = (CH == 32) ? 0xFFFFFFFFu : ((1u << CH) - 1u);
  unsigned T = 0u;
  int kk = KSEL;
#pragma unroll
  for (int bb = 30; bb >= 2; bb -= 2) {
    const unsigned mh = x[bb], mlo = x[bb - 1];
    const unsigned a00 = active & ~mh & ~mlo;
    const unsigned a01 = active & ~mh & mlo;
    const unsigned a10 = active & mh & ~mlo;
    unsigned pA = (unsigned)__popc(a00) | ((unsigned)__popc(a01) << 16);
    unsigned pB = (unsigned)__popc(a10);
#pragma unroll
    for (int off = 32; off; off >>= 1) {
      pA += __shfl_xor(pA, off);
      pB += __shfl_xor(pB, off);
    }
    const int C00 = (int)(pA & 0xFFFFu), C01 = (int)(pA >> 16), C10 = (int)pB;
    if (kk <= C00) {
      active = a00;
    } else if (kk <= C00 + C01) {
      kk -= C00; active = a01; T |= 1u << (bb - 1);
    } else if (kk <= C00 + C01 + C10) {
      kk -= C00 + C01; active = a10; T |= 1u << bb;
    } else {
      kk -= C00 + C01 + C10; active = active & mh & mlo; T |= 3u << (bb - 1);
    }
  }
  {
    const unsigned zn = active & ~x[0];
    int c0 = __popc(zn);
#pragma unroll
    for (int off = 32; off; off >>= 1) c0 += __shfl_xor(c0, off);
    if (kk <= c0) active = zn;
    else { active &= x[0]; T |= 1u; }
  }
  int* orow = outIdx + ((size_t)b * Nq + qi) * KSEL;
  const unsigned long long ltmask = (1ull << lane) - 1ull;
  int base = 0;
#pragma unroll
  for (int j = 0; j < CH; ++j) {
    const bool sel = d[j] < T;
    const unsigned long long bal = __ballot(sel);
    const int pos = base + (int)__popcll(bal & ltmask);
    if (sel) orow[pos] = lane + j * 64;
    base += (int)__popcll(bal);
  }
  for (int j = 0; j < CH; ++j) {
    if (base >= KSEL) break;
    const bool sel = ((active >> j) & 1u) != 0u;
    const unsigned long long bal = __ballot(sel);
    const int pos = base + (int)__popcll(bal & ltmask);
    if (sel && pos < KSEL) orow[pos] = lane + j * 64;
    base += (int)__popcll(bal);
  }
}

template <int NCAND, int KSEL>
__global__ __launch_bounds__(256) void k_knn2(const float* __restrict__ pts, int Nq,
                                              int* __restrict__ outIdx) {
  __shared__ float sp[NCAND * 3];
  const int b = blockIdx.y;
  const float* pb = pts + (size_t)b * VS0;
  for (int i = threadIdx.x; i < NCAND * 3; i += 256) sp[i] = pb[i];
  __syncthreads();
  const int wave = threadIdx.x >> 6, lane = threadIdx.x & 63;
  const int qi = blockIdx.x * 4 + wave;
  const float qx = sp[qi * 3], qy = sp[qi * 3 + 1], qz = sp[qi * 3 + 2];
  constexpr int CH = NCAND / 64;
  float d[CH];
#pragma unroll
  for (int j = 0; j < CH; ++j) {
    const int m = lane + j * 64;
    const float dx = sp[m * 3] - qx, dy = sp[m * 3 + 1] - qy, dz = sp[m * 3 + 2] - qz;
    const float dd = dx * dx + dy * dy + dz * dz;
    d[j] = (m == qi) ? FLT_MAX : dd;
  }
  int* orow = outIdx + ((size_t)b * Nq + qi) * KSEL;
#pragma unroll 1
  for (int s = 0; s < KSEL; ++s) {
    float bd = FLT_MAX; int bj = 0;
#pragma unroll
    for (int j = 0; j < CH; ++j) {
      const bool better = d[j] < bd;
      bd = better ? d[j] : bd;
      bj = better ? j : bj;
    }
    int bm = lane + bj * 64;
#pragma unroll
    for (int off = 32; off; off >>= 1) {
      const float od = __shfl_xor(bd, off);
      const int om = __shfl_xor(bm, off);
      if (od < bd || (od == bd && om < bm)) { bd = od; bm = om; }
    }
    if (lane == 0) orow[s] = bm;
#pragma unroll
    for (int j = 0; j < CH; ++j)
      if (bm == lane + j * 64) d[j] = FLT_MAX;
  }
}

__global__ void k_transpose(const float* __restrict__ in, float* __restrict__ out) {
  int i = blockIdx.x * 256 + threadIdx.x;
  if (i >= BB * NP0 * 3) return;
  int dd = i % 3, tt = (i / 3) % NP0, b = i / (3 * NP0);
  out[i] = in[((size_t)b * 3 + dd) * NP0 + tt];
}

__global__ void k_conv_surface(const float* __restrict__ v, const int* __restrict__ idx,
                               const float* __restrict__ dirs, float* __restrict__ out,
                               int N, int M) {
  __shared__ float su[KNB_ * 3];
  int b = blockIdx.y, n = blockIdx.x, c = threadIdx.x;
  const float* vb = v + (size_t)b * VS0;
  float cx = vb[n * 3], cy = vb[n * 3 + 1], cz = vb[n * 3 + 2];
  const int* irow = idx + ((size_t)b * N + n) * KNB_;
  if (c < KNB_) {
    int j = irow[c];
    float dx = vb[j * 3] - cx, dy = vb[j * 3 + 1] - cy, dz = vb[j * 3 + 2] - cz;
    float inv = 1.f / fmaxf(sqrtf(dx * dx + dy * dy + dz * dz), 1e-12f);
    su[c * 3] = dx * inv; su[c * 3 + 1] = dy * inv; su[c * 3 + 2] = dz * inv;
  }
  __syncthreads();
  float d0 = dirs[c], d1 = dirs[M + c], d2 = dirs[2 * M + c];
  float inv = 1.f / fmaxf(sqrtf(d0 * d0 + d1 * d1 + d2 * d2), 1e-12f);
  d0 *= inv; d1 *= inv; d2 *= inv;
  float acc = 0.f;
  for (int k = 0; k < KNB_; ++k) {
    float th = fmaxf(su[k * 3] * d0 + su[k * 3 + 1] * d1 + su[k * 3 + 2] * d2, 0.f);
    acc = fmaxf(acc, th);
  }
  out[((size_t)b * N + n) * M + c] = acc;
}

__global__ void k_conv_layer(const float* __restrict__ v, const int* __restrict__ idx,
                             const float* __restrict__ dirs, const float* __restrict__ fout,
                             float* __restrict__ out, int N, int C) {
  __shared__ float su[KNB_ * 3];
  __shared__ int sidx[KNB_];
  int b = blockIdx.y, n = blockIdx.x, c = threadIdx.x;
  const float* vb = v + (size_t)b * VS0;
  float cx = vb[n * 3], cy = vb[n * 3 + 1], cz = vb[n * 3 + 2];
  const int* irow = idx + ((size_t)b * N + n) * KNB_;
  if (c < KNB_) {
    int j = irow[c]; sidx[c] = j;
    float dx = vb[j * 3] - cx, dy = vb[j * 3 + 1] - cy, dz = vb[j * 3 + 2] - cz;
    float inv = 1.f / fmaxf(sqrtf(dx * dx + dy * dy + dz * dz), 1e-12f);
    su[c * 3] = dx * inv; su[c * 3 + 1] = dy * inv; su[c * 3 + 2] = dz * inv;
  }
  __syncthreads();
  float d0 = dirs[c], d1 = dirs[C + c], d2 = dirs[2 * C + c];
  float inv = 1.f / fmaxf(sqrtf(d0 * d0 + d1 * d1 + d2 * d2), 1e-12f);
  d0 *= inv; d1 *= inv; d2 *= inv;
  const float* fb = fout + (size_t)b * N * 2 * C;
  float acc = -FLT_MAX;
  for (int k = 0; k < KNB_; ++k) {
    float th = fmaxf(su[k * 3] * d0 + su[k * 3 + 1] * d1 + su[k * 3 + 2] * d2, 0.f);
    float fs = fb[(size_t)sidx[k] * 2 * C + C + c];
    acc = fmaxf(acc, th * fs);
  }
  out[((size_t)b * N + n) * C + c] = fb[(size_t)n * 2 * C + c] + acc;
}

// ===========================================================================
// BN (256-block partials; parallel fin) / pool / misc
// ===========================================================================
__global__ void k_bn_part(const float* __restrict__ x, int rows, int C, float* __restrict__ part) {
  const int blk = blockIdx.x;
  const int chunk = rows / 256;
  const int r0 = blk * chunk;
  const int c0 = threadIdx.x, c1 = threadIdx.x + 256;
  float s0 = 0, s20 = 0, s1 = 0, s21 = 0;
  for (int r = 0; r < chunk; ++r) {
    const float* row = x + (size_t)(r0 + r) * C;
    if (c0 < C) { float v = row[c0]; s0 += v; s20 += v * v; }
    if (c1 < C) { float v = row[c1]; s1 += v; s21 += v * v; }
  }
  float* p = part + (size_t)blk * 1024;
  if (c0 < C) { p[c0] = s0; p[512 + c0] = s20; }
  if (c1 < C) { p[c1] = s1; p[512 + c1] = s21; }
}

__global__ void k_bn_fin(const float* __restrict__ part, int rows, int C, float* __restrict__ stats) {
  __shared__ float sm0[8][32], sm1[8][32];
  const int cl = threadIdx.x & 31, ch = threadIdx.x >> 5;
  const int c = blockIdx.x * 32 + cl;
  float s = 0, s2 = 0;
  if (c < C) {
    for (int b2 = ch * 32; b2 < ch * 32 + 32; ++b2) {
      s += part[b2 * 1024 + c];
      s2 += part[b2 * 1024 + 512 + c];
    }
  }
  sm0[ch][cl] = s; sm1[ch][cl] = s2;
  __syncthreads();
  if (ch == 0 && c < C) {
    float S = 0, S2 = 0;
#pragma unroll
    for (int k = 0; k < 8; ++k) { S += sm0[k][cl]; S2 += sm1[k][cl]; }
    float m = S / rows;
    float var = S2 / rows - m * m;
    stats[c] = m;
    stats[C + c] = rsqrtf(var + 1e-5f);
  }
}

template <bool ADD>
__global__ void k_bn_apply(const float* __restrict__ x, const float* __restrict__ stats,
                           const float* __restrict__ g, const float* __restrict__ bb,
                           const float* __restrict__ base, float* __restrict__ outf,
                           u16* __restrict__ ph, u16* __restrict__ pl, int total, int C) {
  int i = blockIdx.x * 256 + threadIdx.x;
  if (i >= total) return;
  int c = i % C;
  float v = (x[i] - stats[c]) * stats[C + c] * g[c] + bb[c];
  v = fmaxf(v, 0.f);
  float r = ADD ? base[i] + v : v;
  outf[i] = r;
  u16 h = f2bf(r);
  ph[i] = h;
  pl[i] = f2bf(r - bf2f(h));
}

__global__ void k_pool(const u16* __restrict__ fh, const u16* __restrict__ fl,
                       const int* __restrict__ idxp, u16* __restrict__ oh,
                       u16* __restrict__ ol, int Nin, int pn, int C) {
  int b = blockIdx.y, p = blockIdx.x, c = threadIdx.x;
  const int* ir = idxp + ((size_t)b * pn + p) * 4;
  const u16* fhb = fh + (size_t)b * Nin * C;
  const u16* flb = fl + (size_t)b * Nin * C;
  float acc = -FLT_MAX;
#pragma unroll
  for (int k = 0; k < 4; ++k) {
    size_t o = (size_t)ir[k] * C + c;
    acc = fmaxf(acc, bf2f(fhb[o]) + bf2f(flb[o]));
  }
  u16 h = f2bf(acc);
  oh[((size_t)b * pn + p) * C + c] = h;
  ol[((size_t)b * pn + p) * C + c] = f2bf(acc - bf2f(h));
}

__global__ void k_maxn(const u16* __restrict__ fh, const u16* __restrict__ fl,
                       float* __restrict__ out, int N, int C) {
  int b = blockIdx.y;
  int c = blockIdx.x * 256 + threadIdx.x;
  if (c >= C) return;
  float acc = -FLT_MAX;
  for (int n = 0; n < N; ++n) {
    size_t o = ((size_t)b * N + n) * C + c;
    acc = fmaxf(acc, bf2f(fh[o]) + bf2f(fl[o]));
  }
  out[(size_t)b * C + c] = acc;
}

__global__ void k_nearest(const float* __restrict__ v, int Ns, int* __restrict__ out) {
  extern __shared__ float sp[];
  int b = blockIdx.y;
  const float* vsb = v + (size_t)b * VS0;
  for (int i = threadIdx.x; i < Ns * 3; i += 256) sp[i] = vsb[i];
  __syncthreads();
  int t = blockIdx.x * 256 + threadIdx.x;
  float tx = vsb[t * 3], ty = vsb[t * 3 + 1], tz = vsb[t * 3 + 2];
  float bd = FLT_MAX; int bi = 0;
#pragma unroll 4
  for (int s = 0; s < Ns; ++s) {
    float dx = sp[s * 3] - tx, dy = sp[s * 3 + 1] - ty, dz = sp[s * 3 + 2] - tz;
    float dd = dx * dx + dy * dy + dz * dz;
    if (dd < bd) { bd = dd; bi = s; }
  }
  out[(size_t)b * NP0 + t] = bi;
}

__global__ void k_glob1(const float* __restrict__ fglob, const float* __restrict__ onehot,
                        const float* __restrict__ h1w, const float* __restrict__ h1b,
                        float* __restrict__ out) {
  int b = blockIdx.x, j = threadIdx.x;
  float s = h1b[j];
  for (int i = 0; i < 512; ++i) s = fmaf(fglob[b * 512 + i], h1w[(size_t)(1280 + i) * 512 + j], s);
  for (int i = 0; i < 16; ++i) s = fmaf(onehot[b * 16 + i], h1w[(size_t)(1792 + i) * 512 + j], s);
  out[b * 512 + j] = s;
}

__global__ void k_logsoftmax(float* __restrict__ x, int rows, int C) {
  int r = blockIdx.x * 4 + (threadIdx.x >> 6);
  int lane = threadIdx.x & 63;
  if (r >= rows) return;
  float* xr = x + (size_t)r * C;
  float v = (lane < C) ? xr[lane] : -FLT_MAX;
  float mx = v;
  for (int o = 32; o; o >>= 1) mx = fmaxf(mx, __shfl_xor(mx, o));
  float e = (lane < C) ? __expf(v - mx) : 0.f;
  float s = e;
  for (int o = 32; o; o >>= 1) s += __shfl_xor(s, o);
  float lse = mx + logf(s);
  if (lane < C) xr[lane] = v - lse;
}

// ===========================================================================
// host
// ===========================================================================
struct Ws {
  float *v0, *fglob, *glob1, *mx, *inv, *csump, *stats, *bpart, *xcur, *pre, *fout, *xrp;
  int *idx0, *idxp0, *idx1, *idxp1, *idx2, *ni1, *ni2;
  u16 *wh, *wl;
  u16 *fm0h, *fm0l, *fm1h, *fm1l, *fm2h, *fm2l, *fm3h, *fm3l, *fm4h, *fm4l;
  u16 *fmp1h, *fmp1l, *fmp2h, *fmp2l, *qh, *ql, *vmh, *vml, *xsh, *xsl;
  u16 *x1h, *x2b, *xcat;
};

static void run_sa(hipStream_t st, Ws& ws, int N, int C, int Q,
                   const u16* qkh, const u16* qkl, const u16* vwh, const u16* vwl,
                   const u16* twh, const u16* twl,
                   const float* vb, const float* tb, const float* g, const float* be,
                   u16* xh, u16* xl) {
  const long sx = (long)N * C;
  mmp<64, 0, 0, 1, false, false>(st, xh, xl, qkh, qkl, nullptr, ws.qh, ws.ql,
                                 N, Q, C, sx, 0, (long)N * Q, BB, 1);
  mmp<64, 0, 1, 2, false, false>(st, xh, xl, vwh, vwl, vb, ws.vmh, ws.vml,
                                 N, C, C, sx, 0, sx, BB, 1);
  dim3 gs(N / 64, BB);
  if (Q == 32) {        // N=2048, C=128: NSPLIT=2
    k_sa_stats<32><<<gs, 256, 0, st>>>(ws.qh, ws.ql, N, ws.mx, ws.inv);
    dim3 gx(N / 64, C / 128, BB * 2);
    k_sa_xr<32, 2><<<gx, 256, 0, st>>>(ws.qh, ws.ql, ws.vmh, ws.vml, ws.mx, ws.inv,
                                       nullptr, nullptr, nullptr, ws.xrp, ws.csump, N, C);
    k_xsub2<2><<<((size_t)BB * N * C + 255) / 256, 256, 0, st>>>(
        ws.xrp, ws.csump, ws.xcur, ws.xsh, ws.xsl, N, C);
  } else if (Q == 64) { // N=512, C=256: NSPLIT=4
    k_sa_stats<64><<<gs, 256, 0, st>>>(ws.qh, ws.ql, N, ws.mx, ws.inv);
    dim3 gx(N / 64, C / 128, BB * 4);
    k_sa_xr<64, 4><<<gx, 256, 0, st>>>(ws.qh, ws.ql, ws.vmh, ws.vml, ws.mx, ws.inv,
                                       nullptr, nullptr, nullptr, ws.xrp, ws.csump, N, C);
    k_xsub2<4><<<((size_t)BB * N * C + 255) / 256, 256, 0, st>>>(
        ws.xrp, ws.csump, ws.xcur, ws.xsh, ws.xsl, N, C);
  } else {              // N=128, C=512: in-kernel epilogue
    k_sa_stats<128><<<gs, 256, 0, st>>>(ws.qh, ws.ql, N, ws.mx, ws.inv);
    dim3 gx(N / 64, C / 128, BB);
    k_sa_xr<128, 1><<<gx, 256, 0, st>>>(ws.qh, ws.ql, ws.vmh, ws.vml, ws.mx, ws.inv,
                                        ws.xcur, ws.xsh, ws.xsl, nullptr, nullptr, N, C);
  }
  mmp<64, 0, 1, 0, false, false>(st, ws.xsh, ws.xsl, twh, twl, tb, ws.pre, nullptr,
                                 N, C, C, sx, 0, sx, BB, 1);
  k_bn_part<<<256, 256, 0, st>>>(ws.pre, BB * N, C, ws.bpart);
  k_bn_fin<<<(C + 31) / 32, 256, 0, st>>>(ws.bpart, BB * N, C, ws.stats);
  k_bn_apply<true><<<(BB * N * C + 255) / 256, 256, 0, st>>>(ws.pre, ws.stats, g, be,
                                                             ws.xcur, ws.xcur, xh, xl, BB * N * C, C);
}

static void run_conv(hipStream_t st, Ws& ws, const u16* finh, const u16* finl, int Cin,
                     const u16* cwh, const u16* cwl, const float* bias, const float* dirs,
                     const int* idx, int N, int C,
                     const float* bng, const float* bnb, bool doBN, u16* fmh, u16* fml) {
  if (N == NP0)
    mmp<128, 0, 1, 0, false, false>(st, finh, finl, cwh, cwl, bias, ws.fout, nullptr,
                                    N, 2 * C, Cin, (long)N * Cin, 0, (long)N * 2 * C, BB, 1);
  else
    mmp<64, 0, 1, 0, false, false>(st, finh, finl, cwh, cwl, bias, ws.fout, nullptr,
                                   N, 2 * C, Cin, (long)N * Cin, 0, (long)N * 2 * C, BB, 1);
  k_conv_layer<<<dim3(N, BB), C, 0, st>>>(ws.v0, idx, dirs, ws.fout, ws.xcur, N, C);
  if (doBN) {
    k_bn_part<<<256, 256, 0, st>>>(ws.xcur, BB * N, C, ws.bpart);
    k_bn_fin<<<(C + 31) / 32, 256, 0, st>>>(ws.bpart, BB * N, C, ws.stats);
    k_bn_apply<false><<<(BB * N * C + 255) / 256, 256, 0, st>>>(
        ws.xcur, ws.stats, bng, bnb, nullptr, ws.xcur, fmh, fml, BB * N * C, C);
  } else {
    k_split4<false, true><<<(BB * N * C / 4 + 255) / 256, 256, 0, st>>>(
        ws.xcur, fmh, fml, BB * N * C / 4);
  }
}

extern "C" void kernel_launch(void* const* d_in, const int* in_sizes, int n_in,
                              void* d_out, int out_size, void* d_ws, size_t ws_size,
                              hipStream_t stream) {
  auto in = [&](int i) { return (const float*)d_in[i]; };
  char* p = (char*)d_ws;
  Ws ws;
  ws.v0 = (float*)(p + O_V0);
  ws.idx0 = (int*)(p + O_IDX0); ws.idxp0 = (int*)(p + O_IDXP0);
  ws.idx1 = (int*)(p + O_IDX1); ws.idxp1 = (int*)(p + O_IDXP1);
  ws.idx2 = (int*)(p + O_IDX2);
  ws.ni1 = (int*)(p + O_NI1); ws.ni2 = (int*)(p + O_NI2);
  ws.fglob = (float*)(p + O_FGLOB); ws.glob1 = (float*)(p + O_GLOB1);
  ws.mx = (float*)(p + O_COLS); ws.inv = (float*)(p + O_CPART);
  ws.csump = (float*)(p + O_CPART + 65536);
  ws.stats = (float*)(p + O_STATS); ws.bpart = (float*)(p + O_BPART);
  ws.xcur = (float*)(p + O_XCUR);
  ws.pre = (float*)(p + O_AREA);
  ws.fout = (float*)(p + O_AREA);
  ws.xrp = (float*)(p + O_AREA);
  ws.xcat = (u16*)(p + O_AREA);
  char* pl = p + O_PL;
  ws.wh = (u16*)(pl + PL_WH); ws.wl = (u16*)(pl + PL_WL);
  ws.fm0h = (u16*)(pl + PL_FM0H); ws.fm0l = (u16*)(pl + PL_FM0L);
  ws.fm1h = (u16*)(pl + PL_FM1H); ws.fm1l = (u16*)(pl + PL_FM1L);
  ws.fm2h = (u16*)(pl + PL_FM2H); ws.fm2l = (u16*)(pl + PL_FM2L);
  ws.fm3h = (u16*)(pl + PL_FM3H); ws.fm3l = (u16*)(pl + PL_FM3L);
  ws.fm4h = (u16*)(pl + PL_FM4H); ws.fm4l = (u16*)(pl + PL_FM4L);
  ws.fmp1h = (u16*)(pl + PL_FMP1H); ws.fmp1l = (u16*)(pl + PL_FMP1L);
  ws.fmp2h = (u16*)(pl + PL_FMP2H); ws.fmp2l = (u16*)(pl + PL_FMP2L);
  ws.qh = (u16*)(pl + PL_QH); ws.ql = (u16*)(pl + PL_QL);
  ws.vmh = (u16*)(pl + PL_VMH); ws.vml = (u16*)(pl + PL_VML);
  ws.xsh = (u16*)(pl + PL_XSH); ws.xsl = (u16*)(pl + PL_XSL);
  ws.x1h = (u16*)(pl + PL_X1H);
  ws.x2b = (u16*)(p + O_XCUR);
  float* out = (float*)d_out;

  // ---- one-time weight plane split (pre-transposed to [N,K]) ----
  SplitJobs jobs;
  size_t wq[22];
  size_t off = 0;
  int ji = 0;
  auto addjob = [&](const float* s, int K, int N, int trans) {
    int n = K * N;
    jobs.j[ji] = {s, ws.wh + off, ws.wl + off, n, K, N, trans};
    wq[ji] = off; off += (size_t)n; ++ji;
  };
  addjob(in(5), 128, 32, 0);  addjob(in(6), 128, 128, 0);  addjob(in(8), 128, 128, 0);
  addjob(in(17), 128, 32, 0); addjob(in(18), 128, 128, 0); addjob(in(20), 128, 128, 0);
  addjob(in(29), 256, 64, 0); addjob(in(30), 256, 256, 0); addjob(in(32), 256, 256, 0);
  addjob(in(41), 256, 64, 0); addjob(in(42), 256, 256, 0); addjob(in(44), 256, 256, 0);
  addjob(in(51), 512, 128, 0); addjob(in(52), 512, 512, 0); addjob(in(54), 512, 512, 0);
  addjob(in(12), 128, 256, 1);   // conv1
  addjob(in(24), 128, 512, 1);   // conv2
  addjob(in(36), 256, 512, 1);   // conv3
  addjob(in(48), 256, 1024, 1);  // conv4
  addjob(in(58), 1280, 512, 1);  // h1 combined [512][1280]
  addjob(in(60), 512, 512, 1);   // h2
  addjob(in(62), 512, 50, 1);    // h3
  k_splitjobs<<<dim3(32, 22), 256, 0, stream>>>(jobs);
  auto W = [&](int i) { return ws.wh + wq[i]; };
  auto Wl = [&](int i) { return ws.wl + wq[i]; };

  // ---- geometry ----
  k_transpose<<<(BB * NP0 * 3 + 255) / 256, 256, 0, stream>>>(in(0), ws.v0);
  k_knn_radix<NP0, KNB_><<<dim3(NP0 / 4, BB), 256, 0, stream>>>(ws.v0, NP0, ws.idx0);

  // ---- conv0 + bn0 ----
  k_conv_surface<<<dim3(NP0, BB), 128, 0, stream>>>(ws.v0, ws.idx0, in(2), ws.xcur, NP0, 128);
  k_bn_part<<<256, 256, 0, stream>>>(ws.xcur, BB * NP0, 128, ws.bpart);
  k_bn_fin<<<4, 256, 0, stream>>>(ws.bpart, BB * NP0, 128, ws.stats);
  k_bn_apply<false><<<(BB * NP0 * 128 + 255) / 256, 256, 0, stream>>>(
      ws.xcur, ws.stats, in(3), in(4), nullptr, ws.xcur, ws.fm0h, ws.fm0l, BB * NP0 * 128, 128);

  // ---- sa0, conv1+bn1, sa1 ----
  run_sa(stream, ws, NP0, 128, 32, W(0), Wl(0), W(1), Wl(1), W(2), Wl(2),
         in(7), in(9), in(10), in(11), ws.fm0h, ws.fm0l);
  run_conv(stream, ws, ws.fm0h, ws.fm0l, 128, W(15), Wl(15), in(13), in(14), ws.idx0,
           NP0, 128, in(15), in(16), true, ws.fm1h, ws.fm1l);
  run_sa(stream, ws, NP0, 128, 32, W(3), Wl(3), W(4), Wl(4), W(5), Wl(5),
         in(19), in(21), in(22), in(23), ws.fm1h, ws.fm1l);

  // ---- pool1, knn1 ----
  k_knn2<NP0, 4><<<dim3(NP1 / 4, BB), 256, 0, stream>>>(ws.v0, NP1, ws.idxp0);
  k_pool<<<dim3(NP1, BB), 128, 0, stream>>>(ws.fm1h, ws.fm1l, ws.idxp0,
                                            ws.fmp1h, ws.fmp1l, NP0, NP1, 128);
  k_knn_radix<NP1, KNB_><<<dim3(NP1 / 4, BB), 256, 0, stream>>>(ws.v0, NP1, ws.idx1);

  // ---- conv2+bn2, sa2, conv3+bn3, sa3 ----
  run_conv(stream, ws, ws.fmp1h, ws.fmp1l, 128, W(16), Wl(16), in(25), in(26), ws.idx1,
           NP1, 256, in(27), in(28), true, ws.fm2h, ws.fm2l);
  run_sa(stream, ws, NP1, 256, 64, W(6), Wl(6), W(7), Wl(7), W(8), Wl(8),
         in(31), in(33), in(34), in(35), ws.fm2h, ws.fm2l);
  run_conv(stream, ws, ws.fm2h, ws.fm2l, 256, W(17), Wl(17), in(37), in(38), ws.idx1,
           NP1, 256, in(39), in(40), true, ws.fm3h, ws.fm3l);
  run_sa(stream, ws, NP1, 256, 64, W(9), Wl(9), W(10), Wl(10), W(11), Wl(11),
         in(43), in(45), in(46), in(47), ws.fm3h, ws.fm3l);

  // ---- pool2, knn2, conv4 (no bn), sa4 ----
  k_knn2<NP1, 4><<<dim3(NP2 / 4, BB), 256, 0, stream>>>(ws.v0, NP2, ws.idxp1);
  k_pool<<<dim3(NP2, BB), 256, 0, stream>>>(ws.fm3h, ws.fm3l, ws.idxp1,
                                            ws.fmp2h, ws.fmp2l, NP1, NP2, 256);
  k_knn_radix<NP2, KNB_><<<dim3(NP2 / 4, BB), 256, 0, stream>>>(ws.v0, NP2, ws.idx2);
  run_conv(stream, ws, ws.fmp2h, ws.fmp2l, 256, W(18), Wl(18), in(49), in(50), ws.idx2,
           NP2, 512, nullptr, nullptr, false, ws.fm4h, ws.fm4l);
  run_sa(stream, ws, NP2, 512, 128, W(12), Wl(12), W(13), Wl(13), W(14), Wl(14),
         in(53), in(55), in(56), in(57), ws.fm4h, ws.fm4l);

  // ---- global max, nearest, head (gather + fused K=1280 GEMM per half) ----
  k_maxn<<<dim3(2, BB), 256, 0, stream>>>(ws.fm4h, ws.fm4l, ws.fglob, NP2, 512);
  k_nearest<<<dim3(NP0 / 256, BB), 256, NP1 * 3 * 4, stream>>>(ws.v0, NP1, ws.ni1);
  k_nearest<<<dim3(NP0 / 256, BB), 256, NP2 * 3 * 4, stream>>>(ws.v0, NP2, ws.ni2);
  k_glob1<<<BB, 512, 0, stream>>>(ws.fglob, in(1), in(58), in(59), ws.glob1);

  for (int hf = 0; hf < 2; ++hf) {
    const int b0 = hf * 4;
    k_xcat<<<(4 * NP0 * 160 + 255) / 256, 256, 0, stream>>>(
        ws.fm0h, ws.fm1h, ws.fm2h, ws.fm3h, ws.fm4h, ws.ni1, ws.ni2, ws.xcat, b0);
    // x1 = relu(xcat @ h1 + glob1[b]) -> bf16 (register accumulation, K=1280)
    mmp<128, 2, 2, 3, false, false, false>(stream, ws.xcat, nullptr, W(19), nullptr,
        ws.glob1 + b0 * 512, ws.x1h, nullptr,
        NP0, 512, 1280, (long)NP0 * 1280, 0, (long)NP0 * 512, 4, 1);
    // x2 = relu(x1 @ h2 + h2b) -> bf16
    mmp<128, 2, 1, 3, false, false, false>(stream, ws.x1h, nullptr, W(20), nullptr, in(61),
        ws.x2b, nullptr, NP0, 512, 512, (long)NP0 * 512, 0, (long)NP0 * 512, 4, 1);
    // logits = x2 @ h3 + h3b -> f32
    mmp<64, 2, 1, 0, false, false, false>(stream, ws.x2b, nullptr, W(21), nullptr, in(63),
        out + (size_t)b0 * NP0 * 50, nullptr, NP0, 50, 512,
        (long)NP0 * 512, 0, (long)NP0 * 50, 4, 1);
  }

  k_logsoftmax<<<(BB * NP0) / 4, 256, 0, stream>>>(out, BB * NP0, 50);
}